// Round 3
// baseline (1834.728 us; speedup 1.0000x reference)
//
#include <hip/hip_runtime.h>
#include <hip/hip_bf16.h>

typedef __hip_bfloat16 bf16;

#define DEV static __device__ __forceinline__

DEV float b2f(bf16 h){ return __bfloat162float(h); }
DEV float lrelu(float x){ return x >= 0.f ? x : 0.1f*x; }
DEV float geluf(float x){ return 0.5f*x*(1.f + erff(x*0.70710678118654752440f)); }
DEV float sigmoidf(float x){ return 1.f/(1.f + expf(-x)); }

// B=4, C=64, H=W=256, HW=65536, WS=8, N=1024 windows/batch, embed=4096
// Dtype hedge: device tensors may be f32 (reference dtype) or bf16 (dataset
// conversion). k_detect sniffs x; k_cvt normalizes all small weights to f32
// wbuf; big tensors (x, Wm1, Wm2) and the final store use uniform if/else.

// ---------------- K0a: detect storage dtype ----------------
__global__ __launch_bounds__(256) void k_detect(const void* x, int* flag){
  __shared__ int cnt;
  if(threadIdx.x==0) cnt=0;
  __syncthreads();
  const unsigned short* up=(const unsigned short*)x;
  int c=0;
  for(int k=0;k<16;k++){
    unsigned short u=up[(threadIdx.x*16+k)*2];   // even bf16-view slots
    if(((u>>7)&0xFF)==0xFF) c++;                 // inf/NaN exponent
  }
  atomicAdd(&cnt,c);
  __syncthreads();
  if(threadIdx.x==0) flag[0] = (cnt>0) ? 1 : 0;  // 1 => f32 storage
}

// ---------------- K0b: convert small weights to f32 wbuf ----------------
struct CvtArgs { const void* src[31]; int sz[31]; int off[31]; };
__global__ __launch_bounds__(256) void k_cvt(CvtArgs a, const int* fl, float* wbuf){
  int t=blockIdx.x; int n=a.sz[t]; const void* s=a.src[t]; float* d=wbuf+a.off[t];
  if(fl[0]){
    const float* sp=(const float*)s;
    for(int i=threadIdx.x;i<n;i+=256) d[i]=sp[i];
  } else {
    const bf16* sp=(const bf16*)s;
    for(int i=threadIdx.x;i<n;i+=256) d[i]=b2f(sp[i]);
  }
}

// ---------------- K1: v = Wv x + bv (1x1 conv) ----------------
__global__ __launch_bounds__(256) void k_conv_v(const void* __restrict__ x,
    const float* __restrict__ Wv, const float* __restrict__ bv, float* __restrict__ v,
    const int* __restrict__ fl){
  __shared__ float ws[4096]; __shared__ float bs[64];
  int tid = threadIdx.x;
  for(int i=tid;i<4096;i+=256) ws[i]=Wv[i];
  if(tid<64) bs[tid]=bv[tid];
  __syncthreads();
  int pix = blockIdx.x*256+tid; int b=pix>>16, p=pix&65535;
  float acc[64];
  #pragma unroll
  for(int o=0;o<64;o++) acc[o]=bs[o];
  size_t xbase=(((size_t)b*64)<<16)+p;
  if(fl[0]){
    const float* xp=(const float*)x+xbase;
    for(int c=0;c<64;c++){
      float xv=xp[((size_t)c)<<16];
      #pragma unroll
      for(int o=0;o<64;o++) acc[o]+=ws[(o<<6)+c]*xv;
    }
  } else {
    const bf16* xp=(const bf16*)x+xbase;
    for(int c=0;c<64;c++){
      float xv=b2f(xp[((size_t)c)<<16]);
      #pragma unroll
      for(int o=0;o<64;o++) acc[o]+=ws[(o<<6)+c]*xv;
    }
  }
  float* vp = v + (((size_t)b*64)<<16) + p;
  #pragma unroll
  for(int o=0;o<64;o++) vp[((size_t)o)<<16]=acc[o];
}

// ---------------- K2: xin/x_/xm/ca partial sums ----------------
__global__ __launch_bounds__(256) void k_route(const float* __restrict__ v,
    const float* __restrict__ W_in, const float* __restrict__ b_in,
    const float* __restrict__ Wc, const float* __restrict__ bc,
    const float* __restrict__ lnw, const float* __restrict__ lnb,
    float* __restrict__ x_, float* __restrict__ xm, float* __restrict__ capart){
  __shared__ float wA[1024], wB[1024], sba[16], sbb[16], slw[16], slb[16];
  __shared__ float sred[4][16];
  int tid=threadIdx.x;
  for(int i=tid;i<1024;i+=256){ wA[i]=W_in[i]; wB[i]=Wc[i]; }
  if(tid<16){ sba[tid]=b_in[tid]; sbb[tid]=bc[tid]; slw[tid]=lnw[tid]; slb[tid]=lnb[tid]; }
  __syncthreads();
  int pix=blockIdx.x*256+tid; int b=pix>>16, p=pix&65535;
  float aA[16], aB[16];
  #pragma unroll
  for(int i=0;i<16;i++){ aA[i]=sba[i]; aB[i]=sbb[i]; }
  const float* vp=v+(((size_t)b*64)<<16)+p;
  for(int c=0;c<64;c++){
    float vv=vp[((size_t)c)<<16];
    #pragma unroll
    for(int i=0;i<16;i++){ aA[i]+=wA[(i<<6)+c]*vv; aB[i]+=wB[(i<<6)+c]*vv; }
  }
  float s=0.f;
  #pragma unroll
  for(int i=0;i<16;i++){ aA[i]=lrelu(aA[i]); s+=aA[i]; }
  xm[pix]=s*(1.f/16.f);
  float u=0.f;
  #pragma unroll
  for(int i=0;i<16;i++) u+=aB[i];
  u*=(1.f/16.f);
  float varr=0.f;
  #pragma unroll
  for(int i=0;i<16;i++){ float d=aB[i]-u; varr+=d*d; }
  varr*=(1.f/16.f);
  float inv=1.f/sqrtf(varr+1e-6f);
  float* xp=x_+(((size_t)b*16)<<16)+p;
  #pragma unroll
  for(int i=0;i<16;i++){
    float xv=lrelu(slw[i]*((aB[i]-u)*inv)+slb[i]);
    xp[((size_t)i)<<16]=xv; aA[i]=xv;
  }
  int lane=tid&63, wid=tid>>6;
  #pragma unroll
  for(int i=0;i<16;i++){
    float val=aA[i];
    for(int m=32;m>0;m>>=1) val+=__shfl_xor(val,m);
    if(lane==0) sred[wid][i]=val;
  }
  __syncthreads();
  if(tid<16) capart[blockIdx.x*16+tid]=sred[0][tid]+sred[1][tid]+sred[2][tid]+sred[3][tid];
}

// ---------------- K3: sa = sigmoid(conv3x3(x_)) ----------------
__global__ __launch_bounds__(256) void k_sa(const float* __restrict__ x_,
    const float* __restrict__ Wsa, const float* __restrict__ bsa, float* __restrict__ sa){
  __shared__ float w[144]; __shared__ float bb;
  int tid=threadIdx.x;
  if(tid<144) w[tid]=Wsa[tid];
  if(tid==0) bb=bsa[0];
  __syncthreads();
  int pix=blockIdx.x*256+tid; int b=pix>>16, p=pix&65535;
  int y=p>>8, xx=p&255;
  float acc=bb;
  #pragma unroll
  for(int i=0;i<16;i++){
    const float* pl=x_+(((size_t)(b*16+i))<<16);
    #pragma unroll
    for(int ky=0;ky<3;ky++){
      int yy=y+ky-1;
      if((unsigned)yy<256u){
        #pragma unroll
        for(int kx=0;kx<3;kx++){
          int x2=xx+kx-1;
          if((unsigned)x2<256u) acc+=pl[(yy<<8)+x2]*w[i*9+ky*3+kx];
        }
      }
    }
  }
  sa[pix]=sigmoidf(acc);
}

// ---------------- K4: per-window variance (ddof=1) ----------------
__global__ __launch_bounds__(64) void k_var(const float* __restrict__ xm, float* __restrict__ var){
  int blk=blockIdx.x, tid=threadIdx.x;
  int b=blk>>10, n=blk&1023;
  int pix=((n>>5)<<11) + ((n&31)<<3) + ((tid>>3)<<8) + (tid&7);
  float val=xm[(b<<16)+pix];
  float s=val;
  for(int m=32;m>0;m>>=1) s+=__shfl_xor(s,m);
  float mean=s*(1.f/64.f);
  float d=val-mean; float q=d*d;
  for(int m=32;m>0;m>>=1) q+=__shfl_xor(q,m);
  if(tid==0) var[blk]=q*(1.f/63.f);
}

// ---------------- K5: rank -> mbin (bottom 512 var -> 0) ----------------
__global__ __launch_bounds__(256) void k_rank(const float* __restrict__ var, float* __restrict__ mbin){
  __shared__ float va[1024];
  int b=blockIdx.x, tid=threadIdx.x;
  for(int i=tid;i<1024;i+=256) va[i]=var[(b<<10)+i];
  __syncthreads();
  for(int n=tid;n<1024;n+=256){
    float vn=va[n]; int r=0;
    for(int m=0;m<1024;m++){ float vm=va[m]; r += (vm<vn) || (vm==vn && m<n); }
    mbin[(b<<10)+n] = (r<512)?0.f:1.f;
  }
}

// ---------------- K6: h0/h1 from Wm1 rowsums ----------------
__global__ __launch_bounds__(64) void k_hvec(const void* __restrict__ Wm1, const float* __restrict__ bm1,
    float* __restrict__ h0, float* __restrict__ h1, const int* __restrict__ fl){
  int j=blockIdx.x, tid=threadIdx.x;
  float s=0.f;
  if(fl[0]){
    const float* row=(const float*)Wm1+((size_t)j<<12);
    for(int k=tid;k<4096;k+=64) s+=row[k];
  } else {
    const bf16* row=(const bf16*)Wm1+((size_t)j<<12);
    for(int k=tid;k<4096;k+=64) s+=b2f(row[k]);
  }
  for(int m=32;m>0;m>>=1) s+=__shfl_xor(s,m);
  if(tid==0){ float bb=bm1[j]; h0[j]=lrelu(bb); h1[j]=lrelu(bb+s); }
}

// ---------------- K7: mask0/mask1 vectors ----------------
__global__ __launch_bounds__(64) void k_mask(const void* __restrict__ Wm2, const float* __restrict__ bm2,
    const float* __restrict__ h0, const float* __restrict__ h1,
    float* __restrict__ m0, float* __restrict__ m1, const int* __restrict__ fl){
  int e=blockIdx.x, tid=threadIdx.x;
  float p0=0.f,p1=0.f;
  if(fl[0]){
    const float* row=(const float*)Wm2+((size_t)e<<11);
    for(int j=tid;j<2048;j+=64){ float w=row[j]; p0+=w*h0[j]; p1+=w*h1[j]; }
  } else {
    const bf16* row=(const bf16*)Wm2+((size_t)e<<11);
    for(int j=tid;j<2048;j+=64){ float w=b2f(row[j]); p0+=w*h0[j]; p1+=w*h1[j]; }
  }
  for(int m=32;m>0;m>>=1){ p0+=__shfl_xor(p0,m); p1+=__shfl_xor(p1,m); }
  if(tid==0){ float bb=bm2[e]; m0[e]=p0+bb; m1[e]=p1+bb; }
}

// ---------------- K8: ca = sigmoid(Wca * mean(x_) + bca) ----------------
__global__ __launch_bounds__(64) void k_ca(const float* __restrict__ capart,
    const float* __restrict__ Wca, const float* __restrict__ bca, float* __restrict__ ca){
  __shared__ float m[16];
  int b=blockIdx.x, tid=threadIdx.x;
  if(tid<16){
    float s=0.f;
    for(int blk=0;blk<256;blk++) s+=capart[((b<<8)+blk)*16+tid];
    m[tid]=s*(1.f/65536.f);
  }
  __syncthreads();
  float a=bca[tid];
  #pragma unroll
  for(int i=0;i<16;i++) a+=Wca[(tid<<4)+i]*m[i];
  ca[(b<<6)+tid]=sigmoidf(a);
}

// ---------------- K9: windowed attention -> img ----------------
__global__ __launch_bounds__(256) void k_attn(const void* __restrict__ x, const float* __restrict__ v,
    const float* __restrict__ sa, const float* __restrict__ mbin,
    const float* __restrict__ m0, const float* __restrict__ m1,
    const float* __restrict__ Wq, const float* __restrict__ bq,
    const float* __restrict__ Wk, const float* __restrict__ bk,
    float* __restrict__ img, const int* __restrict__ fl){
  __shared__ float sA[64*65];  // t -> attn
  __shared__ float sQ[64*65];  // q -> raw v
  __shared__ float sK[64*65];  // k -> v1 (= v*mask)
  int tid=threadIdx.x, blk=blockIdx.x;
  int b=blk>>10, n=blk&1023;
  int base=((n>>5)<<11) + ((n&31)<<3);
  const float* mp = (mbin[blk]>0.5f)? m1 : m0;
  // t = x * mask
  if(fl[0]){
    const float* xp=(const float*)x;
    for(int idx=tid; idx<4096; idx+=256){
      int p=idx&63, c=idx>>6;
      int pix=base+((p>>3)<<8)+(p&7);
      sA[p*65+c]=xp[(((size_t)(b*64+c))<<16)+pix]*mp[(p<<6)+c];
    }
  } else {
    const bf16* xp=(const bf16*)x;
    for(int idx=tid; idx<4096; idx+=256){
      int p=idx&63, c=idx>>6;
      int pix=base+((p>>3)<<8)+(p&7);
      sA[p*65+c]=b2f(xp[(((size_t)(b*64+c))<<16)+pix])*mp[(p<<6)+c];
    }
  }
  __syncthreads();
  // q = t Wq^T + bq ; k = t Wk^T + bk
  for(int idx=tid; idx<4096; idx+=256){
    int p=idx>>6, o=idx&63;
    float aq=bq[o], ak=bk[o];
    for(int c=0;c<64;c++){
      float tv=sA[p*65+c];
      aq+=tv*Wq[(o<<6)+c];
      ak+=tv*Wk[(o<<6)+c];
    }
    sQ[p*65+o]=aq; sK[p*65+o]=ak;
  }
  __syncthreads();
  // scores
  for(int idx=tid; idx<4096; idx+=256){
    int p=idx>>6, j=idx&63;
    float a=0.f;
    for(int o=0;o<64;o++) a+=sQ[p*65+o]*sK[j*65+o];
    sA[p*65+j]=a;
  }
  __syncthreads();
  // softmax rows
  if(tid<64){
    int p=tid;
    float mx=-1e30f;
    for(int j=0;j<64;j++) mx=fmaxf(mx,sA[p*65+j]);
    float s=0.f;
    for(int j=0;j<64;j++){ float e=expf(sA[p*65+j]-mx); sA[p*65+j]=e; s+=e; }
    float inv=1.f/s;
    for(int j=0;j<64;j++) sA[p*65+j]*=inv;
  }
  // load v (raw + masked)
  for(int idx=tid; idx<4096; idx+=256){
    int p=idx&63, c=idx>>6;
    int pix=base+((p>>3)<<8)+(p&7);
    float vv=v[(((size_t)(b*64+c))<<16)+pix];
    sQ[p*65+c]=vv;
    sK[p*65+c]=vv*mp[(p<<6)+c];
  }
  __syncthreads();
  // f = attn @ v1 ; out = f + v*sa*(1-mask)
  for(int idx=tid; idx<4096; idx+=256){
    int p=idx&63, c=idx>>6;
    int pix=base+((p>>3)<<8)+(p&7);
    float f=0.f;
    for(int j=0;j<64;j++) f+=sA[p*65+j]*sK[j*65+c];
    float sav=sa[(b<<16)+pix];
    float mv=mp[(p<<6)+c];
    img[(((size_t)(b*64+c))<<16)+pix]=f+sQ[p*65+c]*sav*(1.f-mv);
  }
}

// ---------------- K10: depthwise 3x3 (dil 1) ----------------
__global__ __launch_bounds__(256) void k_dw1(const float* __restrict__ img,
    const float* __restrict__ dw1, const float* __restrict__ dwb1, float* __restrict__ tmp){
  int idx=blockIdx.x*256+threadIdx.x;
  int p=idx&65535, bc=idx>>16, c=bc&63;
  int y=p>>8, xx=p&255;
  float acc=dwb1[c];
  const float* pl=img+(((size_t)bc)<<16);
  #pragma unroll
  for(int ky=0;ky<3;ky++){
    int yy=y+ky-1;
    if((unsigned)yy<256u){
      #pragma unroll
      for(int kx=0;kx<3;kx++){
        int x2=xx+kx-1;
        if((unsigned)x2<256u) acc+=pl[(yy<<8)+x2]*dw1[c*9+ky*3+kx];
      }
    }
  }
  tmp[idx]=acc;
}

// ---------------- K11: depthwise 3x3 (dil 2) + gelu*ca + img ----------------
__global__ __launch_bounds__(256) void k_dw2gate(const float* __restrict__ tmp, const float* __restrict__ img,
    const float* __restrict__ dw2, const float* __restrict__ dwb2,
    const float* __restrict__ ca, float* __restrict__ outb){
  int idx=blockIdx.x*256+threadIdx.x;
  int p=idx&65535, bc=idx>>16, b=bc>>6, c=bc&63;
  int y=p>>8, xx=p&255;
  float acc=dwb2[c];
  const float* pl=tmp+(((size_t)bc)<<16);
  #pragma unroll
  for(int ky=0;ky<3;ky++){
    int yy=y+2*(ky-1);
    if((unsigned)yy<256u){
      #pragma unroll
      for(int kx=0;kx<3;kx++){
        int x2=xx+2*(kx-1);
        if((unsigned)x2<256u) acc+=pl[(yy<<8)+x2]*dw2[c*9+ky*3+kx];
      }
    }
  }
  outb[idx]=geluf(acc)*ca[(b<<6)+c]+img[idx];
}

// ---------------- K12: res = Wo*out + bo; x1 = LN(x + res) ----------------
__global__ __launch_bounds__(256) void k_proj_ln1(const float* __restrict__ outb, const void* __restrict__ x,
    const float* __restrict__ Wo, const float* __restrict__ bo,
    const float* __restrict__ wn, const float* __restrict__ bn, float* __restrict__ x1,
    const int* __restrict__ fl){
  __shared__ float ws[4096]; __shared__ float sb[64], swn[64], sbn[64];
  int tid=threadIdx.x;
  for(int i=tid;i<4096;i+=256) ws[i]=Wo[i];
  if(tid<64){ sb[tid]=bo[tid]; swn[tid]=wn[tid]; sbn[tid]=bn[tid]; }
  __syncthreads();
  int pix=blockIdx.x*256+tid; int b=pix>>16, p=pix&65535;
  float r[64];
  #pragma unroll
  for(int o=0;o<64;o++) r[o]=sb[o];
  const float* op=outb+(((size_t)b*64)<<16)+p;
  for(int c=0;c<64;c++){
    float ov=op[((size_t)c)<<16];
    #pragma unroll
    for(int o=0;o<64;o++) r[o]+=ws[(o<<6)+c]*ov;
  }
  size_t xbase=(((size_t)b*64)<<16)+p;
  if(fl[0]){
    const float* xp=(const float*)x+xbase;
    #pragma unroll
    for(int o=0;o<64;o++) r[o]+=xp[((size_t)o)<<16];
  } else {
    const bf16* xp=(const bf16*)x+xbase;
    #pragma unroll
    for(int o=0;o<64;o++) r[o]+=b2f(xp[((size_t)o)<<16]);
  }
  float mean=0.f;
  #pragma unroll
  for(int o=0;o<64;o++) mean+=r[o];
  mean*=(1.f/64.f);
  float varr=0.f;
  #pragma unroll
  for(int o=0;o<64;o++){ float d=r[o]-mean; varr+=d*d; }
  varr*=(1.f/64.f);
  float inv=1.f/sqrtf(varr+1e-6f);
  float* x1p=x1+(((size_t)b*64)<<16)+p;
  #pragma unroll
  for(int o=0;o<64;o++) x1p[((size_t)o)<<16]=swn[o]*((r[o]-mean)*inv)+sbn[o];
}

// ---------------- K13: y_pre = Wffn_in * x1 (128 out ch, no bias) -> E (bf16) ----------------
__global__ __launch_bounds__(256) void k_ffn_in(const float* __restrict__ x1,
    const float* __restrict__ W, bf16* __restrict__ E){
  __shared__ float ws[4096];
  int tid=threadIdx.x; int half=blockIdx.y<<6;
  for(int i=tid;i<4096;i+=256) ws[i]=W[(half<<6)+i];
  __syncthreads();
  int pix=blockIdx.x*256+tid; int b=pix>>16, p=pix&65535;
  float r[64];
  #pragma unroll
  for(int o=0;o<64;o++) r[o]=0.f;
  const float* xp=x1+(((size_t)b*64)<<16)+p;
  for(int c=0;c<64;c++){
    float xv=xp[((size_t)c)<<16];
    #pragma unroll
    for(int o=0;o<64;o++) r[o]+=ws[(o<<6)+c]*xv;
  }
  bf16* ep=E+(((size_t)(b*128+half))<<16)+p;
  #pragma unroll
  for(int o=0;o<64;o++) ep[((size_t)o)<<16]=__float2bfloat16(r[o]);
}

// ---------------- K14: depthwise 3x3 on y (128ch, bf16 in) + gelu gate ----------------
__global__ __launch_bounds__(256) void k_ffn_dw(const bf16* __restrict__ E,
    const float* __restrict__ dwf, float* __restrict__ g){
  int idx=blockIdx.x*256+threadIdx.x;
  int p=idx&65535, bc=idx>>16, b=bc>>6, c=bc&63;
  int y=p>>8, xx=p&255;
  float a1=0.f, a2=0.f;
  const bf16* p1=E+(((size_t)(b*128+c))<<16);
  const bf16* p2=E+(((size_t)(b*128+64+c))<<16);
  #pragma unroll
  for(int ky=0;ky<3;ky++){
    int yy=y+ky-1;
    if((unsigned)yy<256u){
      #pragma unroll
      for(int kx=0;kx<3;kx++){
        int x2=xx+kx-1;
        if((unsigned)x2<256u){
          int off=(yy<<8)+x2;
          a1+=b2f(p1[off])*dwf[c*9+ky*3+kx];
          a2+=b2f(p2[off])*dwf[(64+c)*9+ky*3+kx];
        }
      }
    }
  }
  g[idx]=geluf(a1)*a2;
}

// ---------------- K15: res2 = Wffn_out*g; out = LN2(x1+res2) ----------------
__global__ __launch_bounds__(256) void k_ffn_out(const float* __restrict__ g, const float* __restrict__ x1,
    const float* __restrict__ Wfo, const float* __restrict__ wn, const float* __restrict__ bn,
    void* __restrict__ out, const int* __restrict__ fl){
  __shared__ float ws[4096]; __shared__ float swn[64], sbn[64];
  int tid=threadIdx.x;
  for(int i=tid;i<4096;i+=256) ws[i]=Wfo[i];
  if(tid<64){ swn[tid]=wn[tid]; sbn[tid]=bn[tid]; }
  __syncthreads();
  int pix=blockIdx.x*256+tid; int b=pix>>16, p=pix&65535;
  float r[64];
  #pragma unroll
  for(int o=0;o<64;o++) r[o]=0.f;
  const float* gp=g+(((size_t)b*64)<<16)+p;
  for(int c=0;c<64;c++){
    float gv=gp[((size_t)c)<<16];
    #pragma unroll
    for(int o=0;o<64;o++) r[o]+=ws[(o<<6)+c]*gv;
  }
  const float* xp=x1+(((size_t)b*64)<<16)+p;
  float mean=0.f;
  #pragma unroll
  for(int o=0;o<64;o++){ r[o]+=xp[((size_t)o)<<16]; mean+=r[o]; }
  mean*=(1.f/64.f);
  float varr=0.f;
  #pragma unroll
  for(int o=0;o<64;o++){ float d=r[o]-mean; varr+=d*d; }
  varr*=(1.f/64.f);
  float inv=1.f/sqrtf(varr+1e-6f);
  size_t obase=(((size_t)b*64)<<16)+p;
  if(fl[0]){
    float* op=(float*)out+obase;
    #pragma unroll
    for(int o=0;o<64;o++) op[((size_t)o)<<16]=swn[o]*((r[o]-mean)*inv)+sbn[o];
  } else {
    bf16* op=(bf16*)out+obase;
    #pragma unroll
    for(int o=0;o<64;o++) op[((size_t)o)<<16]=__float2bfloat16(swn[o]*((r[o]-mean)*inv)+sbn[o]);
  }
}

extern "C" void kernel_launch(void* const* d_in, const int* in_sizes, int n_in,
                              void* d_out, int out_size, void* d_ws, size_t ws_size,
                              hipStream_t stream){
  (void)in_sizes; (void)n_in; (void)out_size; (void)ws_size;
  const void* x  = d_in[0];
  const void* Wm1= d_in[23];
  const void* Wm2= d_in[25];

  char* ws=(char*)d_ws;
  // Slot A [0,64MiB):    v (f32) -> tmp (f32) -> E (bf16)
  // Slot B [64,128MiB):  img (f32) -> x1 (f32)
  // Slot C [128,192MiB): outb (f32) -> g (f32)
  // Slot D [192MiB,...): small buffers + flag + wbuf  (total ~220.5 MB)
  float* v    =(float*)(ws);
  float* tmp  =(float*)(ws);
  bf16*  E    =(bf16*) (ws);
  float* img  =(float*)(ws+67108864);
  float* x1   =(float*)(ws+67108864);
  float* outb =(float*)(ws+134217728);
  float* gbuf =(float*)(ws+134217728);
  char* sm = ws+201326592;
  float* x_    =(float*)(sm);              // 16 MB
  float* sa    =(float*)(sm+16777216);     // 1 MB
  float* xm    =(float*)(sm+17825792);     // 1 MB
  float* var   =(float*)(sm+18874368);     // 16 KB
  float* mbin  =(float*)(sm+18890752);     // 16 KB
  float* h0    =(float*)(sm+18907136);     // 8 KB
  float* h1    =(float*)(sm+18915328);     // 8 KB
  float* m0    =(float*)(sm+18923520);     // 16 KB
  float* m1    =(float*)(sm+18939904);     // 16 KB
  float* capart=(float*)(sm+18956288);     // 64 KB
  float* ca    =(float*)(sm+19021824);     // 1 KB
  int*   flag  =(int*)  (sm+19022848);     // 4 B (padded 1 KB)
  float* wbuf  =(float*)(sm+19023872);     // ~161 KB

  // --- build the weight-conversion table (31 small tensors -> f32 wbuf) ---
  static const int din_idx[31]={5,6,7,8,9,10,11,12,13,14,15,16,17,18,19,20,21,22,24,26,27,28,29,30,31,32,33,1,2,3,4};
  static const int szs[31]  ={4096,64,4096,64,4096,64,576,64,576,64,4096,64,1024,16,1024,16,16,16,2048,4096,1024,64,144,1,8192,1152,4096,64,64,64,64};
  CvtArgs ca_args;
  int off=0;
  int offs[31];
  for(int t=0;t<31;t++){
    ca_args.src[t]=d_in[din_idx[t]];
    ca_args.sz[t]=szs[t];
    ca_args.off[t]=off;
    offs[t]=off;
    off+=szs[t];
  }
  const float* Wv  =wbuf+offs[0];  const float* bv  =wbuf+offs[1];
  const float* Wq  =wbuf+offs[2];  const float* bq  =wbuf+offs[3];
  const float* Wk  =wbuf+offs[4];  const float* bk  =wbuf+offs[5];
  const float* dw1 =wbuf+offs[6];  const float* dwb1=wbuf+offs[7];
  const float* dw2 =wbuf+offs[8];  const float* dwb2=wbuf+offs[9];
  const float* Wo  =wbuf+offs[10]; const float* bo  =wbuf+offs[11];
  const float* W_in=wbuf+offs[12]; const float* b_in=wbuf+offs[13];
  const float* Wc  =wbuf+offs[14]; const float* bc  =wbuf+offs[15];
  const float* lnw =wbuf+offs[16]; const float* lnb =wbuf+offs[17];
  const float* bm1 =wbuf+offs[18]; const float* bm2 =wbuf+offs[19];
  const float* Wca =wbuf+offs[20]; const float* bca =wbuf+offs[21];
  const float* Wsa =wbuf+offs[22]; const float* bsa =wbuf+offs[23];
  const float* Wfi =wbuf+offs[24]; const float* dwf =wbuf+offs[25];
  const float* Wfo =wbuf+offs[26];
  const float* wn1 =wbuf+offs[27]; const float* bn1 =wbuf+offs[28];
  const float* wn2 =wbuf+offs[29]; const float* bn2 =wbuf+offs[30];

  hipLaunchKernelGGL(k_detect,  dim3(1),     dim3(256), 0, stream, x, flag);
  hipLaunchKernelGGL(k_cvt,     dim3(31),    dim3(256), 0, stream, ca_args, flag, wbuf);
  hipLaunchKernelGGL(k_conv_v,  dim3(1024),  dim3(256), 0, stream, x, Wv, bv, v, flag);
  hipLaunchKernelGGL(k_route,   dim3(1024),  dim3(256), 0, stream, v, W_in, b_in, Wc, bc, lnw, lnb, x_, xm, capart);
  hipLaunchKernelGGL(k_sa,      dim3(1024),  dim3(256), 0, stream, x_, Wsa, bsa, sa);
  hipLaunchKernelGGL(k_var,     dim3(4096),  dim3(64),  0, stream, xm, var);
  hipLaunchKernelGGL(k_rank,    dim3(4),     dim3(256), 0, stream, var, mbin);
  hipLaunchKernelGGL(k_hvec,    dim3(2048),  dim3(64),  0, stream, Wm1, bm1, h0, h1, flag);
  hipLaunchKernelGGL(k_mask,    dim3(4096),  dim3(64),  0, stream, Wm2, bm2, h0, h1, m0, m1, flag);
  hipLaunchKernelGGL(k_ca,      dim3(4),     dim3(64),  0, stream, capart, Wca, bca, ca);
  hipLaunchKernelGGL(k_attn,    dim3(4096),  dim3(256), 0, stream, x, v, sa, mbin, m0, m1, Wq, bq, Wk, bk, img, flag);
  hipLaunchKernelGGL(k_dw1,     dim3(65536), dim3(256), 0, stream, img, dw1, dwb1, tmp);
  hipLaunchKernelGGL(k_dw2gate, dim3(65536), dim3(256), 0, stream, tmp, img, dw2, dwb2, ca, outb);
  hipLaunchKernelGGL(k_proj_ln1,dim3(1024),  dim3(256), 0, stream, outb, x, Wo, bo, wn1, bn1, x1, flag);
  hipLaunchKernelGGL(k_ffn_in,  dim3(1024,2),dim3(256), 0, stream, x1, Wfi, E);
  hipLaunchKernelGGL(k_ffn_dw,  dim3(65536), dim3(256), 0, stream, E, dwf, gbuf);
  hipLaunchKernelGGL(k_ffn_out, dim3(1024),  dim3(256), 0, stream, gbuf, x1, Wfo, wn2, bn2, d_out, flag);
}

// Round 4
// 1204.161 us; speedup vs baseline: 1.5237x; 1.5237x over previous
//
#include <hip/hip_runtime.h>
#include <hip/hip_bf16.h>

typedef __hip_bfloat16 bf16;
typedef __attribute__((ext_vector_type(8))) short short8v;
typedef __attribute__((ext_vector_type(4))) float f32x4;

#define DEV static __device__ __forceinline__

DEV float b2f(bf16 h){ return __bfloat162float(h); }
DEV short f2bs(float f){ bf16 h=__float2bfloat16(f); short s; __builtin_memcpy(&s,&h,2); return s; }
DEV float lrelu(float x){ return x >= 0.f ? x : 0.1f*x; }
DEV float geluf(float x){ return 0.5f*x*(1.f + erff(x*0.70710678118654752440f)); }
DEV float sigmoidf(float x){ return 1.f/(1.f + expf(-x)); }

// B=4, C=64, H=W=256, HW=65536, WS=8, N=1024 windows/batch, embed=4096
// Storage dtype detected at runtime (f32 confirmed empirically in round 3).

// ---------------- K0a: detect storage dtype ----------------
__global__ __launch_bounds__(256) void k_detect(const void* x, int* flag){
  __shared__ int cnt;
  if(threadIdx.x==0) cnt=0;
  __syncthreads();
  const unsigned short* up=(const unsigned short*)x;
  int c=0;
  for(int k=0;k<16;k++){
    unsigned short u=up[(threadIdx.x*16+k)*2];
    if(((u>>7)&0xFF)==0xFF) c++;
  }
  atomicAdd(&cnt,c);
  __syncthreads();
  if(threadIdx.x==0) flag[0] = (cnt>0) ? 1 : 0;  // 1 => f32 storage
}

// ---------------- K0b: convert small weights to f32 wbuf ----------------
struct CvtArgs { const void* src[31]; int sz[31]; int off[31]; };
__global__ __launch_bounds__(256) void k_cvt(CvtArgs a, const int* fl, float* wbuf){
  int t=blockIdx.x; int n=a.sz[t]; const void* s=a.src[t]; float* d=wbuf+a.off[t];
  if(fl[0]){
    const float* sp=(const float*)s;
    for(int i=threadIdx.x;i<n;i+=256) d[i]=sp[i];
  } else {
    const bf16* sp=(const bf16*)s;
    for(int i=threadIdx.x;i<n;i+=256) d[i]=b2f(sp[i]);
  }
}

// ---------------- K0c: Wq/Wk -> bf16 copies for MFMA ----------------
__global__ __launch_bounds__(256) void k_w2b(const float* __restrict__ wq, const float* __restrict__ wk,
    short* __restrict__ Wqb, short* __restrict__ Wkb){
  int i=blockIdx.x*256+threadIdx.x;
  if(i<4096){ Wqb[i]=f2bs(wq[i]); Wkb[i]=f2bs(wk[i]); }
}

// ---------------- K1: v = Wv x + bv (1x1 conv) ----------------
__global__ __launch_bounds__(256) void k_conv_v(const void* __restrict__ x,
    const float* __restrict__ Wv, const float* __restrict__ bv, float* __restrict__ v,
    const int* __restrict__ fl){
  __shared__ float ws[4096]; __shared__ float bs[64];
  int tid = threadIdx.x;
  for(int i=tid;i<4096;i+=256) ws[i]=Wv[i];
  if(tid<64) bs[tid]=bv[tid];
  __syncthreads();
  int pix = blockIdx.x*256+tid; int b=pix>>16, p=pix&65535;
  float acc[64];
  #pragma unroll
  for(int o=0;o<64;o++) acc[o]=bs[o];
  size_t xbase=(((size_t)b*64)<<16)+p;
  if(fl[0]){
    const float* xp=(const float*)x+xbase;
    for(int c=0;c<64;c++){
      float xv=xp[((size_t)c)<<16];
      #pragma unroll
      for(int o=0;o<64;o++) acc[o]+=ws[(o<<6)+c]*xv;
    }
  } else {
    const bf16* xp=(const bf16*)x+xbase;
    for(int c=0;c<64;c++){
      float xv=b2f(xp[((size_t)c)<<16]);
      #pragma unroll
      for(int o=0;o<64;o++) acc[o]+=ws[(o<<6)+c]*xv;
    }
  }
  float* vp = v + (((size_t)b*64)<<16) + p;
  #pragma unroll
  for(int o=0;o<64;o++) vp[((size_t)o)<<16]=acc[o];
}

// ---------------- K2: xin/x_/xm/ca partial sums ----------------
__global__ __launch_bounds__(256) void k_route(const float* __restrict__ v,
    const float* __restrict__ W_in, const float* __restrict__ b_in,
    const float* __restrict__ Wc, const float* __restrict__ bc,
    const float* __restrict__ lnw, const float* __restrict__ lnb,
    float* __restrict__ x_, float* __restrict__ xm, float* __restrict__ capart){
  __shared__ float wA[1024], wB[1024], sba[16], sbb[16], slw[16], slb[16];
  __shared__ float sred[4][16];
  int tid=threadIdx.x;
  for(int i=tid;i<1024;i+=256){ wA[i]=W_in[i]; wB[i]=Wc[i]; }
  if(tid<16){ sba[tid]=b_in[tid]; sbb[tid]=bc[tid]; slw[tid]=lnw[tid]; slb[tid]=lnb[tid]; }
  __syncthreads();
  int pix=blockIdx.x*256+tid; int b=pix>>16, p=pix&65535;
  float aA[16], aB[16];
  #pragma unroll
  for(int i=0;i<16;i++){ aA[i]=sba[i]; aB[i]=sbb[i]; }
  const float* vp=v+(((size_t)b*64)<<16)+p;
  for(int c=0;c<64;c++){
    float vv=vp[((size_t)c)<<16];
    #pragma unroll
    for(int i=0;i<16;i++){ aA[i]+=wA[(i<<6)+c]*vv; aB[i]+=wB[(i<<6)+c]*vv; }
  }
  float s=0.f;
  #pragma unroll
  for(int i=0;i<16;i++){ aA[i]=lrelu(aA[i]); s+=aA[i]; }
  xm[pix]=s*(1.f/16.f);
  float u=0.f;
  #pragma unroll
  for(int i=0;i<16;i++) u+=aB[i];
  u*=(1.f/16.f);
  float varr=0.f;
  #pragma unroll
  for(int i=0;i<16;i++){ float d=aB[i]-u; varr+=d*d; }
  varr*=(1.f/16.f);
  float inv=1.f/sqrtf(varr+1e-6f);
  float* xp=x_+(((size_t)b*16)<<16)+p;
  #pragma unroll
  for(int i=0;i<16;i++){
    float xv=lrelu(slw[i]*((aB[i]-u)*inv)+slb[i]);
    xp[((size_t)i)<<16]=xv; aA[i]=xv;
  }
  int lane=tid&63, wid=tid>>6;
  #pragma unroll
  for(int i=0;i<16;i++){
    float val=aA[i];
    for(int m=32;m>0;m>>=1) val+=__shfl_xor(val,m);
    if(lane==0) sred[wid][i]=val;
  }
  __syncthreads();
  if(tid<16) capart[blockIdx.x*16+tid]=sred[0][tid]+sred[1][tid]+sred[2][tid]+sred[3][tid];
}

// ---------------- K3: sa = sigmoid(conv3x3(x_)) ----------------
__global__ __launch_bounds__(256) void k_sa(const float* __restrict__ x_,
    const float* __restrict__ Wsa, const float* __restrict__ bsa, float* __restrict__ sa){
  __shared__ float w[144]; __shared__ float bb;
  int tid=threadIdx.x;
  if(tid<144) w[tid]=Wsa[tid];
  if(tid==0) bb=bsa[0];
  __syncthreads();
  int pix=blockIdx.x*256+tid; int b=pix>>16, p=pix&65535;
  int y=p>>8, xx=p&255;
  float acc=bb;
  #pragma unroll
  for(int i=0;i<16;i++){
    const float* pl=x_+(((size_t)(b*16+i))<<16);
    #pragma unroll
    for(int ky=0;ky<3;ky++){
      int yy=y+ky-1;
      if((unsigned)yy<256u){
        #pragma unroll
        for(int kx=0;kx<3;kx++){
          int x2=xx+kx-1;
          if((unsigned)x2<256u) acc+=pl[(yy<<8)+x2]*w[i*9+ky*3+kx];
        }
      }
    }
  }
  sa[pix]=sigmoidf(acc);
}

// ---------------- K4: per-window variance (ddof=1) ----------------
__global__ __launch_bounds__(64) void k_var(const float* __restrict__ xm, float* __restrict__ var){
  int blk=blockIdx.x, tid=threadIdx.x;
  int b=blk>>10, n=blk&1023;
  int pix=((n>>5)<<11) + ((n&31)<<3) + ((tid>>3)<<8) + (tid&7);
  float val=xm[(b<<16)+pix];
  float s=val;
  for(int m=32;m>0;m>>=1) s+=__shfl_xor(s,m);
  float mean=s*(1.f/64.f);
  float d=val-mean; float q=d*d;
  for(int m=32;m>0;m>>=1) q+=__shfl_xor(q,m);
  if(tid==0) var[blk]=q*(1.f/63.f);
}

// ---------------- K5: rank -> mbin (bottom 512 var -> 0) ----------------
__global__ __launch_bounds__(256) void k_rank(const float* __restrict__ var, float* __restrict__ mbin){
  __shared__ float va[1024];
  int b=blockIdx.x, tid=threadIdx.x;
  for(int i=tid;i<1024;i+=256) va[i]=var[(b<<10)+i];
  __syncthreads();
  for(int n=tid;n<1024;n+=256){
    float vn=va[n]; int r=0;
    for(int m=0;m<1024;m++){ float vm=va[m]; r += (vm<vn) || (vm==vn && m<n); }
    mbin[(b<<10)+n] = (r<512)?0.f:1.f;
  }
}

// ---------------- K6: h0/h1 from Wm1 rowsums ----------------
__global__ __launch_bounds__(64) void k_hvec(const void* __restrict__ Wm1, const float* __restrict__ bm1,
    float* __restrict__ h0, float* __restrict__ h1, const int* __restrict__ fl){
  int j=blockIdx.x, tid=threadIdx.x;
  float s=0.f;
  if(fl[0]){
    const float* row=(const float*)Wm1+((size_t)j<<12);
    for(int k=tid;k<4096;k+=64) s+=row[k];
  } else {
    const bf16* row=(const bf16*)Wm1+((size_t)j<<12);
    for(int k=tid;k<4096;k+=64) s+=b2f(row[k]);
  }
  for(int m=32;m>0;m>>=1) s+=__shfl_xor(s,m);
  if(tid==0){ float bb=bm1[j]; h0[j]=lrelu(bb); h1[j]=lrelu(bb+s); }
}

// ---------------- K7: mask0/mask1 vectors ----------------
__global__ __launch_bounds__(64) void k_mask(const void* __restrict__ Wm2, const float* __restrict__ bm2,
    const float* __restrict__ h0, const float* __restrict__ h1,
    float* __restrict__ m0, float* __restrict__ m1, const int* __restrict__ fl){
  int e=blockIdx.x, tid=threadIdx.x;
  float p0=0.f,p1=0.f;
  if(fl[0]){
    const float* row=(const float*)Wm2+((size_t)e<<11);
    for(int j=tid;j<2048;j+=64){ float w=row[j]; p0+=w*h0[j]; p1+=w*h1[j]; }
  } else {
    const bf16* row=(const bf16*)Wm2+((size_t)e<<11);
    for(int j=tid;j<2048;j+=64){ float w=b2f(row[j]); p0+=w*h0[j]; p1+=w*h1[j]; }
  }
  for(int m=32;m>0;m>>=1){ p0+=__shfl_xor(p0,m); p1+=__shfl_xor(p1,m); }
  if(tid==0){ float bb=bm2[e]; m0[e]=p0+bb; m1[e]=p1+bb; }
}

// ---------------- K8: ca = sigmoid(Wca * mean(x_) + bca) ----------------
__global__ __launch_bounds__(64) void k_ca(const float* __restrict__ capart,
    const float* __restrict__ Wca, const float* __restrict__ bca, float* __restrict__ ca){
  __shared__ float m[16];
  int b=blockIdx.x, tid=threadIdx.x;
  if(tid<16){
    float s=0.f;
    for(int blk=0;blk<256;blk++) s+=capart[((b<<8)+blk)*16+tid];
    m[tid]=s*(1.f/65536.f);
  }
  __syncthreads();
  float a=bca[tid];
  #pragma unroll
  for(int i=0;i<16;i++) a+=Wca[(tid<<4)+i]*m[i];
  ca[(b<<6)+tid]=sigmoidf(a);
}

// ---------------- K9: windowed attention via MFMA -> img ----------------
// One block = one window. 4 waves, wave w owns output rows [w*16, w*16+16).
// LDS matrices bf16 stride 72 (144B rows -> frag ds_read_b128 2-way = free).
#define STR 72
#define STRF 65
__global__ __launch_bounds__(256,4) void k_attn_mfma(
    const void* __restrict__ x, const float* __restrict__ v,
    const float* __restrict__ sa, const float* __restrict__ mbin,
    const float* __restrict__ m0, const float* __restrict__ m1,
    const short* __restrict__ Wqb, const float* __restrict__ bq,
    const short* __restrict__ Wkb, const float* __restrict__ bk,
    float* __restrict__ img, const int* __restrict__ fl){
  __shared__ short sT[64*STR];        // t, later attn-probs (per-wave rows)
  __shared__ short sQK[2*64*STR];     // q | k ; reused as f32 out-staging sF
  __shared__ short sV1[64*STR];       // v1 transposed: sV1[c][j]
  short* sQ=sQK; short* sK=sQK+64*STR;
  float* sF=(float*)sQK;              // [64][65] f32 = 16640B <= 18432B
  int tid=threadIdx.x, blk=blockIdx.x;
  int b=blk>>10, n=blk&1023;
  int base=((n>>5)<<11) + ((n&31)<<3);
  const float* mp = (mbin[blk]>0.5f)? m1 : m0;
  size_t plane=((size_t)b*64)<<16;
  int isf32=fl[0];
  // ---- P1: stage t = x*mask  and  v1^T = (v*mask)^T ----
  for(int e=tid;e<2048;e+=256){
    int c=e>>5, pp=e&31; int j0=pp*2;
    int pix0=base+((j0>>3)<<8)+(j0&7);
    float mk0=mp[j0*64+c], mk1=mp[j0*64+64+c];
    float x0,x1v;
    if(isf32){ const float* xp=(const float*)x+plane+(((size_t)c)<<16)+pix0; x0=xp[0]; x1v=xp[1]; }
    else { const bf16* xp=(const bf16*)x+plane+(((size_t)c)<<16)+pix0; x0=b2f(xp[0]); x1v=b2f(xp[1]); }
    sT[j0*STR+c]=f2bs(x0*mk0);
    sT[j0*STR+STR+c]=f2bs(x1v*mk1);
    const float* vp=v+plane+(((size_t)c)<<16)+pix0;
    sV1[c*STR+j0]=f2bs(vp[0]*mk0);
    sV1[c*STR+j0+1]=f2bs(vp[1]*mk1);
  }
  __syncthreads();
  int lane=tid&63, wid=tid>>6;
  int pb=wid*16, lr=lane&15, lg=lane>>4;
  // ---- P2: q = t Wq^T + bq ; k = t Wk^T + bk ----
  short8v ta[2];
  #pragma unroll
  for(int ks=0;ks<2;ks++) ta[ks]=*(const short8v*)&sT[(pb+lr)*STR + ks*32 + lg*8];
  #pragma unroll
  for(int nt=0;nt<4;nt++){
    float bqv=bq[nt*16+lr], bkv=bk[nt*16+lr];
    f32x4 qa={bqv,bqv,bqv,bqv}, ka={bkv,bkv,bkv,bkv};
    #pragma unroll
    for(int ks=0;ks<2;ks++){
      short8v wq=*(const short8v*)(Wqb + (nt*16+lr)*64 + ks*32 + lg*8);
      short8v wk=*(const short8v*)(Wkb + (nt*16+lr)*64 + ks*32 + lg*8);
      qa=__builtin_amdgcn_mfma_f32_16x16x32_bf16(ta[ks],wq,qa,0,0,0);
      ka=__builtin_amdgcn_mfma_f32_16x16x32_bf16(ta[ks],wk,ka,0,0,0);
    }
    #pragma unroll
    for(int r=0;r<4;r++){
      sQ[(pb+lg*4+r)*STR + nt*16+lr]=f2bs(qa[r]);
      sK[(pb+lg*4+r)*STR + nt*16+lr]=f2bs(ka[r]);
    }
  }
  __syncthreads();
  // ---- P3: s = q k^T ; register softmax over rows ----
  short8v qa2[2];
  #pragma unroll
  for(int ks=0;ks<2;ks++) qa2[ks]=*(const short8v*)&sQ[(pb+lr)*STR + ks*32 + lg*8];
  f32x4 sacc[4];
  #pragma unroll
  for(int nt=0;nt<4;nt++){
    f32x4 a={0.f,0.f,0.f,0.f};
    #pragma unroll
    for(int ks=0;ks<2;ks++){
      short8v kb=*(const short8v*)&sK[(nt*16+lr)*STR + ks*32 + lg*8];
      a=__builtin_amdgcn_mfma_f32_16x16x32_bf16(qa2[ks],kb,a,0,0,0);
    }
    sacc[nt]=a;
  }
  f32x4 pa[4];
  #pragma unroll
  for(int r=0;r<4;r++){
    float mx=fmaxf(fmaxf(sacc[0][r],sacc[1][r]),fmaxf(sacc[2][r],sacc[3][r]));
    #pragma unroll
    for(int m=1;m<16;m<<=1) mx=fmaxf(mx,__shfl_xor(mx,m));
    float e0=expf(sacc[0][r]-mx), e1=expf(sacc[1][r]-mx);
    float e2=expf(sacc[2][r]-mx), e3=expf(sacc[3][r]-mx);
    float sum=e0+e1+e2+e3;
    #pragma unroll
    for(int m=1;m<16;m<<=1) sum+=__shfl_xor(sum,m);
    float inv=1.f/sum;
    pa[0][r]=e0*inv; pa[1][r]=e1*inv; pa[2][r]=e2*inv; pa[3][r]=e3*inv;
  }
  #pragma unroll
  for(int nt=0;nt<4;nt++){
    #pragma unroll
    for(int r=0;r<4;r++)
      sT[(pb+lg*4+r)*STR + nt*16+lr]=f2bs(pa[nt][r]);
  }
  __syncthreads();   // protects sF (aliases sQ/sK) from in-flight P3 reads
  // ---- P4: f = attn @ v1 -> sF ----
  short8v aa[2];
  #pragma unroll
  for(int ks=0;ks<2;ks++) aa[ks]=*(const short8v*)&sT[(pb+lr)*STR + ks*32 + lg*8];
  #pragma unroll
  for(int nt=0;nt<4;nt++){
    f32x4 f={0.f,0.f,0.f,0.f};
    #pragma unroll
    for(int ks=0;ks<2;ks++){
      short8v vb=*(const short8v*)&sV1[(nt*16+lr)*STR + ks*32 + lg*8];
      f=__builtin_amdgcn_mfma_f32_16x16x32_bf16(aa[ks],vb,f,0,0,0);
    }
    #pragma unroll
    for(int r=0;r<4;r++) sF[(pb+lg*4+r)*STRF + nt*16+lr]=f[r];
  }
  __syncthreads();
  // ---- P5: epilogue out = f + v*sa*(1-mask), coalesced write ----
  for(int e=tid;e<2048;e+=256){
    int c=e>>5, pp=e&31; int j0=pp*2;
    int pix0=base+((j0>>3)<<8)+(j0&7);
    float f0=sF[j0*STRF+c], f1=sF[(j0+1)*STRF+c];
    const float* vp=v+plane+(((size_t)c)<<16)+pix0;
    float mk0=mp[j0*64+c], mk1=mp[j0*64+64+c];
    float s0=sa[(b<<16)+pix0], s1=sa[(b<<16)+pix0+1];
    float2 o; o.x=f0+vp[0]*s0*(1.f-mk0); o.y=f1+vp[1]*s1*(1.f-mk1);
    *(float2*)(img+plane+(((size_t)c)<<16)+pix0)=o;
  }
}

// ---------------- K10: depthwise 3x3 (dil 1) ----------------
__global__ __launch_bounds__(256) void k_dw1(const float* __restrict__ img,
    const float* __restrict__ dw1, const float* __restrict__ dwb1, float* __restrict__ tmp){
  int idx=blockIdx.x*256+threadIdx.x;
  int p=idx&65535, bc=idx>>16, c=bc&63;
  int y=p>>8, xx=p&255;
  float acc=dwb1[c];
  const float* pl=img+(((size_t)bc)<<16);
  #pragma unroll
  for(int ky=0;ky<3;ky++){
    int yy=y+ky-1;
    if((unsigned)yy<256u){
      #pragma unroll
      for(int kx=0;kx<3;kx++){
        int x2=xx+kx-1;
        if((unsigned)x2<256u) acc+=pl[(yy<<8)+x2]*dw1[c*9+ky*3+kx];
      }
    }
  }
  tmp[idx]=acc;
}

// ---------------- K11: depthwise 3x3 (dil 2) + gelu*ca + img ----------------
__global__ __launch_bounds__(256) void k_dw2gate(const float* __restrict__ tmp, const float* __restrict__ img,
    const float* __restrict__ dw2, const float* __restrict__ dwb2,
    const float* __restrict__ ca, float* __restrict__ outb){
  int idx=blockIdx.x*256+threadIdx.x;
  int p=idx&65535, bc=idx>>16, b=bc>>6, c=bc&63;
  int y=p>>8, xx=p&255;
  float acc=dwb2[c];
  const float* pl=tmp+(((size_t)bc)<<16);
  #pragma unroll
  for(int ky=0;ky<3;ky++){
    int yy=y+2*(ky-1);
    if((unsigned)yy<256u){
      #pragma unroll
      for(int kx=0;kx<3;kx++){
        int x2=xx+2*(kx-1);
        if((unsigned)x2<256u) acc+=pl[(yy<<8)+x2]*dw2[c*9+ky*3+kx];
      }
    }
  }
  outb[idx]=geluf(acc)*ca[(b<<6)+c]+img[idx];
}

// ---------------- K12: res = Wo*out + bo; x1 = LN(x + res) ----------------
__global__ __launch_bounds__(256) void k_proj_ln1(const float* __restrict__ outb, const void* __restrict__ x,
    const float* __restrict__ Wo, const float* __restrict__ bo,
    const float* __restrict__ wn, const float* __restrict__ bn, float* __restrict__ x1,
    const int* __restrict__ fl){
  __shared__ float ws[4096]; __shared__ float sb[64], swn[64], sbn[64];
  int tid=threadIdx.x;
  for(int i=tid;i<4096;i+=256) ws[i]=Wo[i];
  if(tid<64){ sb[tid]=bo[tid]; swn[tid]=wn[tid]; sbn[tid]=bn[tid]; }
  __syncthreads();
  int pix=blockIdx.x*256+tid; int b=pix>>16, p=pix&65535;
  float r[64];
  #pragma unroll
  for(int o=0;o<64;o++) r[o]=sb[o];
  const float* op=outb+(((size_t)b*64)<<16)+p;
  for(int c=0;c<64;c++){
    float ov=op[((size_t)c)<<16];
    #pragma unroll
    for(int o=0;o<64;o++) r[o]+=ws[(o<<6)+c]*ov;
  }
  size_t xbase=(((size_t)b*64)<<16)+p;
  if(fl[0]){
    const float* xp=(const float*)x+xbase;
    #pragma unroll
    for(int o=0;o<64;o++) r[o]+=xp[((size_t)o)<<16];
  } else {
    const bf16* xp=(const bf16*)x+xbase;
    #pragma unroll
    for(int o=0;o<64;o++) r[o]+=b2f(xp[((size_t)o)<<16]);
  }
  float mean=0.f;
  #pragma unroll
  for(int o=0;o<64;o++) mean+=r[o];
  mean*=(1.f/64.f);
  float varr=0.f;
  #pragma unroll
  for(int o=0;o<64;o++){ float d=r[o]-mean; varr+=d*d; }
  varr*=(1.f/64.f);
  float inv=1.f/sqrtf(varr+1e-6f);
  float* x1p=x1+(((size_t)b*64)<<16)+p;
  #pragma unroll
  for(int o=0;o<64;o++) x1p[((size_t)o)<<16]=swn[o]*((r[o]-mean)*inv)+sbn[o];
}

// ---------------- K13: y_pre = Wffn_in * x1 -> E (bf16) ----------------
__global__ __launch_bounds__(256) void k_ffn_in(const float* __restrict__ x1,
    const float* __restrict__ W, bf16* __restrict__ E){
  __shared__ float ws[4096];
  int tid=threadIdx.x; int half=blockIdx.y<<6;
  for(int i=tid;i<4096;i+=256) ws[i]=W[(half<<6)+i];
  __syncthreads();
  int pix=blockIdx.x*256+tid; int b=pix>>16, p=pix&65535;
  float r[64];
  #pragma unroll
  for(int o=0;o<64;o++) r[o]=0.f;
  const float* xp=x1+(((size_t)b*64)<<16)+p;
  for(int c=0;c<64;c++){
    float xv=xp[((size_t)c)<<16];
    #pragma unroll
    for(int o=0;o<64;o++) r[o]+=ws[(o<<6)+c]*xv;
  }
  bf16* ep=E+(((size_t)(b*128+half))<<16)+p;
  #pragma unroll
  for(int o=0;o<64;o++) ep[((size_t)o)<<16]=__float2bfloat16(r[o]);
}

// ---------------- K14: depthwise 3x3 on y (128ch, bf16 in) + gelu gate ----------------
__global__ __launch_bounds__(256) void k_ffn_dw(const bf16* __restrict__ E,
    const float* __restrict__ dwf, float* __restrict__ g){
  int idx=blockIdx.x*256+threadIdx.x;
  int p=idx&65535, bc=idx>>16, b=bc>>6, c=bc&63;
  int y=p>>8, xx=p&255;
  float a1=0.f, a2=0.f;
  const bf16* p1=E+(((size_t)(b*128+c))<<16);
  const bf16* p2=E+(((size_t)(b*128+64+c))<<16);
  #pragma unroll
  for(int ky=0;ky<3;ky++){
    int yy=y+ky-1;
    if((unsigned)yy<256u){
      #pragma unroll
      for(int kx=0;kx<3;kx++){
        int x2=xx+kx-1;
        if((unsigned)x2<256u){
          int off=(yy<<8)+x2;
          a1+=b2f(p1[off])*dwf[c*9+ky*3+kx];
          a2+=b2f(p2[off])*dwf[(64+c)*9+ky*3+kx];
        }
      }
    }
  }
  g[idx]=geluf(a1)*a2;
}

// ---------------- K15: res2 = Wffn_out*g; out = LN2(x1+res2) ----------------
__global__ __launch_bounds__(256) void k_ffn_out(const float* __restrict__ g, const float* __restrict__ x1,
    const float* __restrict__ Wfo, const float* __restrict__ wn, const float* __restrict__ bn,
    void* __restrict__ out, const int* __restrict__ fl){
  __shared__ float ws[4096]; __shared__ float swn[64], sbn[64];
  int tid=threadIdx.x;
  for(int i=tid;i<4096;i+=256) ws[i]=Wfo[i];
  if(tid<64){ swn[tid]=wn[tid]; sbn[tid]=bn[tid]; }
  __syncthreads();
  int pix=blockIdx.x*256+tid; int b=pix>>16, p=pix&65535;
  float r[64];
  #pragma unroll
  for(int o=0;o<64;o++) r[o]=0.f;
  const float* gp=g+(((size_t)b*64)<<16)+p;
  for(int c=0;c<64;c++){
    float gv=gp[((size_t)c)<<16];
    #pragma unroll
    for(int o=0;o<64;o++) r[o]+=ws[(o<<6)+c]*gv;
  }
  const float* xp=x1+(((size_t)b*64)<<16)+p;
  float mean=0.f;
  #pragma unroll
  for(int o=0;o<64;o++){ r[o]+=xp[((size_t)o)<<16]; mean+=r[o]; }
  mean*=(1.f/64.f);
  float varr=0.f;
  #pragma unroll
  for(int o=0;o<64;o++){ float d=r[o]-mean; varr+=d*d; }
  varr*=(1.f/64.f);
  float inv=1.f/sqrtf(varr+1e-6f);
  size_t obase=(((size_t)b*64)<<16)+p;
  if(fl[0]){
    float* op=(float*)out+obase;
    #pragma unroll
    for(int o=0;o<64;o++) op[((size_t)o)<<16]=swn[o]*((r[o]-mean)*inv)+sbn[o];
  } else {
    bf16* op=(bf16*)out+obase;
    #pragma unroll
    for(int o=0;o<64;o++) op[((size_t)o)<<16]=__float2bfloat16(swn[o]*((r[o]-mean)*inv)+sbn[o]);
  }
}

extern "C" void kernel_launch(void* const* d_in, const int* in_sizes, int n_in,
                              void* d_out, int out_size, void* d_ws, size_t ws_size,
                              hipStream_t stream){
  (void)in_sizes; (void)n_in; (void)out_size; (void)ws_size;
  const void* x  = d_in[0];
  const void* Wm1= d_in[23];
  const void* Wm2= d_in[25];

  char* ws=(char*)d_ws;
  float* v    =(float*)(ws);
  float* tmp  =(float*)(ws);
  bf16*  E    =(bf16*) (ws);
  float* img  =(float*)(ws+67108864);
  float* x1   =(float*)(ws+67108864);
  float* outb =(float*)(ws+134217728);
  float* gbuf =(float*)(ws+134217728);
  char* sm = ws+201326592;
  float* x_    =(float*)(sm);              // 16 MB
  float* sa    =(float*)(sm+16777216);     // 1 MB
  float* xm    =(float*)(sm+17825792);     // 1 MB
  float* var   =(float*)(sm+18874368);     // 16 KB
  float* mbin  =(float*)(sm+18890752);     // 16 KB
  float* h0    =(float*)(sm+18907136);     // 8 KB
  float* h1    =(float*)(sm+18915328);     // 8 KB
  float* m0    =(float*)(sm+18923520);     // 16 KB
  float* m1    =(float*)(sm+18939904);     // 16 KB
  float* capart=(float*)(sm+18956288);     // 64 KB
  float* ca    =(float*)(sm+19021824);     // 1 KB
  int*   flag  =(int*)  (sm+19022848);     // 4 B
  float* wbuf  =(float*)(sm+19023872);     // ~161 KB
  short* Wqb   =(short*)(sm+19200000);     // 8 KB bf16
  short* Wkb   =(short*)(sm+19208192);     // 8 KB bf16

  static const int din_idx[31]={5,6,7,8,9,10,11,12,13,14,15,16,17,18,19,20,21,22,24,26,27,28,29,30,31,32,33,1,2,3,4};
  static const int szs[31]  ={4096,64,4096,64,4096,64,576,64,576,64,4096,64,1024,16,1024,16,16,16,2048,4096,1024,64,144,1,8192,1152,4096,64,64,64,64};
  CvtArgs ca_args;
  int off=0;
  int offs[31];
  for(int t=0;t<31;t++){
    ca_args.src[t]=d_in[din_idx[t]];
    ca_args.sz[t]=szs[t];
    ca_args.off[t]=off;
    offs[t]=off;
    off+=szs[t];
  }
  const float* Wv  =wbuf+offs[0];  const float* bv  =wbuf+offs[1];
  const float* Wq  =wbuf+offs[2];  const float* bq  =wbuf+offs[3];
  const float* Wk  =wbuf+offs[4];  const float* bk  =wbuf+offs[5];
  const float* dw1 =wbuf+offs[6];  const float* dwb1=wbuf+offs[7];
  const float* dw2 =wbuf+offs[8];  const float* dwb2=wbuf+offs[9];
  const float* Wo  =wbuf+offs[10]; const float* bo  =wbuf+offs[11];
  const float* W_in=wbuf+offs[12]; const float* b_in=wbuf+offs[13];
  const float* Wc  =wbuf+offs[14]; const float* bc  =wbuf+offs[15];
  const float* lnw =wbuf+offs[16]; const float* lnb =wbuf+offs[17];
  const float* bm1 =wbuf+offs[18]; const float* bm2 =wbuf+offs[19];
  const float* Wca =wbuf+offs[20]; const float* bca =wbuf+offs[21];
  const float* Wsa =wbuf+offs[22]; const float* bsa =wbuf+offs[23];
  const float* Wfi =wbuf+offs[24]; const float* dwf =wbuf+offs[25];
  const float* Wfo =wbuf+offs[26];
  const float* wn1 =wbuf+offs[27]; const float* bn1 =wbuf+offs[28];
  const float* wn2 =wbuf+offs[29]; const float* bn2 =wbuf+offs[30];

  hipLaunchKernelGGL(k_detect,  dim3(1),     dim3(256), 0, stream, x, flag);
  hipLaunchKernelGGL(k_cvt,     dim3(31),    dim3(256), 0, stream, ca_args, flag, wbuf);
  hipLaunchKernelGGL(k_w2b,     dim3(16),    dim3(256), 0, stream, Wq, Wk, Wqb, Wkb);
  hipLaunchKernelGGL(k_conv_v,  dim3(1024),  dim3(256), 0, stream, x, Wv, bv, v, flag);
  hipLaunchKernelGGL(k_route,   dim3(1024),  dim3(256), 0, stream, v, W_in, b_in, Wc, bc, lnw, lnb, x_, xm, capart);
  hipLaunchKernelGGL(k_sa,      dim3(1024),  dim3(256), 0, stream, x_, Wsa, bsa, sa);
  hipLaunchKernelGGL(k_var,     dim3(4096),  dim3(64),  0, stream, xm, var);
  hipLaunchKernelGGL(k_rank,    dim3(4),     dim3(256), 0, stream, var, mbin);
  hipLaunchKernelGGL(k_hvec,    dim3(2048),  dim3(64),  0, stream, Wm1, bm1, h0, h1, flag);
  hipLaunchKernelGGL(k_mask,    dim3(4096),  dim3(64),  0, stream, Wm2, bm2, h0, h1, m0, m1, flag);
  hipLaunchKernelGGL(k_ca,      dim3(4),     dim3(64),  0, stream, capart, Wca, bca, ca);
  hipLaunchKernelGGL(k_attn_mfma,dim3(4096), dim3(256), 0, stream, x, v, sa, mbin, m0, m1, Wqb, bq, Wkb, bk, img, flag);
  hipLaunchKernelGGL(k_dw1,     dim3(65536), dim3(256), 0, stream, img, dw1, dwb1, tmp);
  hipLaunchKernelGGL(k_dw2gate, dim3(65536), dim3(256), 0, stream, tmp, img, dw2, dwb2, ca, outb);
  hipLaunchKernelGGL(k_proj_ln1,dim3(1024),  dim3(256), 0, stream, outb, x, Wo, bo, wn1, bn1, x1, flag);
  hipLaunchKernelGGL(k_ffn_in,  dim3(1024,2),dim3(256), 0, stream, x1, Wfi, E);
  hipLaunchKernelGGL(k_ffn_dw,  dim3(65536), dim3(256), 0, stream, E, dwf, gbuf);
  hipLaunchKernelGGL(k_ffn_out, dim3(1024),  dim3(256), 0, stream, gbuf, x1, Wfo, wn2, bn2, d_out, flag);
}

// Round 5
// 1001.725 us; speedup vs baseline: 1.8316x; 1.2021x over previous
//
#include <hip/hip_runtime.h>
#include <hip/hip_bf16.h>

typedef __hip_bfloat16 bf16;
typedef __attribute__((ext_vector_type(8))) short short8v;
typedef __attribute__((ext_vector_type(4))) float f32x4;

#define DEV static __device__ __forceinline__

DEV float b2f(bf16 h){ return __bfloat162float(h); }
DEV short f2bs(float f){ bf16 h=__float2bfloat16(f); short s; __builtin_memcpy(&s,&h,2); return s; }
DEV unsigned pack2(float a, float b){ return ((unsigned)(unsigned short)f2bs(b)<<16)|(unsigned short)f2bs(a); }
DEV float lrelu(float x){ return x >= 0.f ? x : 0.1f*x; }
DEV float geluf(float x){ return 0.5f*x*(1.f + erff(x*0.70710678118654752440f)); }
DEV float sigmoidf(float x){ return 1.f/(1.f + expf(-x)); }

// B=4, C=64, H=W=256, HW=65536, WS=8, N=1024 windows/batch, embed=4096

// ---------------- K0a: detect storage dtype ----------------
__global__ __launch_bounds__(256) void k_detect(const void* x, int* flag){
  __shared__ int cnt;
  if(threadIdx.x==0) cnt=0;
  __syncthreads();
  const unsigned short* up=(const unsigned short*)x;
  int c=0;
  for(int k=0;k<16;k++){
    unsigned short u=up[(threadIdx.x*16+k)*2];
    if(((u>>7)&0xFF)==0xFF) c++;
  }
  atomicAdd(&cnt,c);
  __syncthreads();
  if(threadIdx.x==0) flag[0] = (cnt>0) ? 1 : 0;  // 1 => f32 storage
}

// ---------------- K0b: convert small weights to f32 wbuf ----------------
struct CvtArgs { const void* src[31]; int sz[31]; int off[31]; };
__global__ __launch_bounds__(256) void k_cvt(CvtArgs a, const int* fl, float* wbuf){
  int t=blockIdx.x; int n=a.sz[t]; const void* s=a.src[t]; float* d=wbuf+a.off[t];
  if(fl[0]){
    const float* sp=(const float*)s;
    for(int i=threadIdx.x;i<n;i+=256) d[i]=sp[i];
  } else {
    const bf16* sp=(const bf16*)s;
    for(int i=threadIdx.x;i<n;i+=256) d[i]=b2f(sp[i]);
  }
}

// ---------------- K0c: Wq/Wk -> bf16 copies for MFMA ----------------
__global__ __launch_bounds__(256) void k_w2b(const float* __restrict__ wq, const float* __restrict__ wk,
    short* __restrict__ Wqb, short* __restrict__ Wkb){
  int i=blockIdx.x*256+threadIdx.x;
  if(i<4096){ Wqb[i]=f2bs(wq[i]); Wkb[i]=f2bs(wk[i]); }
}

// ---------------- K_G1: 16-och x 4-pix GEMM template, f32 out ----------------
// out[b][og*16+o][p] = sum_c W[og*16+o][c] * in[b][c][p] (+bias)
__global__ __launch_bounds__(256) void k_gemm16(
    const void* __restrict__ in, const float* __restrict__ W,
    const float* __restrict__ bias, int has_bias,
    float* __restrict__ out, int out_nch,
    const int* __restrict__ fl, int force_f32){
  __shared__ float sW[1024]; __shared__ float sb[16];
  int tid=threadIdx.x, og=blockIdx.y;
  for(int i=tid;i<1024;i+=256) sW[i]=W[og*1024+i];
  if(tid<16) sb[tid]= has_bias ? bias[og*16+tid] : 0.f;
  __syncthreads();
  int g=blockIdx.x*1024+tid*4; int b=g>>16, p=g&65535;
  float4 a[16];
  #pragma unroll
  for(int o=0;o<16;o++){ float bv=sb[o]; a[o]=make_float4(bv,bv,bv,bv); }
  bool f32in = force_f32 || (fl[0]!=0);
  size_t base=(((size_t)b*64)<<16)+p;
  if(f32in){
    const float* ip=(const float*)in + base;
    for(int c=0;c<64;c++){
      float4 xv=*(const float4*)(ip + (((size_t)c)<<16));
      #pragma unroll
      for(int o=0;o<16;o++){ float w=sW[o*64+c];
        a[o].x+=w*xv.x; a[o].y+=w*xv.y; a[o].z+=w*xv.z; a[o].w+=w*xv.w; }
    }
  } else {
    const bf16* ip=(const bf16*)in + base;
    for(int c=0;c<64;c++){
      const bf16* q=ip+(((size_t)c)<<16);
      float4 xv=make_float4(b2f(q[0]),b2f(q[1]),b2f(q[2]),b2f(q[3]));
      #pragma unroll
      for(int o=0;o<16;o++){ float w=sW[o*64+c];
        a[o].x+=w*xv.x; a[o].y+=w*xv.y; a[o].z+=w*xv.z; a[o].w+=w*xv.w; }
    }
  }
  float* op=out + (((size_t)(b*out_nch+og*16))<<16) + p;
  #pragma unroll
  for(int o=0;o<16;o++) *(float4*)(op+(((size_t)o)<<16))=a[o];
}

// ---------------- K_G2: 16-och x 4-pix GEMM, bf16 out (ffn_in -> E) ----------------
__global__ __launch_bounds__(256) void k_gemm16_b(
    const float* __restrict__ in, const float* __restrict__ W, bf16* __restrict__ out){
  __shared__ float sW[1024];
  int tid=threadIdx.x, og=blockIdx.y;
  for(int i=tid;i<1024;i+=256) sW[i]=W[og*1024+i];
  __syncthreads();
  int g=blockIdx.x*1024+tid*4; int b=g>>16, p=g&65535;
  float4 a[16];
  #pragma unroll
  for(int o=0;o<16;o++) a[o]=make_float4(0.f,0.f,0.f,0.f);
  const float* ip=in + (((size_t)b*64)<<16)+p;
  for(int c=0;c<64;c++){
    float4 xv=*(const float4*)(ip + (((size_t)c)<<16));
    #pragma unroll
    for(int o=0;o<16;o++){ float w=sW[o*64+c];
      a[o].x+=w*xv.x; a[o].y+=w*xv.y; a[o].z+=w*xv.z; a[o].w+=w*xv.w; }
  }
  bf16* op=out + (((size_t)(b*128+og*16))<<16) + p;
  #pragma unroll
  for(int o=0;o<16;o++){
    uint2 u; u.x=pack2(a[o].x,a[o].y); u.y=pack2(a[o].z,a[o].w);
    *(uint2*)(op+(((size_t)o)<<16))=u;
  }
}

// ---------------- K_LN: out = LN(res + base), 2 pix/thread ----------------
__global__ __launch_bounds__(256) void k_add_ln(
    const float* __restrict__ res, const void* __restrict__ base,
    const float* __restrict__ w, const float* __restrict__ bb,
    void* __restrict__ out,
    const int* __restrict__ fl, int base_force_f32, int out_force_f32){
  __shared__ float sw[64], sb[64];
  int tid=threadIdx.x;
  if(tid<64){ sw[tid]=w[tid]; sb[tid]=bb[tid]; }
  __syncthreads();
  int g=blockIdx.x*512+tid*2; int b=g>>16, p=g&65535;
  size_t off=(((size_t)b*64)<<16)+p;
  float2 r[64];
  bool bf32 = base_force_f32 || (fl[0]!=0);
  const float* rp=res+off;
  if(bf32){
    const float* xp=(const float*)base+off;
    #pragma unroll
    for(int o=0;o<64;o++){
      float2 rv=*(const float2*)(rp+(((size_t)o)<<16));
      float2 xv=*(const float2*)(xp+(((size_t)o)<<16));
      r[o].x=rv.x+xv.x; r[o].y=rv.y+xv.y;
    }
  } else {
    const bf16* xp=(const bf16*)base+off;
    #pragma unroll
    for(int o=0;o<64;o++){
      float2 rv=*(const float2*)(rp+(((size_t)o)<<16));
      const bf16* q=xp+(((size_t)o)<<16);
      r[o].x=rv.x+b2f(q[0]); r[o].y=rv.y+b2f(q[1]);
    }
  }
  float m0=0.f,m1=0.f;
  #pragma unroll
  for(int o=0;o<64;o++){ m0+=r[o].x; m1+=r[o].y; }
  m0*=(1.f/64.f); m1*=(1.f/64.f);
  float v0=0.f,v1=0.f;
  #pragma unroll
  for(int o=0;o<64;o++){ float d0=r[o].x-m0, d1=r[o].y-m1; v0+=d0*d0; v1+=d1*d1; }
  v0*=(1.f/64.f); v1*=(1.f/64.f);
  float i0=1.f/sqrtf(v0+1e-6f), i1=1.f/sqrtf(v1+1e-6f);
  bool of32 = out_force_f32 || (fl[0]!=0);
  if(of32){
    float* op=(float*)out+off;
    #pragma unroll
    for(int o=0;o<64;o++){
      float2 st; st.x=sw[o]*((r[o].x-m0)*i0)+sb[o]; st.y=sw[o]*((r[o].y-m1)*i1)+sb[o];
      *(float2*)(op+(((size_t)o)<<16))=st;
    }
  } else {
    bf16* op=(bf16*)out+off;
    #pragma unroll
    for(int o=0;o<64;o++){
      float s0=sw[o]*((r[o].x-m0)*i0)+sb[o], s1=sw[o]*((r[o].y-m1)*i1)+sb[o];
      *(unsigned*)(op+(((size_t)o)<<16))=pack2(s0,s1);
    }
  }
}

// ---------------- K2: route (2 pix/thread): xin/x_/xm/ca partials ----------------
__global__ __launch_bounds__(256) void k_route(const float* __restrict__ v,
    const float* __restrict__ W_in, const float* __restrict__ b_in,
    const float* __restrict__ Wc, const float* __restrict__ bc,
    const float* __restrict__ lnw, const float* __restrict__ lnb,
    float* __restrict__ x_, float* __restrict__ xm, float* __restrict__ capart){
  __shared__ float wA[1024], wB[1024], sba[16], sbb[16], slw[16], slb[16];
  __shared__ float sred[4][16];
  int tid=threadIdx.x;
  for(int i=tid;i<1024;i+=256){ wA[i]=W_in[i]; wB[i]=Wc[i]; }
  if(tid<16){ sba[tid]=b_in[tid]; sbb[tid]=bc[tid]; slw[tid]=lnw[tid]; slb[tid]=lnb[tid]; }
  __syncthreads();
  int g=blockIdx.x*512+tid*2; int b=g>>16, p=g&65535;
  float2 aA[16], aB[16];
  #pragma unroll
  for(int i=0;i<16;i++){ aA[i]=make_float2(sba[i],sba[i]); aB[i]=make_float2(sbb[i],sbb[i]); }
  const float* vp=v+(((size_t)b*64)<<16)+p;
  for(int c=0;c<64;c++){
    float2 vv=*(const float2*)(vp+(((size_t)c)<<16));
    #pragma unroll
    for(int i=0;i<16;i++){
      float wa=wA[(i<<6)+c], wb=wB[(i<<6)+c];
      aA[i].x+=wa*vv.x; aA[i].y+=wa*vv.y;
      aB[i].x+=wb*vv.x; aB[i].y+=wb*vv.y;
    }
  }
  float s0=0.f,s1=0.f;
  #pragma unroll
  for(int i=0;i<16;i++){ aA[i].x=lrelu(aA[i].x); aA[i].y=lrelu(aA[i].y); s0+=aA[i].x; s1+=aA[i].y; }
  float2 xmst; xmst.x=s0*(1.f/16.f); xmst.y=s1*(1.f/16.f);
  *(float2*)(xm+g)=xmst;
  float u0=0.f,u1=0.f;
  #pragma unroll
  for(int i=0;i<16;i++){ u0+=aB[i].x; u1+=aB[i].y; }
  u0*=(1.f/16.f); u1*=(1.f/16.f);
  float q0=0.f,q1=0.f;
  #pragma unroll
  for(int i=0;i<16;i++){ float d0=aB[i].x-u0, d1=aB[i].y-u1; q0+=d0*d0; q1+=d1*d1; }
  q0*=(1.f/16.f); q1*=(1.f/16.f);
  float i0=1.f/sqrtf(q0+1e-6f), i1=1.f/sqrtf(q1+1e-6f);
  float red[16];
  float* xp=x_+(((size_t)b*16)<<16)+p;
  #pragma unroll
  for(int i=0;i<16;i++){
    float xv0=lrelu(slw[i]*((aB[i].x-u0)*i0)+slb[i]);
    float xv1=lrelu(slw[i]*((aB[i].y-u1)*i1)+slb[i]);
    float2 st; st.x=xv0; st.y=xv1;
    *(float2*)(xp+(((size_t)i)<<16))=st;
    red[i]=xv0+xv1;
  }
  int lane=tid&63, wid=tid>>6;
  #pragma unroll
  for(int i=0;i<16;i++){
    float val=red[i];
    for(int m=32;m>0;m>>=1) val+=__shfl_xor(val,m);
    if(lane==0) sred[wid][i]=val;
  }
  __syncthreads();
  if(tid<16) capart[blockIdx.x*16+tid]=sred[0][tid]+sred[1][tid]+sred[2][tid]+sred[3][tid];
}

// ---------------- K3: sa = sigmoid(conv3x3(x_)) ----------------
__global__ __launch_bounds__(256) void k_sa(const float* __restrict__ x_,
    const float* __restrict__ Wsa, const float* __restrict__ bsa, float* __restrict__ sa){
  __shared__ float w[144]; __shared__ float bb;
  int tid=threadIdx.x;
  if(tid<144) w[tid]=Wsa[tid];
  if(tid==0) bb=bsa[0];
  __syncthreads();
  int pix=blockIdx.x*256+tid; int b=pix>>16, p=pix&65535;
  int y=p>>8, xx=p&255;
  float acc=bb;
  #pragma unroll
  for(int i=0;i<16;i++){
    const float* pl=x_+(((size_t)(b*16+i))<<16);
    #pragma unroll
    for(int ky=0;ky<3;ky++){
      int yy=y+ky-1;
      if((unsigned)yy<256u){
        #pragma unroll
        for(int kx=0;kx<3;kx++){
          int x2=xx+kx-1;
          if((unsigned)x2<256u) acc+=pl[(yy<<8)+x2]*w[i*9+ky*3+kx];
        }
      }
    }
  }
  sa[pix]=sigmoidf(acc);
}

// ---------------- K4: per-window variance (ddof=1) ----------------
__global__ __launch_bounds__(64) void k_var(const float* __restrict__ xm, float* __restrict__ var){
  int blk=blockIdx.x, tid=threadIdx.x;
  int b=blk>>10, n=blk&1023;
  int pix=((n>>5)<<11) + ((n&31)<<3) + ((tid>>3)<<8) + (tid&7);
  float val=xm[(b<<16)+pix];
  float s=val;
  for(int m=32;m>0;m>>=1) s+=__shfl_xor(s,m);
  float mean=s*(1.f/64.f);
  float d=val-mean; float q=d*d;
  for(int m=32;m>0;m>>=1) q+=__shfl_xor(q,m);
  if(tid==0) var[blk]=q*(1.f/63.f);
}

// ---------------- K5: rank -> mbin (bottom 512 var -> 0) ----------------
__global__ __launch_bounds__(256) void k_rank(const float* __restrict__ var, float* __restrict__ mbin){
  __shared__ float va[1024];
  int b=blockIdx.x, tid=threadIdx.x;
  for(int i=tid;i<1024;i+=256) va[i]=var[(b<<10)+i];
  __syncthreads();
  for(int n=tid;n<1024;n+=256){
    float vn=va[n]; int r=0;
    for(int m=0;m<1024;m++){ float vm=va[m]; r += (vm<vn) || (vm==vn && m<n); }
    mbin[(b<<10)+n] = (r<512)?0.f:1.f;
  }
}

// ---------------- K6: h0/h1 from Wm1 rowsums ----------------
__global__ __launch_bounds__(64) void k_hvec(const void* __restrict__ Wm1, const float* __restrict__ bm1,
    float* __restrict__ h0, float* __restrict__ h1, const int* __restrict__ fl){
  int j=blockIdx.x, tid=threadIdx.x;
  float s=0.f;
  if(fl[0]){
    const float* row=(const float*)Wm1+((size_t)j<<12);
    for(int k=tid;k<4096;k+=64) s+=row[k];
  } else {
    const bf16* row=(const bf16*)Wm1+((size_t)j<<12);
    for(int k=tid;k<4096;k+=64) s+=b2f(row[k]);
  }
  for(int m=32;m>0;m>>=1) s+=__shfl_xor(s,m);
  if(tid==0){ float bb=bm1[j]; h0[j]=lrelu(bb); h1[j]=lrelu(bb+s); }
}

// ---------------- K7: mask0/mask1 vectors ----------------
__global__ __launch_bounds__(64) void k_mask(const void* __restrict__ Wm2, const float* __restrict__ bm2,
    const float* __restrict__ h0, const float* __restrict__ h1,
    float* __restrict__ m0, float* __restrict__ m1, const int* __restrict__ fl){
  int e=blockIdx.x, tid=threadIdx.x;
  float p0=0.f,p1=0.f;
  if(fl[0]){
    const float* row=(const float*)Wm2+((size_t)e<<11);
    for(int j=tid;j<2048;j+=64){ float w=row[j]; p0+=w*h0[j]; p1+=w*h1[j]; }
  } else {
    const bf16* row=(const bf16*)Wm2+((size_t)e<<11);
    for(int j=tid;j<2048;j+=64){ float w=b2f(row[j]); p0+=w*h0[j]; p1+=w*h1[j]; }
  }
  for(int m=32;m>0;m>>=1){ p0+=__shfl_xor(p0,m); p1+=__shfl_xor(p1,m); }
  if(tid==0){ float bb=bm2[e]; m0[e]=p0+bb; m1[e]=p1+bb; }
}

// ---------------- K8: ca = sigmoid(Wca * mean(x_) + bca) ----------------
__global__ __launch_bounds__(64) void k_ca(const float* __restrict__ capart,
    const float* __restrict__ Wca, const float* __restrict__ bca, float* __restrict__ ca){
  __shared__ float m[16];
  int b=blockIdx.x, tid=threadIdx.x;
  if(tid<16){
    float s=0.f;
    for(int blk=0;blk<128;blk++) s+=capart[((b*128)+blk)*16+tid];
    m[tid]=s*(1.f/65536.f);
  }
  __syncthreads();
  float a=bca[tid];
  #pragma unroll
  for(int i=0;i<16;i++) a+=Wca[(tid<<4)+i]*m[i];
  ca[(b<<6)+tid]=sigmoidf(a);
}

// ---------------- K9: windowed attention via MFMA -> img ----------------
#define STR 72
#define STRF 65
__global__ __launch_bounds__(256,4) void k_attn_mfma(
    const void* __restrict__ x, const float* __restrict__ v,
    const float* __restrict__ sa, const float* __restrict__ mbin,
    const float* __restrict__ m0, const float* __restrict__ m1,
    const short* __restrict__ Wqb, const float* __restrict__ bq,
    const short* __restrict__ Wkb, const float* __restrict__ bk,
    float* __restrict__ img, const int* __restrict__ fl){
  __shared__ short sT[64*STR];
  __shared__ short sQK[2*64*STR];
  __shared__ short sV1[64*STR];
  short* sQ=sQK; short* sK=sQK+64*STR;
  float* sF=(float*)sQK;
  int tid=threadIdx.x, blk=blockIdx.x;
  int b=blk>>10, n=blk&1023;
  int base=((n>>5)<<11) + ((n&31)<<3);
  const float* mp = (mbin[blk]>0.5f)? m1 : m0;
  size_t plane=((size_t)b*64)<<16;
  int isf32=fl[0];
  for(int e=tid;e<2048;e+=256){
    int c=e>>5, pp=e&31; int j0=pp*2;
    int pix0=base+((j0>>3)<<8)+(j0&7);
    float mk0=mp[j0*64+c], mk1=mp[j0*64+64+c];
    float x0,x1v;
    if(isf32){ const float* xp=(const float*)x+plane+(((size_t)c)<<16)+pix0; x0=xp[0]; x1v=xp[1]; }
    else { const bf16* xp=(const bf16*)x+plane+(((size_t)c)<<16)+pix0; x0=b2f(xp[0]); x1v=b2f(xp[1]); }
    sT[j0*STR+c]=f2bs(x0*mk0);
    sT[j0*STR+STR+c]=f2bs(x1v*mk1);
    const float* vp=v+plane+(((size_t)c)<<16)+pix0;
    sV1[c*STR+j0]=f2bs(vp[0]*mk0);
    sV1[c*STR+j0+1]=f2bs(vp[1]*mk1);
  }
  __syncthreads();
  int lane=tid&63, wid=tid>>6;
  int pb=wid*16, lr=lane&15, lg=lane>>4;
  short8v ta[2];
  #pragma unroll
  for(int ks=0;ks<2;ks++) ta[ks]=*(const short8v*)&sT[(pb+lr)*STR + ks*32 + lg*8];
  #pragma unroll
  for(int nt=0;nt<4;nt++){
    float bqv=bq[nt*16+lr], bkv=bk[nt*16+lr];
    f32x4 qa={bqv,bqv,bqv,bqv}, ka={bkv,bkv,bkv,bkv};
    #pragma unroll
    for(int ks=0;ks<2;ks++){
      short8v wq=*(const short8v*)(Wqb + (nt*16+lr)*64 + ks*32 + lg*8);
      short8v wk=*(const short8v*)(Wkb + (nt*16+lr)*64 + ks*32 + lg*8);
      qa=__builtin_amdgcn_mfma_f32_16x16x32_bf16(ta[ks],wq,qa,0,0,0);
      ka=__builtin_amdgcn_mfma_f32_16x16x32_bf16(ta[ks],wk,ka,0,0,0);
    }
    #pragma unroll
    for(int r=0;r<4;r++){
      sQ[(pb+lg*4+r)*STR + nt*16+lr]=f2bs(qa[r]);
      sK[(pb+lg*4+r)*STR + nt*16+lr]=f2bs(ka[r]);
    }
  }
  __syncthreads();
  short8v qa2[2];
  #pragma unroll
  for(int ks=0;ks<2;ks++) qa2[ks]=*(const short8v*)&sQ[(pb+lr)*STR + ks*32 + lg*8];
  f32x4 sacc[4];
  #pragma unroll
  for(int nt=0;nt<4;nt++){
    f32x4 a={0.f,0.f,0.f,0.f};
    #pragma unroll
    for(int ks=0;ks<2;ks++){
      short8v kb=*(const short8v*)&sK[(nt*16+lr)*STR + ks*32 + lg*8];
      a=__builtin_amdgcn_mfma_f32_16x16x32_bf16(qa2[ks],kb,a,0,0,0);
    }
    sacc[nt]=a;
  }
  f32x4 pa[4];
  #pragma unroll
  for(int r=0;r<4;r++){
    float mx=fmaxf(fmaxf(sacc[0][r],sacc[1][r]),fmaxf(sacc[2][r],sacc[3][r]));
    #pragma unroll
    for(int m=1;m<16;m<<=1) mx=fmaxf(mx,__shfl_xor(mx,m));
    float e0=expf(sacc[0][r]-mx), e1=expf(sacc[1][r]-mx);
    float e2=expf(sacc[2][r]-mx), e3=expf(sacc[3][r]-mx);
    float sum=e0+e1+e2+e3;
    #pragma unroll
    for(int m=1;m<16;m<<=1) sum+=__shfl_xor(sum,m);
    float inv=1.f/sum;
    pa[0][r]=e0*inv; pa[1][r]=e1*inv; pa[2][r]=e2*inv; pa[3][r]=e3*inv;
  }
  #pragma unroll
  for(int nt=0;nt<4;nt++){
    #pragma unroll
    for(int r=0;r<4;r++)
      sT[(pb+lg*4+r)*STR + nt*16+lr]=f2bs(pa[nt][r]);
  }
  __syncthreads();
  short8v aa[2];
  #pragma unroll
  for(int ks=0;ks<2;ks++) aa[ks]=*(const short8v*)&sT[(pb+lr)*STR + ks*32 + lg*8];
  #pragma unroll
  for(int nt=0;nt<4;nt++){
    f32x4 f={0.f,0.f,0.f,0.f};
    #pragma unroll
    for(int ks=0;ks<2;ks++){
      short8v vb=*(const short8v*)&sV1[(nt*16+lr)*STR + ks*32 + lg*8];
      f=__builtin_amdgcn_mfma_f32_16x16x32_bf16(aa[ks],vb,f,0,0,0);
    }
    #pragma unroll
    for(int r=0;r<4;r++) sF[(pb+lg*4+r)*STRF + nt*16+lr]=f[r];
  }
  __syncthreads();
  for(int e=tid;e<2048;e+=256){
    int c=e>>5, pp=e&31; int j0=pp*2;
    int pix0=base+((j0>>3)<<8)+(j0&7);
    float f0=sF[j0*STRF+c], f1=sF[(j0+1)*STRF+c];
    const float* vp=v+plane+(((size_t)c)<<16)+pix0;
    float mk0=mp[j0*64+c], mk1=mp[j0*64+64+c];
    float s0=sa[(b<<16)+pix0], s1=sa[(b<<16)+pix0+1];
    float2 o; o.x=f0+vp[0]*s0*(1.f-mk0); o.y=f1+vp[1]*s1*(1.f-mk1);
    *(float2*)(img+plane+(((size_t)c)<<16)+pix0)=o;
  }
}

// ---------------- K10: depthwise 3x3 (dil 1) ----------------
__global__ __launch_bounds__(256) void k_dw1(const float* __restrict__ img,
    const float* __restrict__ dw1, const float* __restrict__ dwb1, float* __restrict__ tmp){
  int idx=blockIdx.x*256+threadIdx.x;
  int p=idx&65535, bc=idx>>16, c=bc&63;
  int y=p>>8, xx=p&255;
  float acc=dwb1[c];
  const float* pl=img+(((size_t)bc)<<16);
  #pragma unroll
  for(int ky=0;ky<3;ky++){
    int yy=y+ky-1;
    if((unsigned)yy<256u){
      #pragma unroll
      for(int kx=0;kx<3;kx++){
        int x2=xx+kx-1;
        if((unsigned)x2<256u) acc+=pl[(yy<<8)+x2]*dw1[c*9+ky*3+kx];
      }
    }
  }
  tmp[idx]=acc;
}

// ---------------- K11: depthwise 3x3 (dil 2) + gelu*ca + img ----------------
__global__ __launch_bounds__(256) void k_dw2gate(const float* __restrict__ tmp, const float* __restrict__ img,
    const float* __restrict__ dw2, const float* __restrict__ dwb2,
    const float* __restrict__ ca, float* __restrict__ outb){
  int idx=blockIdx.x*256+threadIdx.x;
  int p=idx&65535, bc=idx>>16, b=bc>>6, c=bc&63;
  int y=p>>8, xx=p&255;
  float acc=dwb2[c];
  const float* pl=tmp+(((size_t)bc)<<16);
  #pragma unroll
  for(int ky=0;ky<3;ky++){
    int yy=y+2*(ky-1);
    if((unsigned)yy<256u){
      #pragma unroll
      for(int kx=0;kx<3;kx++){
        int x2=xx+2*(kx-1);
        if((unsigned)x2<256u) acc+=pl[(yy<<8)+x2]*dw2[c*9+ky*3+kx];
      }
    }
  }
  outb[idx]=geluf(acc)*ca[(b<<6)+c]+img[idx];
}

// ---------------- K14: depthwise 3x3 on y (128ch, bf16 in) + gelu gate ----------------
__global__ __launch_bounds__(256) void k_ffn_dw(const bf16* __restrict__ E,
    const float* __restrict__ dwf, float* __restrict__ g){
  int idx=blockIdx.x*256+threadIdx.x;
  int p=idx&65535, bc=idx>>16, b=bc>>6, c=bc&63;
  int y=p>>8, xx=p&255;
  float a1=0.f, a2=0.f;
  const bf16* p1=E+(((size_t)(b*128+c))<<16);
  const bf16* p2=E+(((size_t)(b*128+64+c))<<16);
  #pragma unroll
  for(int ky=0;ky<3;ky++){
    int yy=y+ky-1;
    if((unsigned)yy<256u){
      #pragma unroll
      for(int kx=0;kx<3;kx++){
        int x2=xx+kx-1;
        if((unsigned)x2<256u){
          int off=(yy<<8)+x2;
          a1+=b2f(p1[off])*dwf[c*9+ky*3+kx];
          a2+=b2f(p2[off])*dwf[(64+c)*9+ky*3+kx];
        }
      }
    }
  }
  g[idx]=geluf(a1)*a2;
}

extern "C" void kernel_launch(void* const* d_in, const int* in_sizes, int n_in,
                              void* d_out, int out_size, void* d_ws, size_t ws_size,
                              hipStream_t stream){
  (void)in_sizes; (void)n_in; (void)out_size; (void)ws_size;
  const void* x  = d_in[0];
  const void* Wm1= d_in[23];
  const void* Wm2= d_in[25];

  char* ws=(char*)d_ws;
  // Slot A [0,64MiB):    v -> tmp -> res -> E(bf16) -> res2
  // Slot B [64,128MiB):  img -> x1
  // Slot C [128,192MiB): outb -> g
  float* v    =(float*)(ws);
  float* tmp  =(float*)(ws);
  float* res  =(float*)(ws);
  bf16*  E    =(bf16*) (ws);
  float* res2 =(float*)(ws);
  float* img  =(float*)(ws+67108864);
  float* x1   =(float*)(ws+67108864);
  float* outb =(float*)(ws+134217728);
  float* gbuf =(float*)(ws+134217728);
  char* sm = ws+201326592;
  float* x_    =(float*)(sm);              // 16 MB
  float* sa    =(float*)(sm+16777216);     // 1 MB
  float* xm    =(float*)(sm+17825792);     // 1 MB
  float* var   =(float*)(sm+18874368);     // 16 KB
  float* mbin  =(float*)(sm+18890752);     // 16 KB
  float* h0    =(float*)(sm+18907136);     // 8 KB
  float* h1    =(float*)(sm+18915328);     // 8 KB
  float* m0    =(float*)(sm+18923520);     // 16 KB
  float* m1    =(float*)(sm+18939904);     // 16 KB
  float* capart=(float*)(sm+18956288);     // 64 KB
  float* ca    =(float*)(sm+19021824);     // 1 KB
  int*   flag  =(int*)  (sm+19022848);     // 4 B
  float* wbuf  =(float*)(sm+19023872);     // ~161 KB
  short* Wqb   =(short*)(sm+19200000);     // 8 KB bf16
  short* Wkb   =(short*)(sm+19208192);     // 8 KB bf16

  static const int din_idx[31]={5,6,7,8,9,10,11,12,13,14,15,16,17,18,19,20,21,22,24,26,27,28,29,30,31,32,33,1,2,3,4};
  static const int szs[31]  ={4096,64,4096,64,4096,64,576,64,576,64,4096,64,1024,16,1024,16,16,16,2048,4096,1024,64,144,1,8192,1152,4096,64,64,64,64};
  CvtArgs ca_args;
  int off=0;
  int offs[31];
  for(int t=0;t<31;t++){
    ca_args.src[t]=d_in[din_idx[t]];
    ca_args.sz[t]=szs[t];
    ca_args.off[t]=off;
    offs[t]=off;
    off+=szs[t];
  }
  const float* Wv  =wbuf+offs[0];  const float* bv  =wbuf+offs[1];
  const float* Wq  =wbuf+offs[2];  const float* bq  =wbuf+offs[3];
  const float* Wk  =wbuf+offs[4];  const float* bk  =wbuf+offs[5];
  const float* dw1 =wbuf+offs[6];  const float* dwb1=wbuf+offs[7];
  const float* dw2 =wbuf+offs[8];  const float* dwb2=wbuf+offs[9];
  const float* Wo  =wbuf+offs[10]; const float* bo  =wbuf+offs[11];
  const float* W_in=wbuf+offs[12]; const float* b_in=wbuf+offs[13];
  const float* Wc  =wbuf+offs[14]; const float* bc  =wbuf+offs[15];
  const float* lnw =wbuf+offs[16]; const float* lnb =wbuf+offs[17];
  const float* bm1 =wbuf+offs[18]; const float* bm2 =wbuf+offs[19];
  const float* Wca =wbuf+offs[20]; const float* bca =wbuf+offs[21];
  const float* Wsa =wbuf+offs[22]; const float* bsa =wbuf+offs[23];
  const float* Wfi =wbuf+offs[24]; const float* dwf =wbuf+offs[25];
  const float* Wfo =wbuf+offs[26];
  const float* wn1 =wbuf+offs[27]; const float* bn1 =wbuf+offs[28];
  const float* wn2 =wbuf+offs[29]; const float* bn2 =wbuf+offs[30];

  hipLaunchKernelGGL(k_detect,  dim3(1),      dim3(256), 0, stream, x, flag);
  hipLaunchKernelGGL(k_cvt,     dim3(31),     dim3(256), 0, stream, ca_args, flag, wbuf);
  hipLaunchKernelGGL(k_w2b,     dim3(16),     dim3(256), 0, stream, Wq, Wk, Wqb, Wkb);
  // v = Wv x + bv
  hipLaunchKernelGGL(k_gemm16,  dim3(256,4),  dim3(256), 0, stream, x, Wv, bv, 1, v, 64, flag, 0);
  hipLaunchKernelGGL(k_route,   dim3(512),    dim3(256), 0, stream, v, W_in, b_in, Wc, bc, lnw, lnb, x_, xm, capart);
  hipLaunchKernelGGL(k_sa,      dim3(1024),   dim3(256), 0, stream, x_, Wsa, bsa, sa);
  hipLaunchKernelGGL(k_var,     dim3(4096),   dim3(64),  0, stream, xm, var);
  hipLaunchKernelGGL(k_rank,    dim3(4),      dim3(256), 0, stream, var, mbin);
  hipLaunchKernelGGL(k_hvec,    dim3(2048),   dim3(64),  0, stream, Wm1, bm1, h0, h1, flag);
  hipLaunchKernelGGL(k_mask,    dim3(4096),   dim3(64),  0, stream, Wm2, bm2, h0, h1, m0, m1, flag);
  hipLaunchKernelGGL(k_ca,      dim3(4),      dim3(64),  0, stream, capart, Wca, bca, ca);
  hipLaunchKernelGGL(k_attn_mfma,dim3(4096),  dim3(256), 0, stream, x, v, sa, mbin, m0, m1, Wqb, bq, Wkb, bk, img, flag);
  hipLaunchKernelGGL(k_dw1,     dim3(65536),  dim3(256), 0, stream, img, dw1, dwb1, tmp);
  hipLaunchKernelGGL(k_dw2gate, dim3(65536),  dim3(256), 0, stream, tmp, img, dw2, dwb2, ca, outb);
  // res = Wo*outb + bo ; x1 = LN1(x + res)
  hipLaunchKernelGGL(k_gemm16,  dim3(256,4),  dim3(256), 0, stream, outb, Wo, bo, 1, res, 64, flag, 1);
  hipLaunchKernelGGL(k_add_ln,  dim3(512),    dim3(256), 0, stream, res, x, wn1, bn1, (void*)x1, flag, 0, 1);
  // E = bf16(Wfi * x1)
  hipLaunchKernelGGL(k_gemm16_b,dim3(256,8),  dim3(256), 0, stream, x1, Wfi, E);
  hipLaunchKernelGGL(k_ffn_dw,  dim3(65536),  dim3(256), 0, stream, E, dwf, gbuf);
  // res2 = Wfo * g ; out = LN2(x1 + res2)
  hipLaunchKernelGGL(k_gemm16,  dim3(256,4),  dim3(256), 0, stream, gbuf, Wfo, wbuf, 0, res2, 64, flag, 1);
  hipLaunchKernelGGL(k_add_ln,  dim3(512),    dim3(256), 0, stream, res2, x1, wn2, bn2, d_out, flag, 1, 0);
}

// Round 6
// 778.393 us; speedup vs baseline: 2.3571x; 1.2869x over previous
//
#include <hip/hip_runtime.h>
#include <hip/hip_bf16.h>

typedef __hip_bfloat16 bf16;
typedef __attribute__((ext_vector_type(8))) short short8v;
typedef __attribute__((ext_vector_type(4))) float f32x4;

#define DEV static __device__ __forceinline__

DEV float b2f(bf16 h){ return __bfloat162float(h); }
DEV float us2f(unsigned short u){ unsigned v=((unsigned)u)<<16; float f; __builtin_memcpy(&f,&v,4); return f; }
DEV short f2bs(float f){ bf16 h=__float2bfloat16(f); short s; __builtin_memcpy(&s,&h,2); return s; }
DEV unsigned pack2(float a, float b){ return ((unsigned)(unsigned short)f2bs(b)<<16)|(unsigned short)f2bs(a); }
DEV float lrelu(float x){ return x >= 0.f ? x : 0.1f*x; }
DEV float geluf(float x){ return 0.5f*x*(1.f + erff(x*0.70710678118654752440f)); }
DEV float sigmoidf(float x){ return 1.f/(1.f + expf(-x)); }

// B=4, C=64, H=W=256, HW=65536, WS=8, N=1024 windows/batch, embed=4096

// ---------------- K0a: detect storage dtype ----------------
__global__ __launch_bounds__(256) void k_detect(const void* x, int* flag){
  __shared__ int cnt;
  if(threadIdx.x==0) cnt=0;
  __syncthreads();
  const unsigned short* up=(const unsigned short*)x;
  int c=0;
  for(int k=0;k<16;k++){
    unsigned short u=up[(threadIdx.x*16+k)*2];
    if(((u>>7)&0xFF)==0xFF) c++;
  }
  atomicAdd(&cnt,c);
  __syncthreads();
  if(threadIdx.x==0) flag[0] = (cnt>0) ? 1 : 0;  // 1 => f32 storage
}

// ---------------- K0b: convert small weights to f32 wbuf ----------------
struct CvtArgs { const void* src[31]; int sz[31]; int off[31]; };
__global__ __launch_bounds__(256) void k_cvt(CvtArgs a, const int* fl, float* wbuf){
  int t=blockIdx.x; int n=a.sz[t]; const void* s=a.src[t]; float* d=wbuf+a.off[t];
  if(fl[0]){
    const float* sp=(const float*)s;
    for(int i=threadIdx.x;i<n;i+=256) d[i]=sp[i];
  } else {
    const bf16* sp=(const bf16*)s;
    for(int i=threadIdx.x;i<n;i+=256) d[i]=b2f(sp[i]);
  }
}

// ---------------- K0c: Wq/Wk -> bf16 for MFMA ----------------
__global__ __launch_bounds__(256) void k_w2b(const float* __restrict__ wq, const float* __restrict__ wk,
    short* __restrict__ Wqb, short* __restrict__ Wkb){
  int i=blockIdx.x*256+threadIdx.x;
  if(i<4096){ Wqb[i]=f2bs(wq[i]); Wkb[i]=f2bs(wk[i]); }
}

// ---------------- K_G: 32-och x 4-pix 1x1-conv GEMM, f32 out (64 out ch) ----------------
__global__ __launch_bounds__(256) void k_gemm32(
    const void* __restrict__ in, const float* __restrict__ W,
    const float* __restrict__ bias, int has_bias,
    float* __restrict__ out, const int* __restrict__ fl, int force_f32){
  __shared__ float sW[2048]; __shared__ float sb[32];
  int tid=threadIdx.x, og=blockIdx.y;
  for(int i=tid;i<2048;i+=256) sW[i]=W[og*2048+i];
  if(tid<32) sb[tid]= has_bias ? bias[og*32+tid] : 0.f;
  __syncthreads();
  int g=blockIdx.x*1024+tid*4; int b=g>>16, p=g&65535;
  float4 a[32];
  #pragma unroll
  for(int o=0;o<32;o++){ float bv=sb[o]; a[o]=make_float4(bv,bv,bv,bv); }
  bool f32in = force_f32 || (fl[0]!=0);
  size_t base=(((size_t)b*64)<<16)+p;
  if(f32in){
    const float* ip=(const float*)in + base;
    for(int c=0;c<64;c++){
      float4 xv=*(const float4*)(ip + (((size_t)c)<<16));
      #pragma unroll
      for(int o=0;o<32;o++){ float w=sW[o*64+c];
        a[o].x+=w*xv.x; a[o].y+=w*xv.y; a[o].z+=w*xv.z; a[o].w+=w*xv.w; }
    }
  } else {
    const bf16* ip=(const bf16*)in + base;
    for(int c=0;c<64;c++){
      const bf16* q=ip+(((size_t)c)<<16);
      float4 xv=make_float4(b2f(q[0]),b2f(q[1]),b2f(q[2]),b2f(q[3]));
      #pragma unroll
      for(int o=0;o<32;o++){ float w=sW[o*64+c];
        a[o].x+=w*xv.x; a[o].y+=w*xv.y; a[o].z+=w*xv.z; a[o].w+=w*xv.w; }
    }
  }
  float* op=out + (((size_t)(b*64+og*32))<<16) + p;
  #pragma unroll
  for(int o=0;o<32;o++) *(float4*)(op+(((size_t)o)<<16))=a[o];
}

// ---------------- K_G2: 32-och x 4-pix GEMM, bf16 in (x1b) -> E bf16 (128 och) ----------------
__global__ __launch_bounds__(256) void k_gemm32_b(
    const unsigned short* __restrict__ in, const float* __restrict__ W,
    unsigned short* __restrict__ E){
  __shared__ float sW[2048];
  int tid=threadIdx.x, og=blockIdx.y;
  for(int i=tid;i<2048;i+=256) sW[i]=W[og*2048+i];
  __syncthreads();
  int g=blockIdx.x*1024+tid*4; int b=g>>16, p=g&65535;
  float4 a[32];
  #pragma unroll
  for(int o=0;o<32;o++) a[o]=make_float4(0.f,0.f,0.f,0.f);
  const unsigned short* ip=in + (((size_t)b*64)<<16)+p;
  for(int c=0;c<64;c++){
    uint2 u=*(const uint2*)(ip + (((size_t)c)<<16));
    float4 xv=make_float4(us2f(u.x&0xffff),us2f(u.x>>16),us2f(u.y&0xffff),us2f(u.y>>16));
    #pragma unroll
    for(int o=0;o<32;o++){ float w=sW[o*64+c];
      a[o].x+=w*xv.x; a[o].y+=w*xv.y; a[o].z+=w*xv.z; a[o].w+=w*xv.w; }
  }
  unsigned short* op=E + (((size_t)(b*128+og*32))<<16) + p;
  #pragma unroll
  for(int o=0;o<32;o++){
    uint2 u; u.x=pack2(a[o].x,a[o].y); u.y=pack2(a[o].z,a[o].w);
    *(uint2*)(op+(((size_t)o)<<16))=u;
  }
}

// ---------------- K_LN: out = LN(res + base), 2 pix/thread ----------------
// base_mode / out_mode: 0 = follow flag (f32 if fl), 1 = force f32, 2 = force bf16
__global__ __launch_bounds__(256) void k_add_ln(
    const float* __restrict__ res, const void* __restrict__ base,
    const float* __restrict__ w, const float* __restrict__ bb,
    void* __restrict__ out,
    const int* __restrict__ fl, int base_mode, int out_mode){
  __shared__ float sw[64], sb[64];
  int tid=threadIdx.x;
  if(tid<64){ sw[tid]=w[tid]; sb[tid]=bb[tid]; }
  __syncthreads();
  int g=blockIdx.x*512+tid*2; int b=g>>16, p=g&65535;
  size_t off=(((size_t)b*64)<<16)+p;
  float2 r[64];
  bool bf32 = (base_mode==1) || (base_mode==0 && fl[0]);
  const float* rp=res+off;
  if(bf32){
    const float* xp=(const float*)base+off;
    #pragma unroll
    for(int o=0;o<64;o++){
      float2 rv=*(const float2*)(rp+(((size_t)o)<<16));
      float2 xv=*(const float2*)(xp+(((size_t)o)<<16));
      r[o].x=rv.x+xv.x; r[o].y=rv.y+xv.y;
    }
  } else {
    const unsigned short* xp=(const unsigned short*)base+off;
    #pragma unroll
    for(int o=0;o<64;o++){
      float2 rv=*(const float2*)(rp+(((size_t)o)<<16));
      unsigned u=*(const unsigned*)(xp+(((size_t)o)<<16));
      r[o].x=rv.x+us2f(u&0xffff); r[o].y=rv.y+us2f(u>>16);
    }
  }
  float m0=0.f,m1=0.f;
  #pragma unroll
  for(int o=0;o<64;o++){ m0+=r[o].x; m1+=r[o].y; }
  m0*=(1.f/64.f); m1*=(1.f/64.f);
  float v0=0.f,v1=0.f;
  #pragma unroll
  for(int o=0;o<64;o++){ float d0=r[o].x-m0, d1=r[o].y-m1; v0+=d0*d0; v1+=d1*d1; }
  v0*=(1.f/64.f); v1*=(1.f/64.f);
  float i0=1.f/sqrtf(v0+1e-6f), i1=1.f/sqrtf(v1+1e-6f);
  bool of32 = (out_mode==1) || (out_mode==0 && fl[0]);
  if(of32){
    float* op=(float*)out+off;
    #pragma unroll
    for(int o=0;o<64;o++){
      float2 st; st.x=sw[o]*((r[o].x-m0)*i0)+sb[o]; st.y=sw[o]*((r[o].y-m1)*i1)+sb[o];
      *(float2*)(op+(((size_t)o)<<16))=st;
    }
  } else {
    unsigned short* op=(unsigned short*)out+off;
    #pragma unroll
    for(int o=0;o<64;o++){
      float s0=sw[o]*((r[o].x-m0)*i0)+sb[o], s1=sw[o]*((r[o].y-m1)*i1)+sb[o];
      *(unsigned*)(op+(((size_t)o)<<16))=pack2(s0,s1);
    }
  }
}

// ---------------- K2: route (2 pix/thread) ----------------
__global__ __launch_bounds__(256) void k_route(const float* __restrict__ v,
    const float* __restrict__ W_in, const float* __restrict__ b_in,
    const float* __restrict__ Wc, const float* __restrict__ bc,
    const float* __restrict__ lnw, const float* __restrict__ lnb,
    float* __restrict__ x_, float* __restrict__ xm, float* __restrict__ capart){
  __shared__ float wA[1024], wB[1024], sba[16], sbb[16], slw[16], slb[16];
  __shared__ float sred[4][16];
  int tid=threadIdx.x;
  for(int i=tid;i<1024;i+=256){ wA[i]=W_in[i]; wB[i]=Wc[i]; }
  if(tid<16){ sba[tid]=b_in[tid]; sbb[tid]=bc[tid]; slw[tid]=lnw[tid]; slb[tid]=lnb[tid]; }
  __syncthreads();
  int g=blockIdx.x*512+tid*2; int b=g>>16, p=g&65535;
  float2 aA[16], aB[16];
  #pragma unroll
  for(int i=0;i<16;i++){ aA[i]=make_float2(sba[i],sba[i]); aB[i]=make_float2(sbb[i],sbb[i]); }
  const float* vp=v+(((size_t)b*64)<<16)+p;
  for(int c=0;c<64;c++){
    float2 vv=*(const float2*)(vp+(((size_t)c)<<16));
    #pragma unroll
    for(int i=0;i<16;i++){
      float wa=wA[(i<<6)+c], wb=wB[(i<<6)+c];
      aA[i].x+=wa*vv.x; aA[i].y+=wa*vv.y;
      aB[i].x+=wb*vv.x; aB[i].y+=wb*vv.y;
    }
  }
  float s0=0.f,s1=0.f;
  #pragma unroll
  for(int i=0;i<16;i++){ aA[i].x=lrelu(aA[i].x); aA[i].y=lrelu(aA[i].y); s0+=aA[i].x; s1+=aA[i].y; }
  float2 xmst; xmst.x=s0*(1.f/16.f); xmst.y=s1*(1.f/16.f);
  *(float2*)(xm+g)=xmst;
  float u0=0.f,u1=0.f;
  #pragma unroll
  for(int i=0;i<16;i++){ u0+=aB[i].x; u1+=aB[i].y; }
  u0*=(1.f/16.f); u1*=(1.f/16.f);
  float q0=0.f,q1=0.f;
  #pragma unroll
  for(int i=0;i<16;i++){ float d0=aB[i].x-u0, d1=aB[i].y-u1; q0+=d0*d0; q1+=d1*d1; }
  q0*=(1.f/16.f); q1*=(1.f/16.f);
  float i0=1.f/sqrtf(q0+1e-6f), i1=1.f/sqrtf(q1+1e-6f);
  float red[16];
  float* xp=x_+(((size_t)b*16)<<16)+p;
  #pragma unroll
  for(int i=0;i<16;i++){
    float xv0=lrelu(slw[i]*((aB[i].x-u0)*i0)+slb[i]);
    float xv1=lrelu(slw[i]*((aB[i].y-u1)*i1)+slb[i]);
    float2 st; st.x=xv0; st.y=xv1;
    *(float2*)(xp+(((size_t)i)<<16))=st;
    red[i]=xv0+xv1;
  }
  int lane=tid&63, wid=tid>>6;
  #pragma unroll
  for(int i=0;i<16;i++){
    float val=red[i];
    for(int m=32;m>0;m>>=1) val+=__shfl_xor(val,m);
    if(lane==0) sred[wid][i]=val;
  }
  __syncthreads();
  if(tid<16) capart[blockIdx.x*16+tid]=sred[0][tid]+sred[1][tid]+sred[2][tid]+sred[3][tid];
}

// ---------------- K3: sa = sigmoid(conv3x3(x_)) ----------------
__global__ __launch_bounds__(256) void k_sa(const float* __restrict__ x_,
    const float* __restrict__ Wsa, const float* __restrict__ bsa, float* __restrict__ sa){
  __shared__ float w[144]; __shared__ float bb;
  int tid=threadIdx.x;
  if(tid<144) w[tid]=Wsa[tid];
  if(tid==0) bb=bsa[0];
  __syncthreads();
  int pix=blockIdx.x*256+tid; int b=pix>>16, p=pix&65535;
  int y=p>>8, xx=p&255;
  float acc=bb;
  #pragma unroll
  for(int i=0;i<16;i++){
    const float* pl=x_+(((size_t)(b*16+i))<<16);
    #pragma unroll
    for(int ky=0;ky<3;ky++){
      int yy=y+ky-1;
      if((unsigned)yy<256u){
        #pragma unroll
        for(int kx=0;kx<3;kx++){
          int x2=xx+kx-1;
          if((unsigned)x2<256u) acc+=pl[(yy<<8)+x2]*w[i*9+ky*3+kx];
        }
      }
    }
  }
  sa[pix]=sigmoidf(acc);
}

// ---------------- K4: per-window variance (ddof=1) ----------------
__global__ __launch_bounds__(64) void k_var(const float* __restrict__ xm, float* __restrict__ var){
  int blk=blockIdx.x, tid=threadIdx.x;
  int b=blk>>10, n=blk&1023;
  int pix=((n>>5)<<11) + ((n&31)<<3) + ((tid>>3)<<8) + (tid&7);
  float val=xm[(b<<16)+pix];
  float s=val;
  for(int m=32;m>0;m>>=1) s+=__shfl_xor(s,m);
  float mean=s*(1.f/64.f);
  float d=val-mean; float q=d*d;
  for(int m=32;m>0;m>>=1) q+=__shfl_xor(q,m);
  if(tid==0) var[blk]=q*(1.f/63.f);
}

// ---------------- K5: rank -> mbin ----------------
__global__ __launch_bounds__(256) void k_rank(const float* __restrict__ var, float* __restrict__ mbin){
  __shared__ float va[1024];
  int bid=blockIdx.x; int b=bid>>2, seg=bid&3;
  int tid=threadIdx.x;
  for(int i=tid;i<1024;i+=256) va[i]=var[(b<<10)+i];
  __syncthreads();
  int n=seg*256+tid;
  float vn=va[n]; int r=0;
  for(int m=0;m<1024;m++){ float vm=va[m]; r += (vm<vn) || (vm==vn && m<n); }
  mbin[(b<<10)+n] = (r<512)?0.f:1.f;
}

// ---------------- K6: h0/h1 from Wm1 rowsums ----------------
__global__ __launch_bounds__(64) void k_hvec(const void* __restrict__ Wm1, const float* __restrict__ bm1,
    float* __restrict__ h0, float* __restrict__ h1, const int* __restrict__ fl){
  int j=blockIdx.x, tid=threadIdx.x;
  float s=0.f;
  if(fl[0]){
    const float* row=(const float*)Wm1+((size_t)j<<12);
    for(int k=tid;k<4096;k+=64) s+=row[k];
  } else {
    const bf16* row=(const bf16*)Wm1+((size_t)j<<12);
    for(int k=tid;k<4096;k+=64) s+=b2f(row[k]);
  }
  for(int m=32;m>0;m>>=1) s+=__shfl_xor(s,m);
  if(tid==0){ float bb=bm1[j]; h0[j]=lrelu(bb); h1[j]=lrelu(bb+s); }
}

// ---------------- K7: mask vectors (+ transposed copies) ----------------
__global__ __launch_bounds__(64) void k_mask(const void* __restrict__ Wm2, const float* __restrict__ bm2,
    const float* __restrict__ h0, const float* __restrict__ h1,
    float* __restrict__ m0, float* __restrict__ m1,
    float* __restrict__ m0T, float* __restrict__ m1T, const int* __restrict__ fl){
  int e=blockIdx.x, tid=threadIdx.x;
  float p0=0.f,p1=0.f;
  if(fl[0]){
    const float* row=(const float*)Wm2+((size_t)e<<11);
    for(int j=tid;j<2048;j+=64){ float w=row[j]; p0+=w*h0[j]; p1+=w*h1[j]; }
  } else {
    const bf16* row=(const bf16*)Wm2+((size_t)e<<11);
    for(int j=tid;j<2048;j+=64){ float w=b2f(row[j]); p0+=w*h0[j]; p1+=w*h1[j]; }
  }
  for(int m=32;m>0;m>>=1){ p0+=__shfl_xor(p0,m); p1+=__shfl_xor(p1,m); }
  if(tid==0){
    float bb=bm2[e]; float v0=p0+bb, v1=p1+bb;
    m0[e]=v0; m1[e]=v1;
    int te=(e&63)*64+(e>>6);
    m0T[te]=v0; m1T[te]=v1;
  }
}

// ---------------- K8: ca = sigmoid(Wca * mean(x_) + bca) ----------------
__global__ __launch_bounds__(64) void k_ca(const float* __restrict__ capart,
    const float* __restrict__ Wca, const float* __restrict__ bca, float* __restrict__ ca){
  __shared__ float m[16];
  int b=blockIdx.x, tid=threadIdx.x;
  if(tid<16){
    float s=0.f;
    for(int blk=0;blk<128;blk++) s+=capart[((b*128)+blk)*16+tid];
    m[tid]=s*(1.f/65536.f);
  }
  __syncthreads();
  float a=bca[tid];
  #pragma unroll
  for(int i=0;i<16;i++) a+=Wca[(tid<<4)+i]*m[i];
  ca[(b<<6)+tid]=sigmoidf(a);
}

// ---------------- K_PACK: x, v, v*sa -> window-major bf16 ----------------
// xwb/vwb/vswb[(b*1024+n)*4096 + c*64 + tok], tok = wrow*8 + wcol
__global__ __launch_bounds__(256) void k_pack(const void* __restrict__ x, const float* __restrict__ v,
    const float* __restrict__ sa, const int* __restrict__ fl,
    unsigned short* __restrict__ xwb, unsigned short* __restrict__ vwb, unsigned short* __restrict__ vswb){
  int wp=blockIdx.x; int b=wp>>9, np=wp&511;
  int n0=np*2;
  int base=((n0>>5)<<11)+((n0&31)<<3);
  int t=threadIdx.x; int c0=t>>3, row=t&7;
  int isf32=fl[0];
  for(int h=0;h<2;h++){
    int ch=c0+h*32;
    size_t gb=(((size_t)(b*64+ch))<<16) + base + row*256;
    float xv[16], vv[16], sv[16];
    if(isf32){
      const float* xp=(const float*)x+gb;
      #pragma unroll
      for(int i=0;i<16;i++) xv[i]=xp[i];
    } else {
      const bf16* xp=(const bf16*)x+gb;
      #pragma unroll
      for(int i=0;i<16;i++) xv[i]=b2f(xp[i]);
    }
    const float* vp=v+gb;
    const float* sp=sa+(((size_t)b)<<16)+base+row*256;
    #pragma unroll
    for(int i=0;i<16;i++){ vv[i]=vp[i]; sv[i]=sp[i]; }
    size_t o0=((size_t)(b*1024+n0)*64+ch)*64 + row*8;
    #pragma unroll
    for(int wnd=0;wnd<2;wnd++){
      size_t oo=o0+(size_t)wnd*4096;
      int s=wnd*8;
      uint4 ux, uv, us;
      ux.x=pack2(xv[s+0],xv[s+1]); ux.y=pack2(xv[s+2],xv[s+3]);
      ux.z=pack2(xv[s+4],xv[s+5]); ux.w=pack2(xv[s+6],xv[s+7]);
      uv.x=pack2(vv[s+0],vv[s+1]); uv.y=pack2(vv[s+2],vv[s+3]);
      uv.z=pack2(vv[s+4],vv[s+5]); uv.w=pack2(vv[s+6],vv[s+7]);
      us.x=pack2(vv[s+0]*sv[s+0],vv[s+1]*sv[s+1]); us.y=pack2(vv[s+2]*sv[s+2],vv[s+3]*sv[s+3]);
      us.z=pack2(vv[s+4]*sv[s+4],vv[s+5]*sv[s+5]); us.w=pack2(vv[s+6]*sv[s+6],vv[s+7]*sv[s+7]);
      *(uint4*)(xwb+oo)=ux; *(uint4*)(vwb+oo)=uv; *(uint4*)(vswb+oo)=us;
    }
  }
}

// ---------------- K9: windowed attention via MFMA -> img ----------------
#define STR 72
#define STRF 65
__global__ __launch_bounds__(256,4) void k_attn_mfma(
    const unsigned short* __restrict__ xwb, const unsigned short* __restrict__ vwb,
    const unsigned short* __restrict__ vswb, const float* __restrict__ mbin,
    const float* __restrict__ m0T, const float* __restrict__ m1T,
    const short* __restrict__ Wqb, const float* __restrict__ bq,
    const short* __restrict__ Wkb, const float* __restrict__ bk,
    float* __restrict__ img){
  __shared__ short sT[64*STR];
  __shared__ short sQK[2*64*STR];
  __shared__ short sV1[64*STR];
  short* sQ=sQK; short* sK=sQK+64*STR;
  float* sF=(float*)sQK;
  int tid=threadIdx.x, blk=blockIdx.x;
  int b=blk>>10, n=blk&1023;
  int base=((n>>5)<<11) + ((n&31)<<3);
  const float* mT = (mbin[blk]>0.5f)? m1T : m0T;
  size_t plane=((size_t)b*64)<<16;
  const unsigned short* xw=xwb+(size_t)blk*4096;
  const unsigned short* vw=vwb+(size_t)blk*4096;
  // ---- P1: stage t = x*mask ; v1^T = (v*mask)^T ----
  for(int e=tid;e<4096;e+=256){
    int c=e>>6, tok=e&63;
    float mk=mT[e];
    sT[tok*STR+c]=f2bs(us2f(xw[e])*mk);
    sV1[c*STR+tok]=f2bs(us2f(vw[e])*mk);
  }
  __syncthreads();
  int lane=tid&63, wid=tid>>6;
  int pb=wid*16, lr=lane&15, lg=lane>>4;
  // ---- P2: q,k ----
  short8v ta[2];
  #pragma unroll
  for(int ks=0;ks<2;ks++) ta[ks]=*(const short8v*)&sT[(pb+lr)*STR + ks*32 + lg*8];
  #pragma unroll
  for(int nt=0;nt<4;nt++){
    float bqv=bq[nt*16+lr], bkv=bk[nt*16+lr];
    f32x4 qa={bqv,bqv,bqv,bqv}, ka={bkv,bkv,bkv,bkv};
    #pragma unroll
    for(int ks=0;ks<2;ks++){
      short8v wq=*(const short8v*)(Wqb + (nt*16+lr)*64 + ks*32 + lg*8);
      short8v wk=*(const short8v*)(Wkb + (nt*16+lr)*64 + ks*32 + lg*8);
      qa=__builtin_amdgcn_mfma_f32_16x16x32_bf16(ta[ks],wq,qa,0,0,0);
      ka=__builtin_amdgcn_mfma_f32_16x16x32_bf16(ta[ks],wk,ka,0,0,0);
    }
    #pragma unroll
    for(int r=0;r<4;r++){
      sQ[(pb+lg*4+r)*STR + nt*16+lr]=f2bs(qa[r]);
      sK[(pb+lg*4+r)*STR + nt*16+lr]=f2bs(ka[r]);
    }
  }
  __syncthreads();
  // ---- P3: s = q k^T ; softmax ----
  short8v qa2[2];
  #pragma unroll
  for(int ks=0;ks<2;ks++) qa2[ks]=*(const short8v*)&sQ[(pb+lr)*STR + ks*32 + lg*8];
  f32x4 sacc[4];
  #pragma unroll
  for(int nt=0;nt<4;nt++){
    f32x4 a={0.f,0.f,0.f,0.f};
    #pragma unroll
    for(int ks=0;ks<2;ks++){
      short8v kb=*(const short8v*)&sK[(nt*16+lr)*STR + ks*32 + lg*8];
      a=__builtin_amdgcn_mfma_f32_16x16x32_bf16(qa2[ks],kb,a,0,0,0);
    }
    sacc[nt]=a;
  }
  f32x4 pa[4];
  #pragma unroll
  for(int r=0;r<4;r++){
    float mx=fmaxf(fmaxf(sacc[0][r],sacc[1][r]),fmaxf(sacc[2][r],sacc[3][r]));
    #pragma unroll
    for(int m=1;m<16;m<<=1) mx=fmaxf(mx,__shfl_xor(mx,m));
    float e0=expf(sacc[0][r]-mx), e1=expf(sacc[1][r]-mx);
    float e2=expf(sacc[2][r]-mx), e3=expf(sacc[3][r]-mx);
    float sum=e0+e1+e2+e3;
    #pragma unroll
    for(int m=1;m<16;m<<=1) sum+=__shfl_xor(sum,m);
    float inv=1.f/sum;
    pa[0][r]=e0*inv; pa[1][r]=e1*inv; pa[2][r]=e2*inv; pa[3][r]=e3*inv;
  }
  #pragma unroll
  for(int nt=0;nt<4;nt++){
    #pragma unroll
    for(int r=0;r<4;r++)
      sT[(pb+lg*4+r)*STR + nt*16+lr]=f2bs(pa[nt][r]);
  }
  __syncthreads();
  // ---- P4: f = attn @ v1 -> sF ----
  short8v aa[2];
  #pragma unroll
  for(int ks=0;ks<2;ks++) aa[ks]=*(const short8v*)&sT[(pb+lr)*STR + ks*32 + lg*8];
  #pragma unroll
  for(int nt=0;nt<4;nt++){
    f32x4 f={0.f,0.f,0.f,0.f};
    #pragma unroll
    for(int ks=0;ks<2;ks++){
      short8v vb=*(const short8v*)&sV1[(nt*16+lr)*STR + ks*32 + lg*8];
      f=__builtin_amdgcn_mfma_f32_16x16x32_bf16(aa[ks],vb,f,0,0,0);
    }
    #pragma unroll
    for(int r=0;r<4;r++) sF[(pb+lg*4+r)*STRF + nt*16+lr]=f[r];
  }
  __syncthreads();
  // ---- P5: out = f + vs*(1-mask) ----
  const unsigned short* vsw=vswb+(size_t)blk*4096;
  for(int e=tid;e<4096;e+=256){
    int c=e>>6, tok=e&63;
    float f=sF[tok*STRF+c];
    float vs=us2f(vsw[e]);
    float mk=mT[e];
    int pix=base+((tok>>3)<<8)+(tok&7);
    img[plane+(((size_t)c)<<16)+pix]=f+vs*(1.f-mk);
  }
}

// ---------------- K_DWF: fused depthwise dil1 + dil2 + gelu*ca + img ----------------
__global__ __launch_bounds__(256) void k_dwfuse(const float* __restrict__ img,
    const float* __restrict__ dw1w, const float* __restrict__ dwb1,
    const float* __restrict__ dw2w, const float* __restrict__ dwb2,
    const float* __restrict__ ca, float* __restrict__ outb){
  __shared__ float sImg[38*40];
  __shared__ float sTmp[36*40];
  __shared__ float k1[9], k2[9];
  __shared__ float bb1, bb2, cav;
  int bid=blockIdx.x; int b=bid>>12, c=(bid>>6)&63, tile=bid&63;
  int y0=(tile>>3)*32, x0=(tile&7)*32;
  int tid=threadIdx.x;
  if(tid<9){ k1[tid]=dw1w[c*9+tid]; k2[tid]=dw2w[c*9+tid]; }
  if(tid==9)  bb1=dwb1[c];
  if(tid==10) bb2=dwb2[c];
  if(tid==11) cav=ca[b*64+c];
  const float* ip=img+(((size_t)(b*64+c))<<16);
  for(int i=tid;i<38*38;i+=256){
    int r=i/38, cl=i-r*38;
    int gy=y0-3+r, gx=x0-3+cl;
    sImg[r*40+cl]=((unsigned)gy<256u && (unsigned)gx<256u)? ip[(gy<<8)+gx] : 0.f;
  }
  __syncthreads();
  for(int i=tid;i<36*36;i+=256){
    int rt=i/36, ct=i-rt*36;
    int gy=y0-2+rt, gx=x0-2+ct;
    float t=0.f;
    if((unsigned)gy<256u && (unsigned)gx<256u){
      t=bb1;
      #pragma unroll
      for(int dy=0;dy<3;dy++)
        #pragma unroll
        for(int dx=0;dx<3;dx++)
          t+=sImg[(rt+dy)*40+(ct+dx)]*k1[dy*3+dx];
    }
    sTmp[rt*40+ct]=t;
  }
  __syncthreads();
  float* op=outb+(((size_t)(b*64+c))<<16);
  for(int k=0;k<4;k++){
    int j=tid+k*256;
    int ly=j>>5, lx=j&31;
    float cs=bb2;
    #pragma unroll
    for(int dy=0;dy<3;dy++)
      #pragma unroll
      for(int dx=0;dx<3;dx++)
        cs+=sTmp[(ly+2*dy)*40+(lx+2*dx)]*k2[dy*3+dx];
    float center=sImg[(ly+3)*40+(lx+3)];
    op[((y0+ly)<<8)+(x0+lx)]=geluf(cs)*cav+center;
  }
}

// ---------------- K_FDW: tiled ffn depthwise (E bf16) + gelu gate ----------------
__global__ __launch_bounds__(256) void k_ffn_dw_t(const unsigned short* __restrict__ E,
    const float* __restrict__ dwf, float* __restrict__ g){
  __shared__ unsigned short sE1[34*36];
  __shared__ unsigned short sE2[34*36];
  __shared__ float k1[9], k2[9];
  int bid=blockIdx.x; int b=bid>>12, c=(bid>>6)&63, tile=bid&63;
  int y0=(tile>>3)*32, x0=(tile&7)*32;
  int tid=threadIdx.x;
  if(tid<9){ k1[tid]=dwf[c*9+tid]; k2[tid]=dwf[(64+c)*9+tid]; }
  const unsigned short* p1=E+(((size_t)(b*128+c))<<16);
  const unsigned short* p2=E+(((size_t)(b*128+64+c))<<16);
  for(int i=tid;i<34*34;i+=256){
    int r=i/34, cl=i-r*34;
    int gy=y0-1+r, gx=x0-1+cl;
    bool in=((unsigned)gy<256u && (unsigned)gx<256u);
    int off=(gy<<8)+gx;
    sE1[r*36+cl]= in? p1[off]:0;
    sE2[r*36+cl]= in? p2[off]:0;
  }
  __syncthreads();
  float* op=g+(((size_t)(b*64+c))<<16);
  for(int k=0;k<4;k++){
    int j=tid+k*256;
    int ly=j>>5, lx=j&31;
    float a1=0.f, a2=0.f;
    #pragma unroll
    for(int dy=0;dy<3;dy++)
      #pragma unroll
      for(int dx=0;dx<3;dx++){
        int idx=(ly+dy)*36+(lx+dx);
        a1+=us2f(sE1[idx])*k1[dy*3+dx];
        a2+=us2f(sE2[idx])*k2[dy*3+dx];
      }
    op[((y0+ly)<<8)+(x0+lx)]=geluf(a1)*a2;
  }
}

extern "C" void kernel_launch(void* const* d_in, const int* in_sizes, int n_in,
                              void* d_out, int out_size, void* d_ws, size_t ws_size,
                              hipStream_t stream){
  (void)in_sizes; (void)n_in; (void)out_size; (void)ws_size;
  const void* x  = d_in[0];
  const void* Wm1= d_in[23];
  const void* Wm2= d_in[25];

  char* ws=(char*)d_ws;
  // Slot A [0,64MiB):    v (f32) -> E (bf16, 128ch)
  // Slot B [64,128MiB):  img -> res -> res2
  // Slot C [128,192MiB): xwb(32MiB)+vwb(32MiB) -> outb -> g
  // [192MiB..~211MiB):   small buffers
  // [220MiB,252MiB):     vswb (bf16) -> x1b (bf16)
  float* v    =(float*)(ws);
  unsigned short* E=(unsigned short*)(ws);
  float* img  =(float*)(ws+67108864);
  float* res  =(float*)(ws+67108864);
  float* res2 =(float*)(ws+67108864);
  unsigned short* xwb=(unsigned short*)(ws+134217728);
  unsigned short* vwb=(unsigned short*)(ws+134217728+33554432);
  float* outb =(float*)(ws+134217728);
  float* gbuf =(float*)(ws+134217728);
  unsigned short* vswb=(unsigned short*)(ws+230686720);
  unsigned short* x1b =(unsigned short*)(ws+230686720);
  char* sm = ws+201326592;
  float* x_    =(float*)(sm);              // 16 MB
  float* sa    =(float*)(sm+16777216);     // 1 MB
  float* xm    =(float*)(sm+17825792);     // 1 MB
  float* var   =(float*)(sm+18874368);     // 16 KB
  float* mbin  =(float*)(sm+18890752);     // 16 KB
  float* h0    =(float*)(sm+18907136);     // 8 KB
  float* h1    =(float*)(sm+18915328);     // 8 KB
  float* m0    =(float*)(sm+18923520);     // 16 KB
  float* m1    =(float*)(sm+18939904);     // 16 KB
  float* capart=(float*)(sm+18956288);     // 64 KB
  float* ca    =(float*)(sm+19021824);     // 1 KB
  int*   flag  =(int*)  (sm+19022848);     // 4 B
  float* wbuf  =(float*)(sm+19023872);     // ~161 KB
  short* Wqb   =(short*)(sm+19200000);     // 8 KB
  short* Wkb   =(short*)(sm+19208192);     // 8 KB
  float* m0T   =(float*)(sm+19216384);     // 16 KB
  float* m1T   =(float*)(sm+19232768);     // 16 KB

  static const int din_idx[31]={5,6,7,8,9,10,11,12,13,14,15,16,17,18,19,20,21,22,24,26,27,28,29,30,31,32,33,1,2,3,4};
  static const int szs[31]  ={4096,64,4096,64,4096,64,576,64,576,64,4096,64,1024,16,1024,16,16,16,2048,4096,1024,64,144,1,8192,1152,4096,64,64,64,64};
  CvtArgs ca_args;
  int off=0;
  int offs[31];
  for(int t=0;t<31;t++){
    ca_args.src[t]=d_in[din_idx[t]];
    ca_args.sz[t]=szs[t];
    ca_args.off[t]=off;
    offs[t]=off;
    off+=szs[t];
  }
  const float* Wv  =wbuf+offs[0];  const float* bv  =wbuf+offs[1];
  const float* Wq  =wbuf+offs[2];  const float* bq  =wbuf+offs[3];
  const float* Wk  =wbuf+offs[4];  const float* bk  =wbuf+offs[5];
  const float* dw1 =wbuf+offs[6];  const float* dwb1=wbuf+offs[7];
  const float* dw2 =wbuf+offs[8];  const float* dwb2=wbuf+offs[9];
  const float* Wo  =wbuf+offs[10]; const float* bo  =wbuf+offs[11];
  const float* W_in=wbuf+offs[12]; const float* b_in=wbuf+offs[13];
  const float* Wc  =wbuf+offs[14]; const float* bc  =wbuf+offs[15];
  const float* lnw =wbuf+offs[16]; const float* lnb =wbuf+offs[17];
  const float* bm1 =wbuf+offs[18]; const float* bm2 =wbuf+offs[19];
  const float* Wca =wbuf+offs[20]; const float* bca =wbuf+offs[21];
  const float* Wsa =wbuf+offs[22]; const float* bsa =wbuf+offs[23];
  const float* Wfi =wbuf+offs[24]; const float* dwf =wbuf+offs[25];
  const float* Wfo =wbuf+offs[26];
  const float* wn1 =wbuf+offs[27]; const float* bn1 =wbuf+offs[28];
  const float* wn2 =wbuf+offs[29]; const float* bn2 =wbuf+offs[30];

  hipLaunchKernelGGL(k_detect,   dim3(1),      dim3(256), 0, stream, x, flag);
  hipLaunchKernelGGL(k_cvt,      dim3(31),     dim3(256), 0, stream, ca_args, flag, wbuf);
  hipLaunchKernelGGL(k_w2b,      dim3(16),     dim3(256), 0, stream, Wq, Wk, Wqb, Wkb);
  hipLaunchKernelGGL(k_gemm32,   dim3(256,2),  dim3(256), 0, stream, x, Wv, bv, 1, v, flag, 0);
  hipLaunchKernelGGL(k_route,    dim3(512),    dim3(256), 0, stream, v, W_in, b_in, Wc, bc, lnw, lnb, x_, xm, capart);
  hipLaunchKernelGGL(k_sa,       dim3(1024),   dim3(256), 0, stream, x_, Wsa, bsa, sa);
  hipLaunchKernelGGL(k_var,      dim3(4096),   dim3(64),  0, stream, xm, var);
  hipLaunchKernelGGL(k_rank,     dim3(16),     dim3(256), 0, stream, var, mbin);
  hipLaunchKernelGGL(k_hvec,     dim3(2048),   dim3(64),  0, stream, Wm1, bm1, h0, h1, flag);
  hipLaunchKernelGGL(k_mask,     dim3(4096),   dim3(64),  0, stream, Wm2, bm2, h0, h1, m0, m1, m0T, m1T, flag);
  hipLaunchKernelGGL(k_ca,       dim3(4),      dim3(64),  0, stream, capart, Wca, bca, ca);
  hipLaunchKernelGGL(k_pack,     dim3(2048),   dim3(256), 0, stream, x, v, sa, flag, xwb, vwb, vswb);
  hipLaunchKernelGGL(k_attn_mfma,dim3(4096),   dim3(256), 0, stream, xwb, vwb, vswb, mbin, m0T, m1T, Wqb, bq, Wkb, bk, img);
  hipLaunchKernelGGL(k_dwfuse,   dim3(16384),  dim3(256), 0, stream, img, dw1, dwb1, dw2, dwb2, ca, outb);
  hipLaunchKernelGGL(k_gemm32,   dim3(256,2),  dim3(256), 0, stream, outb, Wo, bo, 1, res, flag, 1);
  hipLaunchKernelGGL(k_add_ln,   dim3(512),    dim3(256), 0, stream, res, x, wn1, bn1, (void*)x1b, flag, 0, 2);
  hipLaunchKernelGGL(k_gemm32_b, dim3(256,4),  dim3(256), 0, stream, x1b, Wfi, E);
  hipLaunchKernelGGL(k_ffn_dw_t, dim3(16384),  dim3(256), 0, stream, E, dwf, gbuf);
  hipLaunchKernelGGL(k_gemm32,   dim3(256,2),  dim3(256), 0, stream, gbuf, Wfo, wbuf, 0, res2, flag, 1);
  hipLaunchKernelGGL(k_add_ln,   dim3(512),    dim3(256), 0, stream, res2, x1b, wn2, bn2, d_out, flag, 2, 0);
}

// Round 7
// 730.631 us; speedup vs baseline: 2.5112x; 1.0654x over previous
//
#include <hip/hip_runtime.h>
#include <hip/hip_bf16.h>

typedef __hip_bfloat16 bf16;
typedef __attribute__((ext_vector_type(8))) short short8v;
typedef __attribute__((ext_vector_type(4))) float f32x4;

#define DEV static __device__ __forceinline__

DEV float b2f(bf16 h){ return __bfloat162float(h); }
DEV float us2f(unsigned short u){ unsigned v=((unsigned)u)<<16; float f; __builtin_memcpy(&f,&v,4); return f; }
DEV short f2bs(float f){ bf16 h=__float2bfloat16(f); short s; __builtin_memcpy(&s,&h,2); return s; }
DEV unsigned pack2(float a, float b){ return ((unsigned)(unsigned short)f2bs(b)<<16)|(unsigned short)f2bs(a); }
DEV float lrelu(float x){ return x >= 0.f ? x : 0.1f*x; }
DEV float geluf(float x){ return 0.5f*x*(1.f + erff(x*0.70710678118654752440f)); }
DEV float sigmoidf(float x){ return 1.f/(1.f + expf(-x)); }

// B=4, C=64, H=W=256, HW=65536, WS=8, N=1024 windows/batch, embed=4096

// ---------------- K0a: detect storage dtype ----------------
__global__ __launch_bounds__(256) void k_detect(const void* x, int* flag){
  __shared__ int cnt;
  if(threadIdx.x==0) cnt=0;
  __syncthreads();
  const unsigned short* up=(const unsigned short*)x;
  int c=0;
  for(int k=0;k<16;k++){
    unsigned short u=up[(threadIdx.x*16+k)*2];
    if(((u>>7)&0xFF)==0xFF) c++;
  }
  atomicAdd(&cnt,c);
  __syncthreads();
  if(threadIdx.x==0) flag[0] = (cnt>0) ? 1 : 0;  // 1 => f32 storage
}

// ---------------- K0b: convert small weights to f32 wbuf ----------------
struct CvtArgs { const void* src[31]; int sz[31]; int off[31]; };
__global__ __launch_bounds__(256) void k_cvt(CvtArgs a, const int* fl, float* wbuf){
  int t=blockIdx.x; int n=a.sz[t]; const void* s=a.src[t]; float* d=wbuf+a.off[t];
  if(fl[0]){
    const float* sp=(const float*)s;
    for(int i=threadIdx.x;i<n;i+=256) d[i]=sp[i];
  } else {
    const bf16* sp=(const bf16*)s;
    for(int i=threadIdx.x;i<n;i+=256) d[i]=b2f(sp[i]);
  }
}

// ---------------- K0c: Wq/Wk -> bf16 for MFMA ----------------
__global__ __launch_bounds__(256) void k_w2b(const float* __restrict__ wq, const float* __restrict__ wk,
    short* __restrict__ Wqb, short* __restrict__ Wkb){
  int i=blockIdx.x*256+threadIdx.x;
  if(i<4096){ Wqb[i]=f2bs(wq[i]); Wkb[i]=f2bs(wk[i]); }
}

// ---------------- K_G: 32-och x 4-pix 1x1-conv GEMM, f32 out (64 out ch) ----------------
__global__ __launch_bounds__(256) void k_gemm32(
    const void* __restrict__ in, const float* __restrict__ W,
    const float* __restrict__ bias, int has_bias,
    float* __restrict__ out, const int* __restrict__ fl, int force_f32){
  __shared__ float sW[2048]; __shared__ float sb[32];
  int tid=threadIdx.x, og=blockIdx.y;
  for(int i=tid;i<2048;i+=256) sW[i]=W[og*2048+i];
  if(tid<32) sb[tid]= has_bias ? bias[og*32+tid] : 0.f;
  __syncthreads();
  int g=blockIdx.x*1024+tid*4; int b=g>>16, p=g&65535;
  float4 a[32];
  #pragma unroll
  for(int o=0;o<32;o++){ float bv=sb[o]; a[o]=make_float4(bv,bv,bv,bv); }
  bool f32in = force_f32 || (fl[0]!=0);
  size_t base=(((size_t)b*64)<<16)+p;
  if(f32in){
    const float* ip=(const float*)in + base;
    for(int c=0;c<64;c++){
      float4 xv=*(const float4*)(ip + (((size_t)c)<<16));
      #pragma unroll
      for(int o=0;o<32;o++){ float w=sW[o*64+c];
        a[o].x+=w*xv.x; a[o].y+=w*xv.y; a[o].z+=w*xv.z; a[o].w+=w*xv.w; }
    }
  } else {
    const bf16* ip=(const bf16*)in + base;
    for(int c=0;c<64;c++){
      const bf16* q=ip+(((size_t)c)<<16);
      float4 xv=make_float4(b2f(q[0]),b2f(q[1]),b2f(q[2]),b2f(q[3]));
      #pragma unroll
      for(int o=0;o<32;o++){ float w=sW[o*64+c];
        a[o].x+=w*xv.x; a[o].y+=w*xv.y; a[o].z+=w*xv.z; a[o].w+=w*xv.w; }
    }
  }
  float* op=out + (((size_t)(b*64+og*32))<<16) + p;
  #pragma unroll
  for(int o=0;o<32;o++) *(float4*)(op+(((size_t)o)<<16))=a[o];
}

// ---------------- K_G2: 32-och x 4-pix GEMM, f32 in (x1) -> E bf16 (128 och) ----------------
__global__ __launch_bounds__(256) void k_gemm32_bo(
    const float* __restrict__ in, const float* __restrict__ W,
    unsigned short* __restrict__ E){
  __shared__ float sW[2048];
  int tid=threadIdx.x, og=blockIdx.y;
  for(int i=tid;i<2048;i+=256) sW[i]=W[og*2048+i];
  __syncthreads();
  int g=blockIdx.x*1024+tid*4; int b=g>>16, p=g&65535;
  float4 a[32];
  #pragma unroll
  for(int o=0;o<32;o++) a[o]=make_float4(0.f,0.f,0.f,0.f);
  const float* ip=in + (((size_t)b*64)<<16)+p;
  for(int c=0;c<64;c++){
    float4 xv=*(const float4*)(ip + (((size_t)c)<<16));
    #pragma unroll
    for(int o=0;o<32;o++){ float w=sW[o*64+c];
      a[o].x+=w*xv.x; a[o].y+=w*xv.y; a[o].z+=w*xv.z; a[o].w+=w*xv.w; }
  }
  unsigned short* op=E + (((size_t)(b*128+og*32))<<16) + p;
  #pragma unroll
  for(int o=0;o<32;o++){
    uint2 u; u.x=pack2(a[o].x,a[o].y); u.y=pack2(a[o].z,a[o].w);
    *(uint2*)(op+(((size_t)o)<<16))=u;
  }
}

// ---------------- K_LN: out = LN(res + base), 2 pix/thread ----------------
// base_mode / out_mode: 0 = follow flag (f32 if fl), 1 = force f32, 2 = force bf16
// NOTE: out may alias res (all loads complete before stores by dataflow).
__global__ __launch_bounds__(256) void k_add_ln(
    const float* __restrict__ res, const void* __restrict__ base,
    const float* __restrict__ w, const float* __restrict__ bb,
    void* __restrict__ out,
    const int* __restrict__ fl, int base_mode, int out_mode){
  __shared__ float sw[64], sb[64];
  int tid=threadIdx.x;
  if(tid<64){ sw[tid]=w[tid]; sb[tid]=bb[tid]; }
  __syncthreads();
  int g=blockIdx.x*512+tid*2; int b=g>>16, p=g&65535;
  size_t off=(((size_t)b*64)<<16)+p;
  float2 r[64];
  bool bf32 = (base_mode==1) || (base_mode==0 && fl[0]);
  const float* rp=res+off;
  if(bf32){
    const float* xp=(const float*)base+off;
    #pragma unroll
    for(int o=0;o<64;o++){
      float2 rv=*(const float2*)(rp+(((size_t)o)<<16));
      float2 xv=*(const float2*)(xp+(((size_t)o)<<16));
      r[o].x=rv.x+xv.x; r[o].y=rv.y+xv.y;
    }
  } else {
    const unsigned short* xp=(const unsigned short*)base+off;
    #pragma unroll
    for(int o=0;o<64;o++){
      float2 rv=*(const float2*)(rp+(((size_t)o)<<16));
      unsigned u=*(const unsigned*)(xp+(((size_t)o)<<16));
      r[o].x=rv.x+us2f(u&0xffff); r[o].y=rv.y+us2f(u>>16);
    }
  }
  float m0=0.f,m1=0.f;
  #pragma unroll
  for(int o=0;o<64;o++){ m0+=r[o].x; m1+=r[o].y; }
  m0*=(1.f/64.f); m1*=(1.f/64.f);
  float v0=0.f,v1=0.f;
  #pragma unroll
  for(int o=0;o<64;o++){ float d0=r[o].x-m0, d1=r[o].y-m1; v0+=d0*d0; v1+=d1*d1; }
  v0*=(1.f/64.f); v1*=(1.f/64.f);
  float i0=1.f/sqrtf(v0+1e-6f), i1=1.f/sqrtf(v1+1e-6f);
  bool of32 = (out_mode==1) || (out_mode==0 && fl[0]);
  if(of32){
    float* op=(float*)out+off;
    #pragma unroll
    for(int o=0;o<64;o++){
      float2 st; st.x=sw[o]*((r[o].x-m0)*i0)+sb[o]; st.y=sw[o]*((r[o].y-m1)*i1)+sb[o];
      *(float2*)(op+(((size_t)o)<<16))=st;
    }
  } else {
    unsigned short* op=(unsigned short*)out+off;
    #pragma unroll
    for(int o=0;o<64;o++){
      float s0=sw[o]*((r[o].x-m0)*i0)+sb[o], s1=sw[o]*((r[o].y-m1)*i1)+sb[o];
      *(unsigned*)(op+(((size_t)o)<<16))=pack2(s0,s1);
    }
  }
}

// ---------------- K2: route (2 pix/thread) ----------------
__global__ __launch_bounds__(256) void k_route(const float* __restrict__ v,
    const float* __restrict__ W_in, const float* __restrict__ b_in,
    const float* __restrict__ Wc, const float* __restrict__ bc,
    const float* __restrict__ lnw, const float* __restrict__ lnb,
    float* __restrict__ x_, float* __restrict__ xm, float* __restrict__ capart){
  __shared__ float wA[1024], wB[1024], sba[16], sbb[16], slw[16], slb[16];
  __shared__ float sred[4][16];
  int tid=threadIdx.x;
  for(int i=tid;i<1024;i+=256){ wA[i]=W_in[i]; wB[i]=Wc[i]; }
  if(tid<16){ sba[tid]=b_in[tid]; sbb[tid]=bc[tid]; slw[tid]=lnw[tid]; slb[tid]=lnb[tid]; }
  __syncthreads();
  int g=blockIdx.x*512+tid*2; int b=g>>16, p=g&65535;
  float2 aA[16], aB[16];
  #pragma unroll
  for(int i=0;i<16;i++){ aA[i]=make_float2(sba[i],sba[i]); aB[i]=make_float2(sbb[i],sbb[i]); }
  const float* vp=v+(((size_t)b*64)<<16)+p;
  for(int c=0;c<64;c++){
    float2 vv=*(const float2*)(vp+(((size_t)c)<<16));
    #pragma unroll
    for(int i=0;i<16;i++){
      float wa=wA[(i<<6)+c], wb=wB[(i<<6)+c];
      aA[i].x+=wa*vv.x; aA[i].y+=wa*vv.y;
      aB[i].x+=wb*vv.x; aB[i].y+=wb*vv.y;
    }
  }
  float s0=0.f,s1=0.f;
  #pragma unroll
  for(int i=0;i<16;i++){ aA[i].x=lrelu(aA[i].x); aA[i].y=lrelu(aA[i].y); s0+=aA[i].x; s1+=aA[i].y; }
  float2 xmst; xmst.x=s0*(1.f/16.f); xmst.y=s1*(1.f/16.f);
  *(float2*)(xm+g)=xmst;
  float u0=0.f,u1=0.f;
  #pragma unroll
  for(int i=0;i<16;i++){ u0+=aB[i].x; u1+=aB[i].y; }
  u0*=(1.f/16.f); u1*=(1.f/16.f);
  float q0=0.f,q1=0.f;
  #pragma unroll
  for(int i=0;i<16;i++){ float d0=aB[i].x-u0, d1=aB[i].y-u1; q0+=d0*d0; q1+=d1*d1; }
  q0*=(1.f/16.f); q1*=(1.f/16.f);
  float i0=1.f/sqrtf(q0+1e-6f), i1=1.f/sqrtf(q1+1e-6f);
  float red[16];
  float* xp=x_+(((size_t)b*16)<<16)+p;
  #pragma unroll
  for(int i=0;i<16;i++){
    float xv0=lrelu(slw[i]*((aB[i].x-u0)*i0)+slb[i]);
    float xv1=lrelu(slw[i]*((aB[i].y-u1)*i1)+slb[i]);
    float2 st; st.x=xv0; st.y=xv1;
    *(float2*)(xp+(((size_t)i)<<16))=st;
    red[i]=xv0+xv1;
  }
  int lane=tid&63, wid=tid>>6;
  #pragma unroll
  for(int i=0;i<16;i++){
    float val=red[i];
    for(int m=32;m>0;m>>=1) val+=__shfl_xor(val,m);
    if(lane==0) sred[wid][i]=val;
  }
  __syncthreads();
  if(tid<16) capart[blockIdx.x*16+tid]=sred[0][tid]+sred[1][tid]+sred[2][tid]+sred[3][tid];
}

// ---------------- K3: sa = sigmoid(conv3x3(x_)) ----------------
__global__ __launch_bounds__(256) void k_sa(const float* __restrict__ x_,
    const float* __restrict__ Wsa, const float* __restrict__ bsa, float* __restrict__ sa){
  __shared__ float w[144]; __shared__ float bb;
  int tid=threadIdx.x;
  if(tid<144) w[tid]=Wsa[tid];
  if(tid==0) bb=bsa[0];
  __syncthreads();
  int pix=blockIdx.x*256+tid; int b=pix>>16, p=pix&65535;
  int y=p>>8, xx=p&255;
  float acc=bb;
  #pragma unroll
  for(int i=0;i<16;i++){
    const float* pl=x_+(((size_t)(b*16+i))<<16);
    #pragma unroll
    for(int ky=0;ky<3;ky++){
      int yy=y+ky-1;
      if((unsigned)yy<256u){
        #pragma unroll
        for(int kx=0;kx<3;kx++){
          int x2=xx+kx-1;
          if((unsigned)x2<256u) acc+=pl[(yy<<8)+x2]*w[i*9+ky*3+kx];
        }
      }
    }
  }
  sa[pix]=sigmoidf(acc);
}

// ---------------- K4: per-window variance (ddof=1) ----------------
__global__ __launch_bounds__(64) void k_var(const float* __restrict__ xm, float* __restrict__ var){
  int blk=blockIdx.x, tid=threadIdx.x;
  int b=blk>>10, n=blk&1023;
  int pix=((n>>5)<<11) + ((n&31)<<3) + ((tid>>3)<<8) + (tid&7);
  float val=xm[(b<<16)+pix];
  float s=val;
  for(int m=32;m>0;m>>=1) s+=__shfl_xor(s,m);
  float mean=s*(1.f/64.f);
  float d=val-mean; float q=d*d;
  for(int m=32;m>0;m>>=1) q+=__shfl_xor(q,m);
  if(tid==0) var[blk]=q*(1.f/63.f);
}

// ---------------- K5: rank -> mbin ----------------
__global__ __launch_bounds__(256) void k_rank(const float* __restrict__ var, float* __restrict__ mbin){
  __shared__ float va[1024];
  int bid=blockIdx.x; int b=bid>>2, seg=bid&3;
  int tid=threadIdx.x;
  for(int i=tid;i<1024;i+=256) va[i]=var[(b<<10)+i];
  __syncthreads();
  int n=seg*256+tid;
  float vn=va[n]; int r=0;
  for(int m=0;m<1024;m++){ float vm=va[m]; r += (vm<vn) || (vm==vn && m<n); }
  mbin[(b<<10)+n] = (r<512)?0.f:1.f;
}

// ---------------- K6: h0/h1 from Wm1 rowsums ----------------
__global__ __launch_bounds__(64) void k_hvec(const void* __restrict__ Wm1, const float* __restrict__ bm1,
    float* __restrict__ h0, float* __restrict__ h1, const int* __restrict__ fl){
  int j=blockIdx.x, tid=threadIdx.x;
  float s=0.f;
  if(fl[0]){
    const float* row=(const float*)Wm1+((size_t)j<<12);
    for(int k=tid;k<4096;k+=64) s+=row[k];
  } else {
    const bf16* row=(const bf16*)Wm1+((size_t)j<<12);
    for(int k=tid;k<4096;k+=64) s+=b2f(row[k]);
  }
  for(int m=32;m>0;m>>=1) s+=__shfl_xor(s,m);
  if(tid==0){ float bb=bm1[j]; h0[j]=lrelu(bb); h1[j]=lrelu(bb+s); }
}

// ---------------- K7: mask vectors (+ transposed copies) ----------------
__global__ __launch_bounds__(64) void k_mask(const void* __restrict__ Wm2, const float* __restrict__ bm2,
    const float* __restrict__ h0, const float* __restrict__ h1,
    float* __restrict__ m0, float* __restrict__ m1,
    float* __restrict__ m0T, float* __restrict__ m1T, const int* __restrict__ fl){
  int e=blockIdx.x, tid=threadIdx.x;
  float p0=0.f,p1=0.f;
  if(fl[0]){
    const float* row=(const float*)Wm2+((size_t)e<<11);
    for(int j=tid;j<2048;j+=64){ float w=row[j]; p0+=w*h0[j]; p1+=w*h1[j]; }
  } else {
    const bf16* row=(const bf16*)Wm2+((size_t)e<<11);
    for(int j=tid;j<2048;j+=64){ float w=b2f(row[j]); p0+=w*h0[j]; p1+=w*h1[j]; }
  }
  for(int m=32;m>0;m>>=1){ p0+=__shfl_xor(p0,m); p1+=__shfl_xor(p1,m); }
  if(tid==0){
    float bb=bm2[e]; float v0=p0+bb, v1=p1+bb;
    m0[e]=v0; m1[e]=v1;
    int te=(e&63)*64+(e>>6);
    m0T[te]=v0; m1T[te]=v1;
  }
}

// ---------------- K8: ca = sigmoid(Wca * mean(x_) + bca) ----------------
__global__ __launch_bounds__(64) void k_ca(const float* __restrict__ capart,
    const float* __restrict__ Wca, const float* __restrict__ bca, float* __restrict__ ca){
  __shared__ float m[16];
  int b=blockIdx.x, tid=threadIdx.x;
  if(tid<16){
    float s=0.f;
    for(int blk=0;blk<128;blk++) s+=capart[((b*128)+blk)*16+tid];
    m[tid]=s*(1.f/65536.f);
  }
  __syncthreads();
  float a=bca[tid];
  #pragma unroll
  for(int i=0;i<16;i++) a+=Wca[(tid<<4)+i]*m[i];
  ca[(b<<6)+tid]=sigmoidf(a);
}

// ---------------- K_PACK: x, v, v*sa -> window-major bf16 ----------------
__global__ __launch_bounds__(256) void k_pack(const void* __restrict__ x, const float* __restrict__ v,
    const float* __restrict__ sa, const int* __restrict__ fl,
    unsigned short* __restrict__ xwb, unsigned short* __restrict__ vwb, unsigned short* __restrict__ vswb){
  int wp=blockIdx.x; int b=wp>>9, np=wp&511;
  int n0=np*2;
  int base=((n0>>5)<<11)+((n0&31)<<3);
  int t=threadIdx.x; int c0=t>>3, row=t&7;
  int isf32=fl[0];
  for(int h=0;h<2;h++){
    int ch=c0+h*32;
    size_t gb=(((size_t)(b*64+ch))<<16) + base + row*256;
    float xv[16], vv[16], sv[16];
    if(isf32){
      const float* xp=(const float*)x+gb;
      #pragma unroll
      for(int i=0;i<16;i++) xv[i]=xp[i];
    } else {
      const bf16* xp=(const bf16*)x+gb;
      #pragma unroll
      for(int i=0;i<16;i++) xv[i]=b2f(xp[i]);
    }
    const float* vp=v+gb;
    const float* sp=sa+(((size_t)b)<<16)+base+row*256;
    #pragma unroll
    for(int i=0;i<16;i++){ vv[i]=vp[i]; sv[i]=sp[i]; }
    size_t o0=((size_t)(b*1024+n0)*64+ch)*64 + row*8;
    #pragma unroll
    for(int wnd=0;wnd<2;wnd++){
      size_t oo=o0+(size_t)wnd*4096;
      int s=wnd*8;
      uint4 ux, uv, us;
      ux.x=pack2(xv[s+0],xv[s+1]); ux.y=pack2(xv[s+2],xv[s+3]);
      ux.z=pack2(xv[s+4],xv[s+5]); ux.w=pack2(xv[s+6],xv[s+7]);
      uv.x=pack2(vv[s+0],vv[s+1]); uv.y=pack2(vv[s+2],vv[s+3]);
      uv.z=pack2(vv[s+4],vv[s+5]); uv.w=pack2(vv[s+6],vv[s+7]);
      us.x=pack2(vv[s+0]*sv[s+0],vv[s+1]*sv[s+1]); us.y=pack2(vv[s+2]*sv[s+2],vv[s+3]*sv[s+3]);
      us.z=pack2(vv[s+4]*sv[s+4],vv[s+5]*sv[s+5]); us.w=pack2(vv[s+6]*sv[s+6],vv[s+7]*sv[s+7]);
      *(uint4*)(xwb+oo)=ux; *(uint4*)(vwb+oo)=uv; *(uint4*)(vswb+oo)=us;
    }
  }
}

// ---------------- K9: windowed attention via MFMA -> img ----------------
#define STR 72
#define STRF 65
__global__ __launch_bounds__(256,4) void k_attn_mfma(
    const unsigned short* __restrict__ xwb, const unsigned short* __restrict__ vwb,
    const unsigned short* __restrict__ vswb, const float* __restrict__ mbin,
    const float* __restrict__ m0T, const float* __restrict__ m1T,
    const short* __restrict__ Wqb, const float* __restrict__ bq,
    const short* __restrict__ Wkb, const float* __restrict__ bk,
    float* __restrict__ img){
  __shared__ short sT[64*STR];
  __shared__ short sQK[2*64*STR];
  __shared__ short sV1[64*STR];
  short* sQ=sQK; short* sK=sQK+64*STR;
  float* sF=(float*)sQK;
  int tid=threadIdx.x, blk=blockIdx.x;
  int b=blk>>10, n=blk&1023;
  int base=((n>>5)<<11) + ((n&31)<<3);
  const float* mT = (mbin[blk]>0.5f)? m1T : m0T;
  size_t plane=((size_t)b*64)<<16;
  const unsigned short* xw=xwb+(size_t)blk*4096;
  const unsigned short* vw=vwb+(size_t)blk*4096;
  for(int e=tid;e<4096;e+=256){
    int c=e>>6, tok=e&63;
    float mk=mT[e];
    sT[tok*STR+c]=f2bs(us2f(xw[e])*mk);
    sV1[c*STR+tok]=f2bs(us2f(vw[e])*mk);
  }
  __syncthreads();
  int lane=tid&63, wid=tid>>6;
  int pb=wid*16, lr=lane&15, lg=lane>>4;
  short8v ta[2];
  #pragma unroll
  for(int ks=0;ks<2;ks++) ta[ks]=*(const short8v*)&sT[(pb+lr)*STR + ks*32 + lg*8];
  #pragma unroll
  for(int nt=0;nt<4;nt++){
    float bqv=bq[nt*16+lr], bkv=bk[nt*16+lr];
    f32x4 qa={bqv,bqv,bqv,bqv}, ka={bkv,bkv,bkv,bkv};
    #pragma unroll
    for(int ks=0;ks<2;ks++){
      short8v wq=*(const short8v*)(Wqb + (nt*16+lr)*64 + ks*32 + lg*8);
      short8v wk=*(const short8v*)(Wkb + (nt*16+lr)*64 + ks*32 + lg*8);
      qa=__builtin_amdgcn_mfma_f32_16x16x32_bf16(ta[ks],wq,qa,0,0,0);
      ka=__builtin_amdgcn_mfma_f32_16x16x32_bf16(ta[ks],wk,ka,0,0,0);
    }
    #pragma unroll
    for(int r=0;r<4;r++){
      sQ[(pb+lg*4+r)*STR + nt*16+lr]=f2bs(qa[r]);
      sK[(pb+lg*4+r)*STR + nt*16+lr]=f2bs(ka[r]);
    }
  }
  __syncthreads();
  short8v qa2[2];
  #pragma unroll
  for(int ks=0;ks<2;ks++) qa2[ks]=*(const short8v*)&sQ[(pb+lr)*STR + ks*32 + lg*8];
  f32x4 sacc[4];
  #pragma unroll
  for(int nt=0;nt<4;nt++){
    f32x4 a={0.f,0.f,0.f,0.f};
    #pragma unroll
    for(int ks=0;ks<2;ks++){
      short8v kb=*(const short8v*)&sK[(nt*16+lr)*STR + ks*32 + lg*8];
      a=__builtin_amdgcn_mfma_f32_16x16x32_bf16(qa2[ks],kb,a,0,0,0);
    }
    sacc[nt]=a;
  }
  f32x4 pa[4];
  #pragma unroll
  for(int r=0;r<4;r++){
    float mx=fmaxf(fmaxf(sacc[0][r],sacc[1][r]),fmaxf(sacc[2][r],sacc[3][r]));
    #pragma unroll
    for(int m=1;m<16;m<<=1) mx=fmaxf(mx,__shfl_xor(mx,m));
    float e0=expf(sacc[0][r]-mx), e1=expf(sacc[1][r]-mx);
    float e2=expf(sacc[2][r]-mx), e3=expf(sacc[3][r]-mx);
    float sum=e0+e1+e2+e3;
    #pragma unroll
    for(int m=1;m<16;m<<=1) sum+=__shfl_xor(sum,m);
    float inv=1.f/sum;
    pa[0][r]=e0*inv; pa[1][r]=e1*inv; pa[2][r]=e2*inv; pa[3][r]=e3*inv;
  }
  #pragma unroll
  for(int nt=0;nt<4;nt++){
    #pragma unroll
    for(int r=0;r<4;r++)
      sT[(pb+lg*4+r)*STR + nt*16+lr]=f2bs(pa[nt][r]);
  }
  __syncthreads();
  short8v aa[2];
  #pragma unroll
  for(int ks=0;ks<2;ks++) aa[ks]=*(const short8v*)&sT[(pb+lr)*STR + ks*32 + lg*8];
  #pragma unroll
  for(int nt=0;nt<4;nt++){
    f32x4 f={0.f,0.f,0.f,0.f};
    #pragma unroll
    for(int ks=0;ks<2;ks++){
      short8v vb=*(const short8v*)&sV1[(nt*16+lr)*STR + ks*32 + lg*8];
      f=__builtin_amdgcn_mfma_f32_16x16x32_bf16(aa[ks],vb,f,0,0,0);
    }
    #pragma unroll
    for(int r=0;r<4;r++) sF[(pb+lg*4+r)*STRF + nt*16+lr]=f[r];
  }
  __syncthreads();
  const unsigned short* vsw=vswb+(size_t)blk*4096;
  for(int e=tid;e<4096;e+=256){
    int c=e>>6, tok=e&63;
    float f=sF[tok*STRF+c];
    float vs=us2f(vsw[e]);
    float mk=mT[e];
    int pix=base+((tok>>3)<<8)+(tok&7);
    img[plane+(((size_t)c)<<16)+pix]=f+vs*(1.f-mk);
  }
}

// ---------------- K_DWF: fused depthwise dil1+dil2+gelu*ca+img, row-strip tiles ----------------
// block = (b, c, 16-row strip). LDS rows span full width, zero-padded halos.
#define IST 264
__global__ __launch_bounds__(256) void k_dwfuse(const float* __restrict__ img,
    const float* __restrict__ dw1w, const float* __restrict__ dwb1,
    const float* __restrict__ dw2w, const float* __restrict__ dwb2,
    const float* __restrict__ ca, float* __restrict__ outb){
  __shared__ float sImg[22*IST];   // rows y0-3..y0+18, cols -3..258 (LDS col = gx+3)
  __shared__ float sTmp[20*IST];   // rows y0-2..y0+17, cols -2..257 (LDS col = tc+2)
  __shared__ float k1[9], k2[9];
  __shared__ float bb1, bb2, cav;
  int bid=blockIdx.x; int b=bid>>10, c=(bid>>4)&63, sy=bid&15;
  int y0=sy*16;
  int tid=threadIdx.x;
  if(tid<9){ k1[tid]=dw1w[c*9+tid]; k2[tid]=dw2w[c*9+tid]; }
  if(tid==9)  bb1=dwb1[c];
  if(tid==10) bb2=dwb2[c];
  if(tid==11) cav=ca[b*64+c];
  const float* ip=img+(((size_t)(b*64+c))<<16);
  for(int i=tid;i<22*IST;i+=256){
    int r=i/IST, cl=i-r*IST;
    int gy=y0-3+r, gx=cl-3;
    float v=0.f;
    if(cl<262 && (unsigned)gy<256u && (unsigned)gx<256u) v=ip[(gy<<8)+gx];
    sImg[i]=v;
  }
  __syncthreads();
  for(int i=tid;i<20*IST;i+=256){
    int r=i/IST, cl=i-r*IST;
    float t=0.f;
    if(cl<260){
      int ty=y0-2+r, tc=cl-2;
      if((unsigned)ty<256u && (unsigned)tc<256u){
        t=bb1;
        #pragma unroll
        for(int dy=0;dy<3;dy++)
          #pragma unroll
          for(int dx=0;dx<3;dx++)
            t+=sImg[(r+dy)*IST+(cl+dx)]*k1[dy*3+dx];
      }
    }
    sTmp[i]=t;
  }
  __syncthreads();
  float* op=outb+(((size_t)(b*64+c))<<16);
  int lx=tid;
  #pragma unroll 4
  for(int ly=0;ly<16;ly++){
    float cs=bb2;
    #pragma unroll
    for(int dy=0;dy<3;dy++)
      #pragma unroll
      for(int dx=0;dx<3;dx++)
        cs+=sTmp[(ly+2*dy)*IST + lx+2*dx]*k2[dy*3+dx];
    float center=sImg[(ly+3)*IST + lx+3];
    op[((y0+ly)<<8)+lx]=geluf(cs)*cav+center;
  }
}

// ---------------- K_FDW: ffn depthwise (E bf16) + gelu gate, row-strip tiles ----------------
#define EST 260
__global__ __launch_bounds__(256) void k_ffn_dw_t(const unsigned short* __restrict__ E,
    const float* __restrict__ dwf, float* __restrict__ g){
  __shared__ unsigned short sE1[18*EST];  // rows y0-1..y0+16, LDS col = gx+2 (cols 0,1,258,259 = halo)
  __shared__ unsigned short sE2[18*EST];
  __shared__ float k1[9], k2[9];
  int bid=blockIdx.x; int b=bid>>10, c=(bid>>4)&63, sy=bid&15;
  int y0=sy*16;
  int tid=threadIdx.x;
  if(tid<9){ k1[tid]=dwf[c*9+tid]; k2[tid]=dwf[(64+c)*9+tid]; }
  // zero halo cols (0,1,258,259) of both planes
  if(tid<144){
    int pl=tid/72; int rem=tid-pl*72; int rr=rem>>2; int cc=rem&3;
    int col=(cc<2)? cc : (256+cc);
    if(pl==0) sE1[rr*EST+col]=0; else sE2[rr*EST+col]=0;
  }
  const unsigned short* p1=E+(((size_t)(b*128+c))<<16);
  const unsigned short* p2=E+(((size_t)(b*128+64+c))<<16);
  int half=tid>>7, t2=tid&127;
  const unsigned short* pp = half? p2 : p1;
  for(int r=0;r<18;r++){
    int gy=y0-1+r;
    unsigned val=0;
    if((unsigned)gy<256u) val=*(const unsigned*)(pp+(gy<<8)+t2*2);
    unsigned short* dst = half? sE2 : sE1;
    *(unsigned*)(dst + r*EST + 2 + t2*2) = val;
  }
  __syncthreads();
  float* op=g+(((size_t)(b*64+c))<<16);
  int lx=tid;
  #pragma unroll 4
  for(int ly=0;ly<16;ly++){
    float a1=0.f, a2=0.f;
    #pragma unroll
    for(int dy=0;dy<3;dy++)
      #pragma unroll
      for(int dx=0;dx<3;dx++){
        int idx=(ly+dy)*EST + lx+dx+1;
        a1+=us2f(sE1[idx])*k1[dy*3+dx];
        a2+=us2f(sE2[idx])*k2[dy*3+dx];
      }
    op[((y0+ly)<<8)+lx]=geluf(a1)*a2;
  }
}

extern "C" void kernel_launch(void* const* d_in, const int* in_sizes, int n_in,
                              void* d_out, int out_size, void* d_ws, size_t ws_size,
                              hipStream_t stream){
  (void)in_sizes; (void)n_in; (void)out_size; (void)ws_size;
  const void* x  = d_in[0];
  const void* Wm1= d_in[23];
  const void* Wm2= d_in[25];

  char* ws=(char*)d_ws;
  // Slot A [0,64MiB):    v (f32) -> E (bf16, 128ch) -> res2 (f32)
  // Slot B [64,128MiB):  img -> res -> x1 (in-place f32)
  // Slot C [128,192MiB): xwb(32MiB)+vwb(32MiB) -> outb -> gbuf
  // [192MiB..~211MiB):   small buffers
  // [220MiB,252MiB):     vswb (bf16)
  float* v    =(float*)(ws);
  unsigned short* E=(unsigned short*)(ws);
  float* res2 =(float*)(ws);
  float* img  =(float*)(ws+67108864);
  float* res  =(float*)(ws+67108864);
  float* x1   =(float*)(ws+67108864);
  unsigned short* xwb=(unsigned short*)(ws+134217728);
  unsigned short* vwb=(unsigned short*)(ws+134217728+33554432);
  float* outb =(float*)(ws+134217728);
  float* gbuf =(float*)(ws+134217728);
  unsigned short* vswb=(unsigned short*)(ws+230686720);
  char* sm = ws+201326592;
  float* x_    =(float*)(sm);              // 16 MB
  float* sa    =(float*)(sm+16777216);     // 1 MB
  float* xm    =(float*)(sm+17825792);     // 1 MB
  float* var   =(float*)(sm+18874368);     // 16 KB
  float* mbin  =(float*)(sm+18890752);     // 16 KB
  float* h0    =(float*)(sm+18907136);     // 8 KB
  float* h1    =(float*)(sm+18915328);     // 8 KB
  float* m0    =(float*)(sm+18923520);     // 16 KB
  float* m1    =(float*)(sm+18939904);     // 16 KB
  float* capart=(float*)(sm+18956288);     // 64 KB
  float* ca    =(float*)(sm+19021824);     // 1 KB
  int*   flag  =(int*)  (sm+19022848);     // 4 B
  float* wbuf  =(float*)(sm+19023872);     // ~161 KB
  short* Wqb   =(short*)(sm+19200000);     // 8 KB
  short* Wkb   =(short*)(sm+19208192);     // 8 KB
  float* m0T   =(float*)(sm+19216384);     // 16 KB
  float* m1T   =(float*)(sm+19232768);     // 16 KB

  static const int din_idx[31]={5,6,7,8,9,10,11,12,13,14,15,16,17,18,19,20,21,22,24,26,27,28,29,30,31,32,33,1,2,3,4};
  static const int szs[31]  ={4096,64,4096,64,4096,64,576,64,576,64,4096,64,1024,16,1024,16,16,16,2048,4096,1024,64,144,1,8192,1152,4096,64,64,64,64};
  CvtArgs ca_args;
  int off=0;
  int offs[31];
  for(int t=0;t<31;t++){
    ca_args.src[t]=d_in[din_idx[t]];
    ca_args.sz[t]=szs[t];
    ca_args.off[t]=off;
    offs[t]=off;
    off+=szs[t];
  }
  const float* Wv  =wbuf+offs[0];  const float* bv  =wbuf+offs[1];
  const float* Wq  =wbuf+offs[2];  const float* bq  =wbuf+offs[3];
  const float* Wk  =wbuf+offs[4];  const float* bk  =wbuf+offs[5];
  const float* dw1 =wbuf+offs[6];  const float* dwb1=wbuf+offs[7];
  const float* dw2 =wbuf+offs[8];  const float* dwb2=wbuf+offs[9];
  const float* Wo  =wbuf+offs[10]; const float* bo  =wbuf+offs[11];
  const float* W_in=wbuf+offs[12]; const float* b_in=wbuf+offs[13];
  const float* Wc  =wbuf+offs[14]; const float* bc  =wbuf+offs[15];
  const float* lnw =wbuf+offs[16]; const float* lnb =wbuf+offs[17];
  const float* bm1 =wbuf+offs[18]; const float* bm2 =wbuf+offs[19];
  const float* Wca =wbuf+offs[20]; const float* bca =wbuf+offs[21];
  const float* Wsa =wbuf+offs[22]; const float* bsa =wbuf+offs[23];
  const float* Wfi =wbuf+offs[24]; const float* dwf =wbuf+offs[25];
  const float* Wfo =wbuf+offs[26];
  const float* wn1 =wbuf+offs[27]; const float* bn1 =wbuf+offs[28];
  const float* wn2 =wbuf+offs[29]; const float* bn2 =wbuf+offs[30];

  hipLaunchKernelGGL(k_detect,   dim3(1),      dim3(256), 0, stream, x, flag);
  hipLaunchKernelGGL(k_cvt,      dim3(31),     dim3(256), 0, stream, ca_args, flag, wbuf);
  hipLaunchKernelGGL(k_w2b,      dim3(16),     dim3(256), 0, stream, Wq, Wk, Wqb, Wkb);
  hipLaunchKernelGGL(k_gemm32,   dim3(256,2),  dim3(256), 0, stream, x, Wv, bv, 1, v, flag, 0);
  hipLaunchKernelGGL(k_route,    dim3(512),    dim3(256), 0, stream, v, W_in, b_in, Wc, bc, lnw, lnb, x_, xm, capart);
  hipLaunchKernelGGL(k_sa,       dim3(1024),   dim3(256), 0, stream, x_, Wsa, bsa, sa);
  hipLaunchKernelGGL(k_var,      dim3(4096),   dim3(64),  0, stream, xm, var);
  hipLaunchKernelGGL(k_rank,     dim3(16),     dim3(256), 0, stream, var, mbin);
  hipLaunchKernelGGL(k_hvec,     dim3(2048),   dim3(64),  0, stream, Wm1, bm1, h0, h1, flag);
  hipLaunchKernelGGL(k_mask,     dim3(4096),   dim3(64),  0, stream, Wm2, bm2, h0, h1, m0, m1, m0T, m1T, flag);
  hipLaunchKernelGGL(k_ca,       dim3(4),      dim3(64),  0, stream, capart, Wca, bca, ca);
  hipLaunchKernelGGL(k_pack,     dim3(2048),   dim3(256), 0, stream, x, v, sa, flag, xwb, vwb, vswb);
  hipLaunchKernelGGL(k_attn_mfma,dim3(4096),   dim3(256), 0, stream, xwb, vwb, vswb, mbin, m0T, m1T, Wqb, bq, Wkb, bk, img);
  hipLaunchKernelGGL(k_dwfuse,   dim3(4096),   dim3(256), 0, stream, img, dw1, dwb1, dw2, dwb2, ca, outb);
  hipLaunchKernelGGL(k_gemm32,   dim3(256,2),  dim3(256), 0, stream, outb, Wo, bo, 1, res, flag, 1);
  hipLaunchKernelGGL(k_add_ln,   dim3(512),    dim3(256), 0, stream, res, x, wn1, bn1, (void*)x1, flag, 0, 1);
  hipLaunchKernelGGL(k_gemm32_bo,dim3(256,4),  dim3(256), 0, stream, x1, Wfi, E);
  hipLaunchKernelGGL(k_ffn_dw_t, dim3(4096),   dim3(256), 0, stream, E, dwf, gbuf);
  hipLaunchKernelGGL(k_gemm32,   dim3(256,2),  dim3(256), 0, stream, gbuf, Wfo, wbuf, 0, res2, flag, 1);
  hipLaunchKernelGGL(k_add_ln,   dim3(512),    dim3(256), 0, stream, res2, x1, wn2, bn2, d_out, flag, 1, 0);
}

// Round 8
// 713.984 us; speedup vs baseline: 2.5697x; 1.0233x over previous
//
#include <hip/hip_runtime.h>
#include <hip/hip_bf16.h>

typedef __hip_bfloat16 bf16;
typedef __attribute__((ext_vector_type(8))) short short8v;
typedef __attribute__((ext_vector_type(4))) float f32x4;

#define DEV static __device__ __forceinline__

DEV float b2f(bf16 h){ return __bfloat162float(h); }
DEV float us2f(unsigned short u){ unsigned v=((unsigned)u)<<16; float f; __builtin_memcpy(&f,&v,4); return f; }
DEV short f2bs(float f){ bf16 h=__float2bfloat16(f); short s; __builtin_memcpy(&s,&h,2); return s; }
DEV unsigned pack2(float a, float b){ return ((unsigned)(unsigned short)f2bs(b)<<16)|(unsigned short)f2bs(a); }
DEV float lrelu(float x){ return x >= 0.f ? x : 0.1f*x; }
DEV float geluf(float x){ return 0.5f*x*(1.f + erff(x*0.70710678118654752440f)); }
DEV float sigmoidf(float x){ return 1.f/(1.f + expf(-x)); }

// B=4, C=64, H=W=256, HW=65536, WS=8, N=1024 windows/batch, embed=4096

// ---------------- K0a: detect storage dtype ----------------
__global__ __launch_bounds__(256) void k_detect(const void* x, int* flag){
  __shared__ int cnt;
  if(threadIdx.x==0) cnt=0;
  __syncthreads();
  const unsigned short* up=(const unsigned short*)x;
  int c=0;
  for(int k=0;k<16;k++){
    unsigned short u=up[(threadIdx.x*16+k)*2];
    if(((u>>7)&0xFF)==0xFF) c++;
  }
  atomicAdd(&cnt,c);
  __syncthreads();
  if(threadIdx.x==0) flag[0] = (cnt>0) ? 1 : 0;  // 1 => f32 storage
}

// ---------------- K0b: convert small weights to f32 wbuf ----------------
struct CvtArgs { const void* src[31]; int sz[31]; int off[31]; };
__global__ __launch_bounds__(256) void k_cvt(CvtArgs a, const int* fl, float* wbuf){
  int t=blockIdx.x; int n=a.sz[t]; const void* s=a.src[t]; float* d=wbuf+a.off[t];
  if(fl[0]){
    const float* sp=(const float*)s;
    for(int i=threadIdx.x;i<n;i+=256) d[i]=sp[i];
  } else {
    const bf16* sp=(const bf16*)s;
    for(int i=threadIdx.x;i<n;i+=256) d[i]=b2f(sp[i]);
  }
}

// ---------------- K0c: Wq/Wk -> bf16 for MFMA ----------------
__global__ __launch_bounds__(256) void k_w2b(const float* __restrict__ wq, const float* __restrict__ wk,
    short* __restrict__ Wqb, short* __restrict__ Wkb){
  int i=blockIdx.x*256+threadIdx.x;
  if(i<4096){ Wqb[i]=f2bs(wq[i]); Wkb[i]=f2bs(wk[i]); }
}

// ---------------- K_G: 32-och x 4-pix 1x1-conv GEMM, f32 out (64 out ch) ----------------
__global__ __launch_bounds__(256) void k_gemm32(
    const void* __restrict__ in, const float* __restrict__ W,
    const float* __restrict__ bias, int has_bias,
    float* __restrict__ out, const int* __restrict__ fl, int force_f32){
  __shared__ float sW[2048]; __shared__ float sb[32];
  int tid=threadIdx.x, og=blockIdx.y;
  for(int i=tid;i<2048;i+=256) sW[i]=W[og*2048+i];
  if(tid<32) sb[tid]= has_bias ? bias[og*32+tid] : 0.f;
  __syncthreads();
  int g=blockIdx.x*1024+tid*4; int b=g>>16, p=g&65535;
  float4 a[32];
  #pragma unroll
  for(int o=0;o<32;o++){ float bv=sb[o]; a[o]=make_float4(bv,bv,bv,bv); }
  bool f32in = force_f32 || (fl[0]!=0);
  size_t base=(((size_t)b*64)<<16)+p;
  if(f32in){
    const float* ip=(const float*)in + base;
    for(int c=0;c<64;c++){
      float4 xv=*(const float4*)(ip + (((size_t)c)<<16));
      #pragma unroll
      for(int o=0;o<32;o++){ float w=sW[o*64+c];
        a[o].x+=w*xv.x; a[o].y+=w*xv.y; a[o].z+=w*xv.z; a[o].w+=w*xv.w; }
    }
  } else {
    const bf16* ip=(const bf16*)in + base;
    for(int c=0;c<64;c++){
      const bf16* q=ip+(((size_t)c)<<16);
      float4 xv=make_float4(b2f(q[0]),b2f(q[1]),b2f(q[2]),b2f(q[3]));
      #pragma unroll
      for(int o=0;o<32;o++){ float w=sW[o*64+c];
        a[o].x+=w*xv.x; a[o].y+=w*xv.y; a[o].z+=w*xv.z; a[o].w+=w*xv.w; }
    }
  }
  float* op=out + (((size_t)(b*64+og*32))<<16) + p;
  #pragma unroll
  for(int o=0;o<32;o++) *(float4*)(op+(((size_t)o)<<16))=a[o];
}

// ---------------- K_G2: 32-och x 4-pix GEMM, f32 in (x1) -> E bf16 (128 och) ----------------
__global__ __launch_bounds__(256) void k_gemm32_bo(
    const float* __restrict__ in, const float* __restrict__ W,
    unsigned short* __restrict__ E){
  __shared__ float sW[2048];
  int tid=threadIdx.x, og=blockIdx.y;
  for(int i=tid;i<2048;i+=256) sW[i]=W[og*2048+i];
  __syncthreads();
  int g=blockIdx.x*1024+tid*4; int b=g>>16, p=g&65535;
  float4 a[32];
  #pragma unroll
  for(int o=0;o<32;o++) a[o]=make_float4(0.f,0.f,0.f,0.f);
  const float* ip=in + (((size_t)b*64)<<16)+p;
  for(int c=0;c<64;c++){
    float4 xv=*(const float4*)(ip + (((size_t)c)<<16));
    #pragma unroll
    for(int o=0;o<32;o++){ float w=sW[o*64+c];
      a[o].x+=w*xv.x; a[o].y+=w*xv.y; a[o].z+=w*xv.z; a[o].w+=w*xv.w; }
  }
  unsigned short* op=E + (((size_t)(b*128+og*32))<<16) + p;
  #pragma unroll
  for(int o=0;o<32;o++){
    uint2 u; u.x=pack2(a[o].x,a[o].y); u.y=pack2(a[o].z,a[o].w);
    *(uint2*)(op+(((size_t)o)<<16))=u;
  }
}

// ---------------- K_LN: out = LN(res + base), 2 pix/thread ----------------
// base_mode / out_mode: 0 = follow flag (f32 if fl), 1 = force f32, 2 = force bf16
// NOTE: out may alias res (all loads complete before stores by dataflow).
__global__ __launch_bounds__(256) void k_add_ln(
    const float* __restrict__ res, const void* __restrict__ base,
    const float* __restrict__ w, const float* __restrict__ bb,
    void* __restrict__ out,
    const int* __restrict__ fl, int base_mode, int out_mode){
  __shared__ float sw[64], sb[64];
  int tid=threadIdx.x;
  if(tid<64){ sw[tid]=w[tid]; sb[tid]=bb[tid]; }
  __syncthreads();
  int g=blockIdx.x*512+tid*2; int b=g>>16, p=g&65535;
  size_t off=(((size_t)b*64)<<16)+p;
  float2 r[64];
  bool bf32 = (base_mode==1) || (base_mode==0 && fl[0]);
  const float* rp=res+off;
  if(bf32){
    const float* xp=(const float*)base+off;
    #pragma unroll
    for(int o=0;o<64;o++){
      float2 rv=*(const float2*)(rp+(((size_t)o)<<16));
      float2 xv=*(const float2*)(xp+(((size_t)o)<<16));
      r[o].x=rv.x+xv.x; r[o].y=rv.y+xv.y;
    }
  } else {
    const unsigned short* xp=(const unsigned short*)base+off;
    #pragma unroll
    for(int o=0;o<64;o++){
      float2 rv=*(const float2*)(rp+(((size_t)o)<<16));
      unsigned u=*(const unsigned*)(xp+(((size_t)o)<<16));
      r[o].x=rv.x+us2f(u&0xffff); r[o].y=rv.y+us2f(u>>16);
    }
  }
  float m0=0.f,m1=0.f;
  #pragma unroll
  for(int o=0;o<64;o++){ m0+=r[o].x; m1+=r[o].y; }
  m0*=(1.f/64.f); m1*=(1.f/64.f);
  float v0=0.f,v1=0.f;
  #pragma unroll
  for(int o=0;o<64;o++){ float d0=r[o].x-m0, d1=r[o].y-m1; v0+=d0*d0; v1+=d1*d1; }
  v0*=(1.f/64.f); v1*=(1.f/64.f);
  float i0=1.f/sqrtf(v0+1e-6f), i1=1.f/sqrtf(v1+1e-6f);
  bool of32 = (out_mode==1) || (out_mode==0 && fl[0]);
  if(of32){
    float* op=(float*)out+off;
    #pragma unroll
    for(int o=0;o<64;o++){
      float2 st; st.x=sw[o]*((r[o].x-m0)*i0)+sb[o]; st.y=sw[o]*((r[o].y-m1)*i1)+sb[o];
      *(float2*)(op+(((size_t)o)<<16))=st;
    }
  } else {
    unsigned short* op=(unsigned short*)out+off;
    #pragma unroll
    for(int o=0;o<64;o++){
      float s0=sw[o]*((r[o].x-m0)*i0)+sb[o], s1=sw[o]*((r[o].y-m1)*i1)+sb[o];
      *(unsigned*)(op+(((size_t)o)<<16))=pack2(s0,s1);
    }
  }
}

// ---------------- K2: route (2 pix/thread) ----------------
__global__ __launch_bounds__(256) void k_route(const float* __restrict__ v,
    const float* __restrict__ W_in, const float* __restrict__ b_in,
    const float* __restrict__ Wc, const float* __restrict__ bc,
    const float* __restrict__ lnw, const float* __restrict__ lnb,
    float* __restrict__ x_, float* __restrict__ xm, float* __restrict__ capart){
  __shared__ float wA[1024], wB[1024], sba[16], sbb[16], slw[16], slb[16];
  __shared__ float sred[4][16];
  int tid=threadIdx.x;
  for(int i=tid;i<1024;i+=256){ wA[i]=W_in[i]; wB[i]=Wc[i]; }
  if(tid<16){ sba[tid]=b_in[tid]; sbb[tid]=bc[tid]; slw[tid]=lnw[tid]; slb[tid]=lnb[tid]; }
  __syncthreads();
  int g=blockIdx.x*512+tid*2; int b=g>>16, p=g&65535;
  float2 aA[16], aB[16];
  #pragma unroll
  for(int i=0;i<16;i++){ aA[i]=make_float2(sba[i],sba[i]); aB[i]=make_float2(sbb[i],sbb[i]); }
  const float* vp=v+(((size_t)b*64)<<16)+p;
  for(int c=0;c<64;c++){
    float2 vv=*(const float2*)(vp+(((size_t)c)<<16));
    #pragma unroll
    for(int i=0;i<16;i++){
      float wa=wA[(i<<6)+c], wb=wB[(i<<6)+c];
      aA[i].x+=wa*vv.x; aA[i].y+=wa*vv.y;
      aB[i].x+=wb*vv.x; aB[i].y+=wb*vv.y;
    }
  }
  float s0=0.f,s1=0.f;
  #pragma unroll
  for(int i=0;i<16;i++){ aA[i].x=lrelu(aA[i].x); aA[i].y=lrelu(aA[i].y); s0+=aA[i].x; s1+=aA[i].y; }
  float2 xmst; xmst.x=s0*(1.f/16.f); xmst.y=s1*(1.f/16.f);
  *(float2*)(xm+g)=xmst;
  float u0=0.f,u1=0.f;
  #pragma unroll
  for(int i=0;i<16;i++){ u0+=aB[i].x; u1+=aB[i].y; }
  u0*=(1.f/16.f); u1*=(1.f/16.f);
  float q0=0.f,q1=0.f;
  #pragma unroll
  for(int i=0;i<16;i++){ float d0=aB[i].x-u0, d1=aB[i].y-u1; q0+=d0*d0; q1+=d1*d1; }
  q0*=(1.f/16.f); q1*=(1.f/16.f);
  float i0=1.f/sqrtf(q0+1e-6f), i1=1.f/sqrtf(q1+1e-6f);
  float red[16];
  float* xp=x_+(((size_t)b*16)<<16)+p;
  #pragma unroll
  for(int i=0;i<16;i++){
    float xv0=lrelu(slw[i]*((aB[i].x-u0)*i0)+slb[i]);
    float xv1=lrelu(slw[i]*((aB[i].y-u1)*i1)+slb[i]);
    float2 st; st.x=xv0; st.y=xv1;
    *(float2*)(xp+(((size_t)i)<<16))=st;
    red[i]=xv0+xv1;
  }
  int lane=tid&63, wid=tid>>6;
  #pragma unroll
  for(int i=0;i<16;i++){
    float val=red[i];
    for(int m=32;m>0;m>>=1) val+=__shfl_xor(val,m);
    if(lane==0) sred[wid][i]=val;
  }
  __syncthreads();
  if(tid<16) capart[blockIdx.x*16+tid]=sred[0][tid]+sred[1][tid]+sred[2][tid]+sred[3][tid];
}

// ---------------- K3: sa = sigmoid(conv3x3(x_)) ----------------
__global__ __launch_bounds__(256) void k_sa(const float* __restrict__ x_,
    const float* __restrict__ Wsa, const float* __restrict__ bsa, float* __restrict__ sa){
  __shared__ float w[144]; __shared__ float bb;
  int tid=threadIdx.x;
  if(tid<144) w[tid]=Wsa[tid];
  if(tid==0) bb=bsa[0];
  __syncthreads();
  int pix=blockIdx.x*256+tid; int b=pix>>16, p=pix&65535;
  int y=p>>8, xx=p&255;
  float acc=bb;
  #pragma unroll
  for(int i=0;i<16;i++){
    const float* pl=x_+(((size_t)(b*16+i))<<16);
    #pragma unroll
    for(int ky=0;ky<3;ky++){
      int yy=y+ky-1;
      if((unsigned)yy<256u){
        #pragma unroll
        for(int kx=0;kx<3;kx++){
          int x2=xx+kx-1;
          if((unsigned)x2<256u) acc+=pl[(yy<<8)+x2]*w[i*9+ky*3+kx];
        }
      }
    }
  }
  sa[pix]=sigmoidf(acc);
}

// ---------------- K4: per-window variance (ddof=1) ----------------
__global__ __launch_bounds__(64) void k_var(const float* __restrict__ xm, float* __restrict__ var){
  int blk=blockIdx.x, tid=threadIdx.x;
  int b=blk>>10, n=blk&1023;
  int pix=((n>>5)<<11) + ((n&31)<<3) + ((tid>>3)<<8) + (tid&7);
  float val=xm[(b<<16)+pix];
  float s=val;
  for(int m=32;m>0;m>>=1) s+=__shfl_xor(s,m);
  float mean=s*(1.f/64.f);
  float d=val-mean; float q=d*d;
  for(int m=32;m>0;m>>=1) q+=__shfl_xor(q,m);
  if(tid==0) var[blk]=q*(1.f/63.f);
}

// ---------------- K5: rank -> mbin ----------------
__global__ __launch_bounds__(256) void k_rank(const float* __restrict__ var, float* __restrict__ mbin){
  __shared__ float va[1024];
  int bid=blockIdx.x; int b=bid>>2, seg=bid&3;
  int tid=threadIdx.x;
  for(int i=tid;i<1024;i+=256) va[i]=var[(b<<10)+i];
  __syncthreads();
  int n=seg*256+tid;
  float vn=va[n]; int r=0;
  for(int m=0;m<1024;m++){ float vm=va[m]; r += (vm<vn) || (vm==vn && m<n); }
  mbin[(b<<10)+n] = (r<512)?0.f:1.f;
}

// ---------------- K6: h0/h1 from Wm1 rowsums ----------------
__global__ __launch_bounds__(64) void k_hvec(const void* __restrict__ Wm1, const float* __restrict__ bm1,
    float* __restrict__ h0, float* __restrict__ h1, const int* __restrict__ fl){
  int j=blockIdx.x, tid=threadIdx.x;
  float s=0.f;
  if(fl[0]){
    const float* row=(const float*)Wm1+((size_t)j<<12);
    for(int k=tid;k<4096;k+=64) s+=row[k];
  } else {
    const bf16* row=(const bf16*)Wm1+((size_t)j<<12);
    for(int k=tid;k<4096;k+=64) s+=b2f(row[k]);
  }
  for(int m=32;m>0;m>>=1) s+=__shfl_xor(s,m);
  if(tid==0){ float bb=bm1[j]; h0[j]=lrelu(bb); h1[j]=lrelu(bb+s); }
}

// ---------------- K7: mask vectors (+ transposed copies) ----------------
__global__ __launch_bounds__(64) void k_mask(const void* __restrict__ Wm2, const float* __restrict__ bm2,
    const float* __restrict__ h0, const float* __restrict__ h1,
    float* __restrict__ m0, float* __restrict__ m1,
    float* __restrict__ m0T, float* __restrict__ m1T, const int* __restrict__ fl){
  int e=blockIdx.x, tid=threadIdx.x;
  float p0=0.f,p1=0.f;
  if(fl[0]){
    const float* row=(const float*)Wm2+((size_t)e<<11);
    for(int j=tid;j<2048;j+=64){ float w=row[j]; p0+=w*h0[j]; p1+=w*h1[j]; }
  } else {
    const bf16* row=(const bf16*)Wm2+((size_t)e<<11);
    for(int j=tid;j<2048;j+=64){ float w=b2f(row[j]); p0+=w*h0[j]; p1+=w*h1[j]; }
  }
  for(int m=32;m>0;m>>=1){ p0+=__shfl_xor(p0,m); p1+=__shfl_xor(p1,m); }
  if(tid==0){
    float bb=bm2[e]; float v0=p0+bb, v1=p1+bb;
    m0[e]=v0; m1[e]=v1;
    int te=(e&63)*64+(e>>6);
    m0T[te]=v0; m1T[te]=v1;
  }
}

// ---------------- K8: ca = sigmoid(Wca * mean(x_) + bca) ----------------
__global__ __launch_bounds__(64) void k_ca(const float* __restrict__ capart,
    const float* __restrict__ Wca, const float* __restrict__ bca, float* __restrict__ ca){
  __shared__ float m[16];
  int b=blockIdx.x, tid=threadIdx.x;
  if(tid<16){
    float s=0.f;
    for(int blk=0;blk<128;blk++) s+=capart[((b*128)+blk)*16+tid];
    m[tid]=s*(1.f/65536.f);
  }
  __syncthreads();
  float a=bca[tid];
  #pragma unroll
  for(int i=0;i<16;i++) a+=Wca[(tid<<4)+i]*m[i];
  ca[(b<<6)+tid]=sigmoidf(a);
}

// ---------------- K_PACK: apply masks; x*mk, v*mk, v*sa*(1-mk) -> window-major bf16 ----------------
// layout: buf[(b*1024+n)*4096 + c*64 + tok], tok = wrow*8 + wcol. Single bf16 rounding.
__global__ __launch_bounds__(256) void k_pack(const void* __restrict__ x, const float* __restrict__ v,
    const float* __restrict__ sa, const float* __restrict__ mbin,
    const float* __restrict__ m0T, const float* __restrict__ m1T, const int* __restrict__ fl,
    unsigned short* __restrict__ xwb, unsigned short* __restrict__ vwb, unsigned short* __restrict__ vswb){
  int wp=blockIdx.x; int b=wp>>9, np=wp&511;
  int n0=np*2;
  int base=((n0>>5)<<11)+((n0&31)<<3);
  int t=threadIdx.x; int c0=t>>3, row=t&7;
  int isf32=fl[0];
  const float* mTa = (mbin[b*1024+n0  ]>0.5f)? m1T : m0T;
  const float* mTb = (mbin[b*1024+n0+1]>0.5f)? m1T : m0T;
  for(int h=0;h<2;h++){
    int ch=c0+h*32;
    size_t gb=(((size_t)(b*64+ch))<<16) + base + row*256;
    float xv[16], vv[16], sv[16];
    if(isf32){
      const float* xp=(const float*)x+gb;
      #pragma unroll
      for(int i=0;i<16;i++) xv[i]=xp[i];
    } else {
      const bf16* xp=(const bf16*)x+gb;
      #pragma unroll
      for(int i=0;i<16;i++) xv[i]=b2f(xp[i]);
    }
    const float* vp=v+gb;
    const float* sp=sa+(((size_t)b)<<16)+base+row*256;
    #pragma unroll
    for(int i=0;i<16;i++){ vv[i]=vp[i]; sv[i]=sp[i]; }
    size_t o0=((size_t)(b*1024+n0)*64+ch)*64 + row*8;
    #pragma unroll
    for(int wnd=0;wnd<2;wnd++){
      const float* mT = wnd? mTb : mTa;
      size_t oo=o0+(size_t)wnd*4096;
      int s=wnd*8;
      float mk[8];
      #pragma unroll
      for(int j=0;j<8;j++) mk[j]=mT[ch*64+row*8+j];
      uint4 ux, uv, us;
      ux.x=pack2(xv[s+0]*mk[0],xv[s+1]*mk[1]); ux.y=pack2(xv[s+2]*mk[2],xv[s+3]*mk[3]);
      ux.z=pack2(xv[s+4]*mk[4],xv[s+5]*mk[5]); ux.w=pack2(xv[s+6]*mk[6],xv[s+7]*mk[7]);
      uv.x=pack2(vv[s+0]*mk[0],vv[s+1]*mk[1]); uv.y=pack2(vv[s+2]*mk[2],vv[s+3]*mk[3]);
      uv.z=pack2(vv[s+4]*mk[4],vv[s+5]*mk[5]); uv.w=pack2(vv[s+6]*mk[6],vv[s+7]*mk[7]);
      us.x=pack2(vv[s+0]*sv[s+0]*(1.f-mk[0]),vv[s+1]*sv[s+1]*(1.f-mk[1]));
      us.y=pack2(vv[s+2]*sv[s+2]*(1.f-mk[2]),vv[s+3]*sv[s+3]*(1.f-mk[3]));
      us.z=pack2(vv[s+4]*sv[s+4]*(1.f-mk[4]),vv[s+5]*sv[s+5]*(1.f-mk[5]));
      us.w=pack2(vv[s+6]*sv[s+6]*(1.f-mk[6]),vv[s+7]*sv[s+7]*(1.f-mk[7]));
      *(uint4*)(xwb+oo)=ux; *(uint4*)(vwb+oo)=uv; *(uint4*)(vswb+oo)=us;
    }
  }
}

// ---------------- K9: windowed attention via MFMA -> img ----------------
#define STR 72
#define STRF 65
__global__ __launch_bounds__(256,4) void k_attn_mfma(
    const unsigned short* __restrict__ xwb, const unsigned short* __restrict__ vwb,
    const unsigned short* __restrict__ vswb,
    const short* __restrict__ Wqb, const float* __restrict__ bq,
    const short* __restrict__ Wkb, const float* __restrict__ bk,
    float* __restrict__ img){
  __shared__ short sT[64*STR];
  __shared__ short sQK[2*64*STR];
  __shared__ short sV1[64*STR];
  short* sQ=sQK; short* sK=sQK+64*STR;
  float* sF=(float*)sQK;
  int tid=threadIdx.x, blk=blockIdx.x;
  int b=blk>>10, n=blk&1023;
  int base=((n>>5)<<11) + ((n&31)<<3);
  size_t plane=((size_t)b*64)<<16;
  const unsigned short* xw=xwb+(size_t)blk*4096;
  const unsigned short* vw=vwb+(size_t)blk*4096;
  // ---- P1: copy pre-masked bf16 into LDS (t row-major, v1 transposed) ----
  for(int e=tid;e<4096;e+=256){
    int c=e>>6, tok=e&63;
    sT[tok*STR+c]=(short)xw[e];
    sV1[c*STR+tok]=(short)vw[e];
  }
  __syncthreads();
  int lane=tid&63, wid=tid>>6;
  int pb=wid*16, lr=lane&15, lg=lane>>4;
  short8v ta[2];
  #pragma unroll
  for(int ks=0;ks<2;ks++) ta[ks]=*(const short8v*)&sT[(pb+lr)*STR + ks*32 + lg*8];
  #pragma unroll
  for(int nt=0;nt<4;nt++){
    float bqv=bq[nt*16+lr], bkv=bk[nt*16+lr];
    f32x4 qa={bqv,bqv,bqv,bqv}, ka={bkv,bkv,bkv,bkv};
    #pragma unroll
    for(int ks=0;ks<2;ks++){
      short8v wq=*(const short8v*)(Wqb + (nt*16+lr)*64 + ks*32 + lg*8);
      short8v wk=*(const short8v*)(Wkb + (nt*16+lr)*64 + ks*32 + lg*8);
      qa=__builtin_amdgcn_mfma_f32_16x16x32_bf16(ta[ks],wq,qa,0,0,0);
      ka=__builtin_amdgcn_mfma_f32_16x16x32_bf16(ta[ks],wk,ka,0,0,0);
    }
    #pragma unroll
    for(int r=0;r<4;r++){
      sQ[(pb+lg*4+r)*STR + nt*16+lr]=f2bs(qa[r]);
      sK[(pb+lg*4+r)*STR + nt*16+lr]=f2bs(ka[r]);
    }
  }
  __syncthreads();
  short8v qa2[2];
  #pragma unroll
  for(int ks=0;ks<2;ks++) qa2[ks]=*(const short8v*)&sQ[(pb+lr)*STR + ks*32 + lg*8];
  f32x4 sacc[4];
  #pragma unroll
  for(int nt=0;nt<4;nt++){
    f32x4 a={0.f,0.f,0.f,0.f};
    #pragma unroll
    for(int ks=0;ks<2;ks++){
      short8v kb=*(const short8v*)&sK[(nt*16+lr)*STR + ks*32 + lg*8];
      a=__builtin_amdgcn_mfma_f32_16x16x32_bf16(qa2[ks],kb,a,0,0,0);
    }
    sacc[nt]=a;
  }
  f32x4 pa[4];
  #pragma unroll
  for(int r=0;r<4;r++){
    float mx=fmaxf(fmaxf(sacc[0][r],sacc[1][r]),fmaxf(sacc[2][r],sacc[3][r]));
    #pragma unroll
    for(int m=1;m<16;m<<=1) mx=fmaxf(mx,__shfl_xor(mx,m));
    float e0=expf(sacc[0][r]-mx), e1=expf(sacc[1][r]-mx);
    float e2=expf(sacc[2][r]-mx), e3=expf(sacc[3][r]-mx);
    float sum=e0+e1+e2+e3;
    #pragma unroll
    for(int m=1;m<16;m<<=1) sum+=__shfl_xor(sum,m);
    float inv=1.f/sum;
    pa[0][r]=e0*inv; pa[1][r]=e1*inv; pa[2][r]=e2*inv; pa[3][r]=e3*inv;
  }
  #pragma unroll
  for(int nt=0;nt<4;nt++){
    #pragma unroll
    for(int r=0;r<4;r++)
      sT[(pb+lg*4+r)*STR + nt*16+lr]=f2bs(pa[nt][r]);
  }
  __syncthreads();
  short8v aa[2];
  #pragma unroll
  for(int ks=0;ks<2;ks++) aa[ks]=*(const short8v*)&sT[(pb+lr)*STR + ks*32 + lg*8];
  #pragma unroll
  for(int nt=0;nt<4;nt++){
    f32x4 f={0.f,0.f,0.f,0.f};
    #pragma unroll
    for(int ks=0;ks<2;ks++){
      short8v vb=*(const short8v*)&sV1[(nt*16+lr)*STR + ks*32 + lg*8];
      f=__builtin_amdgcn_mfma_f32_16x16x32_bf16(aa[ks],vb,f,0,0,0);
    }
    #pragma unroll
    for(int r=0;r<4;r++) sF[(pb+lg*4+r)*STRF + nt*16+lr]=f[r];
  }
  __syncthreads();
  const unsigned short* vsw=vswb+(size_t)blk*4096;
  for(int e=tid;e<4096;e+=256){
    int c=e>>6, tok=e&63;
    float f=sF[tok*STRF+c];
    int pix=base+((tok>>3)<<8)+(tok&7);
    img[plane+(((size_t)c)<<16)+pix]=f+us2f(vsw[e]);
  }
}

// ---------------- K_DWF: fused depthwise dil1+dil2+gelu*ca+img, 8-row strips ----------------
// block = (b, c, 8-row strip). LDS 27.5KB -> 5 blocks/CU.
#define IST 264
__global__ __launch_bounds__(256) void k_dwfuse(const float* __restrict__ img,
    const float* __restrict__ dw1w, const float* __restrict__ dwb1,
    const float* __restrict__ dw2w, const float* __restrict__ dwb2,
    const float* __restrict__ ca, float* __restrict__ outb){
  __shared__ float sImg[14*IST];   // rows y0-3..y0+10, LDS col = gx+3
  __shared__ float sTmp[12*IST];   // rows y0-2..y0+9,  LDS col = tc+2
  __shared__ float k1[9], k2[9];
  __shared__ float bb1, bb2, cav;
  int bid=blockIdx.x; int b=bid>>11, c=(bid>>5)&63, sy=bid&31;
  int y0=sy*8;
  int tid=threadIdx.x;
  if(tid<9){ k1[tid]=dw1w[c*9+tid]; k2[tid]=dw2w[c*9+tid]; }
  if(tid==9)  bb1=dwb1[c];
  if(tid==10) bb2=dwb2[c];
  if(tid==11) cav=ca[b*64+c];
  const float* ip=img+(((size_t)(b*64+c))<<16);
  for(int i=tid;i<14*IST;i+=256){
    int r=i/IST, cl=i-r*IST;
    int gy=y0-3+r, gx=cl-3;
    float v=0.f;
    if(cl<262 && (unsigned)gy<256u && (unsigned)gx<256u) v=ip[(gy<<8)+gx];
    sImg[i]=v;
  }
  __syncthreads();
  for(int i=tid;i<12*IST;i+=256){
    int r=i/IST, cl=i-r*IST;
    float t=0.f;
    if(cl<260){
      int ty=y0-2+r, tc=cl-2;
      if((unsigned)ty<256u && (unsigned)tc<256u){
        t=bb1;
        #pragma unroll
        for(int dy=0;dy<3;dy++)
          #pragma unroll
          for(int dx=0;dx<3;dx++)
            t+=sImg[(r+dy)*IST+(cl+dx)]*k1[dy*3+dx];
      }
    }
    sTmp[i]=t;
  }
  __syncthreads();
  float* op=outb+(((size_t)(b*64+c))<<16);
  int lx=tid;
  #pragma unroll
  for(int ly=0;ly<8;ly++){
    float cs=bb2;
    #pragma unroll
    for(int dy=0;dy<3;dy++)
      #pragma unroll
      for(int dx=0;dx<3;dx++)
        cs+=sTmp[(ly+2*dy)*IST + lx+2*dx]*k2[dy*3+dx];
    float center=sImg[(ly+3)*IST + lx+3];
    op[((y0+ly)<<8)+lx]=geluf(cs)*cav+center;
  }
}

// ---------------- K_FDW: ffn depthwise (E bf16) + gelu gate, row-strip tiles ----------------
#define EST 260
__global__ __launch_bounds__(256) void k_ffn_dw_t(const unsigned short* __restrict__ E,
    const float* __restrict__ dwf, float* __restrict__ g){
  __shared__ unsigned short sE1[18*EST];  // rows y0-1..y0+16, LDS col = gx+2
  __shared__ unsigned short sE2[18*EST];
  __shared__ float k1[9], k2[9];
  int bid=blockIdx.x; int b=bid>>10, c=(bid>>4)&63, sy=bid&15;
  int y0=sy*16;
  int tid=threadIdx.x;
  if(tid<9){ k1[tid]=dwf[c*9+tid]; k2[tid]=dwf[(64+c)*9+tid]; }
  if(tid<144){
    int pl=tid/72; int rem=tid-pl*72; int rr=rem>>2; int cc=rem&3;
    int col=(cc<2)? cc : (256+cc);
    if(pl==0) sE1[rr*EST+col]=0; else sE2[rr*EST+col]=0;
  }
  const unsigned short* p1=E+(((size_t)(b*128+c))<<16);
  const unsigned short* p2=E+(((size_t)(b*128+64+c))<<16);
  int half=tid>>7, t2=tid&127;
  const unsigned short* pp = half? p2 : p1;
  for(int r=0;r<18;r++){
    int gy=y0-1+r;
    unsigned val=0;
    if((unsigned)gy<256u) val=*(const unsigned*)(pp+(gy<<8)+t2*2);
    unsigned short* dst = half? sE2 : sE1;
    *(unsigned*)(dst + r*EST + 2 + t2*2) = val;
  }
  __syncthreads();
  float* op=g+(((size_t)(b*64+c))<<16);
  int lx=tid;
  #pragma unroll 4
  for(int ly=0;ly<16;ly++){
    float a1=0.f, a2=0.f;
    #pragma unroll
    for(int dy=0;dy<3;dy++)
      #pragma unroll
      for(int dx=0;dx<3;dx++){
        int idx=(ly+dy)*EST + lx+dx+1;
        a1+=us2f(sE1[idx])*k1[dy*3+dx];
        a2+=us2f(sE2[idx])*k2[dy*3+dx];
      }
    op[((y0+ly)<<8)+lx]=geluf(a1)*a2;
  }
}

extern "C" void kernel_launch(void* const* d_in, const int* in_sizes, int n_in,
                              void* d_out, int out_size, void* d_ws, size_t ws_size,
                              hipStream_t stream){
  (void)in_sizes; (void)n_in; (void)out_size; (void)ws_size;
  const void* x  = d_in[0];
  const void* Wm1= d_in[23];
  const void* Wm2= d_in[25];

  char* ws=(char*)d_ws;
  // Slot A [0,64MiB):    v (f32) -> E (bf16, 128ch) -> res2 (f32)
  // Slot B [64,128MiB):  img -> res -> x1 (in-place f32)
  // Slot C [128,192MiB): xwb(32MiB)+vwb(32MiB) -> outb -> gbuf
  // [192MiB..~211MiB):   small buffers
  // [220MiB,252MiB):     vswb (bf16)
  float* v    =(float*)(ws);
  unsigned short* E=(unsigned short*)(ws);
  float* res2 =(float*)(ws);
  float* img  =(float*)(ws+67108864);
  float* res  =(float*)(ws+67108864);
  float* x1   =(float*)(ws+67108864);
  unsigned short* xwb=(unsigned short*)(ws+134217728);
  unsigned short* vwb=(unsigned short*)(ws+134217728+33554432);
  float* outb =(float*)(ws+134217728);
  float* gbuf =(float*)(ws+134217728);
  unsigned short* vswb=(unsigned short*)(ws+230686720);
  char* sm = ws+201326592;
  float* x_    =(float*)(sm);              // 16 MB
  float* sa    =(float*)(sm+16777216);     // 1 MB
  float* xm    =(float*)(sm+17825792);     // 1 MB
  float* var   =(float*)(sm+18874368);     // 16 KB
  float* mbin  =(float*)(sm+18890752);     // 16 KB
  float* h0    =(float*)(sm+18907136);     // 8 KB
  float* h1    =(float*)(sm+18915328);     // 8 KB
  float* m0    =(float*)(sm+18923520);     // 16 KB
  float* m1    =(float*)(sm+18939904);     // 16 KB
  float* capart=(float*)(sm+18956288);     // 64 KB
  float* ca    =(float*)(sm+19021824);     // 1 KB
  int*   flag  =(int*)  (sm+19022848);     // 4 B
  float* wbuf  =(float*)(sm+19023872);     // ~161 KB
  short* Wqb   =(short*)(sm+19200000);     // 8 KB
  short* Wkb   =(short*)(sm+19208192);     // 8 KB
  float* m0T   =(float*)(sm+19216384);     // 16 KB
  float* m1T   =(float*)(sm+19232768);     // 16 KB

  static const int din_idx[31]={5,6,7,8,9,10,11,12,13,14,15,16,17,18,19,20,21,22,24,26,27,28,29,30,31,32,33,1,2,3,4};
  static const int szs[31]  ={4096,64,4096,64,4096,64,576,64,576,64,4096,64,1024,16,1024,16,16,16,2048,4096,1024,64,144,1,8192,1152,4096,64,64,64,64};
  CvtArgs ca_args;
  int off=0;
  int offs[31];
  for(int t=0;t<31;t++){
    ca_args.src[t]=d_in[din_idx[t]];
    ca_args.sz[t]=szs[t];
    ca_args.off[t]=off;
    offs[t]=off;
    off+=szs[t];
  }
  const float* Wv  =wbuf+offs[0];  const float* bv  =wbuf+offs[1];
  const float* Wq  =wbuf+offs[2];  const float* bq  =wbuf+offs[3];
  const float* Wk  =wbuf+offs[4];  const float* bk  =wbuf+offs[5];
  const float* dw1 =wbuf+offs[6];  const float* dwb1=wbuf+offs[7];
  const float* dw2 =wbuf+offs[8];  const float* dwb2=wbuf+offs[9];
  const float* Wo  =wbuf+offs[10]; const float* bo  =wbuf+offs[11];
  const float* W_in=wbuf+offs[12]; const float* b_in=wbuf+offs[13];
  const float* Wc  =wbuf+offs[14]; const float* bc  =wbuf+offs[15];
  const float* lnw =wbuf+offs[16]; const float* lnb =wbuf+offs[17];
  const float* bm1 =wbuf+offs[18]; const float* bm2 =wbuf+offs[19];
  const float* Wca =wbuf+offs[20]; const float* bca =wbuf+offs[21];
  const float* Wsa =wbuf+offs[22]; const float* bsa =wbuf+offs[23];
  const float* Wfi =wbuf+offs[24]; const float* dwf =wbuf+offs[25];
  const float* Wfo =wbuf+offs[26];
  const float* wn1 =wbuf+offs[27]; const float* bn1 =wbuf+offs[28];
  const float* wn2 =wbuf+offs[29]; const float* bn2 =wbuf+offs[30];

  hipLaunchKernelGGL(k_detect,   dim3(1),      dim3(256), 0, stream, x, flag);
  hipLaunchKernelGGL(k_cvt,      dim3(31),     dim3(256), 0, stream, ca_args, flag, wbuf);
  hipLaunchKernelGGL(k_w2b,      dim3(16),     dim3(256), 0, stream, Wq, Wk, Wqb, Wkb);
  hipLaunchKernelGGL(k_gemm32,   dim3(256,2),  dim3(256), 0, stream, x, Wv, bv, 1, v, flag, 0);
  hipLaunchKernelGGL(k_route,    dim3(512),    dim3(256), 0, stream, v, W_in, b_in, Wc, bc, lnw, lnb, x_, xm, capart);
  hipLaunchKernelGGL(k_sa,       dim3(1024),   dim3(256), 0, stream, x_, Wsa, bsa, sa);
  hipLaunchKernelGGL(k_var,      dim3(4096),   dim3(64),  0, stream, xm, var);
  hipLaunchKernelGGL(k_rank,     dim3(16),     dim3(256), 0, stream, var, mbin);
  hipLaunchKernelGGL(k_hvec,     dim3(2048),   dim3(64),  0, stream, Wm1, bm1, h0, h1, flag);
  hipLaunchKernelGGL(k_mask,     dim3(4096),   dim3(64),  0, stream, Wm2, bm2, h0, h1, m0, m1, m0T, m1T, flag);
  hipLaunchKernelGGL(k_ca,       dim3(4),      dim3(64),  0, stream, capart, Wca, bca, ca);
  hipLaunchKernelGGL(k_pack,     dim3(2048),   dim3(256), 0, stream, x, v, sa, mbin, m0T, m1T, flag, xwb, vwb, vswb);
  hipLaunchKernelGGL(k_attn_mfma,dim3(4096),   dim3(256), 0, stream, xwb, vwb, vswb, Wqb, bq, Wkb, bk, img);
  hipLaunchKernelGGL(k_dwfuse,   dim3(8192),   dim3(256), 0, stream, img, dw1, dwb1, dw2, dwb2, ca, outb);
  hipLaunchKernelGGL(k_gemm32,   dim3(256,2),  dim3(256), 0, stream, outb, Wo, bo, 1, res, flag, 1);
  hipLaunchKernelGGL(k_add_ln,   dim3(512),    dim3(256), 0, stream, res, x, wn1, bn1, (void*)x1, flag, 0, 1);
  hipLaunchKernelGGL(k_gemm32_bo,dim3(256,4),  dim3(256), 0, stream, x1, Wfi, E);
  hipLaunchKernelGGL(k_ffn_dw_t, dim3(4096),   dim3(256), 0, stream, E, dwf, gbuf);
  hipLaunchKernelGGL(k_gemm32,   dim3(256,2),  dim3(256), 0, stream, gbuf, Wfo, wbuf, 0, res2, flag, 1);
  hipLaunchKernelGGL(k_add_ln,   dim3(512),    dim3(256), 0, stream, res2, x1, wn2, bn2, d_out, flag, 1, 0);
}

// Round 9
// 664.230 us; speedup vs baseline: 2.7622x; 1.0749x over previous
//
#include <hip/hip_runtime.h>
#include <hip/hip_bf16.h>

typedef __hip_bfloat16 bf16;
typedef __attribute__((ext_vector_type(8))) short short8v;
typedef __attribute__((ext_vector_type(4))) float f32x4;

#define DEV static __device__ __forceinline__

DEV float b2f(bf16 h){ return __bfloat162float(h); }
DEV float us2f(unsigned short u){ unsigned v=((unsigned)u)<<16; float f; __builtin_memcpy(&f,&v,4); return f; }
DEV short f2bs(float f){ bf16 h=__float2bfloat16(f); short s; __builtin_memcpy(&s,&h,2); return s; }
DEV unsigned pack2(float a, float b){ return ((unsigned)(unsigned short)f2bs(b)<<16)|(unsigned short)f2bs(a); }
DEV float lrelu(float x){ return x >= 0.f ? x : 0.1f*x; }
DEV float geluf(float x){ return 0.5f*x*(1.f + erff(x*0.70710678118654752440f)); }
DEV float sigmoidf(float x){ return 1.f/(1.f + expf(-x)); }

// B=4, C=64, H=W=256, HW=65536, WS=8, N=1024 windows/batch, embed=4096

// ---------------- K0a: detect storage dtype ----------------
__global__ __launch_bounds__(256) void k_detect(const void* x, int* flag){
  __shared__ int cnt;
  if(threadIdx.x==0) cnt=0;
  __syncthreads();
  const unsigned short* up=(const unsigned short*)x;
  int c=0;
  for(int k=0;k<16;k++){
    unsigned short u=up[(threadIdx.x*16+k)*2];
    if(((u>>7)&0xFF)==0xFF) c++;
  }
  atomicAdd(&cnt,c);
  __syncthreads();
  if(threadIdx.x==0) flag[0] = (cnt>0) ? 1 : 0;  // 1 => f32 storage
}

// ---------------- K0b: convert small weights to f32 wbuf ----------------
struct CvtArgs { const void* src[31]; int sz[31]; int off[31]; };
__global__ __launch_bounds__(256) void k_cvt(CvtArgs a, const int* fl, float* wbuf){
  int t=blockIdx.x; int n=a.sz[t]; const void* s=a.src[t]; float* d=wbuf+a.off[t];
  if(fl[0]){
    const float* sp=(const float*)s;
    for(int i=threadIdx.x;i<n;i+=256) d[i]=sp[i];
  } else {
    const bf16* sp=(const bf16*)s;
    for(int i=threadIdx.x;i<n;i+=256) d[i]=b2f(sp[i]);
  }
}

// ---------------- K0c: Wq/Wk -> bf16 for MFMA ----------------
__global__ __launch_bounds__(256) void k_w2b(const float* __restrict__ wq, const float* __restrict__ wk,
    short* __restrict__ Wqb, short* __restrict__ Wkb){
  int i=blockIdx.x*256+threadIdx.x;
  if(i<4096){ Wqb[i]=f2bs(wq[i]); Wkb[i]=f2bs(wk[i]); }
}

// ---------------- K0d: Wo/Wfi/Wfo -> bf16 for MFMA ----------------
__global__ __launch_bounds__(256) void k_w2b3(const float* __restrict__ wo, const float* __restrict__ wfi,
    const float* __restrict__ wfo, short* __restrict__ Wob, short* __restrict__ Wfib, short* __restrict__ Wfob){
  int i=blockIdx.x*256+threadIdx.x;
  if(i<4096) Wob[i]=f2bs(wo[i]);
  if(i<8192) Wfib[i]=f2bs(wfi[i]);
  if(i<4096) Wfob[i]=f2bs(wfo[i]);
}

// ---------------- K_G: 32-och x 4-pix 1x1-conv GEMM, f32 (conv_v only; exact for routing) ----------------
__global__ __launch_bounds__(256) void k_gemm32(
    const void* __restrict__ in, const float* __restrict__ W,
    const float* __restrict__ bias, int has_bias,
    float* __restrict__ out, const int* __restrict__ fl, int force_f32){
  __shared__ float sW[2048]; __shared__ float sb[32];
  int tid=threadIdx.x, og=blockIdx.y;
  for(int i=tid;i<2048;i+=256) sW[i]=W[og*2048+i];
  if(tid<32) sb[tid]= has_bias ? bias[og*32+tid] : 0.f;
  __syncthreads();
  int g=blockIdx.x*1024+tid*4; int b=g>>16, p=g&65535;
  float4 a[32];
  #pragma unroll
  for(int o=0;o<32;o++){ float bv=sb[o]; a[o]=make_float4(bv,bv,bv,bv); }
  bool f32in = force_f32 || (fl[0]!=0);
  size_t base=(((size_t)b*64)<<16)+p;
  if(f32in){
    const float* ip=(const float*)in + base;
    for(int c=0;c<64;c++){
      float4 xv=*(const float4*)(ip + (((size_t)c)<<16));
      #pragma unroll
      for(int o=0;o<32;o++){ float w=sW[o*64+c];
        a[o].x+=w*xv.x; a[o].y+=w*xv.y; a[o].z+=w*xv.z; a[o].w+=w*xv.w; }
    }
  } else {
    const bf16* ip=(const bf16*)in + base;
    for(int c=0;c<64;c++){
      const bf16* q=ip+(((size_t)c)<<16);
      float4 xv=make_float4(b2f(q[0]),b2f(q[1]),b2f(q[2]),b2f(q[3]));
      #pragma unroll
      for(int o=0;o<32;o++){ float w=sW[o*64+c];
        a[o].x+=w*xv.x; a[o].y+=w*xv.y; a[o].z+=w*xv.z; a[o].w+=w*xv.w; }
    }
  }
  float* op=out + (((size_t)(b*64+og*32))<<16) + p;
  #pragma unroll
  for(int o=0;o<32;o++) *(float4*)(op+(((size_t)o)<<16))=a[o];
}

// ---------------- K_GM: MFMA 1x1-conv GEMM: D[och][pix] = W[och][c] * in[c][pix] ----------------
// in: channel-planar, f32 (in_f32=1) or bf16 (in_f32=0). 64-pixel tile/block, 4 waves.
// out: channel-planar, f32 (out_bf16=0) or bf16 (out_bf16=1). och = 64 or 128.
__global__ __launch_bounds__(256) void k_gemm_mf(
    const void* __restrict__ in, int in_f32,
    const short* __restrict__ Wb, const float* __restrict__ bias, int has_bias,
    void* __restrict__ out, int och, int out_bf16){
  __shared__ short Ain[64*72];
  int tid=threadIdx.x;
  int g0=blockIdx.x*64; int b=g0>>16, p0=g0&65535;
  // stage: transpose 64pix x 64ch tile into Ain[pix][c]
  int c=tid>>2, q=tid&3;
  size_t base=(((size_t)(b*64+c))<<16) + p0;
  if(in_f32){
    const float* ip=(const float*)in + base;
    #pragma unroll
    for(int j=0;j<4;j++){
      int po=q*16+j*4;
      float4 xv=*(const float4*)(ip+po);
      Ain[(po+0)*72+c]=f2bs(xv.x); Ain[(po+1)*72+c]=f2bs(xv.y);
      Ain[(po+2)*72+c]=f2bs(xv.z); Ain[(po+3)*72+c]=f2bs(xv.w);
    }
  } else {
    const unsigned short* ip=(const unsigned short*)in + base;
    #pragma unroll
    for(int j=0;j<4;j++){
      int po=q*16+j*4;
      uint2 u=*(const uint2*)(ip+po);
      Ain[(po+0)*72+c]=(short)(u.x&0xffff); Ain[(po+1)*72+c]=(short)(u.x>>16);
      Ain[(po+2)*72+c]=(short)(u.y&0xffff); Ain[(po+3)*72+c]=(short)(u.y>>16);
    }
  }
  __syncthreads();
  int lane=tid&63, wid=tid>>6;
  int lr=lane&15, lg=lane>>4;
  int pix0=wid*16;
  short8v bfrag[2];
  #pragma unroll
  for(int ks=0;ks<2;ks++) bfrag[ks]=*(const short8v*)&Ain[(pix0+lr)*72 + ks*32 + lg*8];
  int ntn=och>>4;
  for(int nt=0;nt<ntn;nt++){
    f32x4 acc;
    if(has_bias){
      #pragma unroll
      for(int r=0;r<4;r++) acc[r]=bias[nt*16+lg*4+r];
    } else {
      acc=(f32x4){0.f,0.f,0.f,0.f};
    }
    #pragma unroll
    for(int ks=0;ks<2;ks++){
      short8v afrag=*(const short8v*)(Wb + (nt*16+lr)*64 + ks*32 + lg*8);
      acc=__builtin_amdgcn_mfma_f32_16x16x32_bf16(afrag,bfrag[ks],acc,0,0,0);
    }
    if(out_bf16){
      unsigned short* op=(unsigned short*)out;
      #pragma unroll
      for(int r=0;r<4;r++){
        int m=nt*16+lg*4+r;
        op[(((size_t)(b*och+m))<<16) + p0 + pix0 + lr]=(unsigned short)f2bs(acc[r]);
      }
    } else {
      float* op=(float*)out;
      #pragma unroll
      for(int r=0;r<4;r++){
        int m=nt*16+lg*4+r;
        op[(((size_t)(b*och+m))<<16) + p0 + pix0 + lr]=acc[r];
      }
    }
  }
}

// ---------------- K_LN: out = LN(res + base), 2 pix/thread ----------------
// base_mode / out_mode: 0 = follow flag (f32 if fl), 1 = force f32, 2 = force bf16
// NOTE: out may alias res (all loads complete before stores by dataflow).
__global__ __launch_bounds__(256) void k_add_ln(
    const float* __restrict__ res, const void* __restrict__ base,
    const float* __restrict__ w, const float* __restrict__ bb,
    void* __restrict__ out,
    const int* __restrict__ fl, int base_mode, int out_mode){
  __shared__ float sw[64], sb[64];
  int tid=threadIdx.x;
  if(tid<64){ sw[tid]=w[tid]; sb[tid]=bb[tid]; }
  __syncthreads();
  int g=blockIdx.x*512+tid*2; int b=g>>16, p=g&65535;
  size_t off=(((size_t)b*64)<<16)+p;
  float2 r[64];
  bool bf32 = (base_mode==1) || (base_mode==0 && fl[0]);
  const float* rp=res+off;
  if(bf32){
    const float* xp=(const float*)base+off;
    #pragma unroll
    for(int o=0;o<64;o++){
      float2 rv=*(const float2*)(rp+(((size_t)o)<<16));
      float2 xv=*(const float2*)(xp+(((size_t)o)<<16));
      r[o].x=rv.x+xv.x; r[o].y=rv.y+xv.y;
    }
  } else {
    const unsigned short* xp=(const unsigned short*)base+off;
    #pragma unroll
    for(int o=0;o<64;o++){
      float2 rv=*(const float2*)(rp+(((size_t)o)<<16));
      unsigned u=*(const unsigned*)(xp+(((size_t)o)<<16));
      r[o].x=rv.x+us2f(u&0xffff); r[o].y=rv.y+us2f(u>>16);
    }
  }
  float m0=0.f,m1=0.f;
  #pragma unroll
  for(int o=0;o<64;o++){ m0+=r[o].x; m1+=r[o].y; }
  m0*=(1.f/64.f); m1*=(1.f/64.f);
  float v0=0.f,v1=0.f;
  #pragma unroll
  for(int o=0;o<64;o++){ float d0=r[o].x-m0, d1=r[o].y-m1; v0+=d0*d0; v1+=d1*d1; }
  v0*=(1.f/64.f); v1*=(1.f/64.f);
  float i0=1.f/sqrtf(v0+1e-6f), i1=1.f/sqrtf(v1+1e-6f);
  bool of32 = (out_mode==1) || (out_mode==0 && fl[0]);
  if(of32){
    float* op=(float*)out+off;
    #pragma unroll
    for(int o=0;o<64;o++){
      float2 st; st.x=sw[o]*((r[o].x-m0)*i0)+sb[o]; st.y=sw[o]*((r[o].y-m1)*i1)+sb[o];
      *(float2*)(op+(((size_t)o)<<16))=st;
    }
  } else {
    unsigned short* op=(unsigned short*)out+off;
    #pragma unroll
    for(int o=0;o<64;o++){
      float s0=sw[o]*((r[o].x-m0)*i0)+sb[o], s1=sw[o]*((r[o].y-m1)*i1)+sb[o];
      *(unsigned*)(op+(((size_t)o)<<16))=pack2(s0,s1);
    }
  }
}

// ---------------- K2: route (2 pix/thread) ----------------
__global__ __launch_bounds__(256) void k_route(const float* __restrict__ v,
    const float* __restrict__ W_in, const float* __restrict__ b_in,
    const float* __restrict__ Wc, const float* __restrict__ bc,
    const float* __restrict__ lnw, const float* __restrict__ lnb,
    float* __restrict__ x_, float* __restrict__ xm, float* __restrict__ capart){
  __shared__ float wA[1024], wB[1024], sba[16], sbb[16], slw[16], slb[16];
  __shared__ float sred[4][16];
  int tid=threadIdx.x;
  for(int i=tid;i<1024;i+=256){ wA[i]=W_in[i]; wB[i]=Wc[i]; }
  if(tid<16){ sba[tid]=b_in[tid]; sbb[tid]=bc[tid]; slw[tid]=lnw[tid]; slb[tid]=lnb[tid]; }
  __syncthreads();
  int g=blockIdx.x*512+tid*2; int b=g>>16, p=g&65535;
  float2 aA[16], aB[16];
  #pragma unroll
  for(int i=0;i<16;i++){ aA[i]=make_float2(sba[i],sba[i]); aB[i]=make_float2(sbb[i],sbb[i]); }
  const float* vp=v+(((size_t)b*64)<<16)+p;
  for(int c=0;c<64;c++){
    float2 vv=*(const float2*)(vp+(((size_t)c)<<16));
    #pragma unroll
    for(int i=0;i<16;i++){
      float wa=wA[(i<<6)+c], wb=wB[(i<<6)+c];
      aA[i].x+=wa*vv.x; aA[i].y+=wa*vv.y;
      aB[i].x+=wb*vv.x; aB[i].y+=wb*vv.y;
    }
  }
  float s0=0.f,s1=0.f;
  #pragma unroll
  for(int i=0;i<16;i++){ aA[i].x=lrelu(aA[i].x); aA[i].y=lrelu(aA[i].y); s0+=aA[i].x; s1+=aA[i].y; }
  float2 xmst; xmst.x=s0*(1.f/16.f); xmst.y=s1*(1.f/16.f);
  *(float2*)(xm+g)=xmst;
  float u0=0.f,u1=0.f;
  #pragma unroll
  for(int i=0;i<16;i++){ u0+=aB[i].x; u1+=aB[i].y; }
  u0*=(1.f/16.f); u1*=(1.f/16.f);
  float q0=0.f,q1=0.f;
  #pragma unroll
  for(int i=0;i<16;i++){ float d0=aB[i].x-u0, d1=aB[i].y-u1; q0+=d0*d0; q1+=d1*d1; }
  q0*=(1.f/16.f); q1*=(1.f/16.f);
  float i0=1.f/sqrtf(q0+1e-6f), i1=1.f/sqrtf(q1+1e-6f);
  float red[16];
  float* xp=x_+(((size_t)b*16)<<16)+p;
  #pragma unroll
  for(int i=0;i<16;i++){
    float xv0=lrelu(slw[i]*((aB[i].x-u0)*i0)+slb[i]);
    float xv1=lrelu(slw[i]*((aB[i].y-u1)*i1)+slb[i]);
    float2 st; st.x=xv0; st.y=xv1;
    *(float2*)(xp+(((size_t)i)<<16))=st;
    red[i]=xv0+xv1;
  }
  int lane=tid&63, wid=tid>>6;
  #pragma unroll
  for(int i=0;i<16;i++){
    float val=red[i];
    for(int m=32;m>0;m>>=1) val+=__shfl_xor(val,m);
    if(lane==0) sred[wid][i]=val;
  }
  __syncthreads();
  if(tid<16) capart[blockIdx.x*16+tid]=sred[0][tid]+sred[1][tid]+sred[2][tid]+sred[3][tid];
}

// ---------------- K3: sa = sigmoid(conv3x3(x_)) ----------------
__global__ __launch_bounds__(256) void k_sa(const float* __restrict__ x_,
    const float* __restrict__ Wsa, const float* __restrict__ bsa, float* __restrict__ sa){
  __shared__ float w[144]; __shared__ float bb;
  int tid=threadIdx.x;
  if(tid<144) w[tid]=Wsa[tid];
  if(tid==0) bb=bsa[0];
  __syncthreads();
  int pix=blockIdx.x*256+tid; int b=pix>>16, p=pix&65535;
  int y=p>>8, xx=p&255;
  float acc=bb;
  #pragma unroll
  for(int i=0;i<16;i++){
    const float* pl=x_+(((size_t)(b*16+i))<<16);
    #pragma unroll
    for(int ky=0;ky<3;ky++){
      int yy=y+ky-1;
      if((unsigned)yy<256u){
        #pragma unroll
        for(int kx=0;kx<3;kx++){
          int x2=xx+kx-1;
          if((unsigned)x2<256u) acc+=pl[(yy<<8)+x2]*w[i*9+ky*3+kx];
        }
      }
    }
  }
  sa[pix]=sigmoidf(acc);
}

// ---------------- K4: per-window variance (ddof=1) ----------------
__global__ __launch_bounds__(64) void k_var(const float* __restrict__ xm, float* __restrict__ var){
  int blk=blockIdx.x, tid=threadIdx.x;
  int b=blk>>10, n=blk&1023;
  int pix=((n>>5)<<11) + ((n&31)<<3) + ((tid>>3)<<8) + (tid&7);
  float val=xm[(b<<16)+pix];
  float s=val;
  for(int m=32;m>0;m>>=1) s+=__shfl_xor(s,m);
  float mean=s*(1.f/64.f);
  float d=val-mean; float q=d*d;
  for(int m=32;m>0;m>>=1) q+=__shfl_xor(q,m);
  if(tid==0) var[blk]=q*(1.f/63.f);
}

// ---------------- K5: rank -> mbin ----------------
__global__ __launch_bounds__(256) void k_rank(const float* __restrict__ var, float* __restrict__ mbin){
  __shared__ float va[1024];
  int bid=blockIdx.x; int b=bid>>2, seg=bid&3;
  int tid=threadIdx.x;
  for(int i=tid;i<1024;i+=256) va[i]=var[(b<<10)+i];
  __syncthreads();
  int n=seg*256+tid;
  float vn=va[n]; int r=0;
  for(int m=0;m<1024;m++){ float vm=va[m]; r += (vm<vn) || (vm==vn && m<n); }
  mbin[(b<<10)+n] = (r<512)?0.f:1.f;
}

// ---------------- K6: h0/h1 from Wm1 rowsums ----------------
__global__ __launch_bounds__(64) void k_hvec(const void* __restrict__ Wm1, const float* __restrict__ bm1,
    float* __restrict__ h0, float* __restrict__ h1, const int* __restrict__ fl){
  int j=blockIdx.x, tid=threadIdx.x;
  float s=0.f;
  if(fl[0]){
    const float* row=(const float*)Wm1+((size_t)j<<12);
    for(int k=tid;k<4096;k+=64) s+=row[k];
  } else {
    const bf16* row=(const bf16*)Wm1+((size_t)j<<12);
    for(int k=tid;k<4096;k+=64) s+=b2f(row[k]);
  }
  for(int m=32;m>0;m>>=1) s+=__shfl_xor(s,m);
  if(tid==0){ float bb=bm1[j]; h0[j]=lrelu(bb); h1[j]=lrelu(bb+s); }
}

// ---------------- K7: mask vectors (+ transposed copies) ----------------
__global__ __launch_bounds__(64) void k_mask(const void* __restrict__ Wm2, const float* __restrict__ bm2,
    const float* __restrict__ h0, const float* __restrict__ h1,
    float* __restrict__ m0, float* __restrict__ m1,
    float* __restrict__ m0T, float* __restrict__ m1T, const int* __restrict__ fl){
  int e=blockIdx.x, tid=threadIdx.x;
  float p0=0.f,p1=0.f;
  if(fl[0]){
    const float* row=(const float*)Wm2+((size_t)e<<11);
    for(int j=tid;j<2048;j+=64){ float w=row[j]; p0+=w*h0[j]; p1+=w*h1[j]; }
  } else {
    const bf16* row=(const bf16*)Wm2+((size_t)e<<11);
    for(int j=tid;j<2048;j+=64){ float w=b2f(row[j]); p0+=w*h0[j]; p1+=w*h1[j]; }
  }
  for(int m=32;m>0;m>>=1){ p0+=__shfl_xor(p0,m); p1+=__shfl_xor(p1,m); }
  if(tid==0){
    float bb=bm2[e]; float v0=p0+bb, v1=p1+bb;
    m0[e]=v0; m1[e]=v1;
    int te=(e&63)*64+(e>>6);
    m0T[te]=v0; m1T[te]=v1;
  }
}

// ---------------- K8: ca = sigmoid(Wca * mean(x_) + bca) ----------------
__global__ __launch_bounds__(64) void k_ca(const float* __restrict__ capart,
    const float* __restrict__ Wca, const float* __restrict__ bca, float* __restrict__ ca){
  __shared__ float m[16];
  int b=blockIdx.x, tid=threadIdx.x;
  if(tid<16){
    float s=0.f;
    for(int blk=0;blk<128;blk++) s+=capart[((b*128)+blk)*16+tid];
    m[tid]=s*(1.f/65536.f);
  }
  __syncthreads();
  float a=bca[tid];
  #pragma unroll
  for(int i=0;i<16;i++) a+=Wca[(tid<<4)+i]*m[i];
  ca[(b<<6)+tid]=sigmoidf(a);
}

// ---------------- K_PACK: apply masks; x*mk, v*mk, v*sa*(1-mk) -> window-major bf16 ----------------
__global__ __launch_bounds__(256) void k_pack(const void* __restrict__ x, const float* __restrict__ v,
    const float* __restrict__ sa, const float* __restrict__ mbin,
    const float* __restrict__ m0T, const float* __restrict__ m1T, const int* __restrict__ fl,
    unsigned short* __restrict__ xwb, unsigned short* __restrict__ vwb, unsigned short* __restrict__ vswb){
  int wp=blockIdx.x; int b=wp>>9, np=wp&511;
  int n0=np*2;
  int base=((n0>>5)<<11)+((n0&31)<<3);
  int t=threadIdx.x; int c0=t>>3, row=t&7;
  int isf32=fl[0];
  const float* mTa = (mbin[b*1024+n0  ]>0.5f)? m1T : m0T;
  const float* mTb = (mbin[b*1024+n0+1]>0.5f)? m1T : m0T;
  for(int h=0;h<2;h++){
    int ch=c0+h*32;
    size_t gb=(((size_t)(b*64+ch))<<16) + base + row*256;
    float xv[16], vv[16], sv[16];
    if(isf32){
      const float* xp=(const float*)x+gb;
      #pragma unroll
      for(int i=0;i<16;i++) xv[i]=xp[i];
    } else {
      const bf16* xp=(const bf16*)x+gb;
      #pragma unroll
      for(int i=0;i<16;i++) xv[i]=b2f(xp[i]);
    }
    const float* vp=v+gb;
    const float* sp=sa+(((size_t)b)<<16)+base+row*256;
    #pragma unroll
    for(int i=0;i<16;i++){ vv[i]=vp[i]; sv[i]=sp[i]; }
    size_t o0=((size_t)(b*1024+n0)*64+ch)*64 + row*8;
    #pragma unroll
    for(int wnd=0;wnd<2;wnd++){
      const float* mT = wnd? mTb : mTa;
      size_t oo=o0+(size_t)wnd*4096;
      int s=wnd*8;
      float mk[8];
      #pragma unroll
      for(int j=0;j<8;j++) mk[j]=mT[ch*64+row*8+j];
      uint4 ux, uv, us;
      ux.x=pack2(xv[s+0]*mk[0],xv[s+1]*mk[1]); ux.y=pack2(xv[s+2]*mk[2],xv[s+3]*mk[3]);
      ux.z=pack2(xv[s+4]*mk[4],xv[s+5]*mk[5]); ux.w=pack2(xv[s+6]*mk[6],xv[s+7]*mk[7]);
      uv.x=pack2(vv[s+0]*mk[0],vv[s+1]*mk[1]); uv.y=pack2(vv[s+2]*mk[2],vv[s+3]*mk[3]);
      uv.z=pack2(vv[s+4]*mk[4],vv[s+5]*mk[5]); uv.w=pack2(vv[s+6]*mk[6],vv[s+7]*mk[7]);
      us.x=pack2(vv[s+0]*sv[s+0]*(1.f-mk[0]),vv[s+1]*sv[s+1]*(1.f-mk[1]));
      us.y=pack2(vv[s+2]*sv[s+2]*(1.f-mk[2]),vv[s+3]*sv[s+3]*(1.f-mk[3]));
      us.z=pack2(vv[s+4]*sv[s+4]*(1.f-mk[4]),vv[s+5]*sv[s+5]*(1.f-mk[5]));
      us.w=pack2(vv[s+6]*sv[s+6]*(1.f-mk[6]),vv[s+7]*sv[s+7]*(1.f-mk[7]));
      *(uint4*)(xwb+oo)=ux; *(uint4*)(vwb+oo)=uv; *(uint4*)(vswb+oo)=us;
    }
  }
}

// ---------------- K9: windowed attention via MFMA -> img ----------------
#define STR 72
#define STRF 65
__global__ __launch_bounds__(256,4) void k_attn_mfma(
    const unsigned short* __restrict__ xwb, const unsigned short* __restrict__ vwb,
    const unsigned short* __restrict__ vswb,
    const short* __restrict__ Wqb, const float* __restrict__ bq,
    const short* __restrict__ Wkb, const float* __restrict__ bk,
    float* __restrict__ img){
  __shared__ short sT[64*STR];
  __shared__ short sQK[2*64*STR];
  __shared__ short sV1[64*STR];
  short* sQ=sQK; short* sK=sQK+64*STR;
  float* sF=(float*)sQK;
  int tid=threadIdx.x, blk=blockIdx.x;
  int b=blk>>10, n=blk&1023;
  int base=((n>>5)<<11) + ((n&31)<<3);
  size_t plane=((size_t)b*64)<<16;
  const unsigned short* xw=xwb+(size_t)blk*4096;
  const unsigned short* vw=vwb+(size_t)blk*4096;
  for(int e=tid;e<4096;e+=256){
    int c=e>>6, tok=e&63;
    sT[tok*STR+c]=(short)xw[e];
    sV1[c*STR+tok]=(short)vw[e];
  }
  __syncthreads();
  int lane=tid&63, wid=tid>>6;
  int pb=wid*16, lr=lane&15, lg=lane>>4;
  short8v ta[2];
  #pragma unroll
  for(int ks=0;ks<2;ks++) ta[ks]=*(const short8v*)&sT[(pb+lr)*STR + ks*32 + lg*8];
  #pragma unroll
  for(int nt=0;nt<4;nt++){
    float bqv=bq[nt*16+lr], bkv=bk[nt*16+lr];
    f32x4 qa={bqv,bqv,bqv,bqv}, ka={bkv,bkv,bkv,bkv};
    #pragma unroll
    for(int ks=0;ks<2;ks++){
      short8v wq=*(const short8v*)(Wqb + (nt*16+lr)*64 + ks*32 + lg*8);
      short8v wk=*(const short8v*)(Wkb + (nt*16+lr)*64 + ks*32 + lg*8);
      qa=__builtin_amdgcn_mfma_f32_16x16x32_bf16(ta[ks],wq,qa,0,0,0);
      ka=__builtin_amdgcn_mfma_f32_16x16x32_bf16(ta[ks],wk,ka,0,0,0);
    }
    #pragma unroll
    for(int r=0;r<4;r++){
      sQ[(pb+lg*4+r)*STR + nt*16+lr]=f2bs(qa[r]);
      sK[(pb+lg*4+r)*STR + nt*16+lr]=f2bs(ka[r]);
    }
  }
  __syncthreads();
  short8v qa2[2];
  #pragma unroll
  for(int ks=0;ks<2;ks++) qa2[ks]=*(const short8v*)&sQ[(pb+lr)*STR + ks*32 + lg*8];
  f32x4 sacc[4];
  #pragma unroll
  for(int nt=0;nt<4;nt++){
    f32x4 a={0.f,0.f,0.f,0.f};
    #pragma unroll
    for(int ks=0;ks<2;ks++){
      short8v kb=*(const short8v*)&sK[(nt*16+lr)*STR + ks*32 + lg*8];
      a=__builtin_amdgcn_mfma_f32_16x16x32_bf16(qa2[ks],kb,a,0,0,0);
    }
    sacc[nt]=a;
  }
  f32x4 pa[4];
  #pragma unroll
  for(int r=0;r<4;r++){
    float mx=fmaxf(fmaxf(sacc[0][r],sacc[1][r]),fmaxf(sacc[2][r],sacc[3][r]));
    #pragma unroll
    for(int m=1;m<16;m<<=1) mx=fmaxf(mx,__shfl_xor(mx,m));
    float e0=expf(sacc[0][r]-mx), e1=expf(sacc[1][r]-mx);
    float e2=expf(sacc[2][r]-mx), e3=expf(sacc[3][r]-mx);
    float sum=e0+e1+e2+e3;
    #pragma unroll
    for(int m=1;m<16;m<<=1) sum+=__shfl_xor(sum,m);
    float inv=1.f/sum;
    pa[0][r]=e0*inv; pa[1][r]=e1*inv; pa[2][r]=e2*inv; pa[3][r]=e3*inv;
  }
  #pragma unroll
  for(int nt=0;nt<4;nt++){
    #pragma unroll
    for(int r=0;r<4;r++)
      sT[(pb+lg*4+r)*STR + nt*16+lr]=f2bs(pa[nt][r]);
  }
  __syncthreads();
  short8v aa[2];
  #pragma unroll
  for(int ks=0;ks<2;ks++) aa[ks]=*(const short8v*)&sT[(pb+lr)*STR + ks*32 + lg*8];
  #pragma unroll
  for(int nt=0;nt<4;nt++){
    f32x4 f={0.f,0.f,0.f,0.f};
    #pragma unroll
    for(int ks=0;ks<2;ks++){
      short8v vb=*(const short8v*)&sV1[(nt*16+lr)*STR + ks*32 + lg*8];
      f=__builtin_amdgcn_mfma_f32_16x16x32_bf16(aa[ks],vb,f,0,0,0);
    }
    #pragma unroll
    for(int r=0;r<4;r++) sF[(pb+lg*4+r)*STRF + nt*16+lr]=f[r];
  }
  __syncthreads();
  const unsigned short* vsw=vswb+(size_t)blk*4096;
  for(int e=tid;e<4096;e+=256){
    int c=e>>6, tok=e&63;
    float f=sF[tok*STRF+c];
    int pix=base+((tok>>3)<<8)+(tok&7);
    img[plane+(((size_t)c)<<16)+pix]=f+us2f(vsw[e]);
  }
}

// ---------------- K_DWF: fused depthwise dil1+dil2+gelu*ca+img -> bf16 out, 8-row strips ----------------
#define IST 264
__global__ __launch_bounds__(256) void k_dwfuse(const float* __restrict__ img,
    const float* __restrict__ dw1w, const float* __restrict__ dwb1,
    const float* __restrict__ dw2w, const float* __restrict__ dwb2,
    const float* __restrict__ ca, unsigned short* __restrict__ outb){
  __shared__ float sImg[14*IST];
  __shared__ float sTmp[12*IST];
  __shared__ float k1[9], k2[9];
  __shared__ float bb1, bb2, cav;
  int bid=blockIdx.x; int b=bid>>11, c=(bid>>5)&63, sy=bid&31;
  int y0=sy*8;
  int tid=threadIdx.x;
  if(tid<9){ k1[tid]=dw1w[c*9+tid]; k2[tid]=dw2w[c*9+tid]; }
  if(tid==9)  bb1=dwb1[c];
  if(tid==10) bb2=dwb2[c];
  if(tid==11) cav=ca[b*64+c];
  const float* ip=img+(((size_t)(b*64+c))<<16);
  for(int i=tid;i<14*IST;i+=256){
    int r=i/IST, cl=i-r*IST;
    int gy=y0-3+r, gx=cl-3;
    float v=0.f;
    if(cl<262 && (unsigned)gy<256u && (unsigned)gx<256u) v=ip[(gy<<8)+gx];
    sImg[i]=v;
  }
  __syncthreads();
  for(int i=tid;i<12*IST;i+=256){
    int r=i/IST, cl=i-r*IST;
    float t=0.f;
    if(cl<260){
      int ty=y0-2+r, tc=cl-2;
      if((unsigned)ty<256u && (unsigned)tc<256u){
        t=bb1;
        #pragma unroll
        for(int dy=0;dy<3;dy++)
          #pragma unroll
          for(int dx=0;dx<3;dx++)
            t+=sImg[(r+dy)*IST+(cl+dx)]*k1[dy*3+dx];
      }
    }
    sTmp[i]=t;
  }
  __syncthreads();
  unsigned short* op=outb+(((size_t)(b*64+c))<<16);
  int lx=tid;
  #pragma unroll
  for(int ly=0;ly<8;ly++){
    float cs=bb2;
    #pragma unroll
    for(int dy=0;dy<3;dy++)
      #pragma unroll
      for(int dx=0;dx<3;dx++)
        cs+=sTmp[(ly+2*dy)*IST + lx+2*dx]*k2[dy*3+dx];
    float center=sImg[(ly+3)*IST + lx+3];
    op[((y0+ly)<<8)+lx]=(unsigned short)f2bs(geluf(cs)*cav+center);
  }
}

// ---------------- K_FDW: ffn depthwise (E bf16) + gelu gate -> bf16 out ----------------
#define EST 260
__global__ __launch_bounds__(256) void k_ffn_dw_t(const unsigned short* __restrict__ E,
    const float* __restrict__ dwf, unsigned short* __restrict__ g){
  __shared__ unsigned short sE1[18*EST];
  __shared__ unsigned short sE2[18*EST];
  __shared__ float k1[9], k2[9];
  int bid=blockIdx.x; int b=bid>>10, c=(bid>>4)&63, sy=bid&15;
  int y0=sy*16;
  int tid=threadIdx.x;
  if(tid<9){ k1[tid]=dwf[c*9+tid]; k2[tid]=dwf[(64+c)*9+tid]; }
  if(tid<144){
    int pl=tid/72; int rem=tid-pl*72; int rr=rem>>2; int cc=rem&3;
    int col=(cc<2)? cc : (256+cc);
    if(pl==0) sE1[rr*EST+col]=0; else sE2[rr*EST+col]=0;
  }
  const unsigned short* p1=E+(((size_t)(b*128+c))<<16);
  const unsigned short* p2=E+(((size_t)(b*128+64+c))<<16);
  int half=tid>>7, t2=tid&127;
  const unsigned short* pp = half? p2 : p1;
  for(int r=0;r<18;r++){
    int gy=y0-1+r;
    unsigned val=0;
    if((unsigned)gy<256u) val=*(const unsigned*)(pp+(gy<<8)+t2*2);
    unsigned short* dst = half? sE2 : sE1;
    *(unsigned*)(dst + r*EST + 2 + t2*2) = val;
  }
  __syncthreads();
  unsigned short* op=g+(((size_t)(b*64+c))<<16);
  int lx=tid;
  #pragma unroll 4
  for(int ly=0;ly<16;ly++){
    float a1=0.f, a2=0.f;
    #pragma unroll
    for(int dy=0;dy<3;dy++)
      #pragma unroll
      for(int dx=0;dx<3;dx++){
        int idx=(ly+dy)*EST + lx+dx+1;
        a1+=us2f(sE1[idx])*k1[dy*3+dx];
        a2+=us2f(sE2[idx])*k2[dy*3+dx];
      }
    op[((y0+ly)<<8)+lx]=(unsigned short)f2bs(geluf(a1)*a2);
  }
}

extern "C" void kernel_launch(void* const* d_in, const int* in_sizes, int n_in,
                              void* d_out, int out_size, void* d_ws, size_t ws_size,
                              hipStream_t stream){
  (void)in_sizes; (void)n_in; (void)out_size; (void)ws_size;
  const void* x  = d_in[0];
  const void* Wm1= d_in[23];
  const void* Wm2= d_in[25];

  char* ws=(char*)d_ws;
  // Slot A [0,64MiB):    v (f32) -> E (bf16, 128ch) -> res2 (f32)
  // Slot B [64,128MiB):  img (f32) -> res -> x1 (in-place f32)
  // Slot C [128,192MiB): xwb(32MiB)+vwb(32MiB) -> outb (bf16) -> gbuf (bf16)
  // [192MiB..~211MiB):   small buffers
  // [220MiB,252MiB):     vswb (bf16)
  float* v    =(float*)(ws);
  unsigned short* E=(unsigned short*)(ws);
  float* res2 =(float*)(ws);
  float* img  =(float*)(ws+67108864);
  float* res  =(float*)(ws+67108864);
  float* x1   =(float*)(ws+67108864);
  unsigned short* xwb=(unsigned short*)(ws+134217728);
  unsigned short* vwb=(unsigned short*)(ws+134217728+33554432);
  unsigned short* outb=(unsigned short*)(ws+134217728);
  unsigned short* gbuf=(unsigned short*)(ws+134217728);
  unsigned short* vswb=(unsigned short*)(ws+230686720);
  char* sm = ws+201326592;
  float* x_    =(float*)(sm);              // 16 MB
  float* sa    =(float*)(sm+16777216);     // 1 MB
  float* xm    =(float*)(sm+17825792);     // 1 MB
  float* var   =(float*)(sm+18874368);     // 16 KB
  float* mbin  =(float*)(sm+18890752);     // 16 KB
  float* h0    =(float*)(sm+18907136);     // 8 KB
  float* h1    =(float*)(sm+18915328);     // 8 KB
  float* m0    =(float*)(sm+18923520);     // 16 KB
  float* m1    =(float*)(sm+18939904);     // 16 KB
  float* capart=(float*)(sm+18956288);     // 64 KB
  float* ca    =(float*)(sm+19021824);     // 1 KB
  int*   flag  =(int*)  (sm+19022848);     // 4 B
  float* wbuf  =(float*)(sm+19023872);     // ~161 KB
  short* Wqb   =(short*)(sm+19200000);     // 8 KB
  short* Wkb   =(short*)(sm+19208192);     // 8 KB
  float* m0T   =(float*)(sm+19216384);     // 16 KB
  float* m1T   =(float*)(sm+19232768);     // 16 KB
  short* Wob   =(short*)(sm+19249152);     // 8 KB
  short* Wfib  =(short*)(sm+19257344);     // 16 KB
  short* Wfob  =(short*)(sm+19273728);     // 8 KB

  static const int din_idx[31]={5,6,7,8,9,10,11,12,13,14,15,16,17,18,19,20,21,22,24,26,27,28,29,30,31,32,33,1,2,3,4};
  static const int szs[31]  ={4096,64,4096,64,4096,64,576,64,576,64,4096,64,1024,16,1024,16,16,16,2048,4096,1024,64,144,1,8192,1152,4096,64,64,64,64};
  CvtArgs ca_args;
  int off=0;
  int offs[31];
  for(int t=0;t<31;t++){
    ca_args.src[t]=d_in[din_idx[t]];
    ca_args.sz[t]=szs[t];
    ca_args.off[t]=off;
    offs[t]=off;
    off+=szs[t];
  }
  const float* Wv  =wbuf+offs[0];  const float* bv  =wbuf+offs[1];
  const float* Wq  =wbuf+offs[2];  const float* bq  =wbuf+offs[3];
  const float* Wk  =wbuf+offs[4];  const float* bk  =wbuf+offs[5];
  const float* dw1 =wbuf+offs[6];  const float* dwb1=wbuf+offs[7];
  const float* dw2 =wbuf+offs[8];  const float* dwb2=wbuf+offs[9];
  const float* Wo  =wbuf+offs[10]; const float* bo  =wbuf+offs[11];
  const float* W_in=wbuf+offs[12]; const float* b_in=wbuf+offs[13];
  const float* Wc  =wbuf+offs[14]; const float* bc  =wbuf+offs[15];
  const float* lnw =wbuf+offs[16]; const float* lnb =wbuf+offs[17];
  const float* bm1 =wbuf+offs[18]; const float* bm2 =wbuf+offs[19];
  const float* Wca =wbuf+offs[20]; const float* bca =wbuf+offs[21];
  const float* Wsa =wbuf+offs[22]; const float* bsa =wbuf+offs[23];
  const float* Wfi =wbuf+offs[24]; const float* dwf =wbuf+offs[25];
  const float* Wfo =wbuf+offs[26];
  const float* wn1 =wbuf+offs[27]; const float* bn1 =wbuf+offs[28];
  const float* wn2 =wbuf+offs[29]; const float* bn2 =wbuf+offs[30];

  hipLaunchKernelGGL(k_detect,   dim3(1),      dim3(256), 0, stream, x, flag);
  hipLaunchKernelGGL(k_cvt,      dim3(31),     dim3(256), 0, stream, ca_args, flag, wbuf);
  hipLaunchKernelGGL(k_w2b,      dim3(16),     dim3(256), 0, stream, Wq, Wk, Wqb, Wkb);
  hipLaunchKernelGGL(k_w2b3,     dim3(32),     dim3(256), 0, stream, Wo, Wfi, Wfo, Wob, Wfib, Wfob);
  hipLaunchKernelGGL(k_gemm32,   dim3(256,2),  dim3(256), 0, stream, x, Wv, bv, 1, v, flag, 0);
  hipLaunchKernelGGL(k_route,    dim3(512),    dim3(256), 0, stream, v, W_in, b_in, Wc, bc, lnw, lnb, x_, xm, capart);
  hipLaunchKernelGGL(k_sa,       dim3(1024),   dim3(256), 0, stream, x_, Wsa, bsa, sa);
  hipLaunchKernelGGL(k_var,      dim3(4096),   dim3(64),  0, stream, xm, var);
  hipLaunchKernelGGL(k_rank,     dim3(16),     dim3(256), 0, stream, var, mbin);
  hipLaunchKernelGGL(k_hvec,     dim3(2048),   dim3(64),  0, stream, Wm1, bm1, h0, h1, flag);
  hipLaunchKernelGGL(k_mask,     dim3(4096),   dim3(64),  0, stream, Wm2, bm2, h0, h1, m0, m1, m0T, m1T, flag);
  hipLaunchKernelGGL(k_ca,       dim3(4),      dim3(64),  0, stream, capart, Wca, bca, ca);
  hipLaunchKernelGGL(k_pack,     dim3(2048),   dim3(256), 0, stream, x, v, sa, mbin, m0T, m1T, flag, xwb, vwb, vswb);
  hipLaunchKernelGGL(k_attn_mfma,dim3(4096),   dim3(256), 0, stream, xwb, vwb, vswb, Wqb, bq, Wkb, bk, img);
  hipLaunchKernelGGL(k_dwfuse,   dim3(8192),   dim3(256), 0, stream, img, dw1, dwb1, dw2, dwb2, ca, outb);
  // res = Wo * outb + bo  (MFMA)
  hipLaunchKernelGGL(k_gemm_mf,  dim3(4096),   dim3(256), 0, stream, (const void*)outb, 0, Wob, bo, 1, (void*)res, 64, 0);
  hipLaunchKernelGGL(k_add_ln,   dim3(512),    dim3(256), 0, stream, res, x, wn1, bn1, (void*)x1, flag, 0, 1);
  // E = bf16(Wfi * x1)  (MFMA, f32 input staged)
  hipLaunchKernelGGL(k_gemm_mf,  dim3(4096),   dim3(256), 0, stream, (const void*)x1, 1, Wfib, wbuf, 0, (void*)E, 128, 1);
  hipLaunchKernelGGL(k_ffn_dw_t, dim3(4096),   dim3(256), 0, stream, E, dwf, gbuf);
  // res2 = Wfo * g  (MFMA)
  hipLaunchKernelGGL(k_gemm_mf,  dim3(4096),   dim3(256), 0, stream, (const void*)gbuf, 0, Wfob, wbuf, 0, (void*)res2, 64, 0);
  hipLaunchKernelGGL(k_add_ln,   dim3(512),    dim3(256), 0, stream, res2, x1, wn2, bn2, d_out, flag, 1, 0);
}

// Round 10
// 609.804 us; speedup vs baseline: 3.0087x; 1.0893x over previous
//
#include <hip/hip_runtime.h>
#include <hip/hip_bf16.h>

typedef __hip_bfloat16 bf16;
typedef __attribute__((ext_vector_type(8))) short short8v;
typedef __attribute__((ext_vector_type(4))) float f32x4;

#define DEV static __device__ __forceinline__

DEV float b2f(bf16 h){ return __bfloat162float(h); }
DEV float us2f(unsigned short u){ unsigned v=((unsigned)u)<<16; float f; __builtin_memcpy(&f,&v,4); return f; }
DEV short f2bs(float f){ bf16 h=__float2bfloat16(f); short s; __builtin_memcpy(&s,&h,2); return s; }
DEV unsigned pack2(float a, float b){ return ((unsigned)(unsigned short)f2bs(b)<<16)|(unsigned short)f2bs(a); }
DEV float lrelu(float x){ return x >= 0.f ? x : 0.1f*x; }
DEV float geluf(float x){ return 0.5f*x*(1.f + erff(x*0.70710678118654752440f)); }
DEV float sigmoidf(float x){ return 1.f/(1.f + expf(-x)); }

// B=4, C=64, H=W=256, HW=65536, WS=8, N=1024 windows/batch, embed=4096

// ---------------- K0a: detect storage dtype ----------------
__global__ __launch_bounds__(256) void k_detect(const void* x, int* flag){
  __shared__ int cnt;
  if(threadIdx.x==0) cnt=0;
  __syncthreads();
  const unsigned short* up=(const unsigned short*)x;
  int c=0;
  for(int k=0;k<16;k++){
    unsigned short u=up[(threadIdx.x*16+k)*2];
    if(((u>>7)&0xFF)==0xFF) c++;
  }
  atomicAdd(&cnt,c);
  __syncthreads();
  if(threadIdx.x==0) flag[0] = (cnt>0) ? 1 : 0;  // 1 => f32 storage
}

// ---------------- K0b: convert small weights to f32 wbuf ----------------
struct CvtArgs { const void* src[31]; int sz[31]; int off[31]; };
__global__ __launch_bounds__(256) void k_cvt(CvtArgs a, const int* fl, float* wbuf){
  int t=blockIdx.x; int n=a.sz[t]; const void* s=a.src[t]; float* d=wbuf+a.off[t];
  if(fl[0]){
    const float* sp=(const float*)s;
    for(int i=threadIdx.x;i<n;i+=256) d[i]=sp[i];
  } else {
    const bf16* sp=(const bf16*)s;
    for(int i=threadIdx.x;i<n;i+=256) d[i]=b2f(sp[i]);
  }
}

// ---------------- K0c: Wq/Wk -> bf16 for MFMA ----------------
__global__ __launch_bounds__(256) void k_w2b(const float* __restrict__ wq, const float* __restrict__ wk,
    short* __restrict__ Wqb, short* __restrict__ Wkb){
  int i=blockIdx.x*256+threadIdx.x;
  if(i<4096){ Wqb[i]=f2bs(wq[i]); Wkb[i]=f2bs(wk[i]); }
}

// ---------------- K0d: Wo/Wfi/Wfo -> bf16 for MFMA ----------------
__global__ __launch_bounds__(256) void k_w2b3(const float* __restrict__ wo, const float* __restrict__ wfi,
    const float* __restrict__ wfo, short* __restrict__ Wob, short* __restrict__ Wfib, short* __restrict__ Wfob){
  int i=blockIdx.x*256+threadIdx.x;
  if(i<4096) Wob[i]=f2bs(wo[i]);
  if(i<8192) Wfib[i]=f2bs(wfi[i]);
  if(i<4096) Wfob[i]=f2bs(wfo[i]);
}

// ---------------- K_G: 32-och x 4-pix 1x1-conv GEMM, f32 (conv_v only; exact for routing) ----------------
__global__ __launch_bounds__(256) void k_gemm32(
    const void* __restrict__ in, const float* __restrict__ W,
    const float* __restrict__ bias, int has_bias,
    float* __restrict__ out, const int* __restrict__ fl, int force_f32){
  __shared__ float sW[2048]; __shared__ float sb[32];
  int tid=threadIdx.x, og=blockIdx.y;
  for(int i=tid;i<2048;i+=256) sW[i]=W[og*2048+i];
  if(tid<32) sb[tid]= has_bias ? bias[og*32+tid] : 0.f;
  __syncthreads();
  int g=blockIdx.x*1024+tid*4; int b=g>>16, p=g&65535;
  float4 a[32];
  #pragma unroll
  for(int o=0;o<32;o++){ float bv=sb[o]; a[o]=make_float4(bv,bv,bv,bv); }
  bool f32in = force_f32 || (fl[0]!=0);
  size_t base=(((size_t)b*64)<<16)+p;
  if(f32in){
    const float* ip=(const float*)in + base;
    for(int c=0;c<64;c++){
      float4 xv=*(const float4*)(ip + (((size_t)c)<<16));
      #pragma unroll
      for(int o=0;o<32;o++){ float w=sW[o*64+c];
        a[o].x+=w*xv.x; a[o].y+=w*xv.y; a[o].z+=w*xv.z; a[o].w+=w*xv.w; }
    }
  } else {
    const bf16* ip=(const bf16*)in + base;
    for(int c=0;c<64;c++){
      const bf16* q=ip+(((size_t)c)<<16);
      float4 xv=make_float4(b2f(q[0]),b2f(q[1]),b2f(q[2]),b2f(q[3]));
      #pragma unroll
      for(int o=0;o<32;o++){ float w=sW[o*64+c];
        a[o].x+=w*xv.x; a[o].y+=w*xv.y; a[o].z+=w*xv.z; a[o].w+=w*xv.w; }
    }
  }
  float* op=out + (((size_t)(b*64+og*32))<<16) + p;
  #pragma unroll
  for(int o=0;o<32;o++) *(float4*)(op+(((size_t)o)<<16))=a[o];
}

// ---------------- K_GM: MFMA 1x1-conv GEMM (ffn_in): D = W * in, bf16/f32 in, f32/bf16 out ----------------
__global__ __launch_bounds__(256) void k_gemm_mf(
    const void* __restrict__ in, int in_f32,
    const short* __restrict__ Wb, const float* __restrict__ bias, int has_bias,
    void* __restrict__ out, int och, int out_bf16){
  __shared__ short Ain[64*72];
  int tid=threadIdx.x;
  int g0=blockIdx.x*64; int b=g0>>16, p0=g0&65535;
  int c=tid>>2, q=tid&3;
  size_t base=(((size_t)(b*64+c))<<16) + p0;
  if(in_f32){
    const float* ip=(const float*)in + base;
    #pragma unroll
    for(int j=0;j<4;j++){
      int po=q*16+j*4;
      float4 xv=*(const float4*)(ip+po);
      Ain[(po+0)*72+c]=f2bs(xv.x); Ain[(po+1)*72+c]=f2bs(xv.y);
      Ain[(po+2)*72+c]=f2bs(xv.z); Ain[(po+3)*72+c]=f2bs(xv.w);
    }
  } else {
    const unsigned short* ip=(const unsigned short*)in + base;
    #pragma unroll
    for(int j=0;j<4;j++){
      int po=q*16+j*4;
      uint2 u=*(const uint2*)(ip+po);
      Ain[(po+0)*72+c]=(short)(u.x&0xffff); Ain[(po+1)*72+c]=(short)(u.x>>16);
      Ain[(po+2)*72+c]=(short)(u.y&0xffff); Ain[(po+3)*72+c]=(short)(u.y>>16);
    }
  }
  __syncthreads();
  int lane=tid&63, wid=tid>>6;
  int lr=lane&15, lg=lane>>4;
  int pix0=wid*16;
  short8v bfrag[2];
  #pragma unroll
  for(int ks=0;ks<2;ks++) bfrag[ks]=*(const short8v*)&Ain[(pix0+lr)*72 + ks*32 + lg*8];
  int ntn=och>>4;
  for(int nt=0;nt<ntn;nt++){
    f32x4 acc;
    if(has_bias){
      #pragma unroll
      for(int r=0;r<4;r++) acc[r]=bias[nt*16+lg*4+r];
    } else {
      acc=(f32x4){0.f,0.f,0.f,0.f};
    }
    #pragma unroll
    for(int ks=0;ks<2;ks++){
      short8v afrag=*(const short8v*)(Wb + (nt*16+lr)*64 + ks*32 + lg*8);
      acc=__builtin_amdgcn_mfma_f32_16x16x32_bf16(afrag,bfrag[ks],acc,0,0,0);
    }
    if(out_bf16){
      unsigned short* op=(unsigned short*)out;
      #pragma unroll
      for(int r=0;r<4;r++){
        int m=nt*16+lg*4+r;
        op[(((size_t)(b*och+m))<<16) + p0 + pix0 + lr]=(unsigned short)f2bs(acc[r]);
      }
    } else {
      float* op=(float*)out;
      #pragma unroll
      for(int r=0;r<4;r++){
        int m=nt*16+lg*4+r;
        op[(((size_t)(b*och+m))<<16) + p0 + pix0 + lr]=acc[r];
      }
    }
  }
}

// ---------------- K_GL: MFMA GEMM (64 och) + residual-add + LayerNorm fused ----------------
// in: bf16 channel-planar. base_mode: 0=follow flag, 1=force f32. out_mode: 0=follow flag, 1=force f32.
__global__ __launch_bounds__(256) void k_gemm_ln(
    const unsigned short* __restrict__ in,
    const short* __restrict__ Wb, const float* __restrict__ bias, int has_bias,
    const void* __restrict__ basex,
    const float* __restrict__ lnw, const float* __restrict__ lnb,
    void* __restrict__ out,
    const int* __restrict__ fl, int base_mode, int out_mode){
  __shared__ short Ain[64*72];
  int tid=threadIdx.x;
  int g0=blockIdx.x*64; int b=g0>>16, p0=g0&65535;
  int c=tid>>2, q=tid&3;
  {
    const unsigned short* ip=in + (((size_t)(b*64+c))<<16) + p0;
    #pragma unroll
    for(int j=0;j<4;j++){
      int po=q*16+j*4;
      uint2 u=*(const uint2*)(ip+po);
      Ain[(po+0)*72+c]=(short)(u.x&0xffff); Ain[(po+1)*72+c]=(short)(u.x>>16);
      Ain[(po+2)*72+c]=(short)(u.y&0xffff); Ain[(po+3)*72+c]=(short)(u.y>>16);
    }
  }
  __syncthreads();
  int lane=tid&63, wid=tid>>6;
  int lr=lane&15, lg=lane>>4;
  int pix0=wid*16;
  short8v bfrag[2];
  #pragma unroll
  for(int ks=0;ks<2;ks++) bfrag[ks]=*(const short8v*)&Ain[(pix0+lr)*72 + ks*32 + lg*8];
  float rl[16];
  #pragma unroll
  for(int nt=0;nt<4;nt++){
    f32x4 acc;
    if(has_bias){
      #pragma unroll
      for(int r=0;r<4;r++) acc[r]=bias[nt*16+lg*4+r];
    } else {
      acc=(f32x4){0.f,0.f,0.f,0.f};
    }
    #pragma unroll
    for(int ks=0;ks<2;ks++){
      short8v afrag=*(const short8v*)(Wb + (nt*16+lr)*64 + ks*32 + lg*8);
      acc=__builtin_amdgcn_mfma_f32_16x16x32_bf16(afrag,bfrag[ks],acc,0,0,0);
    }
    #pragma unroll
    for(int r=0;r<4;r++) rl[nt*4+r]=acc[r];
  }
  int pix=p0+pix0+lr;
  bool bf32 = (base_mode==1) || (base_mode==0 && fl[0]);
  if(bf32){
    const float* xp=(const float*)basex;
    #pragma unroll
    for(int nt=0;nt<4;nt++)
      #pragma unroll
      for(int r=0;r<4;r++)
        rl[nt*4+r]+=xp[(((size_t)(b*64+nt*16+lg*4+r))<<16)+pix];
  } else {
    const unsigned short* xp=(const unsigned short*)basex;
    #pragma unroll
    for(int nt=0;nt<4;nt++)
      #pragma unroll
      for(int r=0;r<4;r++)
        rl[nt*4+r]+=us2f(xp[(((size_t)(b*64+nt*16+lg*4+r))<<16)+pix]);
  }
  // per-pixel LN over 64 channels: 16 local + lanes {lr, lr+16, lr+32, lr+48}
  float s=0.f;
  #pragma unroll
  for(int i=0;i<16;i++) s+=rl[i];
  s+=__shfl_xor(s,16); s+=__shfl_xor(s,32);
  float mean=s*(1.f/64.f);
  float qv=0.f;
  #pragma unroll
  for(int i=0;i<16;i++){ float d=rl[i]-mean; qv+=d*d; }
  qv+=__shfl_xor(qv,16); qv+=__shfl_xor(qv,32);
  float inv=1.f/sqrtf(qv*(1.f/64.f)+1e-6f);
  bool of32 = (out_mode==1) || (out_mode==0 && fl[0]);
  if(of32){
    float* op=(float*)out;
    #pragma unroll
    for(int nt=0;nt<4;nt++)
      #pragma unroll
      for(int r=0;r<4;r++){
        int m=nt*16+lg*4+r;
        op[(((size_t)(b*64+m))<<16)+pix]=lnw[m]*((rl[nt*4+r]-mean)*inv)+lnb[m];
      }
  } else {
    unsigned short* op=(unsigned short*)out;
    #pragma unroll
    for(int nt=0;nt<4;nt++)
      #pragma unroll
      for(int r=0;r<4;r++){
        int m=nt*16+lg*4+r;
        op[(((size_t)(b*64+m))<<16)+pix]=(unsigned short)f2bs(lnw[m]*((rl[nt*4+r]-mean)*inv)+lnb[m]);
      }
  }
}

// ---------------- K2: route (2 pix/thread) ----------------
__global__ __launch_bounds__(256) void k_route(const float* __restrict__ v,
    const float* __restrict__ W_in, const float* __restrict__ b_in,
    const float* __restrict__ Wc, const float* __restrict__ bc,
    const float* __restrict__ lnw, const float* __restrict__ lnb,
    float* __restrict__ x_, float* __restrict__ xm, float* __restrict__ capart){
  __shared__ float wA[1024], wB[1024], sba[16], sbb[16], slw[16], slb[16];
  __shared__ float sred[4][16];
  int tid=threadIdx.x;
  for(int i=tid;i<1024;i+=256){ wA[i]=W_in[i]; wB[i]=Wc[i]; }
  if(tid<16){ sba[tid]=b_in[tid]; sbb[tid]=bc[tid]; slw[tid]=lnw[tid]; slb[tid]=lnb[tid]; }
  __syncthreads();
  int g=blockIdx.x*512+tid*2; int b=g>>16, p=g&65535;
  float2 aA[16], aB[16];
  #pragma unroll
  for(int i=0;i<16;i++){ aA[i]=make_float2(sba[i],sba[i]); aB[i]=make_float2(sbb[i],sbb[i]); }
  const float* vp=v+(((size_t)b*64)<<16)+p;
  for(int c=0;c<64;c++){
    float2 vv=*(const float2*)(vp+(((size_t)c)<<16));
    #pragma unroll
    for(int i=0;i<16;i++){
      float wa=wA[(i<<6)+c], wb=wB[(i<<6)+c];
      aA[i].x+=wa*vv.x; aA[i].y+=wa*vv.y;
      aB[i].x+=wb*vv.x; aB[i].y+=wb*vv.y;
    }
  }
  float s0=0.f,s1=0.f;
  #pragma unroll
  for(int i=0;i<16;i++){ aA[i].x=lrelu(aA[i].x); aA[i].y=lrelu(aA[i].y); s0+=aA[i].x; s1+=aA[i].y; }
  float2 xmst; xmst.x=s0*(1.f/16.f); xmst.y=s1*(1.f/16.f);
  *(float2*)(xm+g)=xmst;
  float u0=0.f,u1=0.f;
  #pragma unroll
  for(int i=0;i<16;i++){ u0+=aB[i].x; u1+=aB[i].y; }
  u0*=(1.f/16.f); u1*=(1.f/16.f);
  float q0=0.f,q1=0.f;
  #pragma unroll
  for(int i=0;i<16;i++){ float d0=aB[i].x-u0, d1=aB[i].y-u1; q0+=d0*d0; q1+=d1*d1; }
  q0*=(1.f/16.f); q1*=(1.f/16.f);
  float i0=1.f/sqrtf(q0+1e-6f), i1=1.f/sqrtf(q1+1e-6f);
  float red[16];
  float* xp=x_+(((size_t)b*16)<<16)+p;
  #pragma unroll
  for(int i=0;i<16;i++){
    float xv0=lrelu(slw[i]*((aB[i].x-u0)*i0)+slb[i]);
    float xv1=lrelu(slw[i]*((aB[i].y-u1)*i1)+slb[i]);
    float2 st; st.x=xv0; st.y=xv1;
    *(float2*)(xp+(((size_t)i)<<16))=st;
    red[i]=xv0+xv1;
  }
  int lane=tid&63, wid=tid>>6;
  #pragma unroll
  for(int i=0;i<16;i++){
    float val=red[i];
    for(int m=32;m>0;m>>=1) val+=__shfl_xor(val,m);
    if(lane==0) sred[wid][i]=val;
  }
  __syncthreads();
  if(tid<16) capart[blockIdx.x*16+tid]=sred[0][tid]+sred[1][tid]+sred[2][tid]+sred[3][tid];
}

// ---------------- K3: sa = sigmoid(conv3x3(x_)) ----------------
__global__ __launch_bounds__(256) void k_sa(const float* __restrict__ x_,
    const float* __restrict__ Wsa, const float* __restrict__ bsa, float* __restrict__ sa){
  __shared__ float w[144]; __shared__ float bb;
  int tid=threadIdx.x;
  if(tid<144) w[tid]=Wsa[tid];
  if(tid==0) bb=bsa[0];
  __syncthreads();
  int pix=blockIdx.x*256+tid; int b=pix>>16, p=pix&65535;
  int y=p>>8, xx=p&255;
  float acc=bb;
  #pragma unroll
  for(int i=0;i<16;i++){
    const float* pl=x_+(((size_t)(b*16+i))<<16);
    #pragma unroll
    for(int ky=0;ky<3;ky++){
      int yy=y+ky-1;
      if((unsigned)yy<256u){
        #pragma unroll
        for(int kx=0;kx<3;kx++){
          int x2=xx+kx-1;
          if((unsigned)x2<256u) acc+=pl[(yy<<8)+x2]*w[i*9+ky*3+kx];
        }
      }
    }
  }
  sa[pix]=sigmoidf(acc);
}

// ---------------- K4: per-window variance (ddof=1) ----------------
__global__ __launch_bounds__(64) void k_var(const float* __restrict__ xm, float* __restrict__ var){
  int blk=blockIdx.x, tid=threadIdx.x;
  int b=blk>>10, n=blk&1023;
  int pix=((n>>5)<<11) + ((n&31)<<3) + ((tid>>3)<<8) + (tid&7);
  float val=xm[(b<<16)+pix];
  float s=val;
  for(int m=32;m>0;m>>=1) s+=__shfl_xor(s,m);
  float mean=s*(1.f/64.f);
  float d=val-mean; float q=d*d;
  for(int m=32;m>0;m>>=1) q+=__shfl_xor(q,m);
  if(tid==0) var[blk]=q*(1.f/63.f);
}

// ---------------- K5: rank -> mbin ----------------
__global__ __launch_bounds__(256) void k_rank(const float* __restrict__ var, float* __restrict__ mbin){
  __shared__ float va[1024];
  int bid=blockIdx.x; int b=bid>>2, seg=bid&3;
  int tid=threadIdx.x;
  for(int i=tid;i<1024;i+=256) va[i]=var[(b<<10)+i];
  __syncthreads();
  int n=seg*256+tid;
  float vn=va[n]; int r=0;
  for(int m=0;m<1024;m++){ float vm=va[m]; r += (vm<vn) || (vm==vn && m<n); }
  mbin[(b<<10)+n] = (r<512)?0.f:1.f;
}

// ---------------- K6: h0/h1 from Wm1 rowsums ----------------
__global__ __launch_bounds__(64) void k_hvec(const void* __restrict__ Wm1, const float* __restrict__ bm1,
    float* __restrict__ h0, float* __restrict__ h1, const int* __restrict__ fl){
  int j=blockIdx.x, tid=threadIdx.x;
  float s=0.f;
  if(fl[0]){
    const float* row=(const float*)Wm1+((size_t)j<<12);
    for(int k=tid;k<4096;k+=64) s+=row[k];
  } else {
    const bf16* row=(const bf16*)Wm1+((size_t)j<<12);
    for(int k=tid;k<4096;k+=64) s+=b2f(row[k]);
  }
  for(int m=32;m>0;m>>=1) s+=__shfl_xor(s,m);
  if(tid==0){ float bb=bm1[j]; h0[j]=lrelu(bb); h1[j]=lrelu(bb+s); }
}

// ---------------- K7: mask vectors (+ transposed copies) ----------------
__global__ __launch_bounds__(64) void k_mask(const void* __restrict__ Wm2, const float* __restrict__ bm2,
    const float* __restrict__ h0, const float* __restrict__ h1,
    float* __restrict__ m0, float* __restrict__ m1,
    float* __restrict__ m0T, float* __restrict__ m1T, const int* __restrict__ fl){
  int e=blockIdx.x, tid=threadIdx.x;
  float p0=0.f,p1=0.f;
  if(fl[0]){
    const float* row=(const float*)Wm2+((size_t)e<<11);
    for(int j=tid;j<2048;j+=64){ float w=row[j]; p0+=w*h0[j]; p1+=w*h1[j]; }
  } else {
    const bf16* row=(const bf16*)Wm2+((size_t)e<<11);
    for(int j=tid;j<2048;j+=64){ float w=b2f(row[j]); p0+=w*h0[j]; p1+=w*h1[j]; }
  }
  for(int m=32;m>0;m>>=1){ p0+=__shfl_xor(p0,m); p1+=__shfl_xor(p1,m); }
  if(tid==0){
    float bb=bm2[e]; float v0=p0+bb, v1=p1+bb;
    m0[e]=v0; m1[e]=v1;
    int te=(e&63)*64+(e>>6);
    m0T[te]=v0; m1T[te]=v1;
  }
}

// ---------------- K8: ca = sigmoid(Wca * mean(x_) + bca) ----------------
__global__ __launch_bounds__(64) void k_ca(const float* __restrict__ capart,
    const float* __restrict__ Wca, const float* __restrict__ bca, float* __restrict__ ca){
  __shared__ float m[16];
  int b=blockIdx.x, tid=threadIdx.x;
  if(tid<16){
    float s=0.f;
    for(int blk=0;blk<128;blk++) s+=capart[((b*128)+blk)*16+tid];
    m[tid]=s*(1.f/65536.f);
  }
  __syncthreads();
  float a=bca[tid];
  #pragma unroll
  for(int i=0;i<16;i++) a+=Wca[(tid<<4)+i]*m[i];
  ca[(b<<6)+tid]=sigmoidf(a);
}

// ---------------- K_PACK: apply masks; x*mk, v*mk, v*sa*(1-mk) -> window-major bf16 ----------------
__global__ __launch_bounds__(256) void k_pack(const void* __restrict__ x, const float* __restrict__ v,
    const float* __restrict__ sa, const float* __restrict__ mbin,
    const float* __restrict__ m0T, const float* __restrict__ m1T, const int* __restrict__ fl,
    unsigned short* __restrict__ xwb, unsigned short* __restrict__ vwb, unsigned short* __restrict__ vswb){
  int wp=blockIdx.x; int b=wp>>9, np=wp&511;
  int n0=np*2;
  int base=((n0>>5)<<11)+((n0&31)<<3);
  int t=threadIdx.x; int c0=t>>3, row=t&7;
  int isf32=fl[0];
  const float* mTa = (mbin[b*1024+n0  ]>0.5f)? m1T : m0T;
  const float* mTb = (mbin[b*1024+n0+1]>0.5f)? m1T : m0T;
  for(int h=0;h<2;h++){
    int ch=c0+h*32;
    size_t gb=(((size_t)(b*64+ch))<<16) + base + row*256;
    float xv[16], vv[16], sv[16];
    if(isf32){
      const float* xp=(const float*)x+gb;
      #pragma unroll
      for(int i=0;i<16;i++) xv[i]=xp[i];
    } else {
      const bf16* xp=(const bf16*)x+gb;
      #pragma unroll
      for(int i=0;i<16;i++) xv[i]=b2f(xp[i]);
    }
    const float* vp=v+gb;
    const float* sp=sa+(((size_t)b)<<16)+base+row*256;
    #pragma unroll
    for(int i=0;i<16;i++){ vv[i]=vp[i]; sv[i]=sp[i]; }
    size_t o0=((size_t)(b*1024+n0)*64+ch)*64 + row*8;
    #pragma unroll
    for(int wnd=0;wnd<2;wnd++){
      const float* mT = wnd? mTb : mTa;
      size_t oo=o0+(size_t)wnd*4096;
      int s=wnd*8;
      float mk[8];
      #pragma unroll
      for(int j=0;j<8;j++) mk[j]=mT[ch*64+row*8+j];
      uint4 ux, uv, us;
      ux.x=pack2(xv[s+0]*mk[0],xv[s+1]*mk[1]); ux.y=pack2(xv[s+2]*mk[2],xv[s+3]*mk[3]);
      ux.z=pack2(xv[s+4]*mk[4],xv[s+5]*mk[5]); ux.w=pack2(xv[s+6]*mk[6],xv[s+7]*mk[7]);
      uv.x=pack2(vv[s+0]*mk[0],vv[s+1]*mk[1]); uv.y=pack2(vv[s+2]*mk[2],vv[s+3]*mk[3]);
      uv.z=pack2(vv[s+4]*mk[4],vv[s+5]*mk[5]); uv.w=pack2(vv[s+6]*mk[6],vv[s+7]*mk[7]);
      us.x=pack2(vv[s+0]*sv[s+0]*(1.f-mk[0]),vv[s+1]*sv[s+1]*(1.f-mk[1]));
      us.y=pack2(vv[s+2]*sv[s+2]*(1.f-mk[2]),vv[s+3]*sv[s+3]*(1.f-mk[3]));
      us.z=pack2(vv[s+4]*sv[s+4]*(1.f-mk[4]),vv[s+5]*sv[s+5]*(1.f-mk[5]));
      us.w=pack2(vv[s+6]*sv[s+6]*(1.f-mk[6]),vv[s+7]*sv[s+7]*(1.f-mk[7]));
      *(uint4*)(xwb+oo)=ux; *(uint4*)(vwb+oo)=uv; *(uint4*)(vswb+oo)=us;
    }
  }
}

// ---------------- K9: windowed attention via MFMA -> img (bf16) ----------------
#define STR 72
#define STRF 65
__global__ __launch_bounds__(256,4) void k_attn_mfma(
    const unsigned short* __restrict__ xwb, const unsigned short* __restrict__ vwb,
    const unsigned short* __restrict__ vswb,
    const short* __restrict__ Wqb, const float* __restrict__ bq,
    const short* __restrict__ Wkb, const float* __restrict__ bk,
    unsigned short* __restrict__ img){
  __shared__ short sT[64*STR];
  __shared__ short sQK[2*64*STR];
  __shared__ short sV1[64*STR];
  short* sQ=sQK; short* sK=sQK+64*STR;
  float* sF=(float*)sQK;
  int tid=threadIdx.x, blk=blockIdx.x;
  int b=blk>>10, n=blk&1023;
  int base=((n>>5)<<11) + ((n&31)<<3);
  size_t plane=((size_t)b*64)<<16;
  const unsigned short* xw=xwb+(size_t)blk*4096;
  const unsigned short* vw=vwb+(size_t)blk*4096;
  for(int e=tid;e<4096;e+=256){
    int c=e>>6, tok=e&63;
    sT[tok*STR+c]=(short)xw[e];
    sV1[c*STR+tok]=(short)vw[e];
  }
  __syncthreads();
  int lane=tid&63, wid=tid>>6;
  int pb=wid*16, lr=lane&15, lg=lane>>4;
  short8v ta[2];
  #pragma unroll
  for(int ks=0;ks<2;ks++) ta[ks]=*(const short8v*)&sT[(pb+lr)*STR + ks*32 + lg*8];
  #pragma unroll
  for(int nt=0;nt<4;nt++){
    float bqv=bq[nt*16+lr], bkv=bk[nt*16+lr];
    f32x4 qa={bqv,bqv,bqv,bqv}, ka={bkv,bkv,bkv,bkv};
    #pragma unroll
    for(int ks=0;ks<2;ks++){
      short8v wq=*(const short8v*)(Wqb + (nt*16+lr)*64 + ks*32 + lg*8);
      short8v wk=*(const short8v*)(Wkb + (nt*16+lr)*64 + ks*32 + lg*8);
      qa=__builtin_amdgcn_mfma_f32_16x16x32_bf16(ta[ks],wq,qa,0,0,0);
      ka=__builtin_amdgcn_mfma_f32_16x16x32_bf16(ta[ks],wk,ka,0,0,0);
    }
    #pragma unroll
    for(int r=0;r<4;r++){
      sQ[(pb+lg*4+r)*STR + nt*16+lr]=f2bs(qa[r]);
      sK[(pb+lg*4+r)*STR + nt*16+lr]=f2bs(ka[r]);
    }
  }
  __syncthreads();
  short8v qa2[2];
  #pragma unroll
  for(int ks=0;ks<2;ks++) qa2[ks]=*(const short8v*)&sQ[(pb+lr)*STR + ks*32 + lg*8];
  f32x4 sacc[4];
  #pragma unroll
  for(int nt=0;nt<4;nt++){
    f32x4 a={0.f,0.f,0.f,0.f};
    #pragma unroll
    for(int ks=0;ks<2;ks++){
      short8v kb=*(const short8v*)&sK[(nt*16+lr)*STR + ks*32 + lg*8];
      a=__builtin_amdgcn_mfma_f32_16x16x32_bf16(qa2[ks],kb,a,0,0,0);
    }
    sacc[nt]=a;
  }
  f32x4 pa[4];
  #pragma unroll
  for(int r=0;r<4;r++){
    float mx=fmaxf(fmaxf(sacc[0][r],sacc[1][r]),fmaxf(sacc[2][r],sacc[3][r]));
    #pragma unroll
    for(int m=1;m<16;m<<=1) mx=fmaxf(mx,__shfl_xor(mx,m));
    float e0=__expf(sacc[0][r]-mx), e1=__expf(sacc[1][r]-mx);
    float e2=__expf(sacc[2][r]-mx), e3=__expf(sacc[3][r]-mx);
    float sum=e0+e1+e2+e3;
    #pragma unroll
    for(int m=1;m<16;m<<=1) sum+=__shfl_xor(sum,m);
    float inv=1.f/sum;
    pa[0][r]=e0*inv; pa[1][r]=e1*inv; pa[2][r]=e2*inv; pa[3][r]=e3*inv;
  }
  #pragma unroll
  for(int nt=0;nt<4;nt++){
    #pragma unroll
    for(int r=0;r<4;r++)
      sT[(pb+lg*4+r)*STR + nt*16+lr]=f2bs(pa[nt][r]);
  }
  __syncthreads();
  short8v aa[2];
  #pragma unroll
  for(int ks=0;ks<2;ks++) aa[ks]=*(const short8v*)&sT[(pb+lr)*STR + ks*32 + lg*8];
  #pragma unroll
  for(int nt=0;nt<4;nt++){
    f32x4 f={0.f,0.f,0.f,0.f};
    #pragma unroll
    for(int ks=0;ks<2;ks++){
      short8v vb=*(const short8v*)&sV1[(nt*16+lr)*STR + ks*32 + lg*8];
      f=__builtin_amdgcn_mfma_f32_16x16x32_bf16(aa[ks],vb,f,0,0,0);
    }
    #pragma unroll
    for(int r=0;r<4;r++) sF[(pb+lg*4+r)*STRF + nt*16+lr]=f[r];
  }
  __syncthreads();
  const unsigned short* vsw=vswb+(size_t)blk*4096;
  for(int e2=tid;e2<2048;e2+=256){
    int c=e2>>5, tp=e2&31; int tok=tp*2;
    float f0=sF[tok*STRF+c], f1=sF[(tok+1)*STRF+c];
    unsigned uv=*(const unsigned*)(vsw + c*64 + tok);
    int pix=base+((tok>>3)<<8)+(tok&7);
    *(unsigned*)(img+plane+(((size_t)c)<<16)+pix)=pack2(f0+us2f(uv&0xffff), f1+us2f(uv>>16));
  }
}

// ---------------- K_DWF: fused depthwise dil1+dil2+gelu*ca+img (bf16 in/out), 8-row strips ----------------
#define IST 264
__global__ __launch_bounds__(256) void k_dwfuse(const unsigned short* __restrict__ img,
    const float* __restrict__ dw1w, const float* __restrict__ dwb1,
    const float* __restrict__ dw2w, const float* __restrict__ dwb2,
    const float* __restrict__ ca, unsigned short* __restrict__ outb){
  __shared__ float sImg[14*IST];
  __shared__ float sTmp[12*IST];
  __shared__ float k1[9], k2[9];
  __shared__ float bb1, bb2, cav;
  int bid=blockIdx.x; int b=bid>>11, c=(bid>>5)&63, sy=bid&31;
  int y0=sy*8;
  int tid=threadIdx.x;
  if(tid<9){ k1[tid]=dw1w[c*9+tid]; k2[tid]=dw2w[c*9+tid]; }
  if(tid==9)  bb1=dwb1[c];
  if(tid==10) bb2=dwb2[c];
  if(tid==11) cav=ca[b*64+c];
  const unsigned short* ip=img+(((size_t)(b*64+c))<<16);
  for(int i=tid;i<14*IST;i+=256){
    int r=i/IST, cl=i-r*IST;
    int gy=y0-3+r, gx=cl-3;
    float v=0.f;
    if(cl<262 && (unsigned)gy<256u && (unsigned)gx<256u) v=us2f(ip[(gy<<8)+gx]);
    sImg[i]=v;
  }
  __syncthreads();
  for(int i=tid;i<12*IST;i+=256){
    int r=i/IST, cl=i-r*IST;
    float t=0.f;
    if(cl<260){
      int ty=y0-2+r, tc=cl-2;
      if((unsigned)ty<256u && (unsigned)tc<256u){
        t=bb1;
        #pragma unroll
        for(int dy=0;dy<3;dy++)
          #pragma unroll
          for(int dx=0;dx<3;dx++)
            t+=sImg[(r+dy)*IST+(cl+dx)]*k1[dy*3+dx];
      }
    }
    sTmp[i]=t;
  }
  __syncthreads();
  unsigned short* op=outb+(((size_t)(b*64+c))<<16);
  int lx=tid;
  #pragma unroll
  for(int ly=0;ly<8;ly++){
    float cs=bb2;
    #pragma unroll
    for(int dy=0;dy<3;dy++)
      #pragma unroll
      for(int dx=0;dx<3;dx++)
        cs+=sTmp[(ly+2*dy)*IST + lx+2*dx]*k2[dy*3+dx];
    float center=sImg[(ly+3)*IST + lx+3];
    op[((y0+ly)<<8)+lx]=(unsigned short)f2bs(geluf(cs)*cav+center);
  }
}

// ---------------- K_FDW: ffn depthwise (E bf16) + gelu gate -> bf16 out ----------------
#define EST 260
__global__ __launch_bounds__(256) void k_ffn_dw_t(const unsigned short* __restrict__ E,
    const float* __restrict__ dwf, unsigned short* __restrict__ g){
  __shared__ unsigned short sE1[18*EST];
  __shared__ unsigned short sE2[18*EST];
  __shared__ float k1[9], k2[9];
  int bid=blockIdx.x; int b=bid>>10, c=(bid>>4)&63, sy=bid&15;
  int y0=sy*16;
  int tid=threadIdx.x;
  if(tid<9){ k1[tid]=dwf[c*9+tid]; k2[tid]=dwf[(64+c)*9+tid]; }
  if(tid<144){
    int pl=tid/72; int rem=tid-pl*72; int rr=rem>>2; int cc=rem&3;
    int col=(cc<2)? cc : (256+cc);
    if(pl==0) sE1[rr*EST+col]=0; else sE2[rr*EST+col]=0;
  }
  const unsigned short* p1=E+(((size_t)(b*128+c))<<16);
  const unsigned short* p2=E+(((size_t)(b*128+64+c))<<16);
  int half=tid>>7, t2=tid&127;
  const unsigned short* pp = half? p2 : p1;
  for(int r=0;r<18;r++){
    int gy=y0-1+r;
    unsigned val=0;
    if((unsigned)gy<256u) val=*(const unsigned*)(pp+(gy<<8)+t2*2);
    unsigned short* dst = half? sE2 : sE1;
    *(unsigned*)(dst + r*EST + 2 + t2*2) = val;
  }
  __syncthreads();
  unsigned short* op=g+(((size_t)(b*64+c))<<16);
  int lx=tid;
  #pragma unroll 4
  for(int ly=0;ly<16;ly++){
    float a1=0.f, a2=0.f;
    #pragma unroll
    for(int dy=0;dy<3;dy++)
      #pragma unroll
      for(int dx=0;dx<3;dx++){
        int idx=(ly+dy)*EST + lx+dx+1;
        a1+=us2f(sE1[idx])*k1[dy*3+dx];
        a2+=us2f(sE2[idx])*k2[dy*3+dx];
      }
    op[((y0+ly)<<8)+lx]=(unsigned short)f2bs(geluf(a1)*a2);
  }
}

extern "C" void kernel_launch(void* const* d_in, const int* in_sizes, int n_in,
                              void* d_out, int out_size, void* d_ws, size_t ws_size,
                              hipStream_t stream){
  (void)in_sizes; (void)n_in; (void)out_size; (void)ws_size;
  const void* x  = d_in[0];
  const void* Wm1= d_in[23];
  const void* Wm2= d_in[25];

  char* ws=(char*)d_ws;
  // Slot A [0,64MiB):    v (f32) -> E (bf16, 128ch)
  // Slot B [64,128MiB):  img (bf16) -> x1 (f32)   [img dead after dwfuse; x1 written by gemm_ln1]
  // Slot C [128,192MiB): xwb(32MiB)+vwb(32MiB) -> outb (bf16) -> gbuf (bf16)
  // [192MiB..~211MiB):   small buffers
  // [220MiB,252MiB):     vswb (bf16)
  float* v    =(float*)(ws);
  unsigned short* E=(unsigned short*)(ws);
  unsigned short* img=(unsigned short*)(ws+67108864);
  float* x1   =(float*)(ws+67108864);
  unsigned short* xwb=(unsigned short*)(ws+134217728);
  unsigned short* vwb=(unsigned short*)(ws+134217728+33554432);
  unsigned short* outb=(unsigned short*)(ws+134217728);
  unsigned short* gbuf=(unsigned short*)(ws+134217728);
  unsigned short* vswb=(unsigned short*)(ws+230686720);
  char* sm = ws+201326592;
  float* x_    =(float*)(sm);              // 16 MB
  float* sa    =(float*)(sm+16777216);     // 1 MB
  float* xm    =(float*)(sm+17825792);     // 1 MB
  float* var   =(float*)(sm+18874368);     // 16 KB
  float* mbin  =(float*)(sm+18890752);     // 16 KB
  float* h0    =(float*)(sm+18907136);     // 8 KB
  float* h1    =(float*)(sm+18915328);     // 8 KB
  float* m0    =(float*)(sm+18923520);     // 16 KB
  float* m1    =(float*)(sm+18939904);     // 16 KB
  float* capart=(float*)(sm+18956288);     // 64 KB
  float* ca    =(float*)(sm+19021824);     // 1 KB
  int*   flag  =(int*)  (sm+19022848);     // 4 B
  float* wbuf  =(float*)(sm+19023872);     // ~161 KB
  short* Wqb   =(short*)(sm+19200000);     // 8 KB
  short* Wkb   =(short*)(sm+19208192);     // 8 KB
  float* m0T   =(float*)(sm+19216384);     // 16 KB
  float* m1T   =(float*)(sm+19232768);     // 16 KB
  short* Wob   =(short*)(sm+19249152);     // 8 KB
  short* Wfib  =(short*)(sm+19257344);     // 16 KB
  short* Wfob  =(short*)(sm+19273728);     // 8 KB

  static const int din_idx[31]={5,6,7,8,9,10,11,12,13,14,15,16,17,18,19,20,21,22,24,26,27,28,29,30,31,32,33,1,2,3,4};
  static const int szs[31]  ={4096,64,4096,64,4096,64,576,64,576,64,4096,64,1024,16,1024,16,16,16,2048,4096,1024,64,144,1,8192,1152,4096,64,64,64,64};
  CvtArgs ca_args;
  int off=0;
  int offs[31];
  for(int t=0;t<31;t++){
    ca_args.src[t]=d_in[din_idx[t]];
    ca_args.sz[t]=szs[t];
    ca_args.off[t]=off;
    offs[t]=off;
    off+=szs[t];
  }
  const float* Wv  =wbuf+offs[0];  const float* bv  =wbuf+offs[1];
  const float* Wq  =wbuf+offs[2];  const float* bq  =wbuf+offs[3];
  const float* Wk  =wbuf+offs[4];  const float* bk  =wbuf+offs[5];
  const float* dw1 =wbuf+offs[6];  const float* dwb1=wbuf+offs[7];
  const float* dw2 =wbuf+offs[8];  const float* dwb2=wbuf+offs[9];
  const float* Wo  =wbuf+offs[10]; const float* bo  =wbuf+offs[11];
  const float* W_in=wbuf+offs[12]; const float* b_in=wbuf+offs[13];
  const float* Wc  =wbuf+offs[14]; const float* bc  =wbuf+offs[15];
  const float* lnw =wbuf+offs[16]; const float* lnb =wbuf+offs[17];
  const float* bm1 =wbuf+offs[18]; const float* bm2 =wbuf+offs[19];
  const float* Wca =wbuf+offs[20]; const float* bca =wbuf+offs[21];
  const float* Wsa =wbuf+offs[22]; const float* bsa =wbuf+offs[23];
  const float* Wfi =wbuf+offs[24]; const float* dwf =wbuf+offs[25];
  const float* Wfo =wbuf+offs[26];
  const float* wn1 =wbuf+offs[27]; const float* bn1 =wbuf+offs[28];
  const float* wn2 =wbuf+offs[29]; const float* bn2 =wbuf+offs[30];

  hipLaunchKernelGGL(k_detect,   dim3(1),      dim3(256), 0, stream, x, flag);
  hipLaunchKernelGGL(k_cvt,      dim3(31),     dim3(256), 0, stream, ca_args, flag, wbuf);
  hipLaunchKernelGGL(k_w2b,      dim3(16),     dim3(256), 0, stream, Wq, Wk, Wqb, Wkb);
  hipLaunchKernelGGL(k_w2b3,     dim3(32),     dim3(256), 0, stream, Wo, Wfi, Wfo, Wob, Wfib, Wfob);
  hipLaunchKernelGGL(k_gemm32,   dim3(256,2),  dim3(256), 0, stream, x, Wv, bv, 1, v, flag, 0);
  hipLaunchKernelGGL(k_route,    dim3(512),    dim3(256), 0, stream, v, W_in, b_in, Wc, bc, lnw, lnb, x_, xm, capart);
  hipLaunchKernelGGL(k_sa,       dim3(1024),   dim3(256), 0, stream, x_, Wsa, bsa, sa);
  hipLaunchKernelGGL(k_var,      dim3(4096),   dim3(64),  0, stream, xm, var);
  hipLaunchKernelGGL(k_rank,     dim3(16),     dim3(256), 0, stream, var, mbin);
  hipLaunchKernelGGL(k_hvec,     dim3(2048),   dim3(64),  0, stream, Wm1, bm1, h0, h1, flag);
  hipLaunchKernelGGL(k_mask,     dim3(4096),   dim3(64),  0, stream, Wm2, bm2, h0, h1, m0, m1, m0T, m1T, flag);
  hipLaunchKernelGGL(k_ca,       dim3(4),      dim3(64),  0, stream, capart, Wca, bca, ca);
  hipLaunchKernelGGL(k_pack,     dim3(2048),   dim3(256), 0, stream, x, v, sa, mbin, m0T, m1T, flag, xwb, vwb, vswb);
  hipLaunchKernelGGL(k_attn_mfma,dim3(4096),   dim3(256), 0, stream, xwb, vwb, vswb, Wqb, bq, Wkb, bk, img);
  hipLaunchKernelGGL(k_dwfuse,   dim3(8192),   dim3(256), 0, stream, img, dw1, dwb1, dw2, dwb2, ca, outb);
  // x1 = LN1(x + Wo*outb + bo)   (MFMA + fused LN)
  hipLaunchKernelGGL(k_gemm_ln,  dim3(4096),   dim3(256), 0, stream, outb, Wob, bo, 1, x, wn1, bn1, (void*)x1, flag, 0, 1);
  // E = bf16(Wfi * x1)  (MFMA)
  hipLaunchKernelGGL(k_gemm_mf,  dim3(4096),   dim3(256), 0, stream, (const void*)x1, 1, Wfib, wbuf, 0, (void*)E, 128, 1);
  hipLaunchKernelGGL(k_ffn_dw_t, dim3(4096),   dim3(256), 0, stream, E, dwf, gbuf);
  // out = LN2(x1 + Wfo*gbuf)  (MFMA + fused LN)
  hipLaunchKernelGGL(k_gemm_ln,  dim3(4096),   dim3(256), 0, stream, gbuf, Wfob, wbuf, 0, (const void*)x1, wn2, bn2, d_out, flag, 1, 0);
}

// Round 11
// 602.268 us; speedup vs baseline: 3.0464x; 1.0125x over previous
//
#include <hip/hip_runtime.h>
#include <hip/hip_bf16.h>

typedef __hip_bfloat16 bf16;
typedef __attribute__((ext_vector_type(8))) short short8v;
typedef __attribute__((ext_vector_type(4))) float f32x4;

#define DEV static __device__ __forceinline__

DEV float b2f(bf16 h){ return __bfloat162float(h); }
DEV float us2f(unsigned short u){ unsigned v=((unsigned)u)<<16; float f; __builtin_memcpy(&f,&v,4); return f; }
DEV short f2bs(float f){ bf16 h=__float2bfloat16(f); short s; __builtin_memcpy(&s,&h,2); return s; }
DEV unsigned pack2(float a, float b){ return ((unsigned)(unsigned short)f2bs(b)<<16)|(unsigned short)f2bs(a); }
DEV float lrelu(float x){ return x >= 0.f ? x : 0.1f*x; }
DEV float geluf(float x){ return 0.5f*x*(1.f + erff(x*0.70710678118654752440f)); }
DEV float sigmoidf(float x){ return 1.f/(1.f + expf(-x)); }

// B=4, C=64, H=W=256, HW=65536, WS=8, N=1024 windows/batch, embed=4096

// ---------------- K0a: detect storage dtype ----------------
__global__ __launch_bounds__(256) void k_detect(const void* x, int* flag){
  __shared__ int cnt;
  if(threadIdx.x==0) cnt=0;
  __syncthreads();
  const unsigned short* up=(const unsigned short*)x;
  int c=0;
  for(int k=0;k<16;k++){
    unsigned short u=up[(threadIdx.x*16+k)*2];
    if(((u>>7)&0xFF)==0xFF) c++;
  }
  atomicAdd(&cnt,c);
  __syncthreads();
  if(threadIdx.x==0) flag[0] = (cnt>0) ? 1 : 0;  // 1 => f32 storage
}

// ---------------- K0b: convert small weights to f32 wbuf ----------------
struct CvtArgs { const void* src[31]; int sz[31]; int off[31]; };
__global__ __launch_bounds__(256) void k_cvt(CvtArgs a, const int* fl, float* wbuf){
  int t=blockIdx.x; int n=a.sz[t]; const void* s=a.src[t]; float* d=wbuf+a.off[t];
  if(fl[0]){
    const float* sp=(const float*)s;
    for(int i=threadIdx.x;i<n;i+=256) d[i]=sp[i];
  } else {
    const bf16* sp=(const bf16*)s;
    for(int i=threadIdx.x;i<n;i+=256) d[i]=b2f(sp[i]);
  }
}

// ---------------- K0c: Wq/Wk -> bf16 for MFMA ----------------
__global__ __launch_bounds__(256) void k_w2b(const float* __restrict__ wq, const float* __restrict__ wk,
    short* __restrict__ Wqb, short* __restrict__ Wkb){
  int i=blockIdx.x*256+threadIdx.x;
  if(i<4096){ Wqb[i]=f2bs(wq[i]); Wkb[i]=f2bs(wk[i]); }
}

// ---------------- K0d: Wo/Wfi/Wfo -> bf16 for MFMA ----------------
__global__ __launch_bounds__(256) void k_w2b3(const float* __restrict__ wo, const float* __restrict__ wfi,
    const float* __restrict__ wfo, short* __restrict__ Wob, short* __restrict__ Wfib, short* __restrict__ Wfob){
  int i=blockIdx.x*256+threadIdx.x;
  if(i<4096) Wob[i]=f2bs(wo[i]);
  if(i<8192) Wfib[i]=f2bs(wfi[i]);
  if(i<4096) Wfob[i]=f2bs(wfo[i]);
}

// ---------------- K1: conv_v GEMM (exact f32 for routing) + window-major bf16 vw ----------------
__global__ __launch_bounds__(256) void k_conv_vw(
    const void* __restrict__ in, const float* __restrict__ W,
    const float* __restrict__ bias,
    float* __restrict__ out, unsigned short* __restrict__ vw,
    const int* __restrict__ fl){
  __shared__ float sW[2048]; __shared__ float sb[32];
  int tid=threadIdx.x, og=blockIdx.y;
  for(int i=tid;i<2048;i+=256) sW[i]=W[og*2048+i];
  if(tid<32) sb[tid]=bias[og*32+tid];
  __syncthreads();
  int g=blockIdx.x*1024+tid*4; int b=g>>16, p=g&65535;
  float4 a[32];
  #pragma unroll
  for(int o=0;o<32;o++){ float bv=sb[o]; a[o]=make_float4(bv,bv,bv,bv); }
  size_t base=(((size_t)b*64)<<16)+p;
  if(fl[0]){
    const float* ip=(const float*)in + base;
    for(int c=0;c<64;c++){
      float4 xv=*(const float4*)(ip + (((size_t)c)<<16));
      #pragma unroll
      for(int o=0;o<32;o++){ float w=sW[o*64+c];
        a[o].x+=w*xv.x; a[o].y+=w*xv.y; a[o].z+=w*xv.z; a[o].w+=w*xv.w; }
    }
  } else {
    const bf16* ip=(const bf16*)in + base;
    for(int c=0;c<64;c++){
      const bf16* q=ip+(((size_t)c)<<16);
      float4 xv=make_float4(b2f(q[0]),b2f(q[1]),b2f(q[2]),b2f(q[3]));
      #pragma unroll
      for(int o=0;o<32;o++){ float w=sW[o*64+c];
        a[o].x+=w*xv.x; a[o].y+=w*xv.y; a[o].z+=w*xv.z; a[o].w+=w*xv.w; }
    }
  }
  float* op=out + (((size_t)(b*64+og*32))<<16) + p;
  #pragma unroll
  for(int o=0;o<32;o++) *(float4*)(op+(((size_t)o)<<16))=a[o];
  // window-major bf16 copy (unmasked)
  int y=p>>8, xx=p&255;
  int n=((y>>3)<<5)|(xx>>3), tok=((y&7)<<3)|(xx&7);
  unsigned short* wp=vw + (((size_t)(b*1024+n))<<12) + (size_t)(og*32)*64 + tok;
  #pragma unroll
  for(int o=0;o<32;o++){
    uint2 u; u.x=pack2(a[o].x,a[o].y); u.y=pack2(a[o].z,a[o].w);
    *(uint2*)(wp + (size_t)o*64)=u;
  }
}

// ---------------- K_GM: MFMA 1x1-conv GEMM (ffn_in): D = W * in, f32 in, bf16 out ----------------
__global__ __launch_bounds__(256) void k_gemm_mf(
    const void* __restrict__ in, int in_f32,
    const short* __restrict__ Wb, const float* __restrict__ bias, int has_bias,
    void* __restrict__ out, int och, int out_bf16){
  __shared__ short Ain[64*72];
  int tid=threadIdx.x;
  int g0=blockIdx.x*64; int b=g0>>16, p0=g0&65535;
  int c=tid>>2, q=tid&3;
  size_t base=(((size_t)(b*64+c))<<16) + p0;
  if(in_f32){
    const float* ip=(const float*)in + base;
    #pragma unroll
    for(int j=0;j<4;j++){
      int po=q*16+j*4;
      float4 xv=*(const float4*)(ip+po);
      Ain[(po+0)*72+c]=f2bs(xv.x); Ain[(po+1)*72+c]=f2bs(xv.y);
      Ain[(po+2)*72+c]=f2bs(xv.z); Ain[(po+3)*72+c]=f2bs(xv.w);
    }
  } else {
    const unsigned short* ip=(const unsigned short*)in + base;
    #pragma unroll
    for(int j=0;j<4;j++){
      int po=q*16+j*4;
      uint2 u=*(const uint2*)(ip+po);
      Ain[(po+0)*72+c]=(short)(u.x&0xffff); Ain[(po+1)*72+c]=(short)(u.x>>16);
      Ain[(po+2)*72+c]=(short)(u.y&0xffff); Ain[(po+3)*72+c]=(short)(u.y>>16);
    }
  }
  __syncthreads();
  int lane=tid&63, wid=tid>>6;
  int lr=lane&15, lg=lane>>4;
  int pix0=wid*16;
  short8v bfrag[2];
  #pragma unroll
  for(int ks=0;ks<2;ks++) bfrag[ks]=*(const short8v*)&Ain[(pix0+lr)*72 + ks*32 + lg*8];
  int ntn=och>>4;
  for(int nt=0;nt<ntn;nt++){
    f32x4 acc;
    if(has_bias){
      #pragma unroll
      for(int r=0;r<4;r++) acc[r]=bias[nt*16+lg*4+r];
    } else {
      acc=(f32x4){0.f,0.f,0.f,0.f};
    }
    #pragma unroll
    for(int ks=0;ks<2;ks++){
      short8v afrag=*(const short8v*)(Wb + (nt*16+lr)*64 + ks*32 + lg*8);
      acc=__builtin_amdgcn_mfma_f32_16x16x32_bf16(afrag,bfrag[ks],acc,0,0,0);
    }
    if(out_bf16){
      unsigned short* op=(unsigned short*)out;
      #pragma unroll
      for(int r=0;r<4;r++){
        int m=nt*16+lg*4+r;
        op[(((size_t)(b*och+m))<<16) + p0 + pix0 + lr]=(unsigned short)f2bs(acc[r]);
      }
    } else {
      float* op=(float*)out;
      #pragma unroll
      for(int r=0;r<4;r++){
        int m=nt*16+lg*4+r;
        op[(((size_t)(b*och+m))<<16) + p0 + pix0 + lr]=acc[r];
      }
    }
  }
}

// ---------------- K_GL: MFMA GEMM (64 och) + residual-add + LayerNorm fused ----------------
__global__ __launch_bounds__(256) void k_gemm_ln(
    const unsigned short* __restrict__ in,
    const short* __restrict__ Wb, const float* __restrict__ bias, int has_bias,
    const void* __restrict__ basex,
    const float* __restrict__ lnw, const float* __restrict__ lnb,
    void* __restrict__ out,
    const int* __restrict__ fl, int base_mode, int out_mode){
  __shared__ short Ain[64*72];
  int tid=threadIdx.x;
  int g0=blockIdx.x*64; int b=g0>>16, p0=g0&65535;
  int c=tid>>2, q=tid&3;
  {
    const unsigned short* ip=in + (((size_t)(b*64+c))<<16) + p0;
    #pragma unroll
    for(int j=0;j<4;j++){
      int po=q*16+j*4;
      uint2 u=*(const uint2*)(ip+po);
      Ain[(po+0)*72+c]=(short)(u.x&0xffff); Ain[(po+1)*72+c]=(short)(u.x>>16);
      Ain[(po+2)*72+c]=(short)(u.y&0xffff); Ain[(po+3)*72+c]=(short)(u.y>>16);
    }
  }
  __syncthreads();
  int lane=tid&63, wid=tid>>6;
  int lr=lane&15, lg=lane>>4;
  int pix0=wid*16;
  short8v bfrag[2];
  #pragma unroll
  for(int ks=0;ks<2;ks++) bfrag[ks]=*(const short8v*)&Ain[(pix0+lr)*72 + ks*32 + lg*8];
  float rl[16];
  #pragma unroll
  for(int nt=0;nt<4;nt++){
    f32x4 acc;
    if(has_bias){
      #pragma unroll
      for(int r=0;r<4;r++) acc[r]=bias[nt*16+lg*4+r];
    } else {
      acc=(f32x4){0.f,0.f,0.f,0.f};
    }
    #pragma unroll
    for(int ks=0;ks<2;ks++){
      short8v afrag=*(const short8v*)(Wb + (nt*16+lr)*64 + ks*32 + lg*8);
      acc=__builtin_amdgcn_mfma_f32_16x16x32_bf16(afrag,bfrag[ks],acc,0,0,0);
    }
    #pragma unroll
    for(int r=0;r<4;r++) rl[nt*4+r]=acc[r];
  }
  int pix=p0+pix0+lr;
  bool bf32 = (base_mode==1) || (base_mode==0 && fl[0]);
  if(bf32){
    const float* xp=(const float*)basex;
    #pragma unroll
    for(int nt=0;nt<4;nt++)
      #pragma unroll
      for(int r=0;r<4;r++)
        rl[nt*4+r]+=xp[(((size_t)(b*64+nt*16+lg*4+r))<<16)+pix];
  } else {
    const unsigned short* xp=(const unsigned short*)basex;
    #pragma unroll
    for(int nt=0;nt<4;nt++)
      #pragma unroll
      for(int r=0;r<4;r++)
        rl[nt*4+r]+=us2f(xp[(((size_t)(b*64+nt*16+lg*4+r))<<16)+pix]);
  }
  float s=0.f;
  #pragma unroll
  for(int i=0;i<16;i++) s+=rl[i];
  s+=__shfl_xor(s,16); s+=__shfl_xor(s,32);
  float mean=s*(1.f/64.f);
  float qv=0.f;
  #pragma unroll
  for(int i=0;i<16;i++){ float d=rl[i]-mean; qv+=d*d; }
  qv+=__shfl_xor(qv,16); qv+=__shfl_xor(qv,32);
  float inv=1.f/sqrtf(qv*(1.f/64.f)+1e-6f);
  bool of32 = (out_mode==1) || (out_mode==0 && fl[0]);
  if(of32){
    float* op=(float*)out;
    #pragma unroll
    for(int nt=0;nt<4;nt++)
      #pragma unroll
      for(int r=0;r<4;r++){
        int m=nt*16+lg*4+r;
        op[(((size_t)(b*64+m))<<16)+pix]=lnw[m]*((rl[nt*4+r]-mean)*inv)+lnb[m];
      }
  } else {
    unsigned short* op=(unsigned short*)out;
    #pragma unroll
    for(int nt=0;nt<4;nt++)
      #pragma unroll
      for(int r=0;r<4;r++){
        int m=nt*16+lg*4+r;
        op[(((size_t)(b*64+m))<<16)+pix]=(unsigned short)f2bs(lnw[m]*((rl[nt*4+r]-mean)*inv)+lnb[m]);
      }
  }
}

// ---------------- K2: route (2 pix/thread) ----------------
__global__ __launch_bounds__(256) void k_route(const float* __restrict__ v,
    const float* __restrict__ W_in, const float* __restrict__ b_in,
    const float* __restrict__ Wc, const float* __restrict__ bc,
    const float* __restrict__ lnw, const float* __restrict__ lnb,
    float* __restrict__ x_, float* __restrict__ xm, float* __restrict__ capart){
  __shared__ float wA[1024], wB[1024], sba[16], sbb[16], slw[16], slb[16];
  __shared__ float sred[4][16];
  int tid=threadIdx.x;
  for(int i=tid;i<1024;i+=256){ wA[i]=W_in[i]; wB[i]=Wc[i]; }
  if(tid<16){ sba[tid]=b_in[tid]; sbb[tid]=bc[tid]; slw[tid]=lnw[tid]; slb[tid]=lnb[tid]; }
  __syncthreads();
  int g=blockIdx.x*512+tid*2; int b=g>>16, p=g&65535;
  float2 aA[16], aB[16];
  #pragma unroll
  for(int i=0;i<16;i++){ aA[i]=make_float2(sba[i],sba[i]); aB[i]=make_float2(sbb[i],sbb[i]); }
  const float* vp=v+(((size_t)b*64)<<16)+p;
  for(int c=0;c<64;c++){
    float2 vv=*(const float2*)(vp+(((size_t)c)<<16));
    #pragma unroll
    for(int i=0;i<16;i++){
      float wa=wA[(i<<6)+c], wb=wB[(i<<6)+c];
      aA[i].x+=wa*vv.x; aA[i].y+=wa*vv.y;
      aB[i].x+=wb*vv.x; aB[i].y+=wb*vv.y;
    }
  }
  float s0=0.f,s1=0.f;
  #pragma unroll
  for(int i=0;i<16;i++){ aA[i].x=lrelu(aA[i].x); aA[i].y=lrelu(aA[i].y); s0+=aA[i].x; s1+=aA[i].y; }
  float2 xmst; xmst.x=s0*(1.f/16.f); xmst.y=s1*(1.f/16.f);
  *(float2*)(xm+g)=xmst;
  float u0=0.f,u1=0.f;
  #pragma unroll
  for(int i=0;i<16;i++){ u0+=aB[i].x; u1+=aB[i].y; }
  u0*=(1.f/16.f); u1*=(1.f/16.f);
  float q0=0.f,q1=0.f;
  #pragma unroll
  for(int i=0;i<16;i++){ float d0=aB[i].x-u0, d1=aB[i].y-u1; q0+=d0*d0; q1+=d1*d1; }
  q0*=(1.f/16.f); q1*=(1.f/16.f);
  float i0=1.f/sqrtf(q0+1e-6f), i1=1.f/sqrtf(q1+1e-6f);
  float red[16];
  float* xp=x_+(((size_t)b*16)<<16)+p;
  #pragma unroll
  for(int i=0;i<16;i++){
    float xv0=lrelu(slw[i]*((aB[i].x-u0)*i0)+slb[i]);
    float xv1=lrelu(slw[i]*((aB[i].y-u1)*i1)+slb[i]);
    float2 st; st.x=xv0; st.y=xv1;
    *(float2*)(xp+(((size_t)i)<<16))=st;
    red[i]=xv0+xv1;
  }
  int lane=tid&63, wid=tid>>6;
  #pragma unroll
  for(int i=0;i<16;i++){
    float val=red[i];
    for(int m=32;m>0;m>>=1) val+=__shfl_xor(val,m);
    if(lane==0) sred[wid][i]=val;
  }
  __syncthreads();
  if(tid<16) capart[blockIdx.x*16+tid]=sred[0][tid]+sred[1][tid]+sred[2][tid]+sred[3][tid];
}

// ---------------- K3: sa = sigmoid(conv3x3(x_)) -> window-major bf16 ----------------
__global__ __launch_bounds__(256) void k_sa(const float* __restrict__ x_,
    const float* __restrict__ Wsa, const float* __restrict__ bsa, unsigned short* __restrict__ sa_w){
  __shared__ float w[144]; __shared__ float bb;
  int tid=threadIdx.x;
  if(tid<144) w[tid]=Wsa[tid];
  if(tid==0) bb=bsa[0];
  __syncthreads();
  int pix=blockIdx.x*256+tid; int b=pix>>16, p=pix&65535;
  int y=p>>8, xx=p&255;
  float acc=bb;
  #pragma unroll
  for(int i=0;i<16;i++){
    const float* pl=x_+(((size_t)(b*16+i))<<16);
    #pragma unroll
    for(int ky=0;ky<3;ky++){
      int yy=y+ky-1;
      if((unsigned)yy<256u){
        #pragma unroll
        for(int kx=0;kx<3;kx++){
          int x2=xx+kx-1;
          if((unsigned)x2<256u) acc+=pl[(yy<<8)+x2]*w[i*9+ky*3+kx];
        }
      }
    }
  }
  int n=((y>>3)<<5)|(xx>>3), tok=((y&7)<<3)|(xx&7);
  sa_w[(((size_t)(b<<10)+n)<<6)+tok]=(unsigned short)f2bs(sigmoidf(acc));
}

// ---------------- K4: per-window variance (ddof=1) ----------------
__global__ __launch_bounds__(64) void k_var(const float* __restrict__ xm, float* __restrict__ var){
  int blk=blockIdx.x, tid=threadIdx.x;
  int b=blk>>10, n=blk&1023;
  int pix=((n>>5)<<11) + ((n&31)<<3) + ((tid>>3)<<8) + (tid&7);
  float val=xm[(b<<16)+pix];
  float s=val;
  for(int m=32;m>0;m>>=1) s+=__shfl_xor(s,m);
  float mean=s*(1.f/64.f);
  float d=val-mean; float q=d*d;
  for(int m=32;m>0;m>>=1) q+=__shfl_xor(q,m);
  if(tid==0) var[blk]=q*(1.f/63.f);
}

// ---------------- K5: rank -> mbin ----------------
__global__ __launch_bounds__(256) void k_rank(const float* __restrict__ var, float* __restrict__ mbin){
  __shared__ float va[1024];
  int bid=blockIdx.x; int b=bid>>2, seg=bid&3;
  int tid=threadIdx.x;
  for(int i=tid;i<1024;i+=256) va[i]=var[(b<<10)+i];
  __syncthreads();
  int n=seg*256+tid;
  float vn=va[n]; int r=0;
  for(int m=0;m<1024;m++){ float vm=va[m]; r += (vm<vn) || (vm==vn && m<n); }
  mbin[(b<<10)+n] = (r<512)?0.f:1.f;
}

// ---------------- K6: h0/h1 from Wm1 rowsums ----------------
__global__ __launch_bounds__(64) void k_hvec(const void* __restrict__ Wm1, const float* __restrict__ bm1,
    float* __restrict__ h0, float* __restrict__ h1, const int* __restrict__ fl){
  int j=blockIdx.x, tid=threadIdx.x;
  float s=0.f;
  if(fl[0]){
    const float* row=(const float*)Wm1+((size_t)j<<12);
    for(int k=tid;k<4096;k+=64) s+=row[k];
  } else {
    const bf16* row=(const bf16*)Wm1+((size_t)j<<12);
    for(int k=tid;k<4096;k+=64) s+=b2f(row[k]);
  }
  for(int m=32;m>0;m>>=1) s+=__shfl_xor(s,m);
  if(tid==0){ float bb=bm1[j]; h0[j]=lrelu(bb); h1[j]=lrelu(bb+s); }
}

// ---------------- K7: mask vectors (+ transposed copies) ----------------
__global__ __launch_bounds__(64) void k_mask(const void* __restrict__ Wm2, const float* __restrict__ bm2,
    const float* __restrict__ h0, const float* __restrict__ h1,
    float* __restrict__ m0, float* __restrict__ m1,
    float* __restrict__ m0T, float* __restrict__ m1T, const int* __restrict__ fl){
  int e=blockIdx.x, tid=threadIdx.x;
  float p0=0.f,p1=0.f;
  if(fl[0]){
    const float* row=(const float*)Wm2+((size_t)e<<11);
    for(int j=tid;j<2048;j+=64){ float w=row[j]; p0+=w*h0[j]; p1+=w*h1[j]; }
  } else {
    const bf16* row=(const bf16*)Wm2+((size_t)e<<11);
    for(int j=tid;j<2048;j+=64){ float w=b2f(row[j]); p0+=w*h0[j]; p1+=w*h1[j]; }
  }
  for(int m=32;m>0;m>>=1){ p0+=__shfl_xor(p0,m); p1+=__shfl_xor(p1,m); }
  if(tid==0){
    float bb=bm2[e]; float v0=p0+bb, v1=p1+bb;
    m0[e]=v0; m1[e]=v1;
    int te=(e&63)*64+(e>>6);
    m0T[te]=v0; m1T[te]=v1;
  }
}

// ---------------- K8: ca = sigmoid(Wca * mean(x_) + bca) ----------------
__global__ __launch_bounds__(64) void k_ca(const float* __restrict__ capart,
    const float* __restrict__ Wca, const float* __restrict__ bca, float* __restrict__ ca){
  __shared__ float m[16];
  int b=blockIdx.x, tid=threadIdx.x;
  if(tid<16){
    float s=0.f;
    for(int blk=0;blk<128;blk++) s+=capart[((b*128)+blk)*16+tid];
    m[tid]=s*(1.f/65536.f);
  }
  __syncthreads();
  float a=bca[tid];
  #pragma unroll
  for(int i=0;i<16;i++) a+=Wca[(tid<<4)+i]*m[i];
  ca[(b<<6)+tid]=sigmoidf(a);
}

// ---------------- K_PX: xwb = bf16(x * mask) window-major (single rounding) ----------------
__global__ __launch_bounds__(256) void k_pack_x(const void* __restrict__ x,
    const float* __restrict__ mbin, const float* __restrict__ m0T, const float* __restrict__ m1T,
    const int* __restrict__ fl, unsigned short* __restrict__ xwb){
  int wp=blockIdx.x; int b=wp>>9, np=wp&511;
  int n0=np*2;
  int base=((n0>>5)<<11)+((n0&31)<<3);
  int t=threadIdx.x; int c0=t>>3, row=t&7;
  int isf32=fl[0];
  const float* mTa = (mbin[b*1024+n0  ]>0.5f)? m1T : m0T;
  const float* mTb = (mbin[b*1024+n0+1]>0.5f)? m1T : m0T;
  for(int h=0;h<2;h++){
    int ch=c0+h*32;
    size_t gb=(((size_t)(b*64+ch))<<16) + base + row*256;
    float xv[16];
    if(isf32){
      const float* xp=(const float*)x+gb;
      #pragma unroll
      for(int i=0;i<16;i++) xv[i]=xp[i];
    } else {
      const bf16* xp=(const bf16*)x+gb;
      #pragma unroll
      for(int i=0;i<16;i++) xv[i]=b2f(xp[i]);
    }
    size_t o0=((size_t)(b*1024+n0)*64+ch)*64 + row*8;
    #pragma unroll
    for(int wnd=0;wnd<2;wnd++){
      const float* mT = wnd? mTb : mTa;
      size_t oo=o0+(size_t)wnd*4096;
      int s=wnd*8;
      float mk[8];
      #pragma unroll
      for(int j=0;j<8;j++) mk[j]=mT[ch*64+row*8+j];
      uint4 ux;
      ux.x=pack2(xv[s+0]*mk[0],xv[s+1]*mk[1]); ux.y=pack2(xv[s+2]*mk[2],xv[s+3]*mk[3]);
      ux.z=pack2(xv[s+4]*mk[4],xv[s+5]*mk[5]); ux.w=pack2(xv[s+6]*mk[6],xv[s+7]*mk[7]);
      *(uint4*)(xwb+oo)=ux;
    }
  }
}

// ---------------- K9: windowed attention via MFMA -> img (bf16) ----------------
#define STR 72
#define STRF 65
__global__ __launch_bounds__(256,4) void k_attn_mfma(
    const unsigned short* __restrict__ xwb, const unsigned short* __restrict__ vw,
    const unsigned short* __restrict__ sa_w, const float* __restrict__ mbin,
    const float* __restrict__ m0T, const float* __restrict__ m1T,
    const short* __restrict__ Wqb, const float* __restrict__ bq,
    const short* __restrict__ Wkb, const float* __restrict__ bk,
    unsigned short* __restrict__ img){
  __shared__ short sT[64*STR];
  __shared__ short sQK[2*64*STR];
  __shared__ short sV1[64*STR];
  __shared__ float ssa[64];
  short* sQ=sQK; short* sK=sQK+64*STR;
  float* sF=(float*)sQK;
  int tid=threadIdx.x, blk=blockIdx.x;
  int b=blk>>10, n=blk&1023;
  int base=((n>>5)<<11) + ((n&31)<<3);
  size_t plane=((size_t)b*64)<<16;
  const float* mT = (mbin[blk]>0.5f)? m1T : m0T;
  const unsigned short* xw=xwb+(size_t)blk*4096;
  const unsigned short* vw2=vw+(size_t)blk*4096;
  if(tid<64) ssa[tid]=us2f(sa_w[((size_t)blk<<6)+tid]);
  for(int e=tid;e<4096;e+=256){
    int c=e>>6, tok=e&63;
    sT[tok*STR+c]=(short)xw[e];
    sV1[c*STR+tok]=f2bs(us2f(vw2[e])*mT[e]);
  }
  __syncthreads();
  int lane=tid&63, wid=tid>>6;
  int pb=wid*16, lr=lane&15, lg=lane>>4;
  short8v ta[2];
  #pragma unroll
  for(int ks=0;ks<2;ks++) ta[ks]=*(const short8v*)&sT[(pb+lr)*STR + ks*32 + lg*8];
  #pragma unroll
  for(int nt=0;nt<4;nt++){
    float bqv=bq[nt*16+lr], bkv=bk[nt*16+lr];
    f32x4 qa={bqv,bqv,bqv,bqv}, ka={bkv,bkv,bkv,bkv};
    #pragma unroll
    for(int ks=0;ks<2;ks++){
      short8v wq=*(const short8v*)(Wqb + (nt*16+lr)*64 + ks*32 + lg*8);
      short8v wk=*(const short8v*)(Wkb + (nt*16+lr)*64 + ks*32 + lg*8);
      qa=__builtin_amdgcn_mfma_f32_16x16x32_bf16(ta[ks],wq,qa,0,0,0);
      ka=__builtin_amdgcn_mfma_f32_16x16x32_bf16(ta[ks],wk,ka,0,0,0);
    }
    #pragma unroll
    for(int r=0;r<4;r++){
      sQ[(pb+lg*4+r)*STR + nt*16+lr]=f2bs(qa[r]);
      sK[(pb+lg*4+r)*STR + nt*16+lr]=f2bs(ka[r]);
    }
  }
  __syncthreads();
  short8v qa2[2];
  #pragma unroll
  for(int ks=0;ks<2;ks++) qa2[ks]=*(const short8v*)&sQ[(pb+lr)*STR + ks*32 + lg*8];
  f32x4 sacc[4];
  #pragma unroll
  for(int nt=0;nt<4;nt++){
    f32x4 a={0.f,0.f,0.f,0.f};
    #pragma unroll
    for(int ks=0;ks<2;ks++){
      short8v kb=*(const short8v*)&sK[(nt*16+lr)*STR + ks*32 + lg*8];
      a=__builtin_amdgcn_mfma_f32_16x16x32_bf16(qa2[ks],kb,a,0,0,0);
    }
    sacc[nt]=a;
  }
  f32x4 pa[4];
  #pragma unroll
  for(int r=0;r<4;r++){
    float mx=fmaxf(fmaxf(sacc[0][r],sacc[1][r]),fmaxf(sacc[2][r],sacc[3][r]));
    #pragma unroll
    for(int m=1;m<16;m<<=1) mx=fmaxf(mx,__shfl_xor(mx,m));
    float e0=__expf(sacc[0][r]-mx), e1=__expf(sacc[1][r]-mx);
    float e2=__expf(sacc[2][r]-mx), e3=__expf(sacc[3][r]-mx);
    float sum=e0+e1+e2+e3;
    #pragma unroll
    for(int m=1;m<16;m<<=1) sum+=__shfl_xor(sum,m);
    float inv=1.f/sum;
    pa[0][r]=e0*inv; pa[1][r]=e1*inv; pa[2][r]=e2*inv; pa[3][r]=e3*inv;
  }
  #pragma unroll
  for(int nt=0;nt<4;nt++){
    #pragma unroll
    for(int r=0;r<4;r++)
      sT[(pb+lg*4+r)*STR + nt*16+lr]=f2bs(pa[nt][r]);
  }
  __syncthreads();
  short8v aa[2];
  #pragma unroll
  for(int ks=0;ks<2;ks++) aa[ks]=*(const short8v*)&sT[(pb+lr)*STR + ks*32 + lg*8];
  #pragma unroll
  for(int nt=0;nt<4;nt++){
    f32x4 f={0.f,0.f,0.f,0.f};
    #pragma unroll
    for(int ks=0;ks<2;ks++){
      short8v vb=*(const short8v*)&sV1[(nt*16+lr)*STR + ks*32 + lg*8];
      f=__builtin_amdgcn_mfma_f32_16x16x32_bf16(aa[ks],vb,f,0,0,0);
    }
    #pragma unroll
    for(int r=0;r<4;r++) sF[(pb+lg*4+r)*STRF + nt*16+lr]=f[r];
  }
  __syncthreads();
  for(int e2=tid;e2<2048;e2+=256){
    int c=e2>>5, tp=e2&31; int tok=tp*2;
    float f0=sF[tok*STRF+c], f1=sF[(tok+1)*STRF+c];
    unsigned uv=*(const unsigned*)(vw2 + c*64 + tok);
    float mk0=mT[c*64+tok], mk1=mT[c*64+tok+1];
    float vs0=us2f(uv&0xffff)*ssa[tok]*(1.f-mk0);
    float vs1=us2f(uv>>16)*ssa[tok+1]*(1.f-mk1);
    int pix=base+((tok>>3)<<8)+(tok&7);
    *(unsigned*)(img+plane+(((size_t)c)<<16)+pix)=pack2(f0+vs0, f1+vs1);
  }
}

// ---------------- K_DWF: fused depthwise dil1+dil2+gelu*ca+img (bf16 in/out), 8-row strips ----------------
#define IST 264
__global__ __launch_bounds__(256) void k_dwfuse(const unsigned short* __restrict__ img,
    const float* __restrict__ dw1w, const float* __restrict__ dwb1,
    const float* __restrict__ dw2w, const float* __restrict__ dwb2,
    const float* __restrict__ ca, unsigned short* __restrict__ outb){
  __shared__ float sImg[14*IST];
  __shared__ float sTmp[12*IST];
  __shared__ float k1[9], k2[9];
  __shared__ float bb1, bb2, cav;
  int bid=blockIdx.x; int b=bid>>11, c=(bid>>5)&63, sy=bid&31;
  int y0=sy*8;
  int tid=threadIdx.x;
  if(tid<9){ k1[tid]=dw1w[c*9+tid]; k2[tid]=dw2w[c*9+tid]; }
  if(tid==9)  bb1=dwb1[c];
  if(tid==10) bb2=dwb2[c];
  if(tid==11) cav=ca[b*64+c];
  const unsigned short* ip=img+(((size_t)(b*64+c))<<16);
  for(int i=tid;i<14*IST;i+=256){
    int r=i/IST, cl=i-r*IST;
    int gy=y0-3+r, gx=cl-3;
    float v=0.f;
    if(cl<262 && (unsigned)gy<256u && (unsigned)gx<256u) v=us2f(ip[(gy<<8)+gx]);
    sImg[i]=v;
  }
  __syncthreads();
  for(int i=tid;i<12*IST;i+=256){
    int r=i/IST, cl=i-r*IST;
    float t=0.f;
    if(cl<260){
      int ty=y0-2+r, tc=cl-2;
      if((unsigned)ty<256u && (unsigned)tc<256u){
        t=bb1;
        #pragma unroll
        for(int dy=0;dy<3;dy++)
          #pragma unroll
          for(int dx=0;dx<3;dx++)
            t+=sImg[(r+dy)*IST+(cl+dx)]*k1[dy*3+dx];
      }
    }
    sTmp[i]=t;
  }
  __syncthreads();
  unsigned short* op=outb+(((size_t)(b*64+c))<<16);
  int lx=tid;
  #pragma unroll
  for(int ly=0;ly<8;ly++){
    float cs=bb2;
    #pragma unroll
    for(int dy=0;dy<3;dy++)
      #pragma unroll
      for(int dx=0;dx<3;dx++)
        cs+=sTmp[(ly+2*dy)*IST + lx+2*dx]*k2[dy*3+dx];
    float center=sImg[(ly+3)*IST + lx+3];
    op[((y0+ly)<<8)+lx]=(unsigned short)f2bs(geluf(cs)*cav+center);
  }
}

// ---------------- K_FDW: ffn depthwise (E bf16) + gelu gate -> bf16 out ----------------
#define EST 260
__global__ __launch_bounds__(256) void k_ffn_dw_t(const unsigned short* __restrict__ E,
    const float* __restrict__ dwf, unsigned short* __restrict__ g){
  __shared__ unsigned short sE1[18*EST];
  __shared__ unsigned short sE2[18*EST];
  __shared__ float k1[9], k2[9];
  int bid=blockIdx.x; int b=bid>>10, c=(bid>>4)&63, sy=bid&15;
  int y0=sy*16;
  int tid=threadIdx.x;
  if(tid<9){ k1[tid]=dwf[c*9+tid]; k2[tid]=dwf[(64+c)*9+tid]; }
  if(tid<144){
    int pl=tid/72; int rem=tid-pl*72; int rr=rem>>2; int cc=rem&3;
    int col=(cc<2)? cc : (256+cc);
    if(pl==0) sE1[rr*EST+col]=0; else sE2[rr*EST+col]=0;
  }
  const unsigned short* p1=E+(((size_t)(b*128+c))<<16);
  const unsigned short* p2=E+(((size_t)(b*128+64+c))<<16);
  int half=tid>>7, t2=tid&127;
  const unsigned short* pp = half? p2 : p1;
  for(int r=0;r<18;r++){
    int gy=y0-1+r;
    unsigned val=0;
    if((unsigned)gy<256u) val=*(const unsigned*)(pp+(gy<<8)+t2*2);
    unsigned short* dst = half? sE2 : sE1;
    *(unsigned*)(dst + r*EST + 2 + t2*2) = val;
  }
  __syncthreads();
  unsigned short* op=g+(((size_t)(b*64+c))<<16);
  int lx=tid;
  #pragma unroll 4
  for(int ly=0;ly<16;ly++){
    float a1=0.f, a2=0.f;
    #pragma unroll
    for(int dy=0;dy<3;dy++)
      #pragma unroll
      for(int dx=0;dx<3;dx++){
        int idx=(ly+dy)*EST + lx+dx+1;
        a1+=us2f(sE1[idx])*k1[dy*3+dx];
        a2+=us2f(sE2[idx])*k2[dy*3+dx];
      }
    op[((y0+ly)<<8)+lx]=(unsigned short)f2bs(geluf(a1)*a2);
  }
}

extern "C" void kernel_launch(void* const* d_in, const int* in_sizes, int n_in,
                              void* d_out, int out_size, void* d_ws, size_t ws_size,
                              hipStream_t stream){
  (void)in_sizes; (void)n_in; (void)out_size; (void)ws_size;
  const void* x  = d_in[0];
  const void* Wm1= d_in[23];
  const void* Wm2= d_in[25];

  char* ws=(char*)d_ws;
  // Slot A [0,64MiB):    v (f32) -> E (bf16, 128ch)         [v dead after route]
  // Slot B [64,128MiB):  img (bf16) -> x1 (f32)             [img dead after dwfuse]
  // Slot C [128,192MiB): xwb (bf16) -> outb (bf16) -> gbuf (bf16)
  // [192MiB..~211MiB):   small buffers
  // [220MiB,252MiB):     vw (bf16, window-major unmasked v)
  float* v    =(float*)(ws);
  unsigned short* E=(unsigned short*)(ws);
  unsigned short* img=(unsigned short*)(ws+67108864);
  float* x1   =(float*)(ws+67108864);
  unsigned short* xwb=(unsigned short*)(ws+134217728);
  unsigned short* outb=(unsigned short*)(ws+134217728);
  unsigned short* gbuf=(unsigned short*)(ws+134217728);
  unsigned short* vw =(unsigned short*)(ws+230686720);
  char* sm = ws+201326592;
  float* x_    =(float*)(sm);              // 16 MB
  unsigned short* sa_w=(unsigned short*)(sm+16777216); // 0.5 MB
  float* xm    =(float*)(sm+17825792);     // 1 MB
  float* var   =(float*)(sm+18874368);     // 16 KB
  float* mbin  =(float*)(sm+18890752);     // 16 KB
  float* h0    =(float*)(sm+18907136);     // 8 KB
  float* h1    =(float*)(sm+18915328);     // 8 KB
  float* m0    =(float*)(sm+18923520);     // 16 KB
  float* m1    =(float*)(sm+18939904);     // 16 KB
  float* capart=(float*)(sm+18956288);     // 64 KB
  float* ca    =(float*)(sm+19021824);     // 1 KB
  int*   flag  =(int*)  (sm+19022848);     // 4 B
  float* wbuf  =(float*)(sm+19023872);     // ~161 KB
  short* Wqb   =(short*)(sm+19200000);     // 8 KB
  short* Wkb   =(short*)(sm+19208192);     // 8 KB
  float* m0T   =(float*)(sm+19216384);     // 16 KB
  float* m1T   =(float*)(sm+19232768);     // 16 KB
  short* Wob   =(short*)(sm+19249152);     // 8 KB
  short* Wfib  =(short*)(sm+19257344);     // 16 KB
  short* Wfob  =(short*)(sm+19273728);     // 8 KB

  static const int din_idx[31]={5,6,7,8,9,10,11,12,13,14,15,16,17,18,19,20,21,22,24,26,27,28,29,30,31,32,33,1,2,3,4};
  static const int szs[31]  ={4096,64,4096,64,4096,64,576,64,576,64,4096,64,1024,16,1024,16,16,16,2048,4096,1024,64,144,1,8192,1152,4096,64,64,64,64};
  CvtArgs ca_args;
  int off=0;
  int offs[31];
  for(int t=0;t<31;t++){
    ca_args.src[t]=d_in[din_idx[t]];
    ca_args.sz[t]=szs[t];
    ca_args.off[t]=off;
    offs[t]=off;
    off+=szs[t];
  }
  const float* Wv  =wbuf+offs[0];  const float* bv  =wbuf+offs[1];
  const float* Wq  =wbuf+offs[2];  const float* bq  =wbuf+offs[3];
  const float* Wk  =wbuf+offs[4];  const float* bk  =wbuf+offs[5];
  const float* dw1 =wbuf+offs[6];  const float* dwb1=wbuf+offs[7];
  const float* dw2 =wbuf+offs[8];  const float* dwb2=wbuf+offs[9];
  const float* Wo  =wbuf+offs[10]; const float* bo  =wbuf+offs[11];
  const float* W_in=wbuf+offs[12]; const float* b_in=wbuf+offs[13];
  const float* Wc  =wbuf+offs[14]; const float* bc  =wbuf+offs[15];
  const float* lnw =wbuf+offs[16]; const float* lnb =wbuf+offs[17];
  const float* bm1 =wbuf+offs[18]; const float* bm2 =wbuf+offs[19];
  const float* Wca =wbuf+offs[20]; const float* bca =wbuf+offs[21];
  const float* Wsa =wbuf+offs[22]; const float* bsa =wbuf+offs[23];
  const float* Wfi =wbuf+offs[24]; const float* dwf =wbuf+offs[25];
  const float* Wfo =wbuf+offs[26];
  const float* wn1 =wbuf+offs[27]; const float* bn1 =wbuf+offs[28];
  const float* wn2 =wbuf+offs[29]; const float* bn2 =wbuf+offs[30];

  hipLaunchKernelGGL(k_detect,   dim3(1),      dim3(256), 0, stream, x, flag);
  hipLaunchKernelGGL(k_cvt,      dim3(31),     dim3(256), 0, stream, ca_args, flag, wbuf);
  hipLaunchKernelGGL(k_w2b,      dim3(16),     dim3(256), 0, stream, Wq, Wk, Wqb, Wkb);
  hipLaunchKernelGGL(k_w2b3,     dim3(32),     dim3(256), 0, stream, Wo, Wfi, Wfo, Wob, Wfib, Wfob);
  hipLaunchKernelGGL(k_conv_vw,  dim3(256,2),  dim3(256), 0, stream, x, Wv, bv, v, vw, flag);
  hipLaunchKernelGGL(k_route,    dim3(512),    dim3(256), 0, stream, v, W_in, b_in, Wc, bc, lnw, lnb, x_, xm, capart);
  hipLaunchKernelGGL(k_sa,       dim3(1024),   dim3(256), 0, stream, x_, Wsa, bsa, sa_w);
  hipLaunchKernelGGL(k_var,      dim3(4096),   dim3(64),  0, stream, xm, var);
  hipLaunchKernelGGL(k_rank,     dim3(16),     dim3(256), 0, stream, var, mbin);
  hipLaunchKernelGGL(k_hvec,     dim3(2048),   dim3(64),  0, stream, Wm1, bm1, h0, h1, flag);
  hipLaunchKernelGGL(k_mask,     dim3(4096),   dim3(64),  0, stream, Wm2, bm2, h0, h1, m0, m1, m0T, m1T, flag);
  hipLaunchKernelGGL(k_ca,       dim3(4),      dim3(64),  0, stream, capart, Wca, bca, ca);
  hipLaunchKernelGGL(k_pack_x,   dim3(2048),   dim3(256), 0, stream, x, mbin, m0T, m1T, flag, xwb);
  hipLaunchKernelGGL(k_attn_mfma,dim3(4096),   dim3(256), 0, stream, xwb, vw, sa_w, mbin, m0T, m1T, Wqb, bq, Wkb, bk, img);
  hipLaunchKernelGGL(k_dwfuse,   dim3(8192),   dim3(256), 0, stream, img, dw1, dwb1, dw2, dwb2, ca, outb);
  // x1 = LN1(x + Wo*outb + bo)   (MFMA + fused LN)
  hipLaunchKernelGGL(k_gemm_ln,  dim3(4096),   dim3(256), 0, stream, outb, Wob, bo, 1, x, wn1, bn1, (void*)x1, flag, 0, 1);
  // E = bf16(Wfi * x1)  (MFMA)
  hipLaunchKernelGGL(k_gemm_mf,  dim3(4096),   dim3(256), 0, stream, (const void*)x1, 1, Wfib, wbuf, 0, (void*)E, 128, 1);
  hipLaunchKernelGGL(k_ffn_dw_t, dim3(4096),   dim3(256), 0, stream, E, dwf, gbuf);
  // out = LN2(x1 + Wfo*gbuf)  (MFMA + fused LN)
  hipLaunchKernelGGL(k_gemm_ln,  dim3(4096),   dim3(256), 0, stream, gbuf, Wfob, wbuf, 0, (const void*)x1, wn2, bn2, d_out, flag, 1, 0);
}

// Round 12
// 576.581 us; speedup vs baseline: 3.1821x; 1.0446x over previous
//
#include <hip/hip_runtime.h>
#include <hip/hip_bf16.h>

typedef __hip_bfloat16 bf16;
typedef __attribute__((ext_vector_type(8))) short short8v;
typedef __attribute__((ext_vector_type(4))) float f32x4;

#define DEV static __device__ __forceinline__

DEV float b2f(bf16 h){ return __bfloat162float(h); }
DEV float us2f(unsigned short u){ unsigned v=((unsigned)u)<<16; float f; __builtin_memcpy(&f,&v,4); return f; }
DEV short f2bs(float f){ bf16 h=__float2bfloat16(f); short s; __builtin_memcpy(&s,&h,2); return s; }
DEV unsigned pack2(float a, float b){ return ((unsigned)(unsigned short)f2bs(b)<<16)|(unsigned short)f2bs(a); }
DEV float lrelu(float x){ return x >= 0.f ? x : 0.1f*x; }
DEV float geluf(float x){ return 0.5f*x*(1.f + erff(x*0.70710678118654752440f)); }
DEV float sigmoidf(float x){ return 1.f/(1.f + expf(-x)); }

// B=4, C=64, H=W=256, HW=65536, WS=8, N=1024 windows/batch, embed=4096

// ---------------- K0a: detect storage dtype ----------------
__global__ __launch_bounds__(256) void k_detect(const void* x, int* flag){
  __shared__ int cnt;
  if(threadIdx.x==0) cnt=0;
  __syncthreads();
  const unsigned short* up=(const unsigned short*)x;
  int c=0;
  for(int k=0;k<16;k++){
    unsigned short u=up[(threadIdx.x*16+k)*2];
    if(((u>>7)&0xFF)==0xFF) c++;
  }
  atomicAdd(&cnt,c);
  __syncthreads();
  if(threadIdx.x==0) flag[0] = (cnt>0) ? 1 : 0;  // 1 => f32 storage
}

// ---------------- K0b: convert small weights to f32 wbuf ----------------
struct CvtArgs { const void* src[31]; int sz[31]; int off[31]; };
__global__ __launch_bounds__(256) void k_cvt(CvtArgs a, const int* fl, float* wbuf){
  int t=blockIdx.x; int n=a.sz[t]; const void* s=a.src[t]; float* d=wbuf+a.off[t];
  if(fl[0]){
    const float* sp=(const float*)s;
    for(int i=threadIdx.x;i<n;i+=256) d[i]=sp[i];
  } else {
    const bf16* sp=(const bf16*)s;
    for(int i=threadIdx.x;i<n;i+=256) d[i]=b2f(sp[i]);
  }
}

// ---------------- K0c: Wq/Wk/Wo/Wfi/Wfo -> bf16 for MFMA ----------------
__global__ __launch_bounds__(256) void k_w2b5(const float* __restrict__ wq, const float* __restrict__ wk,
    const float* __restrict__ wo, const float* __restrict__ wfi, const float* __restrict__ wfo,
    short* __restrict__ Wqb, short* __restrict__ Wkb,
    short* __restrict__ Wob, short* __restrict__ Wfib, short* __restrict__ Wfob){
  int i=blockIdx.x*256+threadIdx.x;
  if(i<4096){ Wqb[i]=f2bs(wq[i]); Wkb[i]=f2bs(wk[i]); Wob[i]=f2bs(wo[i]); Wfob[i]=f2bs(wfo[i]); }
  if(i<8192) Wfib[i]=f2bs(wfi[i]);
}

// ---------------- K1: conv_v GEMM (exact f32 for routing) + window-major bf16 vw ----------------
// og=4 groups of 16 och -> a[16] float4 = 64 VGPR, high occupancy; x re-reads L3-hit.
__global__ __launch_bounds__(256) void k_conv_vw(
    const void* __restrict__ in, const float* __restrict__ W,
    const float* __restrict__ bias,
    float* __restrict__ out, unsigned short* __restrict__ vw,
    const int* __restrict__ fl){
  __shared__ float sW[1024]; __shared__ float sb[16];
  int tid=threadIdx.x, og=blockIdx.y;
  for(int i=tid;i<1024;i+=256) sW[i]=W[og*1024+i];
  if(tid<16) sb[tid]=bias[og*16+tid];
  __syncthreads();
  int g=blockIdx.x*1024+tid*4; int b=g>>16, p=g&65535;
  float4 a[16];
  #pragma unroll
  for(int o=0;o<16;o++){ float bv=sb[o]; a[o]=make_float4(bv,bv,bv,bv); }
  size_t base=(((size_t)b*64)<<16)+p;
  if(fl[0]){
    const float* ip=(const float*)in + base;
    for(int c=0;c<64;c++){
      float4 xv=*(const float4*)(ip + (((size_t)c)<<16));
      #pragma unroll
      for(int o=0;o<16;o++){ float w=sW[o*64+c];
        a[o].x+=w*xv.x; a[o].y+=w*xv.y; a[o].z+=w*xv.z; a[o].w+=w*xv.w; }
    }
  } else {
    const bf16* ip=(const bf16*)in + base;
    for(int c=0;c<64;c++){
      const bf16* q=ip+(((size_t)c)<<16);
      float4 xv=make_float4(b2f(q[0]),b2f(q[1]),b2f(q[2]),b2f(q[3]));
      #pragma unroll
      for(int o=0;o<16;o++){ float w=sW[o*64+c];
        a[o].x+=w*xv.x; a[o].y+=w*xv.y; a[o].z+=w*xv.z; a[o].w+=w*xv.w; }
    }
  }
  float* op=out + (((size_t)(b*64+og*16))<<16) + p;
  #pragma unroll
  for(int o=0;o<16;o++) *(float4*)(op+(((size_t)o)<<16))=a[o];
  // window-major bf16 copy (unmasked)
  int y=p>>8, xx=p&255;
  int n=((y>>3)<<5)|(xx>>3), tok=((y&7)<<3)|(xx&7);
  unsigned short* wp=vw + (((size_t)(b*1024+n))<<12) + (size_t)(og*16)*64 + tok;
  #pragma unroll
  for(int o=0;o<16;o++){
    uint2 u; u.x=pack2(a[o].x,a[o].y); u.y=pack2(a[o].z,a[o].w);
    *(uint2*)(wp + (size_t)o*64)=u;
  }
}

// ---------------- K_GM: MFMA 1x1-conv GEMM (ffn_in): D = W * in ----------------
__global__ __launch_bounds__(256) void k_gemm_mf(
    const void* __restrict__ in, int in_f32,
    const short* __restrict__ Wb, const float* __restrict__ bias, int has_bias,
    void* __restrict__ out, int och, int out_bf16){
  __shared__ short Ain[64*72];
  int tid=threadIdx.x;
  int g0=blockIdx.x*64; int b=g0>>16, p0=g0&65535;
  int c=tid>>2, q=tid&3;
  size_t base=(((size_t)(b*64+c))<<16) + p0;
  if(in_f32){
    const float* ip=(const float*)in + base;
    #pragma unroll
    for(int j=0;j<4;j++){
      int po=q*16+j*4;
      float4 xv=*(const float4*)(ip+po);
      Ain[(po+0)*72+c]=f2bs(xv.x); Ain[(po+1)*72+c]=f2bs(xv.y);
      Ain[(po+2)*72+c]=f2bs(xv.z); Ain[(po+3)*72+c]=f2bs(xv.w);
    }
  } else {
    const unsigned short* ip=(const unsigned short*)in + base;
    #pragma unroll
    for(int j=0;j<4;j++){
      int po=q*16+j*4;
      uint2 u=*(const uint2*)(ip+po);
      Ain[(po+0)*72+c]=(short)(u.x&0xffff); Ain[(po+1)*72+c]=(short)(u.x>>16);
      Ain[(po+2)*72+c]=(short)(u.y&0xffff); Ain[(po+3)*72+c]=(short)(u.y>>16);
    }
  }
  __syncthreads();
  int lane=tid&63, wid=tid>>6;
  int lr=lane&15, lg=lane>>4;
  int pix0=wid*16;
  short8v bfrag[2];
  #pragma unroll
  for(int ks=0;ks<2;ks++) bfrag[ks]=*(const short8v*)&Ain[(pix0+lr)*72 + ks*32 + lg*8];
  int ntn=och>>4;
  for(int nt=0;nt<ntn;nt++){
    f32x4 acc;
    if(has_bias){
      #pragma unroll
      for(int r=0;r<4;r++) acc[r]=bias[nt*16+lg*4+r];
    } else {
      acc=(f32x4){0.f,0.f,0.f,0.f};
    }
    #pragma unroll
    for(int ks=0;ks<2;ks++){
      short8v afrag=*(const short8v*)(Wb + (nt*16+lr)*64 + ks*32 + lg*8);
      acc=__builtin_amdgcn_mfma_f32_16x16x32_bf16(afrag,bfrag[ks],acc,0,0,0);
    }
    if(out_bf16){
      unsigned short* op=(unsigned short*)out;
      #pragma unroll
      for(int r=0;r<4;r++){
        int m=nt*16+lg*4+r;
        op[(((size_t)(b*och+m))<<16) + p0 + pix0 + lr]=(unsigned short)f2bs(acc[r]);
      }
    } else {
      float* op=(float*)out;
      #pragma unroll
      for(int r=0;r<4;r++){
        int m=nt*16+lg*4+r;
        op[(((size_t)(b*och+m))<<16) + p0 + pix0 + lr]=acc[r];
      }
    }
  }
}

// ---------------- K_GL: MFMA GEMM (64 och) + residual-add + LayerNorm fused ----------------
// base_mode/out_mode: 0=follow flag, 1=force f32, 2=force bf16
__global__ __launch_bounds__(256) void k_gemm_ln(
    const unsigned short* __restrict__ in,
    const short* __restrict__ Wb, const float* __restrict__ bias, int has_bias,
    const void* __restrict__ basex,
    const float* __restrict__ lnw, const float* __restrict__ lnb,
    void* __restrict__ out,
    const int* __restrict__ fl, int base_mode, int out_mode){
  __shared__ short Ain[64*72];
  int tid=threadIdx.x;
  int g0=blockIdx.x*64; int b=g0>>16, p0=g0&65535;
  int c=tid>>2, q=tid&3;
  {
    const unsigned short* ip=in + (((size_t)(b*64+c))<<16) + p0;
    #pragma unroll
    for(int j=0;j<4;j++){
      int po=q*16+j*4;
      uint2 u=*(const uint2*)(ip+po);
      Ain[(po+0)*72+c]=(short)(u.x&0xffff); Ain[(po+1)*72+c]=(short)(u.x>>16);
      Ain[(po+2)*72+c]=(short)(u.y&0xffff); Ain[(po+3)*72+c]=(short)(u.y>>16);
    }
  }
  __syncthreads();
  int lane=tid&63, wid=tid>>6;
  int lr=lane&15, lg=lane>>4;
  int pix0=wid*16;
  short8v bfrag[2];
  #pragma unroll
  for(int ks=0;ks<2;ks++) bfrag[ks]=*(const short8v*)&Ain[(pix0+lr)*72 + ks*32 + lg*8];
  float rl[16];
  #pragma unroll
  for(int nt=0;nt<4;nt++){
    f32x4 acc;
    if(has_bias){
      #pragma unroll
      for(int r=0;r<4;r++) acc[r]=bias[nt*16+lg*4+r];
    } else {
      acc=(f32x4){0.f,0.f,0.f,0.f};
    }
    #pragma unroll
    for(int ks=0;ks<2;ks++){
      short8v afrag=*(const short8v*)(Wb + (nt*16+lr)*64 + ks*32 + lg*8);
      acc=__builtin_amdgcn_mfma_f32_16x16x32_bf16(afrag,bfrag[ks],acc,0,0,0);
    }
    #pragma unroll
    for(int r=0;r<4;r++) rl[nt*4+r]=acc[r];
  }
  int pix=p0+pix0+lr;
  bool bf32 = (base_mode==1) || (base_mode==0 && fl[0]);
  if(bf32){
    const float* xp=(const float*)basex;
    #pragma unroll
    for(int nt=0;nt<4;nt++)
      #pragma unroll
      for(int r=0;r<4;r++)
        rl[nt*4+r]+=xp[(((size_t)(b*64+nt*16+lg*4+r))<<16)+pix];
  } else {
    const unsigned short* xp=(const unsigned short*)basex;
    #pragma unroll
    for(int nt=0;nt<4;nt++)
      #pragma unroll
      for(int r=0;r<4;r++)
        rl[nt*4+r]+=us2f(xp[(((size_t)(b*64+nt*16+lg*4+r))<<16)+pix]);
  }
  float s=0.f;
  #pragma unroll
  for(int i=0;i<16;i++) s+=rl[i];
  s+=__shfl_xor(s,16); s+=__shfl_xor(s,32);
  float mean=s*(1.f/64.f);
  float qv=0.f;
  #pragma unroll
  for(int i=0;i<16;i++){ float d=rl[i]-mean; qv+=d*d; }
  qv+=__shfl_xor(qv,16); qv+=__shfl_xor(qv,32);
  float inv=1.f/sqrtf(qv*(1.f/64.f)+1e-6f);
  bool of32 = (out_mode==1) || (out_mode==0 && fl[0]);
  if(of32){
    float* op=(float*)out;
    #pragma unroll
    for(int nt=0;nt<4;nt++)
      #pragma unroll
      for(int r=0;r<4;r++){
        int m=nt*16+lg*4+r;
        op[(((size_t)(b*64+m))<<16)+pix]=lnw[m]*((rl[nt*4+r]-mean)*inv)+lnb[m];
      }
  } else {
    unsigned short* op=(unsigned short*)out;
    #pragma unroll
    for(int nt=0;nt<4;nt++)
      #pragma unroll
      for(int r=0;r<4;r++){
        int m=nt*16+lg*4+r;
        op[(((size_t)(b*64+m))<<16)+pix]=(unsigned short)f2bs(lnw[m]*((rl[nt*4+r]-mean)*inv)+lnb[m]);
      }
  }
}

// ---------------- K2: route (2 pix/thread) ----------------
__global__ __launch_bounds__(256) void k_route(const float* __restrict__ v,
    const float* __restrict__ W_in, const float* __restrict__ b_in,
    const float* __restrict__ Wc, const float* __restrict__ bc,
    const float* __restrict__ lnw, const float* __restrict__ lnb,
    float* __restrict__ x_, float* __restrict__ xm, float* __restrict__ capart){
  __shared__ float wA[1024], wB[1024], sba[16], sbb[16], slw[16], slb[16];
  __shared__ float sred[4][16];
  int tid=threadIdx.x;
  for(int i=tid;i<1024;i+=256){ wA[i]=W_in[i]; wB[i]=Wc[i]; }
  if(tid<16){ sba[tid]=b_in[tid]; sbb[tid]=bc[tid]; slw[tid]=lnw[tid]; slb[tid]=lnb[tid]; }
  __syncthreads();
  int g=blockIdx.x*512+tid*2; int b=g>>16, p=g&65535;
  float2 aA[16], aB[16];
  #pragma unroll
  for(int i=0;i<16;i++){ aA[i]=make_float2(sba[i],sba[i]); aB[i]=make_float2(sbb[i],sbb[i]); }
  const float* vp=v+(((size_t)b*64)<<16)+p;
  for(int c=0;c<64;c++){
    float2 vv=*(const float2*)(vp+(((size_t)c)<<16));
    #pragma unroll
    for(int i=0;i<16;i++){
      float wa=wA[(i<<6)+c], wb=wB[(i<<6)+c];
      aA[i].x+=wa*vv.x; aA[i].y+=wa*vv.y;
      aB[i].x+=wb*vv.x; aB[i].y+=wb*vv.y;
    }
  }
  float s0=0.f,s1=0.f;
  #pragma unroll
  for(int i=0;i<16;i++){ aA[i].x=lrelu(aA[i].x); aA[i].y=lrelu(aA[i].y); s0+=aA[i].x; s1+=aA[i].y; }
  float2 xmst; xmst.x=s0*(1.f/16.f); xmst.y=s1*(1.f/16.f);
  *(float2*)(xm+g)=xmst;
  float u0=0.f,u1=0.f;
  #pragma unroll
  for(int i=0;i<16;i++){ u0+=aB[i].x; u1+=aB[i].y; }
  u0*=(1.f/16.f); u1*=(1.f/16.f);
  float q0=0.f,q1=0.f;
  #pragma unroll
  for(int i=0;i<16;i++){ float d0=aB[i].x-u0, d1=aB[i].y-u1; q0+=d0*d0; q1+=d1*d1; }
  q0*=(1.f/16.f); q1*=(1.f/16.f);
  float i0=1.f/sqrtf(q0+1e-6f), i1=1.f/sqrtf(q1+1e-6f);
  float red[16];
  float* xp=x_+(((size_t)b*16)<<16)+p;
  #pragma unroll
  for(int i=0;i<16;i++){
    float xv0=lrelu(slw[i]*((aB[i].x-u0)*i0)+slb[i]);
    float xv1=lrelu(slw[i]*((aB[i].y-u1)*i1)+slb[i]);
    float2 st; st.x=xv0; st.y=xv1;
    *(float2*)(xp+(((size_t)i)<<16))=st;
    red[i]=xv0+xv1;
  }
  int lane=tid&63, wid=tid>>6;
  #pragma unroll
  for(int i=0;i<16;i++){
    float val=red[i];
    for(int m=32;m>0;m>>=1) val+=__shfl_xor(val,m);
    if(lane==0) sred[wid][i]=val;
  }
  __syncthreads();
  if(tid<16) capart[blockIdx.x*16+tid]=sred[0][tid]+sred[1][tid]+sred[2][tid]+sred[3][tid];
}

// ---------------- K3: sa = sigmoid(conv3x3(x_)) -> window-major bf16 ----------------
__global__ __launch_bounds__(256) void k_sa(const float* __restrict__ x_,
    const float* __restrict__ Wsa, const float* __restrict__ bsa, unsigned short* __restrict__ sa_w){
  __shared__ float w[144]; __shared__ float bb;
  int tid=threadIdx.x;
  if(tid<144) w[tid]=Wsa[tid];
  if(tid==0) bb=bsa[0];
  __syncthreads();
  int pix=blockIdx.x*256+tid; int b=pix>>16, p=pix&65535;
  int y=p>>8, xx=p&255;
  float acc=bb;
  #pragma unroll
  for(int i=0;i<16;i++){
    const float* pl=x_+(((size_t)(b*16+i))<<16);
    #pragma unroll
    for(int ky=0;ky<3;ky++){
      int yy=y+ky-1;
      if((unsigned)yy<256u){
        #pragma unroll
        for(int kx=0;kx<3;kx++){
          int x2=xx+kx-1;
          if((unsigned)x2<256u) acc+=pl[(yy<<8)+x2]*w[i*9+ky*3+kx];
        }
      }
    }
  }
  int n=((y>>3)<<5)|(xx>>3), tok=((y&7)<<3)|(xx&7);
  sa_w[(((size_t)(b<<10)+n)<<6)+tok]=(unsigned short)f2bs(sigmoidf(acc));
}

// ---------------- K4: per-window variance (ddof=1) ----------------
__global__ __launch_bounds__(64) void k_var(const float* __restrict__ xm, float* __restrict__ var){
  int blk=blockIdx.x, tid=threadIdx.x;
  int b=blk>>10, n=blk&1023;
  int pix=((n>>5)<<11) + ((n&31)<<3) + ((tid>>3)<<8) + (tid&7);
  float val=xm[(b<<16)+pix];
  float s=val;
  for(int m=32;m>0;m>>=1) s+=__shfl_xor(s,m);
  float mean=s*(1.f/64.f);
  float d=val-mean; float q=d*d;
  for(int m=32;m>0;m>>=1) q+=__shfl_xor(q,m);
  if(tid==0) var[blk]=q*(1.f/63.f);
}

// ---------------- K5: rank -> mbin ----------------
__global__ __launch_bounds__(256) void k_rank(const float* __restrict__ var, float* __restrict__ mbin){
  __shared__ float va[1024];
  int bid=blockIdx.x; int b=bid>>2, seg=bid&3;
  int tid=threadIdx.x;
  for(int i=tid;i<1024;i+=256) va[i]=var[(b<<10)+i];
  __syncthreads();
  int n=seg*256+tid;
  float vn=va[n]; int r=0;
  for(int m=0;m<1024;m++){ float vm=va[m]; r += (vm<vn) || (vm==vn && m<n); }
  mbin[(b<<10)+n] = (r<512)?0.f:1.f;
}

// ---------------- K6: h0/h1 from Wm1 rowsums ----------------
__global__ __launch_bounds__(64) void k_hvec(const void* __restrict__ Wm1, const float* __restrict__ bm1,
    float* __restrict__ h0, float* __restrict__ h1, const int* __restrict__ fl){
  int j=blockIdx.x, tid=threadIdx.x;
  float s=0.f;
  if(fl[0]){
    const float* row=(const float*)Wm1+((size_t)j<<12);
    for(int k=tid;k<4096;k+=64) s+=row[k];
  } else {
    const bf16* row=(const bf16*)Wm1+((size_t)j<<12);
    for(int k=tid;k<4096;k+=64) s+=b2f(row[k]);
  }
  for(int m=32;m>0;m>>=1) s+=__shfl_xor(s,m);
  if(tid==0){ float bb=bm1[j]; h0[j]=lrelu(bb); h1[j]=lrelu(bb+s); }
}

// ---------------- K7: mask vectors (+ transposed copies) ----------------
__global__ __launch_bounds__(64) void k_mask(const void* __restrict__ Wm2, const float* __restrict__ bm2,
    const float* __restrict__ h0, const float* __restrict__ h1,
    float* __restrict__ m0, float* __restrict__ m1,
    float* __restrict__ m0T, float* __restrict__ m1T, const int* __restrict__ fl){
  int e=blockIdx.x, tid=threadIdx.x;
  float p0=0.f,p1=0.f;
  if(fl[0]){
    const float* row=(const float*)Wm2+((size_t)e<<11);
    for(int j=tid;j<2048;j+=64){ float w=row[j]; p0+=w*h0[j]; p1+=w*h1[j]; }
  } else {
    const bf16* row=(const bf16*)Wm2+((size_t)e<<11);
    for(int j=tid;j<2048;j+=64){ float w=b2f(row[j]); p0+=w*h0[j]; p1+=w*h1[j]; }
  }
  for(int m=32;m>0;m>>=1){ p0+=__shfl_xor(p0,m); p1+=__shfl_xor(p1,m); }
  if(tid==0){
    float bb=bm2[e]; float v0=p0+bb, v1=p1+bb;
    m0[e]=v0; m1[e]=v1;
    int te=(e&63)*64+(e>>6);
    m0T[te]=v0; m1T[te]=v1;
  }
}

// ---------------- K8: ca = sigmoid(Wca * mean(x_) + bca) ----------------
__global__ __launch_bounds__(64) void k_ca(const float* __restrict__ capart,
    const float* __restrict__ Wca, const float* __restrict__ bca, float* __restrict__ ca){
  __shared__ float m[16];
  int b=blockIdx.x, tid=threadIdx.x;
  if(tid<16){
    float s=0.f;
    for(int blk=0;blk<128;blk++) s+=capart[((b*128)+blk)*16+tid];
    m[tid]=s*(1.f/65536.f);
  }
  __syncthreads();
  float a=bca[tid];
  #pragma unroll
  for(int i=0;i<16;i++) a+=Wca[(tid<<4)+i]*m[i];
  ca[(b<<6)+tid]=sigmoidf(a);
}

// ---------------- K_PX: xwb = bf16(x * mask) window-major (single rounding) ----------------
__global__ __launch_bounds__(256) void k_pack_x(const void* __restrict__ x,
    const float* __restrict__ mbin, const float* __restrict__ m0T, const float* __restrict__ m1T,
    const int* __restrict__ fl, unsigned short* __restrict__ xwb){
  int wp=blockIdx.x; int b=wp>>9, np=wp&511;
  int n0=np*2;
  int base=((n0>>5)<<11)+((n0&31)<<3);
  int t=threadIdx.x; int c0=t>>3, row=t&7;
  int isf32=fl[0];
  const float* mTa = (mbin[b*1024+n0  ]>0.5f)? m1T : m0T;
  const float* mTb = (mbin[b*1024+n0+1]>0.5f)? m1T : m0T;
  for(int h=0;h<2;h++){
    int ch=c0+h*32;
    size_t gb=(((size_t)(b*64+ch))<<16) + base + row*256;
    float xv[16];
    if(isf32){
      const float* xp=(const float*)x+gb;
      #pragma unroll
      for(int i=0;i<16;i++) xv[i]=xp[i];
    } else {
      const bf16* xp=(const bf16*)x+gb;
      #pragma unroll
      for(int i=0;i<16;i++) xv[i]=b2f(xp[i]);
    }
    size_t o0=((size_t)(b*1024+n0)*64+ch)*64 + row*8;
    #pragma unroll
    for(int wnd=0;wnd<2;wnd++){
      const float* mT = wnd? mTb : mTa;
      size_t oo=o0+(size_t)wnd*4096;
      int s=wnd*8;
      float mk[8];
      #pragma unroll
      for(int j=0;j<8;j++) mk[j]=mT[ch*64+row*8+j];
      uint4 ux;
      ux.x=pack2(xv[s+0]*mk[0],xv[s+1]*mk[1]); ux.y=pack2(xv[s+2]*mk[2],xv[s+3]*mk[3]);
      ux.z=pack2(xv[s+4]*mk[4],xv[s+5]*mk[5]); ux.w=pack2(xv[s+6]*mk[6],xv[s+7]*mk[7]);
      *(uint4*)(xwb+oo)=ux;
    }
  }
}

// ---------------- K9: windowed attention via MFMA -> img (bf16) ----------------
#define STR 72
#define STRF 65
__global__ __launch_bounds__(256,4) void k_attn_mfma(
    const unsigned short* __restrict__ xwb, const unsigned short* __restrict__ vw,
    const unsigned short* __restrict__ sa_w, const float* __restrict__ mbin,
    const float* __restrict__ m0T, const float* __restrict__ m1T,
    const short* __restrict__ Wqb, const float* __restrict__ bq,
    const short* __restrict__ Wkb, const float* __restrict__ bk,
    unsigned short* __restrict__ img){
  __shared__ short sT[64*STR];
  __shared__ short sQK[2*64*STR];
  __shared__ short sV1[64*STR];
  __shared__ float ssa[64];
  short* sQ=sQK; short* sK=sQK+64*STR;
  float* sF=(float*)sQK;
  int tid=threadIdx.x, blk=blockIdx.x;
  int b=blk>>10, n=blk&1023;
  int base=((n>>5)<<11) + ((n&31)<<3);
  size_t plane=((size_t)b*64)<<16;
  const float* mT = (mbin[blk]>0.5f)? m1T : m0T;
  const unsigned short* xw=xwb+(size_t)blk*4096;
  const unsigned short* vw2=vw+(size_t)blk*4096;
  if(tid<64) ssa[tid]=us2f(sa_w[((size_t)blk<<6)+tid]);
  for(int e=tid;e<4096;e+=256){
    int c=e>>6, tok=e&63;
    sT[tok*STR+c]=(short)xw[e];
    sV1[c*STR+tok]=f2bs(us2f(vw2[e])*mT[e]);
  }
  __syncthreads();
  int lane=tid&63, wid=tid>>6;
  int pb=wid*16, lr=lane&15, lg=lane>>4;
  short8v ta[2];
  #pragma unroll
  for(int ks=0;ks<2;ks++) ta[ks]=*(const short8v*)&sT[(pb+lr)*STR + ks*32 + lg*8];
  #pragma unroll
  for(int nt=0;nt<4;nt++){
    float bqv=bq[nt*16+lr], bkv=bk[nt*16+lr];
    f32x4 qa={bqv,bqv,bqv,bqv}, ka={bkv,bkv,bkv,bkv};
    #pragma unroll
    for(int ks=0;ks<2;ks++){
      short8v wq=*(const short8v*)(Wqb + (nt*16+lr)*64 + ks*32 + lg*8);
      short8v wk=*(const short8v*)(Wkb + (nt*16+lr)*64 + ks*32 + lg*8);
      qa=__builtin_amdgcn_mfma_f32_16x16x32_bf16(ta[ks],wq,qa,0,0,0);
      ka=__builtin_amdgcn_mfma_f32_16x16x32_bf16(ta[ks],wk,ka,0,0,0);
    }
    #pragma unroll
    for(int r=0;r<4;r++){
      sQ[(pb+lg*4+r)*STR + nt*16+lr]=f2bs(qa[r]);
      sK[(pb+lg*4+r)*STR + nt*16+lr]=f2bs(ka[r]);
    }
  }
  __syncthreads();
  short8v qa2[2];
  #pragma unroll
  for(int ks=0;ks<2;ks++) qa2[ks]=*(const short8v*)&sQ[(pb+lr)*STR + ks*32 + lg*8];
  f32x4 sacc[4];
  #pragma unroll
  for(int nt=0;nt<4;nt++){
    f32x4 a={0.f,0.f,0.f,0.f};
    #pragma unroll
    for(int ks=0;ks<2;ks++){
      short8v kb=*(const short8v*)&sK[(nt*16+lr)*STR + ks*32 + lg*8];
      a=__builtin_amdgcn_mfma_f32_16x16x32_bf16(qa2[ks],kb,a,0,0,0);
    }
    sacc[nt]=a;
  }
  f32x4 pa[4];
  #pragma unroll
  for(int r=0;r<4;r++){
    float mx=fmaxf(fmaxf(sacc[0][r],sacc[1][r]),fmaxf(sacc[2][r],sacc[3][r]));
    #pragma unroll
    for(int m=1;m<16;m<<=1) mx=fmaxf(mx,__shfl_xor(mx,m));
    float e0=__expf(sacc[0][r]-mx), e1=__expf(sacc[1][r]-mx);
    float e2=__expf(sacc[2][r]-mx), e3=__expf(sacc[3][r]-mx);
    float sum=e0+e1+e2+e3;
    #pragma unroll
    for(int m=1;m<16;m<<=1) sum+=__shfl_xor(sum,m);
    float inv=1.f/sum;
    pa[0][r]=e0*inv; pa[1][r]=e1*inv; pa[2][r]=e2*inv; pa[3][r]=e3*inv;
  }
  #pragma unroll
  for(int nt=0;nt<4;nt++){
    #pragma unroll
    for(int r=0;r<4;r++)
      sT[(pb+lg*4+r)*STR + nt*16+lr]=f2bs(pa[nt][r]);
  }
  __syncthreads();
  short8v aa[2];
  #pragma unroll
  for(int ks=0;ks<2;ks++) aa[ks]=*(const short8v*)&sT[(pb+lr)*STR + ks*32 + lg*8];
  #pragma unroll
  for(int nt=0;nt<4;nt++){
    f32x4 f={0.f,0.f,0.f,0.f};
    #pragma unroll
    for(int ks=0;ks<2;ks++){
      short8v vb=*(const short8v*)&sV1[(nt*16+lr)*STR + ks*32 + lg*8];
      f=__builtin_amdgcn_mfma_f32_16x16x32_bf16(aa[ks],vb,f,0,0,0);
    }
    #pragma unroll
    for(int r=0;r<4;r++) sF[(pb+lg*4+r)*STRF + nt*16+lr]=f[r];
  }
  __syncthreads();
  for(int e2=tid;e2<2048;e2+=256){
    int c=e2>>5, tp=e2&31; int tok=tp*2;
    float f0=sF[tok*STRF+c], f1=sF[(tok+1)*STRF+c];
    unsigned uv=*(const unsigned*)(vw2 + c*64 + tok);
    float mk0=mT[c*64+tok], mk1=mT[c*64+tok+1];
    float vs0=us2f(uv&0xffff)*ssa[tok]*(1.f-mk0);
    float vs1=us2f(uv>>16)*ssa[tok+1]*(1.f-mk1);
    int pix=base+((tok>>3)<<8)+(tok&7);
    *(unsigned*)(img+plane+(((size_t)c)<<16)+pix)=pack2(f0+vs0, f1+vs1);
  }
}

// ---------------- K_DWF: fused depthwise dil1+dil2+gelu*ca+img (bf16 in/out), 8-row strips ----------------
#define IST 264
__global__ __launch_bounds__(256) void k_dwfuse(const unsigned short* __restrict__ img,
    const float* __restrict__ dw1w, const float* __restrict__ dwb1,
    const float* __restrict__ dw2w, const float* __restrict__ dwb2,
    const float* __restrict__ ca, unsigned short* __restrict__ outb){
  __shared__ float sImg[14*IST];
  __shared__ float sTmp[12*IST];
  __shared__ float k1[9], k2[9];
  __shared__ float bb1, bb2, cav;
  int bid=blockIdx.x; int b=bid>>11, c=(bid>>5)&63, sy=bid&31;
  int y0=sy*8;
  int tid=threadIdx.x;
  if(tid<9){ k1[tid]=dw1w[c*9+tid]; k2[tid]=dw2w[c*9+tid]; }
  if(tid==9)  bb1=dwb1[c];
  if(tid==10) bb2=dwb2[c];
  if(tid==11) cav=ca[b*64+c];
  const unsigned short* ip=img+(((size_t)(b*64+c))<<16);
  for(int i=tid;i<14*IST;i+=256){
    int r=i/IST, cl=i-r*IST;
    int gy=y0-3+r, gx=cl-3;
    float v=0.f;
    if(cl<262 && (unsigned)gy<256u && (unsigned)gx<256u) v=us2f(ip[(gy<<8)+gx]);
    sImg[i]=v;
  }
  __syncthreads();
  for(int i=tid;i<12*IST;i+=256){
    int r=i/IST, cl=i-r*IST;
    float t=0.f;
    if(cl<260){
      int ty=y0-2+r, tc=cl-2;
      if((unsigned)ty<256u && (unsigned)tc<256u){
        t=bb1;
        #pragma unroll
        for(int dy=0;dy<3;dy++)
          #pragma unroll
          for(int dx=0;dx<3;dx++)
            t+=sImg[(r+dy)*IST+(cl+dx)]*k1[dy*3+dx];
      }
    }
    sTmp[i]=t;
  }
  __syncthreads();
  unsigned short* op=outb+(((size_t)(b*64+c))<<16);
  int lx=tid;
  #pragma unroll
  for(int ly=0;ly<8;ly++){
    float cs=bb2;
    #pragma unroll
    for(int dy=0;dy<3;dy++)
      #pragma unroll
      for(int dx=0;dx<3;dx++)
        cs+=sTmp[(ly+2*dy)*IST + lx+2*dx]*k2[dy*3+dx];
    float center=sImg[(ly+3)*IST + lx+3];
    op[((y0+ly)<<8)+lx]=(unsigned short)f2bs(geluf(cs)*cav+center);
  }
}

// ---------------- K_FDW: ffn depthwise (E bf16) + gelu gate -> bf16 out ----------------
#define EST 260
__global__ __launch_bounds__(256) void k_ffn_dw_t(const unsigned short* __restrict__ E,
    const float* __restrict__ dwf, unsigned short* __restrict__ g){
  __shared__ unsigned short sE1[18*EST];
  __shared__ unsigned short sE2[18*EST];
  __shared__ float k1[9], k2[9];
  int bid=blockIdx.x; int b=bid>>10, c=(bid>>4)&63, sy=bid&15;
  int y0=sy*16;
  int tid=threadIdx.x;
  if(tid<9){ k1[tid]=dwf[c*9+tid]; k2[tid]=dwf[(64+c)*9+tid]; }
  if(tid<144){
    int pl=tid/72; int rem=tid-pl*72; int rr=rem>>2; int cc=rem&3;
    int col=(cc<2)? cc : (256+cc);
    if(pl==0) sE1[rr*EST+col]=0; else sE2[rr*EST+col]=0;
  }
  const unsigned short* p1=E+(((size_t)(b*128+c))<<16);
  const unsigned short* p2=E+(((size_t)(b*128+64+c))<<16);
  int half=tid>>7, t2=tid&127;
  const unsigned short* pp = half? p2 : p1;
  for(int r=0;r<18;r++){
    int gy=y0-1+r;
    unsigned val=0;
    if((unsigned)gy<256u) val=*(const unsigned*)(pp+(gy<<8)+t2*2);
    unsigned short* dst = half? sE2 : sE1;
    *(unsigned*)(dst + r*EST + 2 + t2*2) = val;
  }
  __syncthreads();
  unsigned short* op=g+(((size_t)(b*64+c))<<16);
  int lx=tid;
  #pragma unroll 4
  for(int ly=0;ly<16;ly++){
    float a1=0.f, a2=0.f;
    #pragma unroll
    for(int dy=0;dy<3;dy++)
      #pragma unroll
      for(int dx=0;dx<3;dx++){
        int idx=(ly+dy)*EST + lx+dx+1;
        a1+=us2f(sE1[idx])*k1[dy*3+dx];
        a2+=us2f(sE2[idx])*k2[dy*3+dx];
      }
    op[((y0+ly)<<8)+lx]=(unsigned short)f2bs(geluf(a1)*a2);
  }
}

extern "C" void kernel_launch(void* const* d_in, const int* in_sizes, int n_in,
                              void* d_out, int out_size, void* d_ws, size_t ws_size,
                              hipStream_t stream){
  (void)in_sizes; (void)n_in; (void)out_size; (void)ws_size;
  const void* x  = d_in[0];
  const void* Wm1= d_in[23];
  const void* Wm2= d_in[25];

  char* ws=(char*)d_ws;
  // Slot A [0,64MiB):    v (f32) -> E (bf16, 128ch)         [v dead after route]
  // Slot B [64,128MiB):  img (bf16) -> x1b (bf16)           [img dead after dwfuse]
  // Slot C [128,192MiB): xwb (bf16) -> outb (bf16) -> gbuf (bf16)
  // [192MiB..~211MiB):   small buffers
  // [220MiB,252MiB):     vw (bf16, window-major unmasked v)
  float* v    =(float*)(ws);
  unsigned short* E=(unsigned short*)(ws);
  unsigned short* img=(unsigned short*)(ws+67108864);
  unsigned short* x1b=(unsigned short*)(ws+67108864);
  unsigned short* xwb=(unsigned short*)(ws+134217728);
  unsigned short* outb=(unsigned short*)(ws+134217728);
  unsigned short* gbuf=(unsigned short*)(ws+134217728);
  unsigned short* vw =(unsigned short*)(ws+230686720);
  char* sm = ws+201326592;
  float* x_    =(float*)(sm);              // 16 MB
  unsigned short* sa_w=(unsigned short*)(sm+16777216); // 0.5 MB
  float* xm    =(float*)(sm+17825792);     // 1 MB
  float* var   =(float*)(sm+18874368);     // 16 KB
  float* mbin  =(float*)(sm+18890752);     // 16 KB
  float* h0    =(float*)(sm+18907136);     // 8 KB
  float* h1    =(float*)(sm+18915328);     // 8 KB
  float* m0    =(float*)(sm+18923520);     // 16 KB
  float* m1    =(float*)(sm+18939904);     // 16 KB
  float* capart=(float*)(sm+18956288);     // 64 KB
  float* ca    =(float*)(sm+19021824);     // 1 KB
  int*   flag  =(int*)  (sm+19022848);     // 4 B
  float* wbuf  =(float*)(sm+19023872);     // ~161 KB
  short* Wqb   =(short*)(sm+19200000);     // 8 KB
  short* Wkb   =(short*)(sm+19208192);     // 8 KB
  float* m0T   =(float*)(sm+19216384);     // 16 KB
  float* m1T   =(float*)(sm+19232768);     // 16 KB
  short* Wob   =(short*)(sm+19249152);     // 8 KB
  short* Wfib  =(short*)(sm+19257344);     // 16 KB
  short* Wfob  =(short*)(sm+19273728);     // 8 KB

  static const int din_idx[31]={5,6,7,8,9,10,11,12,13,14,15,16,17,18,19,20,21,22,24,26,27,28,29,30,31,32,33,1,2,3,4};
  static const int szs[31]  ={4096,64,4096,64,4096,64,576,64,576,64,4096,64,1024,16,1024,16,16,16,2048,4096,1024,64,144,1,8192,1152,4096,64,64,64,64};
  CvtArgs ca_args;
  int off=0;
  int offs[31];
  for(int t=0;t<31;t++){
    ca_args.src[t]=d_in[din_idx[t]];
    ca_args.sz[t]=szs[t];
    ca_args.off[t]=off;
    offs[t]=off;
    off+=szs[t];
  }
  const float* Wv  =wbuf+offs[0];  const float* bv  =wbuf+offs[1];
  const float* Wq  =wbuf+offs[2];  const float* bq  =wbuf+offs[3];
  const float* Wk  =wbuf+offs[4];  const float* bk  =wbuf+offs[5];
  const float* dw1 =wbuf+offs[6];  const float* dwb1=wbuf+offs[7];
  const float* dw2 =wbuf+offs[8];  const float* dwb2=wbuf+offs[9];
  const float* Wo  =wbuf+offs[10]; const float* bo  =wbuf+offs[11];
  const float* W_in=wbuf+offs[12]; const float* b_in=wbuf+offs[13];
  const float* Wc  =wbuf+offs[14]; const float* bc  =wbuf+offs[15];
  const float* lnw =wbuf+offs[16]; const float* lnb =wbuf+offs[17];
  const float* bm1 =wbuf+offs[18]; const float* bm2 =wbuf+offs[19];
  const float* Wca =wbuf+offs[20]; const float* bca =wbuf+offs[21];
  const float* Wsa =wbuf+offs[22]; const float* bsa =wbuf+offs[23];
  const float* Wfi =wbuf+offs[24]; const float* dwf =wbuf+offs[25];
  const float* Wfo =wbuf+offs[26];
  const float* wn1 =wbuf+offs[27]; const float* bn1 =wbuf+offs[28];
  const float* wn2 =wbuf+offs[29]; const float* bn2 =wbuf+offs[30];

  hipLaunchKernelGGL(k_detect,   dim3(1),      dim3(256), 0, stream, x, flag);
  hipLaunchKernelGGL(k_cvt,      dim3(31),     dim3(256), 0, stream, ca_args, flag, wbuf);
  hipLaunchKernelGGL(k_w2b5,     dim3(32),     dim3(256), 0, stream, Wq, Wk, Wo, Wfi, Wfo, Wqb, Wkb, Wob, Wfib, Wfob);
  hipLaunchKernelGGL(k_conv_vw,  dim3(256,4),  dim3(256), 0, stream, x, Wv, bv, v, vw, flag);
  hipLaunchKernelGGL(k_route,    dim3(512),    dim3(256), 0, stream, v, W_in, b_in, Wc, bc, lnw, lnb, x_, xm, capart);
  hipLaunchKernelGGL(k_sa,       dim3(1024),   dim3(256), 0, stream, x_, Wsa, bsa, sa_w);
  hipLaunchKernelGGL(k_var,      dim3(4096),   dim3(64),  0, stream, xm, var);
  hipLaunchKernelGGL(k_rank,     dim3(16),     dim3(256), 0, stream, var, mbin);
  hipLaunchKernelGGL(k_hvec,     dim3(2048),   dim3(64),  0, stream, Wm1, bm1, h0, h1, flag);
  hipLaunchKernelGGL(k_mask,     dim3(4096),   dim3(64),  0, stream, Wm2, bm2, h0, h1, m0, m1, m0T, m1T, flag);
  hipLaunchKernelGGL(k_ca,       dim3(4),      dim3(64),  0, stream, capart, Wca, bca, ca);
  hipLaunchKernelGGL(k_pack_x,   dim3(2048),   dim3(256), 0, stream, x, mbin, m0T, m1T, flag, xwb);
  hipLaunchKernelGGL(k_attn_mfma,dim3(4096),   dim3(256), 0, stream, xwb, vw, sa_w, mbin, m0T, m1T, Wqb, bq, Wkb, bk, img);
  hipLaunchKernelGGL(k_dwfuse,   dim3(8192),   dim3(256), 0, stream, img, dw1, dwb1, dw2, dwb2, ca, outb);
  // x1b = bf16(LN1(x + Wo*outb + bo))   (MFMA + fused LN)
  hipLaunchKernelGGL(k_gemm_ln,  dim3(4096),   dim3(256), 0, stream, outb, Wob, bo, 1, x, wn1, bn1, (void*)x1b, flag, 0, 2);
  // E = bf16(Wfi * x1b)  (MFMA)
  hipLaunchKernelGGL(k_gemm_mf,  dim3(4096),   dim3(256), 0, stream, (const void*)x1b, 0, Wfib, wbuf, 0, (void*)E, 128, 1);
  hipLaunchKernelGGL(k_ffn_dw_t, dim3(4096),   dim3(256), 0, stream, E, dwf, gbuf);
  // out = LN2(x1b + Wfo*gbuf)  (MFMA + fused LN)
  hipLaunchKernelGGL(k_gemm_ln,  dim3(4096),   dim3(256), 0, stream, gbuf, Wfob, wbuf, 0, (const void*)x1b, wn2, bn2, d_out, flag, 2, 0);
}

// Round 13
// 564.948 us; speedup vs baseline: 3.2476x; 1.0206x over previous
//
#include <hip/hip_runtime.h>
#include <hip/hip_bf16.h>

typedef __hip_bfloat16 bf16;
typedef __attribute__((ext_vector_type(8))) short short8v;
typedef __attribute__((ext_vector_type(4))) float f32x4;

#define DEV static __device__ __forceinline__

DEV float b2f(bf16 h){ return __bfloat162float(h); }
DEV float us2f(unsigned short u){ unsigned v=((unsigned)u)<<16; float f; __builtin_memcpy(&f,&v,4); return f; }
DEV short f2bs(float f){ bf16 h=__float2bfloat16(f); short s; __builtin_memcpy(&s,&h,2); return s; }
DEV unsigned pack2(float a, float b){ return ((unsigned)(unsigned short)f2bs(b)<<16)|(unsigned short)f2bs(a); }
DEV float lrelu(float x){ return x >= 0.f ? x : 0.1f*x; }
DEV float geluf(float x){ return 0.5f*x*(1.f + erff(x*0.70710678118654752440f)); }
DEV float sigmoidf(float x){ return 1.f/(1.f + expf(-x)); }

// B=4, C=64, H=W=256, HW=65536, WS=8, N=1024 windows/batch, embed=4096

// ---------------- K0a: detect storage dtype ----------------
__global__ __launch_bounds__(256) void k_detect(const void* x, int* flag){
  __shared__ int cnt;
  if(threadIdx.x==0) cnt=0;
  __syncthreads();
  const unsigned short* up=(const unsigned short*)x;
  int c=0;
  for(int k=0;k<16;k++){
    unsigned short u=up[(threadIdx.x*16+k)*2];
    if(((u>>7)&0xFF)==0xFF) c++;
  }
  atomicAdd(&cnt,c);
  __syncthreads();
  if(threadIdx.x==0) flag[0] = (cnt>0) ? 1 : 0;  // 1 => f32 storage
}

// ---------------- K0b: convert small weights to f32 wbuf ----------------
struct CvtArgs { const void* src[31]; int sz[31]; int off[31]; };
__global__ __launch_bounds__(256) void k_cvt(CvtArgs a, const int* fl, float* wbuf){
  int t=blockIdx.x; int n=a.sz[t]; const void* s=a.src[t]; float* d=wbuf+a.off[t];
  if(fl[0]){
    const float* sp=(const float*)s;
    for(int i=threadIdx.x;i<n;i+=256) d[i]=sp[i];
  } else {
    const bf16* sp=(const bf16*)s;
    for(int i=threadIdx.x;i<n;i+=256) d[i]=b2f(sp[i]);
  }
}

// ---------------- K0c: Wq/Wk/Wo/Wfi/Wfo -> bf16 for MFMA ----------------
__global__ __launch_bounds__(256) void k_w2b5(const float* __restrict__ wq, const float* __restrict__ wk,
    const float* __restrict__ wo, const float* __restrict__ wfi, const float* __restrict__ wfo,
    short* __restrict__ Wqb, short* __restrict__ Wkb,
    short* __restrict__ Wob, short* __restrict__ Wfib, short* __restrict__ Wfob){
  int i=blockIdx.x*256+threadIdx.x;
  if(i<4096){ Wqb[i]=f2bs(wq[i]); Wkb[i]=f2bs(wk[i]); Wob[i]=f2bs(wo[i]); Wfob[i]=f2bs(wfo[i]); }
  if(i<8192) Wfib[i]=f2bs(wfi[i]);
}

// ---------------- K1: conv_v GEMM (exact f32 for routing) + LDS-staged window-major bf16 vw ----------------
// og=4 groups of 16 och. Block = 1024 pixels (4 rows) = 32 half-windows.
// vw writes staged in LDS -> full 64B-line global stores.
__global__ __launch_bounds__(256) void k_conv_vw(
    const void* __restrict__ in, const float* __restrict__ W,
    const float* __restrict__ bias,
    float* __restrict__ out, unsigned short* __restrict__ vw,
    const int* __restrict__ fl){
  __shared__ float sW[1024]; __shared__ float sb[16];
  __shared__ unsigned short sVW[32*16*32];   // 32 KB: [win][chan][tok_half]
  int tid=threadIdx.x, og=blockIdx.y;
  for(int i=tid;i<1024;i+=256) sW[i]=W[og*1024+i];
  if(tid<16) sb[tid]=bias[og*16+tid];
  __syncthreads();
  int g=blockIdx.x*1024+tid*4; int b=g>>16, p=g&65535;
  float4 a[16];
  #pragma unroll
  for(int o=0;o<16;o++){ float bv=sb[o]; a[o]=make_float4(bv,bv,bv,bv); }
  size_t base=(((size_t)b*64)<<16)+p;
  if(fl[0]){
    const float* ip=(const float*)in + base;
    for(int c=0;c<64;c++){
      float4 xv=*(const float4*)(ip + (((size_t)c)<<16));
      #pragma unroll
      for(int o=0;o<16;o++){ float w=sW[o*64+c];
        a[o].x+=w*xv.x; a[o].y+=w*xv.y; a[o].z+=w*xv.z; a[o].w+=w*xv.w; }
    }
  } else {
    const bf16* ip=(const bf16*)in + base;
    for(int c=0;c<64;c++){
      const bf16* q=ip+(((size_t)c)<<16);
      float4 xv=make_float4(b2f(q[0]),b2f(q[1]),b2f(q[2]),b2f(q[3]));
      #pragma unroll
      for(int o=0;o<16;o++){ float w=sW[o*64+c];
        a[o].x+=w*xv.x; a[o].y+=w*xv.y; a[o].z+=w*xv.z; a[o].w+=w*xv.w; }
    }
  }
  float* op=out + (((size_t)(b*64+og*16))<<16) + p;
  #pragma unroll
  for(int o=0;o<16;o++) *(float4*)(op+(((size_t)o)<<16))=a[o];
  // stage bf16 into LDS window tile
  int y=p>>8, xx=p&255;
  int w=xx>>3;
  int tokl=((y&3)<<3)|(xx&7);
  #pragma unroll
  for(int o=0;o<16;o++){
    uint2 u; u.x=pack2(a[o].x,a[o].y); u.y=pack2(a[o].z,a[o].w);
    *(uint2*)&sVW[w*512 + o*32 + tokl]=u;
  }
  __syncthreads();
  // cooperative coalesced write-out: 2048 uint4 units
  int p0=(blockIdx.x*1024)&65535;
  int y0=p0>>8;
  int nbase=(y0>>3)<<5;
  int tokoff=(y0&4)<<3;
  size_t wbase=((size_t)(b*1024+nbase))<<12;
  #pragma unroll
  for(int k=0;k<8;k++){
    int u=tid+k*256;
    int win=u>>6, rem=u&63, c=rem>>2, q4=rem&3;
    uint4 val=*(const uint4*)&sVW[win*512 + c*32 + q4*8];
    *(uint4*)(vw + wbase + (size_t)win*4096 + (size_t)(og*16+c)*64 + tokoff + q4*8) = val;
  }
}

// ---------------- K_GM: MFMA 1x1-conv GEMM (ffn_in): D = W * in ----------------
__global__ __launch_bounds__(256) void k_gemm_mf(
    const void* __restrict__ in, int in_f32,
    const short* __restrict__ Wb, const float* __restrict__ bias, int has_bias,
    void* __restrict__ out, int och, int out_bf16){
  __shared__ short Ain[64*72];
  int tid=threadIdx.x;
  int g0=blockIdx.x*64; int b=g0>>16, p0=g0&65535;
  int c=tid>>2, q=tid&3;
  size_t base=(((size_t)(b*64+c))<<16) + p0;
  if(in_f32){
    const float* ip=(const float*)in + base;
    #pragma unroll
    for(int j=0;j<4;j++){
      int po=q*16+j*4;
      float4 xv=*(const float4*)(ip+po);
      Ain[(po+0)*72+c]=f2bs(xv.x); Ain[(po+1)*72+c]=f2bs(xv.y);
      Ain[(po+2)*72+c]=f2bs(xv.z); Ain[(po+3)*72+c]=f2bs(xv.w);
    }
  } else {
    const unsigned short* ip=(const unsigned short*)in + base;
    #pragma unroll
    for(int j=0;j<4;j++){
      int po=q*16+j*4;
      uint2 u=*(const uint2*)(ip+po);
      Ain[(po+0)*72+c]=(short)(u.x&0xffff); Ain[(po+1)*72+c]=(short)(u.x>>16);
      Ain[(po+2)*72+c]=(short)(u.y&0xffff); Ain[(po+3)*72+c]=(short)(u.y>>16);
    }
  }
  __syncthreads();
  int lane=tid&63, wid=tid>>6;
  int lr=lane&15, lg=lane>>4;
  int pix0=wid*16;
  short8v bfrag[2];
  #pragma unroll
  for(int ks=0;ks<2;ks++) bfrag[ks]=*(const short8v*)&Ain[(pix0+lr)*72 + ks*32 + lg*8];
  int ntn=och>>4;
  for(int nt=0;nt<ntn;nt++){
    f32x4 acc;
    if(has_bias){
      #pragma unroll
      for(int r=0;r<4;r++) acc[r]=bias[nt*16+lg*4+r];
    } else {
      acc=(f32x4){0.f,0.f,0.f,0.f};
    }
    #pragma unroll
    for(int ks=0;ks<2;ks++){
      short8v afrag=*(const short8v*)(Wb + (nt*16+lr)*64 + ks*32 + lg*8);
      acc=__builtin_amdgcn_mfma_f32_16x16x32_bf16(afrag,bfrag[ks],acc,0,0,0);
    }
    if(out_bf16){
      unsigned short* op=(unsigned short*)out;
      #pragma unroll
      for(int r=0;r<4;r++){
        int m=nt*16+lg*4+r;
        op[(((size_t)(b*och+m))<<16) + p0 + pix0 + lr]=(unsigned short)f2bs(acc[r]);
      }
    } else {
      float* op=(float*)out;
      #pragma unroll
      for(int r=0;r<4;r++){
        int m=nt*16+lg*4+r;
        op[(((size_t)(b*och+m))<<16) + p0 + pix0 + lr]=acc[r];
      }
    }
  }
}

// ---------------- K_GL: MFMA GEMM (64 och) + residual-add + LayerNorm fused ----------------
// base_mode/out_mode: 0=follow flag, 1=force f32, 2=force bf16
__global__ __launch_bounds__(256) void k_gemm_ln(
    const unsigned short* __restrict__ in,
    const short* __restrict__ Wb, const float* __restrict__ bias, int has_bias,
    const void* __restrict__ basex,
    const float* __restrict__ lnw, const float* __restrict__ lnb,
    void* __restrict__ out,
    const int* __restrict__ fl, int base_mode, int out_mode){
  __shared__ short Ain[64*72];
  int tid=threadIdx.x;
  int g0=blockIdx.x*64; int b=g0>>16, p0=g0&65535;
  int c=tid>>2, q=tid&3;
  {
    const unsigned short* ip=in + (((size_t)(b*64+c))<<16) + p0;
    #pragma unroll
    for(int j=0;j<4;j++){
      int po=q*16+j*4;
      uint2 u=*(const uint2*)(ip+po);
      Ain[(po+0)*72+c]=(short)(u.x&0xffff); Ain[(po+1)*72+c]=(short)(u.x>>16);
      Ain[(po+2)*72+c]=(short)(u.y&0xffff); Ain[(po+3)*72+c]=(short)(u.y>>16);
    }
  }
  __syncthreads();
  int lane=tid&63, wid=tid>>6;
  int lr=lane&15, lg=lane>>4;
  int pix0=wid*16;
  short8v bfrag[2];
  #pragma unroll
  for(int ks=0;ks<2;ks++) bfrag[ks]=*(const short8v*)&Ain[(pix0+lr)*72 + ks*32 + lg*8];
  float rl[16];
  #pragma unroll
  for(int nt=0;nt<4;nt++){
    f32x4 acc;
    if(has_bias){
      #pragma unroll
      for(int r=0;r<4;r++) acc[r]=bias[nt*16+lg*4+r];
    } else {
      acc=(f32x4){0.f,0.f,0.f,0.f};
    }
    #pragma unroll
    for(int ks=0;ks<2;ks++){
      short8v afrag=*(const short8v*)(Wb + (nt*16+lr)*64 + ks*32 + lg*8);
      acc=__builtin_amdgcn_mfma_f32_16x16x32_bf16(afrag,bfrag[ks],acc,0,0,0);
    }
    #pragma unroll
    for(int r=0;r<4;r++) rl[nt*4+r]=acc[r];
  }
  int pix=p0+pix0+lr;
  bool bf32 = (base_mode==1) || (base_mode==0 && fl[0]);
  if(bf32){
    const float* xp=(const float*)basex;
    #pragma unroll
    for(int nt=0;nt<4;nt++)
      #pragma unroll
      for(int r=0;r<4;r++)
        rl[nt*4+r]+=xp[(((size_t)(b*64+nt*16+lg*4+r))<<16)+pix];
  } else {
    const unsigned short* xp=(const unsigned short*)basex;
    #pragma unroll
    for(int nt=0;nt<4;nt++)
      #pragma unroll
      for(int r=0;r<4;r++)
        rl[nt*4+r]+=us2f(xp[(((size_t)(b*64+nt*16+lg*4+r))<<16)+pix]);
  }
  float s=0.f;
  #pragma unroll
  for(int i=0;i<16;i++) s+=rl[i];
  s+=__shfl_xor(s,16); s+=__shfl_xor(s,32);
  float mean=s*(1.f/64.f);
  float qv=0.f;
  #pragma unroll
  for(int i=0;i<16;i++){ float d=rl[i]-mean; qv+=d*d; }
  qv+=__shfl_xor(qv,16); qv+=__shfl_xor(qv,32);
  float inv=1.f/sqrtf(qv*(1.f/64.f)+1e-6f);
  bool of32 = (out_mode==1) || (out_mode==0 && fl[0]);
  if(of32){
    float* op=(float*)out;
    #pragma unroll
    for(int nt=0;nt<4;nt++)
      #pragma unroll
      for(int r=0;r<4;r++){
        int m=nt*16+lg*4+r;
        op[(((size_t)(b*64+m))<<16)+pix]=lnw[m]*((rl[nt*4+r]-mean)*inv)+lnb[m];
      }
  } else {
    unsigned short* op=(unsigned short*)out;
    #pragma unroll
    for(int nt=0;nt<4;nt++)
      #pragma unroll
      for(int r=0;r<4;r++){
        int m=nt*16+lg*4+r;
        op[(((size_t)(b*64+m))<<16)+pix]=(unsigned short)f2bs(lnw[m]*((rl[nt*4+r]-mean)*inv)+lnb[m]);
      }
  }
}

// ---------------- K2: route (2 pix/thread) ----------------
__global__ __launch_bounds__(256) void k_route(const float* __restrict__ v,
    const float* __restrict__ W_in, const float* __restrict__ b_in,
    const float* __restrict__ Wc, const float* __restrict__ bc,
    const float* __restrict__ lnw, const float* __restrict__ lnb,
    float* __restrict__ x_, float* __restrict__ xm, float* __restrict__ capart){
  __shared__ float wA[1024], wB[1024], sba[16], sbb[16], slw[16], slb[16];
  __shared__ float sred[4][16];
  int tid=threadIdx.x;
  for(int i=tid;i<1024;i+=256){ wA[i]=W_in[i]; wB[i]=Wc[i]; }
  if(tid<16){ sba[tid]=b_in[tid]; sbb[tid]=bc[tid]; slw[tid]=lnw[tid]; slb[tid]=lnb[tid]; }
  __syncthreads();
  int g=blockIdx.x*512+tid*2; int b=g>>16, p=g&65535;
  float2 aA[16], aB[16];
  #pragma unroll
  for(int i=0;i<16;i++){ aA[i]=make_float2(sba[i],sba[i]); aB[i]=make_float2(sbb[i],sbb[i]); }
  const float* vp=v+(((size_t)b*64)<<16)+p;
  for(int c=0;c<64;c++){
    float2 vv=*(const float2*)(vp+(((size_t)c)<<16));
    #pragma unroll
    for(int i=0;i<16;i++){
      float wa=wA[(i<<6)+c], wb=wB[(i<<6)+c];
      aA[i].x+=wa*vv.x; aA[i].y+=wa*vv.y;
      aB[i].x+=wb*vv.x; aB[i].y+=wb*vv.y;
    }
  }
  float s0=0.f,s1=0.f;
  #pragma unroll
  for(int i=0;i<16;i++){ aA[i].x=lrelu(aA[i].x); aA[i].y=lrelu(aA[i].y); s0+=aA[i].x; s1+=aA[i].y; }
  float2 xmst; xmst.x=s0*(1.f/16.f); xmst.y=s1*(1.f/16.f);
  *(float2*)(xm+g)=xmst;
  float u0=0.f,u1=0.f;
  #pragma unroll
  for(int i=0;i<16;i++){ u0+=aB[i].x; u1+=aB[i].y; }
  u0*=(1.f/16.f); u1*=(1.f/16.f);
  float q0=0.f,q1=0.f;
  #pragma unroll
  for(int i=0;i<16;i++){ float d0=aB[i].x-u0, d1=aB[i].y-u1; q0+=d0*d0; q1+=d1*d1; }
  q0*=(1.f/16.f); q1*=(1.f/16.f);
  float i0=1.f/sqrtf(q0+1e-6f), i1=1.f/sqrtf(q1+1e-6f);
  float red[16];
  float* xp=x_+(((size_t)b*16)<<16)+p;
  #pragma unroll
  for(int i=0;i<16;i++){
    float xv0=lrelu(slw[i]*((aB[i].x-u0)*i0)+slb[i]);
    float xv1=lrelu(slw[i]*((aB[i].y-u1)*i1)+slb[i]);
    float2 st; st.x=xv0; st.y=xv1;
    *(float2*)(xp+(((size_t)i)<<16))=st;
    red[i]=xv0+xv1;
  }
  int lane=tid&63, wid=tid>>6;
  #pragma unroll
  for(int i=0;i<16;i++){
    float val=red[i];
    for(int m=32;m>0;m>>=1) val+=__shfl_xor(val,m);
    if(lane==0) sred[wid][i]=val;
  }
  __syncthreads();
  if(tid<16) capart[blockIdx.x*16+tid]=sred[0][tid]+sred[1][tid]+sred[2][tid]+sred[3][tid];
}

// ---------------- K3: sa = sigmoid(conv3x3(x_)) -> window-major bf16 ----------------
__global__ __launch_bounds__(256) void k_sa(const float* __restrict__ x_,
    const float* __restrict__ Wsa, const float* __restrict__ bsa, unsigned short* __restrict__ sa_w){
  __shared__ float w[144]; __shared__ float bb;
  int tid=threadIdx.x;
  if(tid<144) w[tid]=Wsa[tid];
  if(tid==0) bb=bsa[0];
  __syncthreads();
  int pix=blockIdx.x*256+tid; int b=pix>>16, p=pix&65535;
  int y=p>>8, xx=p&255;
  float acc=bb;
  #pragma unroll
  for(int i=0;i<16;i++){
    const float* pl=x_+(((size_t)(b*16+i))<<16);
    #pragma unroll
    for(int ky=0;ky<3;ky++){
      int yy=y+ky-1;
      if((unsigned)yy<256u){
        #pragma unroll
        for(int kx=0;kx<3;kx++){
          int x2=xx+kx-1;
          if((unsigned)x2<256u) acc+=pl[(yy<<8)+x2]*w[i*9+ky*3+kx];
        }
      }
    }
  }
  int n=((y>>3)<<5)|(xx>>3), tok=((y&7)<<3)|(xx&7);
  sa_w[(((size_t)(b<<10)+n)<<6)+tok]=(unsigned short)f2bs(sigmoidf(acc));
}

// ---------------- K4: per-window variance (ddof=1) ----------------
__global__ __launch_bounds__(64) void k_var(const float* __restrict__ xm, float* __restrict__ var){
  int blk=blockIdx.x, tid=threadIdx.x;
  int b=blk>>10, n=blk&1023;
  int pix=((n>>5)<<11) + ((n&31)<<3) + ((tid>>3)<<8) + (tid&7);
  float val=xm[(b<<16)+pix];
  float s=val;
  for(int m=32;m>0;m>>=1) s+=__shfl_xor(s,m);
  float mean=s*(1.f/64.f);
  float d=val-mean; float q=d*d;
  for(int m=32;m>0;m>>=1) q+=__shfl_xor(q,m);
  if(tid==0) var[blk]=q*(1.f/63.f);
}

// ---------------- K5: rank -> mbin ----------------
__global__ __launch_bounds__(256) void k_rank(const float* __restrict__ var, float* __restrict__ mbin){
  __shared__ float va[1024];
  int bid=blockIdx.x; int b=bid>>2, seg=bid&3;
  int tid=threadIdx.x;
  for(int i=tid;i<1024;i+=256) va[i]=var[(b<<10)+i];
  __syncthreads();
  int n=seg*256+tid;
  float vn=va[n]; int r=0;
  for(int m=0;m<1024;m++){ float vm=va[m]; r += (vm<vn) || (vm==vn && m<n); }
  mbin[(b<<10)+n] = (r<512)?0.f:1.f;
}

// ---------------- K6: h0/h1 from Wm1 rowsums ----------------
__global__ __launch_bounds__(64) void k_hvec(const void* __restrict__ Wm1, const float* __restrict__ bm1,
    float* __restrict__ h0, float* __restrict__ h1, const int* __restrict__ fl){
  int j=blockIdx.x, tid=threadIdx.x;
  float s=0.f;
  if(fl[0]){
    const float* row=(const float*)Wm1+((size_t)j<<12);
    for(int k=tid;k<4096;k+=64) s+=row[k];
  } else {
    const bf16* row=(const bf16*)Wm1+((size_t)j<<12);
    for(int k=tid;k<4096;k+=64) s+=b2f(row[k]);
  }
  for(int m=32;m>0;m>>=1) s+=__shfl_xor(s,m);
  if(tid==0){ float bb=bm1[j]; h0[j]=lrelu(bb); h1[j]=lrelu(bb+s); }
}

// ---------------- K7: mask vectors (+ transposed copies) ----------------
__global__ __launch_bounds__(64) void k_mask(const void* __restrict__ Wm2, const float* __restrict__ bm2,
    const float* __restrict__ h0, const float* __restrict__ h1,
    float* __restrict__ m0, float* __restrict__ m1,
    float* __restrict__ m0T, float* __restrict__ m1T, const int* __restrict__ fl){
  int e=blockIdx.x, tid=threadIdx.x;
  float p0=0.f,p1=0.f;
  if(fl[0]){
    const float* row=(const float*)Wm2+((size_t)e<<11);
    for(int j=tid;j<2048;j+=64){ float w=row[j]; p0+=w*h0[j]; p1+=w*h1[j]; }
  } else {
    const bf16* row=(const bf16*)Wm2+((size_t)e<<11);
    for(int j=tid;j<2048;j+=64){ float w=b2f(row[j]); p0+=w*h0[j]; p1+=w*h1[j]; }
  }
  for(int m=32;m>0;m>>=1){ p0+=__shfl_xor(p0,m); p1+=__shfl_xor(p1,m); }
  if(tid==0){
    float bb=bm2[e]; float v0=p0+bb, v1=p1+bb;
    m0[e]=v0; m1[e]=v1;
    int te=(e&63)*64+(e>>6);
    m0T[te]=v0; m1T[te]=v1;
  }
}

// ---------------- K8: ca = sigmoid(Wca * mean(x_) + bca) ----------------
__global__ __launch_bounds__(64) void k_ca(const float* __restrict__ capart,
    const float* __restrict__ Wca, const float* __restrict__ bca, float* __restrict__ ca){
  __shared__ float m[16];
  int b=blockIdx.x, tid=threadIdx.x;
  if(tid<16){
    float s=0.f;
    for(int blk=0;blk<128;blk++) s+=capart[((b*128)+blk)*16+tid];
    m[tid]=s*(1.f/65536.f);
  }
  __syncthreads();
  float a=bca[tid];
  #pragma unroll
  for(int i=0;i<16;i++) a+=Wca[(tid<<4)+i]*m[i];
  ca[(b<<6)+tid]=sigmoidf(a);
}

// ---------------- K_PX: xwb = bf16(x * mask) window-major (single rounding) ----------------
__global__ __launch_bounds__(256) void k_pack_x(const void* __restrict__ x,
    const float* __restrict__ mbin, const float* __restrict__ m0T, const float* __restrict__ m1T,
    const int* __restrict__ fl, unsigned short* __restrict__ xwb){
  int wp=blockIdx.x; int b=wp>>9, np=wp&511;
  int n0=np*2;
  int base=((n0>>5)<<11)+((n0&31)<<3);
  int t=threadIdx.x; int c0=t>>3, row=t&7;
  int isf32=fl[0];
  const float* mTa = (mbin[b*1024+n0  ]>0.5f)? m1T : m0T;
  const float* mTb = (mbin[b*1024+n0+1]>0.5f)? m1T : m0T;
  for(int h=0;h<2;h++){
    int ch=c0+h*32;
    size_t gb=(((size_t)(b*64+ch))<<16) + base + row*256;
    float xv[16];
    if(isf32){
      const float* xp=(const float*)x+gb;
      #pragma unroll
      for(int i=0;i<16;i++) xv[i]=xp[i];
    } else {
      const bf16* xp=(const bf16*)x+gb;
      #pragma unroll
      for(int i=0;i<16;i++) xv[i]=b2f(xp[i]);
    }
    size_t o0=((size_t)(b*1024+n0)*64+ch)*64 + row*8;
    #pragma unroll
    for(int wnd=0;wnd<2;wnd++){
      const float* mT = wnd? mTb : mTa;
      size_t oo=o0+(size_t)wnd*4096;
      int s=wnd*8;
      float mk[8];
      #pragma unroll
      for(int j=0;j<8;j++) mk[j]=mT[ch*64+row*8+j];
      uint4 ux;
      ux.x=pack2(xv[s+0]*mk[0],xv[s+1]*mk[1]); ux.y=pack2(xv[s+2]*mk[2],xv[s+3]*mk[3]);
      ux.z=pack2(xv[s+4]*mk[4],xv[s+5]*mk[5]); ux.w=pack2(xv[s+6]*mk[6],xv[s+7]*mk[7]);
      *(uint4*)(xwb+oo)=ux;
    }
  }
}

// ---------------- K9: windowed attention via MFMA -> img (bf16) ----------------
#define STR 72
#define STRF 65
__global__ __launch_bounds__(256,4) void k_attn_mfma(
    const unsigned short* __restrict__ xwb, const unsigned short* __restrict__ vw,
    const unsigned short* __restrict__ sa_w, const float* __restrict__ mbin,
    const float* __restrict__ m0T, const float* __restrict__ m1T,
    const short* __restrict__ Wqb, const float* __restrict__ bq,
    const short* __restrict__ Wkb, const float* __restrict__ bk,
    unsigned short* __restrict__ img){
  __shared__ short sT[64*STR];
  __shared__ short sQK[2*64*STR];
  __shared__ short sV1[64*STR];
  __shared__ float ssa[64];
  short* sQ=sQK; short* sK=sQK+64*STR;
  float* sF=(float*)sQK;
  int tid=threadIdx.x, blk=blockIdx.x;
  int b=blk>>10, n=blk&1023;
  int base=((n>>5)<<11) + ((n&31)<<3);
  size_t plane=((size_t)b*64)<<16;
  const float* mT = (mbin[blk]>0.5f)? m1T : m0T;
  const unsigned short* xw=xwb+(size_t)blk*4096;
  const unsigned short* vw2=vw+(size_t)blk*4096;
  if(tid<64) ssa[tid]=us2f(sa_w[((size_t)blk<<6)+tid]);
  for(int e=tid;e<4096;e+=256){
    int c=e>>6, tok=e&63;
    sT[tok*STR+c]=(short)xw[e];
    sV1[c*STR+tok]=f2bs(us2f(vw2[e])*mT[e]);
  }
  __syncthreads();
  int lane=tid&63, wid=tid>>6;
  int pb=wid*16, lr=lane&15, lg=lane>>4;
  short8v ta[2];
  #pragma unroll
  for(int ks=0;ks<2;ks++) ta[ks]=*(const short8v*)&sT[(pb+lr)*STR + ks*32 + lg*8];
  #pragma unroll
  for(int nt=0;nt<4;nt++){
    float bqv=bq[nt*16+lr], bkv=bk[nt*16+lr];
    f32x4 qa={bqv,bqv,bqv,bqv}, ka={bkv,bkv,bkv,bkv};
    #pragma unroll
    for(int ks=0;ks<2;ks++){
      short8v wq=*(const short8v*)(Wqb + (nt*16+lr)*64 + ks*32 + lg*8);
      short8v wk=*(const short8v*)(Wkb + (nt*16+lr)*64 + ks*32 + lg*8);
      qa=__builtin_amdgcn_mfma_f32_16x16x32_bf16(ta[ks],wq,qa,0,0,0);
      ka=__builtin_amdgcn_mfma_f32_16x16x32_bf16(ta[ks],wk,ka,0,0,0);
    }
    #pragma unroll
    for(int r=0;r<4;r++){
      sQ[(pb+lg*4+r)*STR + nt*16+lr]=f2bs(qa[r]);
      sK[(pb+lg*4+r)*STR + nt*16+lr]=f2bs(ka[r]);
    }
  }
  __syncthreads();
  short8v qa2[2];
  #pragma unroll
  for(int ks=0;ks<2;ks++) qa2[ks]=*(const short8v*)&sQ[(pb+lr)*STR + ks*32 + lg*8];
  f32x4 sacc[4];
  #pragma unroll
  for(int nt=0;nt<4;nt++){
    f32x4 a={0.f,0.f,0.f,0.f};
    #pragma unroll
    for(int ks=0;ks<2;ks++){
      short8v kb=*(const short8v*)&sK[(nt*16+lr)*STR + ks*32 + lg*8];
      a=__builtin_amdgcn_mfma_f32_16x16x32_bf16(qa2[ks],kb,a,0,0,0);
    }
    sacc[nt]=a;
  }
  f32x4 pa[4];
  #pragma unroll
  for(int r=0;r<4;r++){
    float mx=fmaxf(fmaxf(sacc[0][r],sacc[1][r]),fmaxf(sacc[2][r],sacc[3][r]));
    #pragma unroll
    for(int m=1;m<16;m<<=1) mx=fmaxf(mx,__shfl_xor(mx,m));
    float e0=__expf(sacc[0][r]-mx), e1=__expf(sacc[1][r]-mx);
    float e2=__expf(sacc[2][r]-mx), e3=__expf(sacc[3][r]-mx);
    float sum=e0+e1+e2+e3;
    #pragma unroll
    for(int m=1;m<16;m<<=1) sum+=__shfl_xor(sum,m);
    float inv=1.f/sum;
    pa[0][r]=e0*inv; pa[1][r]=e1*inv; pa[2][r]=e2*inv; pa[3][r]=e3*inv;
  }
  #pragma unroll
  for(int nt=0;nt<4;nt++){
    #pragma unroll
    for(int r=0;r<4;r++)
      sT[(pb+lg*4+r)*STR + nt*16+lr]=f2bs(pa[nt][r]);
  }
  __syncthreads();
  short8v aa[2];
  #pragma unroll
  for(int ks=0;ks<2;ks++) aa[ks]=*(const short8v*)&sT[(pb+lr)*STR + ks*32 + lg*8];
  #pragma unroll
  for(int nt=0;nt<4;nt++){
    f32x4 f={0.f,0.f,0.f,0.f};
    #pragma unroll
    for(int ks=0;ks<2;ks++){
      short8v vb=*(const short8v*)&sV1[(nt*16+lr)*STR + ks*32 + lg*8];
      f=__builtin_amdgcn_mfma_f32_16x16x32_bf16(aa[ks],vb,f,0,0,0);
    }
    #pragma unroll
    for(int r=0;r<4;r++) sF[(pb+lg*4+r)*STRF + nt*16+lr]=f[r];
  }
  __syncthreads();
  for(int e2=tid;e2<2048;e2+=256){
    int c=e2>>5, tp=e2&31; int tok=tp*2;
    float f0=sF[tok*STRF+c], f1=sF[(tok+1)*STRF+c];
    unsigned uv=*(const unsigned*)(vw2 + c*64 + tok);
    float mk0=mT[c*64+tok], mk1=mT[c*64+tok+1];
    float vs0=us2f(uv&0xffff)*ssa[tok]*(1.f-mk0);
    float vs1=us2f(uv>>16)*ssa[tok+1]*(1.f-mk1);
    int pix=base+((tok>>3)<<8)+(tok&7);
    *(unsigned*)(img+plane+(((size_t)c)<<16)+pix)=pack2(f0+vs0, f1+vs1);
  }
}

// ---------------- K_DWF: fused depthwise dil1+dil2+gelu*ca+img (bf16 in/out), 8-row strips ----------------
#define IST 264
__global__ __launch_bounds__(256) void k_dwfuse(const unsigned short* __restrict__ img,
    const float* __restrict__ dw1w, const float* __restrict__ dwb1,
    const float* __restrict__ dw2w, const float* __restrict__ dwb2,
    const float* __restrict__ ca, unsigned short* __restrict__ outb){
  __shared__ float sImg[14*IST];
  __shared__ float sTmp[12*IST];
  __shared__ float k1[9], k2[9];
  __shared__ float bb1, bb2, cav;
  int bid=blockIdx.x; int b=bid>>11, c=(bid>>5)&63, sy=bid&31;
  int y0=sy*8;
  int tid=threadIdx.x;
  if(tid<9){ k1[tid]=dw1w[c*9+tid]; k2[tid]=dw2w[c*9+tid]; }
  if(tid==9)  bb1=dwb1[c];
  if(tid==10) bb2=dwb2[c];
  if(tid==11) cav=ca[b*64+c];
  const unsigned short* ip=img+(((size_t)(b*64+c))<<16);
  for(int i=tid;i<14*IST;i+=256){
    int r=i/IST, cl=i-r*IST;
    int gy=y0-3+r, gx=cl-3;
    float v=0.f;
    if(cl<262 && (unsigned)gy<256u && (unsigned)gx<256u) v=us2f(ip[(gy<<8)+gx]);
    sImg[i]=v;
  }
  __syncthreads();
  for(int i=tid;i<12*IST;i+=256){
    int r=i/IST, cl=i-r*IST;
    float t=0.f;
    if(cl<260){
      int ty=y0-2+r, tc=cl-2;
      if((unsigned)ty<256u && (unsigned)tc<256u){
        t=bb1;
        #pragma unroll
        for(int dy=0;dy<3;dy++)
          #pragma unroll
          for(int dx=0;dx<3;dx++)
            t+=sImg[(r+dy)*IST+(cl+dx)]*k1[dy*3+dx];
      }
    }
    sTmp[i]=t;
  }
  __syncthreads();
  unsigned short* op=outb+(((size_t)(b*64+c))<<16);
  int lx=tid;
  #pragma unroll
  for(int ly=0;ly<8;ly++){
    float cs=bb2;
    #pragma unroll
    for(int dy=0;dy<3;dy++)
      #pragma unroll
      for(int dx=0;dx<3;dx++)
        cs+=sTmp[(ly+2*dy)*IST + lx+2*dx]*k2[dy*3+dx];
    float center=sImg[(ly+3)*IST + lx+3];
    op[((y0+ly)<<8)+lx]=(unsigned short)f2bs(geluf(cs)*cav+center);
  }
}

// ---------------- K_FDW: ffn depthwise (E bf16) + gelu gate -> bf16 out ----------------
#define EST 260
__global__ __launch_bounds__(256) void k_ffn_dw_t(const unsigned short* __restrict__ E,
    const float* __restrict__ dwf, unsigned short* __restrict__ g){
  __shared__ unsigned short sE1[18*EST];
  __shared__ unsigned short sE2[18*EST];
  __shared__ float k1[9], k2[9];
  int bid=blockIdx.x; int b=bid>>10, c=(bid>>4)&63, sy=bid&15;
  int y0=sy*16;
  int tid=threadIdx.x;
  if(tid<9){ k1[tid]=dwf[c*9+tid]; k2[tid]=dwf[(64+c)*9+tid]; }
  if(tid<144){
    int pl=tid/72; int rem=tid-pl*72; int rr=rem>>2; int cc=rem&3;
    int col=(cc<2)? cc : (256+cc);
    if(pl==0) sE1[rr*EST+col]=0; else sE2[rr*EST+col]=0;
  }
  const unsigned short* p1=E+(((size_t)(b*128+c))<<16);
  const unsigned short* p2=E+(((size_t)(b*128+64+c))<<16);
  int half=tid>>7, t2=tid&127;
  const unsigned short* pp = half? p2 : p1;
  for(int r=0;r<18;r++){
    int gy=y0-1+r;
    unsigned val=0;
    if((unsigned)gy<256u) val=*(const unsigned*)(pp+(gy<<8)+t2*2);
    unsigned short* dst = half? sE2 : sE1;
    *(unsigned*)(dst + r*EST + 2 + t2*2) = val;
  }
  __syncthreads();
  unsigned short* op=g+(((size_t)(b*64+c))<<16);
  int lx=tid;
  #pragma unroll 4
  for(int ly=0;ly<16;ly++){
    float a1=0.f, a2=0.f;
    #pragma unroll
    for(int dy=0;dy<3;dy++)
      #pragma unroll
      for(int dx=0;dx<3;dx++){
        int idx=(ly+dy)*EST + lx+dx+1;
        a1+=us2f(sE1[idx])*k1[dy*3+dx];
        a2+=us2f(sE2[idx])*k2[dy*3+dx];
      }
    op[((y0+ly)<<8)+lx]=(unsigned short)f2bs(geluf(a1)*a2);
  }
}

extern "C" void kernel_launch(void* const* d_in, const int* in_sizes, int n_in,
                              void* d_out, int out_size, void* d_ws, size_t ws_size,
                              hipStream_t stream){
  (void)in_sizes; (void)n_in; (void)out_size; (void)ws_size;
  const void* x  = d_in[0];
  const void* Wm1= d_in[23];
  const void* Wm2= d_in[25];

  char* ws=(char*)d_ws;
  // Slot A [0,64MiB):    v (f32) -> E (bf16, 128ch)         [v dead after route]
  // Slot B [64,128MiB):  img (bf16) -> x1b (bf16)           [img dead after dwfuse]
  // Slot C [128,192MiB): xwb (bf16) -> outb (bf16) -> gbuf (bf16)
  // [192MiB..~211MiB):   small buffers
  // [220MiB,252MiB):     vw (bf16, window-major unmasked v)
  float* v    =(float*)(ws);
  unsigned short* E=(unsigned short*)(ws);
  unsigned short* img=(unsigned short*)(ws+67108864);
  unsigned short* x1b=(unsigned short*)(ws+67108864);
  unsigned short* xwb=(unsigned short*)(ws+134217728);
  unsigned short* outb=(unsigned short*)(ws+134217728);
  unsigned short* gbuf=(unsigned short*)(ws+134217728);
  unsigned short* vw =(unsigned short*)(ws+230686720);
  char* sm = ws+201326592;
  float* x_    =(float*)(sm);              // 16 MB
  unsigned short* sa_w=(unsigned short*)(sm+16777216); // 0.5 MB
  float* xm    =(float*)(sm+17825792);     // 1 MB
  float* var   =(float*)(sm+18874368);     // 16 KB
  float* mbin  =(float*)(sm+18890752);     // 16 KB
  float* h0    =(float*)(sm+18907136);     // 8 KB
  float* h1    =(float*)(sm+18915328);     // 8 KB
  float* m0    =(float*)(sm+18923520);     // 16 KB
  float* m1    =(float*)(sm+18939904);     // 16 KB
  float* capart=(float*)(sm+18956288);     // 64 KB
  float* ca    =(float*)(sm+19021824);     // 1 KB
  int*   flag  =(int*)  (sm+19022848);     // 4 B
  float* wbuf  =(float*)(sm+19023872);     // ~161 KB
  short* Wqb   =(short*)(sm+19200000);     // 8 KB
  short* Wkb   =(short*)(sm+19208192);     // 8 KB
  float* m0T   =(float*)(sm+19216384);     // 16 KB
  float* m1T   =(float*)(sm+19232768);     // 16 KB
  short* Wob   =(short*)(sm+19249152);     // 8 KB
  short* Wfib  =(short*)(sm+19257344);     // 16 KB
  short* Wfob  =(short*)(sm+19273728);     // 8 KB

  static const int din_idx[31]={5,6,7,8,9,10,11,12,13,14,15,16,17,18,19,20,21,22,24,26,27,28,29,30,31,32,33,1,2,3,4};
  static const int szs[31]  ={4096,64,4096,64,4096,64,576,64,576,64,4096,64,1024,16,1024,16,16,16,2048,4096,1024,64,144,1,8192,1152,4096,64,64,64,64};
  CvtArgs ca_args;
  int off=0;
  int offs[31];
  for(int t=0;t<31;t++){
    ca_args.src[t]=d_in[din_idx[t]];
    ca_args.sz[t]=szs[t];
    ca_args.off[t]=off;
    offs[t]=off;
    off+=szs[t];
  }
  const float* Wv  =wbuf+offs[0];  const float* bv  =wbuf+offs[1];
  const float* Wq  =wbuf+offs[2];  const float* bq  =wbuf+offs[3];
  const float* Wk  =wbuf+offs[4];  const float* bk  =wbuf+offs[5];
  const float* dw1 =wbuf+offs[6];  const float* dwb1=wbuf+offs[7];
  const float* dw2 =wbuf+offs[8];  const float* dwb2=wbuf+offs[9];
  const float* Wo  =wbuf+offs[10]; const float* bo  =wbuf+offs[11];
  const float* W_in=wbuf+offs[12]; const float* b_in=wbuf+offs[13];
  const float* Wc  =wbuf+offs[14]; const float* bc  =wbuf+offs[15];
  const float* lnw =wbuf+offs[16]; const float* lnb =wbuf+offs[17];
  const float* bm1 =wbuf+offs[18]; const float* bm2 =wbuf+offs[19];
  const float* Wca =wbuf+offs[20]; const float* bca =wbuf+offs[21];
  const float* Wsa =wbuf+offs[22]; const float* bsa =wbuf+offs[23];
  const float* Wfi =wbuf+offs[24]; const float* dwf =wbuf+offs[25];
  const float* Wfo =wbuf+offs[26];
  const float* wn1 =wbuf+offs[27]; const float* bn1 =wbuf+offs[28];
  const float* wn2 =wbuf+offs[29]; const float* bn2 =wbuf+offs[30];

  hipLaunchKernelGGL(k_detect,   dim3(1),      dim3(256), 0, stream, x, flag);
  hipLaunchKernelGGL(k_cvt,      dim3(31),     dim3(256), 0, stream, ca_args, flag, wbuf);
  hipLaunchKernelGGL(k_w2b5,     dim3(32),     dim3(256), 0, stream, Wq, Wk, Wo, Wfi, Wfo, Wqb, Wkb, Wob, Wfib, Wfob);
  hipLaunchKernelGGL(k_conv_vw,  dim3(256,4),  dim3(256), 0, stream, x, Wv, bv, v, vw, flag);
  hipLaunchKernelGGL(k_route,    dim3(512),    dim3(256), 0, stream, v, W_in, b_in, Wc, bc, lnw, lnb, x_, xm, capart);
  hipLaunchKernelGGL(k_sa,       dim3(1024),   dim3(256), 0, stream, x_, Wsa, bsa, sa_w);
  hipLaunchKernelGGL(k_var,      dim3(4096),   dim3(64),  0, stream, xm, var);
  hipLaunchKernelGGL(k_rank,     dim3(16),     dim3(256), 0, stream, var, mbin);
  hipLaunchKernelGGL(k_hvec,     dim3(2048),   dim3(64),  0, stream, Wm1, bm1, h0, h1, flag);
  hipLaunchKernelGGL(k_mask,     dim3(4096),   dim3(64),  0, stream, Wm2, bm2, h0, h1, m0, m1, m0T, m1T, flag);
  hipLaunchKernelGGL(k_ca,       dim3(4),      dim3(64),  0, stream, capart, Wca, bca, ca);
  hipLaunchKernelGGL(k_pack_x,   dim3(2048),   dim3(256), 0, stream, x, mbin, m0T, m1T, flag, xwb);
  hipLaunchKernelGGL(k_attn_mfma,dim3(4096),   dim3(256), 0, stream, xwb, vw, sa_w, mbin, m0T, m1T, Wqb, bq, Wkb, bk, img);
  hipLaunchKernelGGL(k_dwfuse,   dim3(8192),   dim3(256), 0, stream, img, dw1, dwb1, dw2, dwb2, ca, outb);
  // x1b = bf16(LN1(x + Wo*outb + bo))   (MFMA + fused LN)
  hipLaunchKernelGGL(k_gemm_ln,  dim3(4096),   dim3(256), 0, stream, outb, Wob, bo, 1, x, wn1, bn1, (void*)x1b, flag, 0, 2);
  // E = bf16(Wfi * x1b)  (MFMA)
  hipLaunchKernelGGL(k_gemm_mf,  dim3(4096),   dim3(256), 0, stream, (const void*)x1b, 0, Wfib, wbuf, 0, (void*)E, 128, 1);
  hipLaunchKernelGGL(k_ffn_dw_t, dim3(4096),   dim3(256), 0, stream, E, dwf, gbuf);
  // out = LN2(x1b + Wfo*gbuf)  (MFMA + fused LN)
  hipLaunchKernelGGL(k_gemm_ln,  dim3(4096),   dim3(256), 0, stream, gbuf, Wfob, wbuf, 0, (const void*)x1b, wn2, bn2, d_out, flag, 2, 0);
}

// Round 14
// 535.463 us; speedup vs baseline: 3.4264x; 1.0551x over previous
//
#include <hip/hip_runtime.h>
#include <hip/hip_bf16.h>

typedef __hip_bfloat16 bf16;
typedef __attribute__((ext_vector_type(8))) short short8v;
typedef __attribute__((ext_vector_type(4))) float f32x4;

#define DEV static __device__ __forceinline__

DEV float b2f(bf16 h){ return __bfloat162float(h); }
DEV float us2f(unsigned short u){ unsigned v=((unsigned)u)<<16; float f; __builtin_memcpy(&f,&v,4); return f; }
DEV short f2bs(float f){ bf16 h=__float2bfloat16(f); short s; __builtin_memcpy(&s,&h,2); return s; }
DEV unsigned pack2(float a, float b){ return ((unsigned)(unsigned short)f2bs(b)<<16)|(unsigned short)f2bs(a); }
DEV float lrelu(float x){ return x >= 0.f ? x : 0.1f*x; }
DEV float geluf(float x){ return 0.5f*x*(1.f + erff(x*0.70710678118654752440f)); }
DEV float sigmoidf(float x){ return 1.f/(1.f + expf(-x)); }

// B=4, C=64, H=W=256, HW=65536, WS=8, N=1024 windows/batch, embed=4096

// ---------------- K0a: detect storage dtype ----------------
__global__ __launch_bounds__(256) void k_detect(const void* x, int* flag){
  __shared__ int cnt;
  if(threadIdx.x==0) cnt=0;
  __syncthreads();
  const unsigned short* up=(const unsigned short*)x;
  int c=0;
  for(int k=0;k<16;k++){
    unsigned short u=up[(threadIdx.x*16+k)*2];
    if(((u>>7)&0xFF)==0xFF) c++;
  }
  atomicAdd(&cnt,c);
  __syncthreads();
  if(threadIdx.x==0) flag[0] = (cnt>0) ? 1 : 0;  // 1 => f32 storage
}

// ---------------- K0b: convert small weights to f32 wbuf ----------------
struct CvtArgs { const void* src[31]; int sz[31]; int off[31]; };
__global__ __launch_bounds__(256) void k_cvt(CvtArgs a, const int* fl, float* wbuf){
  int t=blockIdx.x; int n=a.sz[t]; const void* s=a.src[t]; float* d=wbuf+a.off[t];
  if(fl[0]){
    const float* sp=(const float*)s;
    for(int i=threadIdx.x;i<n;i+=256) d[i]=sp[i];
  } else {
    const bf16* sp=(const bf16*)s;
    for(int i=threadIdx.x;i<n;i+=256) d[i]=b2f(sp[i]);
  }
}

// ---------------- K0c: Wq/Wk/Wo/Wfi/Wfo/Wv -> bf16 for MFMA ----------------
__global__ __launch_bounds__(256) void k_w2b6(const float* __restrict__ wq, const float* __restrict__ wk,
    const float* __restrict__ wo, const float* __restrict__ wfi, const float* __restrict__ wfo,
    const float* __restrict__ wv,
    short* __restrict__ Wqb, short* __restrict__ Wkb,
    short* __restrict__ Wob, short* __restrict__ Wfib, short* __restrict__ Wfob,
    short* __restrict__ Wvb){
  int i=blockIdx.x*256+threadIdx.x;
  if(i<4096){ Wqb[i]=f2bs(wq[i]); Wkb[i]=f2bs(wk[i]); Wob[i]=f2bs(wo[i]); Wfob[i]=f2bs(wfo[i]); Wvb[i]=f2bs(wv[i]); }
  if(i<8192) Wfib[i]=f2bs(wfi[i]);
}

// ---------------- K0e: compose routing weights (f32): Wa=W_in*Wv, ba=W_in*bv+b_in ----------------
__global__ __launch_bounds__(256) void k_wcomp(const float* __restrict__ W_in, const float* __restrict__ b_in,
    const float* __restrict__ Wc, const float* __restrict__ bc,
    const float* __restrict__ Wv, const float* __restrict__ bv,
    float* __restrict__ Wa, float* __restrict__ ba,
    float* __restrict__ Wb2, float* __restrict__ bb2){
  int t=threadIdx.x;
  #pragma unroll
  for(int ii=0;ii<4;ii++){
    int idx=t+ii*256;          // 1024 elements
    int i=idx>>6, c=idx&63;
    float sa=0.f, sb=0.f;
    for(int k=0;k<64;k++){
      float wv=Wv[k*64+c];
      sa+=W_in[i*64+k]*wv;
      sb+=Wc[i*64+k]*wv;
    }
    Wa[idx]=sa; Wb2[idx]=sb;
  }
  if(t<16){
    float sa=0.f, sb=0.f;
    for(int k=0;k<64;k++){ sa+=W_in[t*64+k]*bv[k]; sb+=Wc[t*64+k]*bv[k]; }
    ba[t]=sa+b_in[t]; bb2[t]=sb+bc[t];
  }
}

// ---------------- K1: v = Wv x + bv via MFMA -> window-major bf16 vw only ----------------
__global__ __launch_bounds__(256) void k_convv_mf(
    const void* __restrict__ in, const int* __restrict__ fl,
    const short* __restrict__ Wvb, const float* __restrict__ bv,
    unsigned short* __restrict__ vw){
  __shared__ short Ain[64*72];
  int tid=threadIdx.x;
  int g0=blockIdx.x*64; int b=g0>>16, p0=g0&65535;
  int c=tid>>2, q=tid&3;
  size_t base=(((size_t)(b*64+c))<<16) + p0;
  if(fl[0]){
    const float* ip=(const float*)in + base;
    #pragma unroll
    for(int j=0;j<4;j++){
      int po=q*16+j*4;
      float4 xv=*(const float4*)(ip+po);
      Ain[(po+0)*72+c]=f2bs(xv.x); Ain[(po+1)*72+c]=f2bs(xv.y);
      Ain[(po+2)*72+c]=f2bs(xv.z); Ain[(po+3)*72+c]=f2bs(xv.w);
    }
  } else {
    const unsigned short* ip=(const unsigned short*)in + base;
    #pragma unroll
    for(int j=0;j<4;j++){
      int po=q*16+j*4;
      uint2 u=*(const uint2*)(ip+po);
      Ain[(po+0)*72+c]=(short)(u.x&0xffff); Ain[(po+1)*72+c]=(short)(u.x>>16);
      Ain[(po+2)*72+c]=(short)(u.y&0xffff); Ain[(po+3)*72+c]=(short)(u.y>>16);
    }
  }
  __syncthreads();
  int lane=tid&63, wid=tid>>6;
  int lr=lane&15, lg=lane>>4;
  int pix0=wid*16;
  short8v bfrag[2];
  #pragma unroll
  for(int ks=0;ks<2;ks++) bfrag[ks]=*(const short8v*)&Ain[(pix0+lr)*72 + ks*32 + lg*8];
  int y=p0>>8;
  int xx=(p0&255)+pix0+lr;
  int n=((y>>3)<<5)|(xx>>3), tok=((y&7)<<3)|(xx&7);
  unsigned short* wp=vw + (((size_t)(b*1024+n))<<12) + tok;
  #pragma unroll
  for(int nt=0;nt<4;nt++){
    f32x4 acc;
    #pragma unroll
    for(int r=0;r<4;r++) acc[r]=bv[nt*16+lg*4+r];
    #pragma unroll
    for(int ks=0;ks<2;ks++){
      short8v afrag=*(const short8v*)(Wvb + (nt*16+lr)*64 + ks*32 + lg*8);
      acc=__builtin_amdgcn_mfma_f32_16x16x32_bf16(afrag,bfrag[ks],acc,0,0,0);
    }
    #pragma unroll
    for(int r=0;r<4;r++){
      int m=nt*16+lg*4+r;
      wp[(size_t)m*64]=(unsigned short)f2bs(acc[r]);
    }
  }
}

// ---------------- K_GM: MFMA 1x1-conv GEMM (ffn_in): D = W * in ----------------
__global__ __launch_bounds__(256) void k_gemm_mf(
    const void* __restrict__ in, int in_f32,
    const short* __restrict__ Wb, const float* __restrict__ bias, int has_bias,
    void* __restrict__ out, int och, int out_bf16){
  __shared__ short Ain[64*72];
  int tid=threadIdx.x;
  int g0=blockIdx.x*64; int b=g0>>16, p0=g0&65535;
  int c=tid>>2, q=tid&3;
  size_t base=(((size_t)(b*64+c))<<16) + p0;
  if(in_f32){
    const float* ip=(const float*)in + base;
    #pragma unroll
    for(int j=0;j<4;j++){
      int po=q*16+j*4;
      float4 xv=*(const float4*)(ip+po);
      Ain[(po+0)*72+c]=f2bs(xv.x); Ain[(po+1)*72+c]=f2bs(xv.y);
      Ain[(po+2)*72+c]=f2bs(xv.z); Ain[(po+3)*72+c]=f2bs(xv.w);
    }
  } else {
    const unsigned short* ip=(const unsigned short*)in + base;
    #pragma unroll
    for(int j=0;j<4;j++){
      int po=q*16+j*4;
      uint2 u=*(const uint2*)(ip+po);
      Ain[(po+0)*72+c]=(short)(u.x&0xffff); Ain[(po+1)*72+c]=(short)(u.x>>16);
      Ain[(po+2)*72+c]=(short)(u.y&0xffff); Ain[(po+3)*72+c]=(short)(u.y>>16);
    }
  }
  __syncthreads();
  int lane=tid&63, wid=tid>>6;
  int lr=lane&15, lg=lane>>4;
  int pix0=wid*16;
  short8v bfrag[2];
  #pragma unroll
  for(int ks=0;ks<2;ks++) bfrag[ks]=*(const short8v*)&Ain[(pix0+lr)*72 + ks*32 + lg*8];
  int ntn=och>>4;
  for(int nt=0;nt<ntn;nt++){
    f32x4 acc;
    if(has_bias){
      #pragma unroll
      for(int r=0;r<4;r++) acc[r]=bias[nt*16+lg*4+r];
    } else {
      acc=(f32x4){0.f,0.f,0.f,0.f};
    }
    #pragma unroll
    for(int ks=0;ks<2;ks++){
      short8v afrag=*(const short8v*)(Wb + (nt*16+lr)*64 + ks*32 + lg*8);
      acc=__builtin_amdgcn_mfma_f32_16x16x32_bf16(afrag,bfrag[ks],acc,0,0,0);
    }
    if(out_bf16){
      unsigned short* op=(unsigned short*)out;
      #pragma unroll
      for(int r=0;r<4;r++){
        int m=nt*16+lg*4+r;
        op[(((size_t)(b*och+m))<<16) + p0 + pix0 + lr]=(unsigned short)f2bs(acc[r]);
      }
    } else {
      float* op=(float*)out;
      #pragma unroll
      for(int r=0;r<4;r++){
        int m=nt*16+lg*4+r;
        op[(((size_t)(b*och+m))<<16) + p0 + pix0 + lr]=acc[r];
      }
    }
  }
}

// ---------------- K_GL: MFMA GEMM (64 och) + residual-add + LayerNorm fused ----------------
// base_mode/out_mode: 0=follow flag, 1=force f32, 2=force bf16
__global__ __launch_bounds__(256) void k_gemm_ln(
    const unsigned short* __restrict__ in,
    const short* __restrict__ Wb, const float* __restrict__ bias, int has_bias,
    const void* __restrict__ basex,
    const float* __restrict__ lnw, const float* __restrict__ lnb,
    void* __restrict__ out,
    const int* __restrict__ fl, int base_mode, int out_mode){
  __shared__ short Ain[64*72];
  int tid=threadIdx.x;
  int g0=blockIdx.x*64; int b=g0>>16, p0=g0&65535;
  int c=tid>>2, q=tid&3;
  {
    const unsigned short* ip=in + (((size_t)(b*64+c))<<16) + p0;
    #pragma unroll
    for(int j=0;j<4;j++){
      int po=q*16+j*4;
      uint2 u=*(const uint2*)(ip+po);
      Ain[(po+0)*72+c]=(short)(u.x&0xffff); Ain[(po+1)*72+c]=(short)(u.x>>16);
      Ain[(po+2)*72+c]=(short)(u.y&0xffff); Ain[(po+3)*72+c]=(short)(u.y>>16);
    }
  }
  __syncthreads();
  int lane=tid&63, wid=tid>>6;
  int lr=lane&15, lg=lane>>4;
  int pix0=wid*16;
  short8v bfrag[2];
  #pragma unroll
  for(int ks=0;ks<2;ks++) bfrag[ks]=*(const short8v*)&Ain[(pix0+lr)*72 + ks*32 + lg*8];
  float rl[16];
  #pragma unroll
  for(int nt=0;nt<4;nt++){
    f32x4 acc;
    if(has_bias){
      #pragma unroll
      for(int r=0;r<4;r++) acc[r]=bias[nt*16+lg*4+r];
    } else {
      acc=(f32x4){0.f,0.f,0.f,0.f};
    }
    #pragma unroll
    for(int ks=0;ks<2;ks++){
      short8v afrag=*(const short8v*)(Wb + (nt*16+lr)*64 + ks*32 + lg*8);
      acc=__builtin_amdgcn_mfma_f32_16x16x32_bf16(afrag,bfrag[ks],acc,0,0,0);
    }
    #pragma unroll
    for(int r=0;r<4;r++) rl[nt*4+r]=acc[r];
  }
  int pix=p0+pix0+lr;
  bool bf32 = (base_mode==1) || (base_mode==0 && fl[0]);
  if(bf32){
    const float* xp=(const float*)basex;
    #pragma unroll
    for(int nt=0;nt<4;nt++)
      #pragma unroll
      for(int r=0;r<4;r++)
        rl[nt*4+r]+=xp[(((size_t)(b*64+nt*16+lg*4+r))<<16)+pix];
  } else {
    const unsigned short* xp=(const unsigned short*)basex;
    #pragma unroll
    for(int nt=0;nt<4;nt++)
      #pragma unroll
      for(int r=0;r<4;r++)
        rl[nt*4+r]+=us2f(xp[(((size_t)(b*64+nt*16+lg*4+r))<<16)+pix]);
  }
  float s=0.f;
  #pragma unroll
  for(int i=0;i<16;i++) s+=rl[i];
  s+=__shfl_xor(s,16); s+=__shfl_xor(s,32);
  float mean=s*(1.f/64.f);
  float qv=0.f;
  #pragma unroll
  for(int i=0;i<16;i++){ float d=rl[i]-mean; qv+=d*d; }
  qv+=__shfl_xor(qv,16); qv+=__shfl_xor(qv,32);
  float inv=1.f/sqrtf(qv*(1.f/64.f)+1e-6f);
  bool of32 = (out_mode==1) || (out_mode==0 && fl[0]);
  if(of32){
    float* op=(float*)out;
    #pragma unroll
    for(int nt=0;nt<4;nt++)
      #pragma unroll
      for(int r=0;r<4;r++){
        int m=nt*16+lg*4+r;
        op[(((size_t)(b*64+m))<<16)+pix]=lnw[m]*((rl[nt*4+r]-mean)*inv)+lnb[m];
      }
  } else {
    unsigned short* op=(unsigned short*)out;
    #pragma unroll
    for(int nt=0;nt<4;nt++)
      #pragma unroll
      for(int r=0;r<4;r++){
        int m=nt*16+lg*4+r;
        op[(((size_t)(b*64+m))<<16)+pix]=(unsigned short)f2bs(lnw[m]*((rl[nt*4+r]-mean)*inv)+lnb[m]);
      }
  }
}

// ---------------- K2: route from x with composed weights (2 pix/thread, f32) ----------------
__global__ __launch_bounds__(256) void k_route(const void* __restrict__ x, const int* __restrict__ fl,
    const float* __restrict__ Wa, const float* __restrict__ ba,
    const float* __restrict__ Wb2, const float* __restrict__ bb2,
    const float* __restrict__ lnw, const float* __restrict__ lnb,
    float* __restrict__ x_, float* __restrict__ xm, float* __restrict__ capart){
  __shared__ float wA[1024], wB[1024], sba[16], sbb[16], slw[16], slb[16];
  __shared__ float sred[4][16];
  int tid=threadIdx.x;
  for(int i=tid;i<1024;i+=256){ wA[i]=Wa[i]; wB[i]=Wb2[i]; }
  if(tid<16){ sba[tid]=ba[tid]; sbb[tid]=bb2[tid]; slw[tid]=lnw[tid]; slb[tid]=lnb[tid]; }
  __syncthreads();
  int g=blockIdx.x*512+tid*2; int b=g>>16, p=g&65535;
  float2 aA[16], aB[16];
  #pragma unroll
  for(int i=0;i<16;i++){ aA[i]=make_float2(sba[i],sba[i]); aB[i]=make_float2(sbb[i],sbb[i]); }
  size_t base=(((size_t)b*64)<<16)+p;
  if(fl[0]){
    const float* vp=(const float*)x+base;
    for(int c=0;c<64;c++){
      float2 vv=*(const float2*)(vp+(((size_t)c)<<16));
      #pragma unroll
      for(int i=0;i<16;i++){
        float wa=wA[(i<<6)+c], wb=wB[(i<<6)+c];
        aA[i].x+=wa*vv.x; aA[i].y+=wa*vv.y;
        aB[i].x+=wb*vv.x; aB[i].y+=wb*vv.y;
      }
    }
  } else {
    const unsigned short* vp=(const unsigned short*)x+base;
    for(int c=0;c<64;c++){
      unsigned u=*(const unsigned*)(vp+(((size_t)c)<<16));
      float v0=us2f(u&0xffff), v1=us2f(u>>16);
      #pragma unroll
      for(int i=0;i<16;i++){
        float wa=wA[(i<<6)+c], wb=wB[(i<<6)+c];
        aA[i].x+=wa*v0; aA[i].y+=wa*v1;
        aB[i].x+=wb*v0; aB[i].y+=wb*v1;
      }
    }
  }
  float s0=0.f,s1=0.f;
  #pragma unroll
  for(int i=0;i<16;i++){ aA[i].x=lrelu(aA[i].x); aA[i].y=lrelu(aA[i].y); s0+=aA[i].x; s1+=aA[i].y; }
  float2 xmst; xmst.x=s0*(1.f/16.f); xmst.y=s1*(1.f/16.f);
  *(float2*)(xm+g)=xmst;
  float u0=0.f,u1=0.f;
  #pragma unroll
  for(int i=0;i<16;i++){ u0+=aB[i].x; u1+=aB[i].y; }
  u0*=(1.f/16.f); u1*=(1.f/16.f);
  float q0=0.f,q1=0.f;
  #pragma unroll
  for(int i=0;i<16;i++){ float d0=aB[i].x-u0, d1=aB[i].y-u1; q0+=d0*d0; q1+=d1*d1; }
  q0*=(1.f/16.f); q1*=(1.f/16.f);
  float i0=1.f/sqrtf(q0+1e-6f), i1=1.f/sqrtf(q1+1e-6f);
  float red[16];
  float* xp=x_+(((size_t)b*16)<<16)+p;
  #pragma unroll
  for(int i=0;i<16;i++){
    float xv0=lrelu(slw[i]*((aB[i].x-u0)*i0)+slb[i]);
    float xv1=lrelu(slw[i]*((aB[i].y-u1)*i1)+slb[i]);
    float2 st; st.x=xv0; st.y=xv1;
    *(float2*)(xp+(((size_t)i)<<16))=st;
    red[i]=xv0+xv1;
  }
  int lane=tid&63, wid=tid>>6;
  #pragma unroll
  for(int i=0;i<16;i++){
    float val=red[i];
    for(int m=32;m>0;m>>=1) val+=__shfl_xor(val,m);
    if(lane==0) sred[wid][i]=val;
  }
  __syncthreads();
  if(tid<16) capart[blockIdx.x*16+tid]=sred[0][tid]+sred[1][tid]+sred[2][tid]+sred[3][tid];
}

// ---------------- K3: sa = sigmoid(conv3x3(x_)) -> window-major bf16 ----------------
__global__ __launch_bounds__(256) void k_sa(const float* __restrict__ x_,
    const float* __restrict__ Wsa, const float* __restrict__ bsa, unsigned short* __restrict__ sa_w){
  __shared__ float w[144]; __shared__ float bb;
  int tid=threadIdx.x;
  if(tid<144) w[tid]=Wsa[tid];
  if(tid==0) bb=bsa[0];
  __syncthreads();
  int pix=blockIdx.x*256+tid; int b=pix>>16, p=pix&65535;
  int y=p>>8, xx=p&255;
  float acc=bb;
  #pragma unroll
  for(int i=0;i<16;i++){
    const float* pl=x_+(((size_t)(b*16+i))<<16);
    #pragma unroll
    for(int ky=0;ky<3;ky++){
      int yy=y+ky-1;
      if((unsigned)yy<256u){
        #pragma unroll
        for(int kx=0;kx<3;kx++){
          int x2=xx+kx-1;
          if((unsigned)x2<256u) acc+=pl[(yy<<8)+x2]*w[i*9+ky*3+kx];
        }
      }
    }
  }
  int n=((y>>3)<<5)|(xx>>3), tok=((y&7)<<3)|(xx&7);
  sa_w[(((size_t)(b<<10)+n)<<6)+tok]=(unsigned short)f2bs(sigmoidf(acc));
}

// ---------------- K4: per-window variance (ddof=1) ----------------
__global__ __launch_bounds__(64) void k_var(const float* __restrict__ xm, float* __restrict__ var){
  int blk=blockIdx.x, tid=threadIdx.x;
  int b=blk>>10, n=blk&1023;
  int pix=((n>>5)<<11) + ((n&31)<<3) + ((tid>>3)<<8) + (tid&7);
  float val=xm[(b<<16)+pix];
  float s=val;
  for(int m=32;m>0;m>>=1) s+=__shfl_xor(s,m);
  float mean=s*(1.f/64.f);
  float d=val-mean; float q=d*d;
  for(int m=32;m>0;m>>=1) q+=__shfl_xor(q,m);
  if(tid==0) var[blk]=q*(1.f/63.f);
}

// ---------------- K5: rank -> mbin ----------------
__global__ __launch_bounds__(256) void k_rank(const float* __restrict__ var, float* __restrict__ mbin){
  __shared__ float va[1024];
  int bid=blockIdx.x; int b=bid>>2, seg=bid&3;
  int tid=threadIdx.x;
  for(int i=tid;i<1024;i+=256) va[i]=var[(b<<10)+i];
  __syncthreads();
  int n=seg*256+tid;
  float vn=va[n]; int r=0;
  for(int m=0;m<1024;m++){ float vm=va[m]; r += (vm<vn) || (vm==vn && m<n); }
  mbin[(b<<10)+n] = (r<512)?0.f:1.f;
}

// ---------------- K6: h0/h1 from Wm1 rowsums ----------------
__global__ __launch_bounds__(64) void k_hvec(const void* __restrict__ Wm1, const float* __restrict__ bm1,
    float* __restrict__ h0, float* __restrict__ h1, const int* __restrict__ fl){
  int j=blockIdx.x, tid=threadIdx.x;
  float s=0.f;
  if(fl[0]){
    const float* row=(const float*)Wm1+((size_t)j<<12);
    for(int k=tid;k<4096;k+=64) s+=row[k];
  } else {
    const bf16* row=(const bf16*)Wm1+((size_t)j<<12);
    for(int k=tid;k<4096;k+=64) s+=b2f(row[k]);
  }
  for(int m=32;m>0;m>>=1) s+=__shfl_xor(s,m);
  if(tid==0){ float bb=bm1[j]; h0[j]=lrelu(bb); h1[j]=lrelu(bb+s); }
}

// ---------------- K7: mask vectors (+ transposed copies) ----------------
__global__ __launch_bounds__(64) void k_mask(const void* __restrict__ Wm2, const float* __restrict__ bm2,
    const float* __restrict__ h0, const float* __restrict__ h1,
    float* __restrict__ m0, float* __restrict__ m1,
    float* __restrict__ m0T, float* __restrict__ m1T, const int* __restrict__ fl){
  int e=blockIdx.x, tid=threadIdx.x;
  float p0=0.f,p1=0.f;
  if(fl[0]){
    const float* row=(const float*)Wm2+((size_t)e<<11);
    for(int j=tid;j<2048;j+=64){ float w=row[j]; p0+=w*h0[j]; p1+=w*h1[j]; }
  } else {
    const bf16* row=(const bf16*)Wm2+((size_t)e<<11);
    for(int j=tid;j<2048;j+=64){ float w=b2f(row[j]); p0+=w*h0[j]; p1+=w*h1[j]; }
  }
  for(int m=32;m>0;m>>=1){ p0+=__shfl_xor(p0,m); p1+=__shfl_xor(p1,m); }
  if(tid==0){
    float bb=bm2[e]; float v0=p0+bb, v1=p1+bb;
    m0[e]=v0; m1[e]=v1;
    int te=(e&63)*64+(e>>6);
    m0T[te]=v0; m1T[te]=v1;
  }
}

// ---------------- K8: ca = sigmoid(Wca * mean(x_) + bca) ----------------
__global__ __launch_bounds__(64) void k_ca(const float* __restrict__ capart,
    const float* __restrict__ Wca, const float* __restrict__ bca, float* __restrict__ ca){
  __shared__ float m[16];
  int b=blockIdx.x, tid=threadIdx.x;
  if(tid<16){
    float s=0.f;
    for(int blk=0;blk<128;blk++) s+=capart[((b*128)+blk)*16+tid];
    m[tid]=s*(1.f/65536.f);
  }
  __syncthreads();
  float a=bca[tid];
  #pragma unroll
  for(int i=0;i<16;i++) a+=Wca[(tid<<4)+i]*m[i];
  ca[(b<<6)+tid]=sigmoidf(a);
}

// ---------------- K_PX: xwb = bf16(x * mask) window-major (single rounding) ----------------
__global__ __launch_bounds__(256) void k_pack_x(const void* __restrict__ x,
    const float* __restrict__ mbin, const float* __restrict__ m0T, const float* __restrict__ m1T,
    const int* __restrict__ fl, unsigned short* __restrict__ xwb){
  int wp=blockIdx.x; int b=wp>>9, np=wp&511;
  int n0=np*2;
  int base=((n0>>5)<<11)+((n0&31)<<3);
  int t=threadIdx.x; int c0=t>>3, row=t&7;
  int isf32=fl[0];
  const float* mTa = (mbin[b*1024+n0  ]>0.5f)? m1T : m0T;
  const float* mTb = (mbin[b*1024+n0+1]>0.5f)? m1T : m0T;
  for(int h=0;h<2;h++){
    int ch=c0+h*32;
    size_t gb=(((size_t)(b*64+ch))<<16) + base + row*256;
    float xv[16];
    if(isf32){
      const float* xp=(const float*)x+gb;
      #pragma unroll
      for(int i=0;i<16;i++) xv[i]=xp[i];
    } else {
      const bf16* xp=(const bf16*)x+gb;
      #pragma unroll
      for(int i=0;i<16;i++) xv[i]=b2f(xp[i]);
    }
    size_t o0=((size_t)(b*1024+n0)*64+ch)*64 + row*8;
    #pragma unroll
    for(int wnd=0;wnd<2;wnd++){
      const float* mT = wnd? mTb : mTa;
      size_t oo=o0+(size_t)wnd*4096;
      int s=wnd*8;
      float mk[8];
      #pragma unroll
      for(int j=0;j<8;j++) mk[j]=mT[ch*64+row*8+j];
      uint4 ux;
      ux.x=pack2(xv[s+0]*mk[0],xv[s+1]*mk[1]); ux.y=pack2(xv[s+2]*mk[2],xv[s+3]*mk[3]);
      ux.z=pack2(xv[s+4]*mk[4],xv[s+5]*mk[5]); ux.w=pack2(xv[s+6]*mk[6],xv[s+7]*mk[7]);
      *(uint4*)(xwb+oo)=ux;
    }
  }
}

// ---------------- K9: windowed attention via MFMA -> img (bf16) ----------------
#define STR 72
#define STRF 65
__global__ __launch_bounds__(256,4) void k_attn_mfma(
    const unsigned short* __restrict__ xwb, const unsigned short* __restrict__ vw,
    const unsigned short* __restrict__ sa_w, const float* __restrict__ mbin,
    const float* __restrict__ m0T, const float* __restrict__ m1T,
    const short* __restrict__ Wqb, const float* __restrict__ bq,
    const short* __restrict__ Wkb, const float* __restrict__ bk,
    unsigned short* __restrict__ img){
  __shared__ short sT[64*STR];
  __shared__ short sQK[2*64*STR];
  __shared__ short sV1[64*STR];
  __shared__ float ssa[64];
  short* sQ=sQK; short* sK=sQK+64*STR;
  float* sF=(float*)sQK;
  int tid=threadIdx.x, blk=blockIdx.x;
  int b=blk>>10, n=blk&1023;
  int base=((n>>5)<<11) + ((n&31)<<3);
  size_t plane=((size_t)b*64)<<16;
  const float* mT = (mbin[blk]>0.5f)? m1T : m0T;
  const unsigned short* xw=xwb+(size_t)blk*4096;
  const unsigned short* vw2=vw+(size_t)blk*4096;
  if(tid<64) ssa[tid]=us2f(sa_w[((size_t)blk<<6)+tid]);
  for(int e=tid;e<4096;e+=256){
    int c=e>>6, tok=e&63;
    sT[tok*STR+c]=(short)xw[e];
    sV1[c*STR+tok]=f2bs(us2f(vw2[e])*mT[e]);
  }
  __syncthreads();
  int lane=tid&63, wid=tid>>6;
  int pb=wid*16, lr=lane&15, lg=lane>>4;
  short8v ta[2];
  #pragma unroll
  for(int ks=0;ks<2;ks++) ta[ks]=*(const short8v*)&sT[(pb+lr)*STR + ks*32 + lg*8];
  #pragma unroll
  for(int nt=0;nt<4;nt++){
    float bqv=bq[nt*16+lr], bkv=bk[nt*16+lr];
    f32x4 qa={bqv,bqv,bqv,bqv}, ka={bkv,bkv,bkv,bkv};
    #pragma unroll
    for(int ks=0;ks<2;ks++){
      short8v wq=*(const short8v*)(Wqb + (nt*16+lr)*64 + ks*32 + lg*8);
      short8v wk=*(const short8v*)(Wkb + (nt*16+lr)*64 + ks*32 + lg*8);
      qa=__builtin_amdgcn_mfma_f32_16x16x32_bf16(ta[ks],wq,qa,0,0,0);
      ka=__builtin_amdgcn_mfma_f32_16x16x32_bf16(ta[ks],wk,ka,0,0,0);
    }
    #pragma unroll
    for(int r=0;r<4;r++){
      sQ[(pb+lg*4+r)*STR + nt*16+lr]=f2bs(qa[r]);
      sK[(pb+lg*4+r)*STR + nt*16+lr]=f2bs(ka[r]);
    }
  }
  __syncthreads();
  short8v qa2[2];
  #pragma unroll
  for(int ks=0;ks<2;ks++) qa2[ks]=*(const short8v*)&sQ[(pb+lr)*STR + ks*32 + lg*8];
  f32x4 sacc[4];
  #pragma unroll
  for(int nt=0;nt<4;nt++){
    f32x4 a={0.f,0.f,0.f,0.f};
    #pragma unroll
    for(int ks=0;ks<2;ks++){
      short8v kb=*(const short8v*)&sK[(nt*16+lr)*STR + ks*32 + lg*8];
      a=__builtin_amdgcn_mfma_f32_16x16x32_bf16(qa2[ks],kb,a,0,0,0);
    }
    sacc[nt]=a;
  }
  f32x4 pa[4];
  #pragma unroll
  for(int r=0;r<4;r++){
    float mx=fmaxf(fmaxf(sacc[0][r],sacc[1][r]),fmaxf(sacc[2][r],sacc[3][r]));
    #pragma unroll
    for(int m=1;m<16;m<<=1) mx=fmaxf(mx,__shfl_xor(mx,m));
    float e0=__expf(sacc[0][r]-mx), e1=__expf(sacc[1][r]-mx);
    float e2=__expf(sacc[2][r]-mx), e3=__expf(sacc[3][r]-mx);
    float sum=e0+e1+e2+e3;
    #pragma unroll
    for(int m=1;m<16;m<<=1) sum+=__shfl_xor(sum,m);
    float inv=1.f/sum;
    pa[0][r]=e0*inv; pa[1][r]=e1*inv; pa[2][r]=e2*inv; pa[3][r]=e3*inv;
  }
  #pragma unroll
  for(int nt=0;nt<4;nt++){
    #pragma unroll
    for(int r=0;r<4;r++)
      sT[(pb+lg*4+r)*STR + nt*16+lr]=f2bs(pa[nt][r]);
  }
  __syncthreads();
  short8v aa[2];
  #pragma unroll
  for(int ks=0;ks<2;ks++) aa[ks]=*(const short8v*)&sT[(pb+lr)*STR + ks*32 + lg*8];
  #pragma unroll
  for(int nt=0;nt<4;nt++){
    f32x4 f={0.f,0.f,0.f,0.f};
    #pragma unroll
    for(int ks=0;ks<2;ks++){
      short8v vb=*(const short8v*)&sV1[(nt*16+lr)*STR + ks*32 + lg*8];
      f=__builtin_amdgcn_mfma_f32_16x16x32_bf16(aa[ks],vb,f,0,0,0);
    }
    #pragma unroll
    for(int r=0;r<4;r++) sF[(pb+lg*4+r)*STRF + nt*16+lr]=f[r];
  }
  __syncthreads();
  for(int e2=tid;e2<2048;e2+=256){
    int c=e2>>5, tp=e2&31; int tok=tp*2;
    float f0=sF[tok*STRF+c], f1=sF[(tok+1)*STRF+c];
    unsigned uv=*(const unsigned*)(vw2 + c*64 + tok);
    float mk0=mT[c*64+tok], mk1=mT[c*64+tok+1];
    float vs0=us2f(uv&0xffff)*ssa[tok]*(1.f-mk0);
    float vs1=us2f(uv>>16)*ssa[tok+1]*(1.f-mk1);
    int pix=base+((tok>>3)<<8)+(tok&7);
    *(unsigned*)(img+plane+(((size_t)c)<<16)+pix)=pack2(f0+vs0, f1+vs1);
  }
}

// ---------------- K_DWF: fused depthwise dil1+dil2+gelu*ca+img (bf16 in/out), 8-row strips ----------------
#define IST 264
__global__ __launch_bounds__(256) void k_dwfuse(const unsigned short* __restrict__ img,
    const float* __restrict__ dw1w, const float* __restrict__ dwb1,
    const float* __restrict__ dw2w, const float* __restrict__ dwb2,
    const float* __restrict__ ca, unsigned short* __restrict__ outb){
  __shared__ float sImg[14*IST];
  __shared__ float sTmp[12*IST];
  __shared__ float k1[9], k2[9];
  __shared__ float bb1, bb2, cav;
  int bid=blockIdx.x; int b=bid>>11, c=(bid>>5)&63, sy=bid&31;
  int y0=sy*8;
  int tid=threadIdx.x;
  if(tid<9){ k1[tid]=dw1w[c*9+tid]; k2[tid]=dw2w[c*9+tid]; }
  if(tid==9)  bb1=dwb1[c];
  if(tid==10) bb2=dwb2[c];
  if(tid==11) cav=ca[b*64+c];
  const unsigned short* ip=img+(((size_t)(b*64+c))<<16);
  for(int i=tid;i<14*IST;i+=256){
    int r=i/IST, cl=i-r*IST;
    int gy=y0-3+r, gx=cl-3;
    float v=0.f;
    if(cl<262 && (unsigned)gy<256u && (unsigned)gx<256u) v=us2f(ip[(gy<<8)+gx]);
    sImg[i]=v;
  }
  __syncthreads();
  for(int i=tid;i<12*IST;i+=256){
    int r=i/IST, cl=i-r*IST;
    float t=0.f;
    if(cl<260){
      int ty=y0-2+r, tc=cl-2;
      if((unsigned)ty<256u && (unsigned)tc<256u){
        t=bb1;
        #pragma unroll
        for(int dy=0;dy<3;dy++)
          #pragma unroll
          for(int dx=0;dx<3;dx++)
            t+=sImg[(r+dy)*IST+(cl+dx)]*k1[dy*3+dx];
      }
    }
    sTmp[i]=t;
  }
  __syncthreads();
  unsigned short* op=outb+(((size_t)(b*64+c))<<16);
  int lx=tid;
  #pragma unroll
  for(int ly=0;ly<8;ly++){
    float cs=bb2;
    #pragma unroll
    for(int dy=0;dy<3;dy++)
      #pragma unroll
      for(int dx=0;dx<3;dx++)
        cs+=sTmp[(ly+2*dy)*IST + lx+2*dx]*k2[dy*3+dx];
    float center=sImg[(ly+3)*IST + lx+3];
    op[((y0+ly)<<8)+lx]=(unsigned short)f2bs(geluf(cs)*cav+center);
  }
}

// ---------------- K_FDW: ffn depthwise (E bf16) + gelu gate -> bf16 out ----------------
#define EST 260
__global__ __launch_bounds__(256) void k_ffn_dw_t(const unsigned short* __restrict__ E,
    const float* __restrict__ dwf, unsigned short* __restrict__ g){
  __shared__ unsigned short sE1[18*EST];
  __shared__ unsigned short sE2[18*EST];
  __shared__ float k1[9], k2[9];
  int bid=blockIdx.x; int b=bid>>10, c=(bid>>4)&63, sy=bid&15;
  int y0=sy*16;
  int tid=threadIdx.x;
  if(tid<9){ k1[tid]=dwf[c*9+tid]; k2[tid]=dwf[(64+c)*9+tid]; }
  if(tid<144){
    int pl=tid/72; int rem=tid-pl*72; int rr=rem>>2; int cc=rem&3;
    int col=(cc<2)? cc : (256+cc);
    if(pl==0) sE1[rr*EST+col]=0; else sE2[rr*EST+col]=0;
  }
  const unsigned short* p1=E+(((size_t)(b*128+c))<<16);
  const unsigned short* p2=E+(((size_t)(b*128+64+c))<<16);
  int half=tid>>7, t2=tid&127;
  const unsigned short* pp = half? p2 : p1;
  for(int r=0;r<18;r++){
    int gy=y0-1+r;
    unsigned val=0;
    if((unsigned)gy<256u) val=*(const unsigned*)(pp+(gy<<8)+t2*2);
    unsigned short* dst = half? sE2 : sE1;
    *(unsigned*)(dst + r*EST + 2 + t2*2) = val;
  }
  __syncthreads();
  unsigned short* op=g+(((size_t)(b*64+c))<<16);
  int lx=tid;
  #pragma unroll 4
  for(int ly=0;ly<16;ly++){
    float a1=0.f, a2=0.f;
    #pragma unroll
    for(int dy=0;dy<3;dy++)
      #pragma unroll
      for(int dx=0;dx<3;dx++){
        int idx=(ly+dy)*EST + lx+dx+1;
        a1+=us2f(sE1[idx])*k1[dy*3+dx];
        a2+=us2f(sE2[idx])*k2[dy*3+dx];
      }
    op[((y0+ly)<<8)+lx]=(unsigned short)f2bs(geluf(a1)*a2);
  }
}

extern "C" void kernel_launch(void* const* d_in, const int* in_sizes, int n_in,
                              void* d_out, int out_size, void* d_ws, size_t ws_size,
                              hipStream_t stream){
  (void)in_sizes; (void)n_in; (void)out_size; (void)ws_size;
  const void* x  = d_in[0];
  const void* Wm1= d_in[23];
  const void* Wm2= d_in[25];

  char* ws=(char*)d_ws;
  // Slot A [0,64MiB):    E (bf16, 128ch)
  // Slot B [64,128MiB):  img (bf16) -> x1b (bf16)
  // Slot C [128,192MiB): xwb (bf16) -> outb (bf16) -> gbuf (bf16)
  // [192MiB..~211MiB):   small buffers
  // [220MiB,252MiB):     vw (bf16, window-major unmasked v)
  unsigned short* E=(unsigned short*)(ws);
  unsigned short* img=(unsigned short*)(ws+67108864);
  unsigned short* x1b=(unsigned short*)(ws+67108864);
  unsigned short* xwb=(unsigned short*)(ws+134217728);
  unsigned short* outb=(unsigned short*)(ws+134217728);
  unsigned short* gbuf=(unsigned short*)(ws+134217728);
  unsigned short* vw =(unsigned short*)(ws+230686720);
  char* sm = ws+201326592;
  float* x_    =(float*)(sm);              // 16 MB
  unsigned short* sa_w=(unsigned short*)(sm+16777216); // 0.5 MB
  float* xm    =(float*)(sm+17825792);     // 1 MB
  float* var   =(float*)(sm+18874368);     // 16 KB
  float* mbin  =(float*)(sm+18890752);     // 16 KB
  float* h0    =(float*)(sm+18907136);     // 8 KB
  float* h1    =(float*)(sm+18915328);     // 8 KB
  float* m0    =(float*)(sm+18923520);     // 16 KB
  float* m1    =(float*)(sm+18939904);     // 16 KB
  float* capart=(float*)(sm+18956288);     // 64 KB
  float* ca    =(float*)(sm+19021824);     // 1 KB
  int*   flag  =(int*)  (sm+19022848);     // 4 B
  float* wbuf  =(float*)(sm+19023872);     // ~161 KB
  short* Wqb   =(short*)(sm+19200000);     // 8 KB
  short* Wkb   =(short*)(sm+19208192);     // 8 KB
  float* m0T   =(float*)(sm+19216384);     // 16 KB
  float* m1T   =(float*)(sm+19232768);     // 16 KB
  short* Wob   =(short*)(sm+19249152);     // 8 KB
  short* Wfib  =(short*)(sm+19257344);     // 16 KB
  short* Wfob  =(short*)(sm+19273728);     // 8 KB
  short* Wvb   =(short*)(sm+19281920);     // 8 KB
  float* WaC   =(float*)(sm+19290112);     // 4 KB
  float* WbC   =(float*)(sm+19294208);     // 4 KB
  float* baC   =(float*)(sm+19298304);     // 64 B
  float* bbC   =(float*)(sm+19298560);     // 64 B

  static const int din_idx[31]={5,6,7,8,9,10,11,12,13,14,15,16,17,18,19,20,21,22,24,26,27,28,29,30,31,32,33,1,2,3,4};
  static const int szs[31]  ={4096,64,4096,64,4096,64,576,64,576,64,4096,64,1024,16,1024,16,16,16,2048,4096,1024,64,144,1,8192,1152,4096,64,64,64,64};
  CvtArgs ca_args;
  int off=0;
  int offs[31];
  for(int t=0;t<31;t++){
    ca_args.src[t]=d_in[din_idx[t]];
    ca_args.sz[t]=szs[t];
    ca_args.off[t]=off;
    offs[t]=off;
    off+=szs[t];
  }
  const float* Wv  =wbuf+offs[0];  const float* bv  =wbuf+offs[1];
  const float* Wq  =wbuf+offs[2];  const float* bq  =wbuf+offs[3];
  const float* Wk  =wbuf+offs[4];  const float* bk  =wbuf+offs[5];
  const float* dw1 =wbuf+offs[6];  const float* dwb1=wbuf+offs[7];
  const float* dw2 =wbuf+offs[8];  const float* dwb2=wbuf+offs[9];
  const float* Wo  =wbuf+offs[10]; const float* bo  =wbuf+offs[11];
  const float* W_in=wbuf+offs[12]; const float* b_in=wbuf+offs[13];
  const float* Wc  =wbuf+offs[14]; const float* bc  =wbuf+offs[15];
  const float* lnw =wbuf+offs[16]; const float* lnb =wbuf+offs[17];
  const float* bm1 =wbuf+offs[18]; const float* bm2 =wbuf+offs[19];
  const float* Wca =wbuf+offs[20]; const float* bca =wbuf+offs[21];
  const float* Wsa =wbuf+offs[22]; const float* bsa =wbuf+offs[23];
  const float* Wfi =wbuf+offs[24]; const float* dwf =wbuf+offs[25];
  const float* Wfo =wbuf+offs[26];
  const float* wn1 =wbuf+offs[27]; const float* bn1 =wbuf+offs[28];
  const float* wn2 =wbuf+offs[29]; const float* bn2 =wbuf+offs[30];

  hipLaunchKernelGGL(k_detect,   dim3(1),      dim3(256), 0, stream, x, flag);
  hipLaunchKernelGGL(k_cvt,      dim3(31),     dim3(256), 0, stream, ca_args, flag, wbuf);
  hipLaunchKernelGGL(k_w2b6,     dim3(32),     dim3(256), 0, stream, Wq, Wk, Wo, Wfi, Wfo, Wv, Wqb, Wkb, Wob, Wfib, Wfob, Wvb);
  hipLaunchKernelGGL(k_wcomp,    dim3(1),      dim3(256), 0, stream, W_in, b_in, Wc, bc, Wv, bv, WaC, baC, WbC, bbC);
  // vw = bf16(Wv x + bv), window-major (MFMA)
  hipLaunchKernelGGL(k_convv_mf, dim3(4096),   dim3(256), 0, stream, x, flag, Wvb, bv, vw);
  // routing path from x with composed f32 weights
  hipLaunchKernelGGL(k_route,    dim3(512),    dim3(256), 0, stream, x, flag, WaC, baC, WbC, bbC, lnw, lnb, x_, xm, capart);
  hipLaunchKernelGGL(k_sa,       dim3(1024),   dim3(256), 0, stream, x_, Wsa, bsa, sa_w);
  hipLaunchKernelGGL(k_var,      dim3(4096),   dim3(64),  0, stream, xm, var);
  hipLaunchKernelGGL(k_rank,     dim3(16),     dim3(256), 0, stream, var, mbin);
  hipLaunchKernelGGL(k_hvec,     dim3(2048),   dim3(64),  0, stream, Wm1, bm1, h0, h1, flag);
  hipLaunchKernelGGL(k_mask,     dim3(4096),   dim3(64),  0, stream, Wm2, bm2, h0, h1, m0, m1, m0T, m1T, flag);
  hipLaunchKernelGGL(k_ca,       dim3(4),      dim3(64),  0, stream, capart, Wca, bca, ca);
  hipLaunchKernelGGL(k_pack_x,   dim3(2048),   dim3(256), 0, stream, x, mbin, m0T, m1T, flag, xwb);
  hipLaunchKernelGGL(k_attn_mfma,dim3(4096),   dim3(256), 0, stream, xwb, vw, sa_w, mbin, m0T, m1T, Wqb, bq, Wkb, bk, img);
  hipLaunchKernelGGL(k_dwfuse,   dim3(8192),   dim3(256), 0, stream, img, dw1, dwb1, dw2, dwb2, ca, outb);
  // x1b = bf16(LN1(x + Wo*outb + bo))   (MFMA + fused LN)
  hipLaunchKernelGGL(k_gemm_ln,  dim3(4096),   dim3(256), 0, stream, outb, Wob, bo, 1, x, wn1, bn1, (void*)x1b, flag, 0, 2);
  // E = bf16(Wfi * x1b)  (MFMA)
  hipLaunchKernelGGL(k_gemm_mf,  dim3(4096),   dim3(256), 0, stream, (const void*)x1b, 0, Wfib, wbuf, 0, (void*)E, 128, 1);
  hipLaunchKernelGGL(k_ffn_dw_t, dim3(4096),   dim3(256), 0, stream, E, dwf, gbuf);
  // out = LN2(x1b + Wfo*gbuf)  (MFMA + fused LN)
  hipLaunchKernelGGL(k_gemm_ln,  dim3(4096),   dim3(256), 0, stream, gbuf, Wfob, wbuf, 0, (const void*)x1b, wn2, bn2, d_out, flag, 2, 0);
}

// Round 15
// 505.144 us; speedup vs baseline: 3.6321x; 1.0600x over previous
//
#include <hip/hip_runtime.h>
#include <hip/hip_bf16.h>

typedef __hip_bfloat16 bf16;
typedef __attribute__((ext_vector_type(8))) short short8v;
typedef __attribute__((ext_vector_type(4))) float f32x4;

#define DEV static __device__ __forceinline__

DEV float b2f(bf16 h){ return __bfloat162float(h); }
DEV float us2f(unsigned short u){ unsigned v=((unsigned)u)<<16; float f; __builtin_memcpy(&f,&v,4); return f; }
DEV short f2bs(float f){ bf16 h=__float2bfloat16(f); short s; __builtin_memcpy(&s,&h,2); return s; }
DEV unsigned pack2(float a, float b){ return ((unsigned)(unsigned short)f2bs(b)<<16)|(unsigned short)f2bs(a); }
DEV float lrelu(float x){ return x >= 0.f ? x : 0.1f*x; }
DEV float geluf(float x){ return 0.5f*x*(1.f + erff(x*0.70710678118654752440f)); }
DEV float sigmoidf(float x){ return 1.f/(1.f + expf(-x)); }

// B=4, C=64, H=W=256, HW=65536, WS=8, N=1024 windows/batch, embed=4096

// ---------------- K0a: detect storage dtype ----------------
__global__ __launch_bounds__(256) void k_detect(const void* x, int* flag){
  __shared__ int cnt;
  if(threadIdx.x==0) cnt=0;
  __syncthreads();
  const unsigned short* up=(const unsigned short*)x;
  int c=0;
  for(int k=0;k<16;k++){
    unsigned short u=up[(threadIdx.x*16+k)*2];
    if(((u>>7)&0xFF)==0xFF) c++;
  }
  atomicAdd(&cnt,c);
  __syncthreads();
  if(threadIdx.x==0) flag[0] = (cnt>0) ? 1 : 0;  // 1 => f32 storage
}

// ---------------- K0b: convert small weights to f32 wbuf ----------------
struct CvtArgs { const void* src[31]; int sz[31]; int off[31]; };
__global__ __launch_bounds__(256) void k_cvt(CvtArgs a, const int* fl, float* wbuf){
  int t=blockIdx.x; int n=a.sz[t]; const void* s=a.src[t]; float* d=wbuf+a.off[t];
  if(fl[0]){
    const float* sp=(const float*)s;
    for(int i=threadIdx.x;i<n;i+=256) d[i]=sp[i];
  } else {
    const bf16* sp=(const bf16*)s;
    for(int i=threadIdx.x;i<n;i+=256) d[i]=b2f(sp[i]);
  }
}

// ---------------- K0c: Wq/Wk/Wo/Wfi/Wfo/Wv -> bf16 for MFMA ----------------
__global__ __launch_bounds__(256) void k_w2b6(const float* __restrict__ wq, const float* __restrict__ wk,
    const float* __restrict__ wo, const float* __restrict__ wfi, const float* __restrict__ wfo,
    const float* __restrict__ wv,
    short* __restrict__ Wqb, short* __restrict__ Wkb,
    short* __restrict__ Wob, short* __restrict__ Wfib, short* __restrict__ Wfob,
    short* __restrict__ Wvb){
  int i=blockIdx.x*256+threadIdx.x;
  if(i<4096){ Wqb[i]=f2bs(wq[i]); Wkb[i]=f2bs(wk[i]); Wob[i]=f2bs(wo[i]); Wfob[i]=f2bs(wfo[i]); Wvb[i]=f2bs(wv[i]); }
  if(i<8192) Wfib[i]=f2bs(wfi[i]);
}

// ---------------- K0e: compose routing weights (f32): Wa=W_in*Wv, ba=W_in*bv+b_in ----------------
__global__ __launch_bounds__(256) void k_wcomp(const float* __restrict__ W_in, const float* __restrict__ b_in,
    const float* __restrict__ Wc, const float* __restrict__ bc,
    const float* __restrict__ Wv, const float* __restrict__ bv,
    float* __restrict__ Wa, float* __restrict__ ba,
    float* __restrict__ Wb2, float* __restrict__ bb2){
  int t=threadIdx.x;
  #pragma unroll
  for(int ii=0;ii<4;ii++){
    int idx=t+ii*256;
    int i=idx>>6, c=idx&63;
    float sa=0.f, sb=0.f;
    for(int k=0;k<64;k++){
      float wv=Wv[k*64+c];
      sa+=W_in[i*64+k]*wv;
      sb+=Wc[i*64+k]*wv;
    }
    Wa[idx]=sa; Wb2[idx]=sb;
  }
  if(t<16){
    float sa=0.f, sb=0.f;
    for(int k=0;k<64;k++){ sa+=W_in[t*64+k]*bv[k]; sb+=Wc[t*64+k]*bv[k]; }
    ba[t]=sa+b_in[t]; bb2[t]=sb+bc[t];
  }
}

// ---------------- K1: v = Wv x + bv via MFMA -> window-major bf16 vw only ----------------
__global__ __launch_bounds__(256) void k_convv_mf(
    const void* __restrict__ in, const int* __restrict__ fl,
    const short* __restrict__ Wvb, const float* __restrict__ bv,
    unsigned short* __restrict__ vw){
  __shared__ short Ain[64*72];
  int tid=threadIdx.x;
  int g0=blockIdx.x*64; int b=g0>>16, p0=g0&65535;
  int c=tid>>2, q=tid&3;
  size_t base=(((size_t)(b*64+c))<<16) + p0;
  if(fl[0]){
    const float* ip=(const float*)in + base;
    #pragma unroll
    for(int j=0;j<4;j++){
      int po=q*16+j*4;
      float4 xv=*(const float4*)(ip+po);
      Ain[(po+0)*72+c]=f2bs(xv.x); Ain[(po+1)*72+c]=f2bs(xv.y);
      Ain[(po+2)*72+c]=f2bs(xv.z); Ain[(po+3)*72+c]=f2bs(xv.w);
    }
  } else {
    const unsigned short* ip=(const unsigned short*)in + base;
    #pragma unroll
    for(int j=0;j<4;j++){
      int po=q*16+j*4;
      uint2 u=*(const uint2*)(ip+po);
      Ain[(po+0)*72+c]=(short)(u.x&0xffff); Ain[(po+1)*72+c]=(short)(u.x>>16);
      Ain[(po+2)*72+c]=(short)(u.y&0xffff); Ain[(po+3)*72+c]=(short)(u.y>>16);
    }
  }
  __syncthreads();
  int lane=tid&63, wid=tid>>6;
  int lr=lane&15, lg=lane>>4;
  int pix0=wid*16;
  short8v bfrag[2];
  #pragma unroll
  for(int ks=0;ks<2;ks++) bfrag[ks]=*(const short8v*)&Ain[(pix0+lr)*72 + ks*32 + lg*8];
  int y=p0>>8;
  int xx=(p0&255)+pix0+lr;
  int n=((y>>3)<<5)|(xx>>3), tok=((y&7)<<3)|(xx&7);
  unsigned short* wp=vw + (((size_t)(b*1024+n))<<12) + tok;
  #pragma unroll
  for(int nt=0;nt<4;nt++){
    f32x4 acc;
    #pragma unroll
    for(int r=0;r<4;r++) acc[r]=bv[nt*16+lg*4+r];
    #pragma unroll
    for(int ks=0;ks<2;ks++){
      short8v afrag=*(const short8v*)(Wvb + (nt*16+lr)*64 + ks*32 + lg*8);
      acc=__builtin_amdgcn_mfma_f32_16x16x32_bf16(afrag,bfrag[ks],acc,0,0,0);
    }
    #pragma unroll
    for(int r=0;r<4;r++){
      int m=nt*16+lg*4+r;
      wp[(size_t)m*64]=(unsigned short)f2bs(acc[r]);
    }
  }
}

// ---------------- K_GM: MFMA 1x1-conv GEMM (ffn_in): D = W * in ----------------
__global__ __launch_bounds__(256) void k_gemm_mf(
    const void* __restrict__ in, int in_f32,
    const short* __restrict__ Wb, const float* __restrict__ bias, int has_bias,
    void* __restrict__ out, int och, int out_bf16){
  __shared__ short Ain[64*72];
  int tid=threadIdx.x;
  int g0=blockIdx.x*64; int b=g0>>16, p0=g0&65535;
  int c=tid>>2, q=tid&3;
  size_t base=(((size_t)(b*64+c))<<16) + p0;
  if(in_f32){
    const float* ip=(const float*)in + base;
    #pragma unroll
    for(int j=0;j<4;j++){
      int po=q*16+j*4;
      float4 xv=*(const float4*)(ip+po);
      Ain[(po+0)*72+c]=f2bs(xv.x); Ain[(po+1)*72+c]=f2bs(xv.y);
      Ain[(po+2)*72+c]=f2bs(xv.z); Ain[(po+3)*72+c]=f2bs(xv.w);
    }
  } else {
    const unsigned short* ip=(const unsigned short*)in + base;
    #pragma unroll
    for(int j=0;j<4;j++){
      int po=q*16+j*4;
      uint2 u=*(const uint2*)(ip+po);
      Ain[(po+0)*72+c]=(short)(u.x&0xffff); Ain[(po+1)*72+c]=(short)(u.x>>16);
      Ain[(po+2)*72+c]=(short)(u.y&0xffff); Ain[(po+3)*72+c]=(short)(u.y>>16);
    }
  }
  __syncthreads();
  int lane=tid&63, wid=tid>>6;
  int lr=lane&15, lg=lane>>4;
  int pix0=wid*16;
  short8v bfrag[2];
  #pragma unroll
  for(int ks=0;ks<2;ks++) bfrag[ks]=*(const short8v*)&Ain[(pix0+lr)*72 + ks*32 + lg*8];
  int ntn=och>>4;
  for(int nt=0;nt<ntn;nt++){
    f32x4 acc;
    if(has_bias){
      #pragma unroll
      for(int r=0;r<4;r++) acc[r]=bias[nt*16+lg*4+r];
    } else {
      acc=(f32x4){0.f,0.f,0.f,0.f};
    }
    #pragma unroll
    for(int ks=0;ks<2;ks++){
      short8v afrag=*(const short8v*)(Wb + (nt*16+lr)*64 + ks*32 + lg*8);
      acc=__builtin_amdgcn_mfma_f32_16x16x32_bf16(afrag,bfrag[ks],acc,0,0,0);
    }
    if(out_bf16){
      unsigned short* op=(unsigned short*)out;
      #pragma unroll
      for(int r=0;r<4;r++){
        int m=nt*16+lg*4+r;
        op[(((size_t)(b*och+m))<<16) + p0 + pix0 + lr]=(unsigned short)f2bs(acc[r]);
      }
    } else {
      float* op=(float*)out;
      #pragma unroll
      for(int r=0;r<4;r++){
        int m=nt*16+lg*4+r;
        op[(((size_t)(b*och+m))<<16) + p0 + pix0 + lr]=acc[r];
      }
    }
  }
}

// ---------------- K_GL: MFMA GEMM (64 och) + residual-add + LayerNorm fused ----------------
// base_mode/out_mode: 0=follow flag, 1=force f32, 2=force bf16
__global__ __launch_bounds__(256) void k_gemm_ln(
    const unsigned short* __restrict__ in,
    const short* __restrict__ Wb, const float* __restrict__ bias, int has_bias,
    const void* __restrict__ basex,
    const float* __restrict__ lnw, const float* __restrict__ lnb,
    void* __restrict__ out,
    const int* __restrict__ fl, int base_mode, int out_mode){
  __shared__ short Ain[64*72];
  int tid=threadIdx.x;
  int g0=blockIdx.x*64; int b=g0>>16, p0=g0&65535;
  int c=tid>>2, q=tid&3;
  {
    const unsigned short* ip=in + (((size_t)(b*64+c))<<16) + p0;
    #pragma unroll
    for(int j=0;j<4;j++){
      int po=q*16+j*4;
      uint2 u=*(const uint2*)(ip+po);
      Ain[(po+0)*72+c]=(short)(u.x&0xffff); Ain[(po+1)*72+c]=(short)(u.x>>16);
      Ain[(po+2)*72+c]=(short)(u.y&0xffff); Ain[(po+3)*72+c]=(short)(u.y>>16);
    }
  }
  __syncthreads();
  int lane=tid&63, wid=tid>>6;
  int lr=lane&15, lg=lane>>4;
  int pix0=wid*16;
  short8v bfrag[2];
  #pragma unroll
  for(int ks=0;ks<2;ks++) bfrag[ks]=*(const short8v*)&Ain[(pix0+lr)*72 + ks*32 + lg*8];
  float rl[16];
  #pragma unroll
  for(int nt=0;nt<4;nt++){
    f32x4 acc;
    if(has_bias){
      #pragma unroll
      for(int r=0;r<4;r++) acc[r]=bias[nt*16+lg*4+r];
    } else {
      acc=(f32x4){0.f,0.f,0.f,0.f};
    }
    #pragma unroll
    for(int ks=0;ks<2;ks++){
      short8v afrag=*(const short8v*)(Wb + (nt*16+lr)*64 + ks*32 + lg*8);
      acc=__builtin_amdgcn_mfma_f32_16x16x32_bf16(afrag,bfrag[ks],acc,0,0,0);
    }
    #pragma unroll
    for(int r=0;r<4;r++) rl[nt*4+r]=acc[r];
  }
  int pix=p0+pix0+lr;
  bool bf32 = (base_mode==1) || (base_mode==0 && fl[0]);
  if(bf32){
    const float* xp=(const float*)basex;
    #pragma unroll
    for(int nt=0;nt<4;nt++)
      #pragma unroll
      for(int r=0;r<4;r++)
        rl[nt*4+r]+=xp[(((size_t)(b*64+nt*16+lg*4+r))<<16)+pix];
  } else {
    const unsigned short* xp=(const unsigned short*)basex;
    #pragma unroll
    for(int nt=0;nt<4;nt++)
      #pragma unroll
      for(int r=0;r<4;r++)
        rl[nt*4+r]+=us2f(xp[(((size_t)(b*64+nt*16+lg*4+r))<<16)+pix]);
  }
  float s=0.f;
  #pragma unroll
  for(int i=0;i<16;i++) s+=rl[i];
  s+=__shfl_xor(s,16); s+=__shfl_xor(s,32);
  float mean=s*(1.f/64.f);
  float qv=0.f;
  #pragma unroll
  for(int i=0;i<16;i++){ float d=rl[i]-mean; qv+=d*d; }
  qv+=__shfl_xor(qv,16); qv+=__shfl_xor(qv,32);
  float inv=1.f/sqrtf(qv*(1.f/64.f)+1e-6f);
  bool of32 = (out_mode==1) || (out_mode==0 && fl[0]);
  if(of32){
    float* op=(float*)out;
    #pragma unroll
    for(int nt=0;nt<4;nt++)
      #pragma unroll
      for(int r=0;r<4;r++){
        int m=nt*16+lg*4+r;
        op[(((size_t)(b*64+m))<<16)+pix]=lnw[m]*((rl[nt*4+r]-mean)*inv)+lnb[m];
      }
  } else {
    unsigned short* op=(unsigned short*)out;
    #pragma unroll
    for(int nt=0;nt<4;nt++)
      #pragma unroll
      for(int r=0;r<4;r++){
        int m=nt*16+lg*4+r;
        op[(((size_t)(b*64+m))<<16)+pix]=(unsigned short)f2bs(lnw[m]*((rl[nt*4+r]-mean)*inv)+lnb[m]);
      }
  }
}

// ---------------- K2: route from x with composed weights (2 pix/thread, f32) ----------------
__global__ __launch_bounds__(256) void k_route(const void* __restrict__ x, const int* __restrict__ fl,
    const float* __restrict__ Wa, const float* __restrict__ ba,
    const float* __restrict__ Wb2, const float* __restrict__ bb2,
    const float* __restrict__ lnw, const float* __restrict__ lnb,
    float* __restrict__ x_, float* __restrict__ xm, float* __restrict__ capart){
  __shared__ float wA[1024], wB[1024], sba[16], sbb[16], slw[16], slb[16];
  __shared__ float sred[4][16];
  int tid=threadIdx.x;
  for(int i=tid;i<1024;i+=256){ wA[i]=Wa[i]; wB[i]=Wb2[i]; }
  if(tid<16){ sba[tid]=ba[tid]; sbb[tid]=bb2[tid]; slw[tid]=lnw[tid]; slb[tid]=lnb[tid]; }
  __syncthreads();
  int g=blockIdx.x*512+tid*2; int b=g>>16, p=g&65535;
  float2 aA[16], aB[16];
  #pragma unroll
  for(int i=0;i<16;i++){ aA[i]=make_float2(sba[i],sba[i]); aB[i]=make_float2(sbb[i],sbb[i]); }
  size_t base=(((size_t)b*64)<<16)+p;
  if(fl[0]){
    const float* vp=(const float*)x+base;
    for(int c=0;c<64;c++){
      float2 vv=*(const float2*)(vp+(((size_t)c)<<16));
      #pragma unroll
      for(int i=0;i<16;i++){
        float wa=wA[(i<<6)+c], wb=wB[(i<<6)+c];
        aA[i].x+=wa*vv.x; aA[i].y+=wa*vv.y;
        aB[i].x+=wb*vv.x; aB[i].y+=wb*vv.y;
      }
    }
  } else {
    const unsigned short* vp=(const unsigned short*)x+base;
    for(int c=0;c<64;c++){
      unsigned u=*(const unsigned*)(vp+(((size_t)c)<<16));
      float v0=us2f(u&0xffff), v1=us2f(u>>16);
      #pragma unroll
      for(int i=0;i<16;i++){
        float wa=wA[(i<<6)+c], wb=wB[(i<<6)+c];
        aA[i].x+=wa*v0; aA[i].y+=wa*v1;
        aB[i].x+=wb*v0; aB[i].y+=wb*v1;
      }
    }
  }
  float s0=0.f,s1=0.f;
  #pragma unroll
  for(int i=0;i<16;i++){ aA[i].x=lrelu(aA[i].x); aA[i].y=lrelu(aA[i].y); s0+=aA[i].x; s1+=aA[i].y; }
  float2 xmst; xmst.x=s0*(1.f/16.f); xmst.y=s1*(1.f/16.f);
  *(float2*)(xm+g)=xmst;
  float u0=0.f,u1=0.f;
  #pragma unroll
  for(int i=0;i<16;i++){ u0+=aB[i].x; u1+=aB[i].y; }
  u0*=(1.f/16.f); u1*=(1.f/16.f);
  float q0=0.f,q1=0.f;
  #pragma unroll
  for(int i=0;i<16;i++){ float d0=aB[i].x-u0, d1=aB[i].y-u1; q0+=d0*d0; q1+=d1*d1; }
  q0*=(1.f/16.f); q1*=(1.f/16.f);
  float i0=1.f/sqrtf(q0+1e-6f), i1=1.f/sqrtf(q1+1e-6f);
  float red[16];
  float* xp=x_+(((size_t)b*16)<<16)+p;
  #pragma unroll
  for(int i=0;i<16;i++){
    float xv0=lrelu(slw[i]*((aB[i].x-u0)*i0)+slb[i]);
    float xv1=lrelu(slw[i]*((aB[i].y-u1)*i1)+slb[i]);
    float2 st; st.x=xv0; st.y=xv1;
    *(float2*)(xp+(((size_t)i)<<16))=st;
    red[i]=xv0+xv1;
  }
  int lane=tid&63, wid=tid>>6;
  #pragma unroll
  for(int i=0;i<16;i++){
    float val=red[i];
    for(int m=32;m>0;m>>=1) val+=__shfl_xor(val,m);
    if(lane==0) sred[wid][i]=val;
  }
  __syncthreads();
  if(tid<16) capart[blockIdx.x*16+tid]=sred[0][tid]+sred[1][tid]+sred[2][tid]+sred[3][tid];
}

// ---------------- K3: sa = sigmoid(conv3x3(x_)) -> window-major bf16 ----------------
__global__ __launch_bounds__(256) void k_sa(const float* __restrict__ x_,
    const float* __restrict__ Wsa, const float* __restrict__ bsa, unsigned short* __restrict__ sa_w){
  __shared__ float w[144]; __shared__ float bb;
  int tid=threadIdx.x;
  if(tid<144) w[tid]=Wsa[tid];
  if(tid==0) bb=bsa[0];
  __syncthreads();
  int pix=blockIdx.x*256+tid; int b=pix>>16, p=pix&65535;
  int y=p>>8, xx=p&255;
  float acc=bb;
  #pragma unroll
  for(int i=0;i<16;i++){
    const float* pl=x_+(((size_t)(b*16+i))<<16);
    #pragma unroll
    for(int ky=0;ky<3;ky++){
      int yy=y+ky-1;
      if((unsigned)yy<256u){
        #pragma unroll
        for(int kx=0;kx<3;kx++){
          int x2=xx+kx-1;
          if((unsigned)x2<256u) acc+=pl[(yy<<8)+x2]*w[i*9+ky*3+kx];
        }
      }
    }
  }
  int n=((y>>3)<<5)|(xx>>3), tok=((y&7)<<3)|(xx&7);
  sa_w[(((size_t)(b<<10)+n)<<6)+tok]=(unsigned short)f2bs(sigmoidf(acc));
}

// ---------------- K4: per-window variance (ddof=1) ----------------
__global__ __launch_bounds__(64) void k_var(const float* __restrict__ xm, float* __restrict__ var){
  int blk=blockIdx.x, tid=threadIdx.x;
  int b=blk>>10, n=blk&1023;
  int pix=((n>>5)<<11) + ((n&31)<<3) + ((tid>>3)<<8) + (tid&7);
  float val=xm[(b<<16)+pix];
  float s=val;
  for(int m=32;m>0;m>>=1) s+=__shfl_xor(s,m);
  float mean=s*(1.f/64.f);
  float d=val-mean; float q=d*d;
  for(int m=32;m>0;m>>=1) q+=__shfl_xor(q,m);
  if(tid==0) var[blk]=q*(1.f/63.f);
}

// ---------------- K5: rank -> mbin ----------------
__global__ __launch_bounds__(256) void k_rank(const float* __restrict__ var, float* __restrict__ mbin){
  __shared__ float va[1024];
  int bid=blockIdx.x; int b=bid>>2, seg=bid&3;
  int tid=threadIdx.x;
  for(int i=tid;i<1024;i+=256) va[i]=var[(b<<10)+i];
  __syncthreads();
  int n=seg*256+tid;
  float vn=va[n]; int r=0;
  for(int m=0;m<1024;m++){ float vm=va[m]; r += (vm<vn) || (vm==vn && m<n); }
  mbin[(b<<10)+n] = (r<512)?0.f:1.f;
}

// ---------------- K6: h0/h1 from Wm1 rowsums ----------------
__global__ __launch_bounds__(64) void k_hvec(const void* __restrict__ Wm1, const float* __restrict__ bm1,
    float* __restrict__ h0, float* __restrict__ h1, const int* __restrict__ fl){
  int j=blockIdx.x, tid=threadIdx.x;
  float s=0.f;
  if(fl[0]){
    const float* row=(const float*)Wm1+((size_t)j<<12);
    for(int k=tid;k<4096;k+=64) s+=row[k];
  } else {
    const bf16* row=(const bf16*)Wm1+((size_t)j<<12);
    for(int k=tid;k<4096;k+=64) s+=b2f(row[k]);
  }
  for(int m=32;m>0;m>>=1) s+=__shfl_xor(s,m);
  if(tid==0){ float bb=bm1[j]; h0[j]=lrelu(bb); h1[j]=lrelu(bb+s); }
}

// ---------------- K7: mask vectors (+ transposed copies) ----------------
__global__ __launch_bounds__(64) void k_mask(const void* __restrict__ Wm2, const float* __restrict__ bm2,
    const float* __restrict__ h0, const float* __restrict__ h1,
    float* __restrict__ m0, float* __restrict__ m1,
    float* __restrict__ m0T, float* __restrict__ m1T, const int* __restrict__ fl){
  int e=blockIdx.x, tid=threadIdx.x;
  float p0=0.f,p1=0.f;
  if(fl[0]){
    const float* row=(const float*)Wm2+((size_t)e<<11);
    for(int j=tid;j<2048;j+=64){ float w=row[j]; p0+=w*h0[j]; p1+=w*h1[j]; }
  } else {
    const bf16* row=(const bf16*)Wm2+((size_t)e<<11);
    for(int j=tid;j<2048;j+=64){ float w=b2f(row[j]); p0+=w*h0[j]; p1+=w*h1[j]; }
  }
  for(int m=32;m>0;m>>=1){ p0+=__shfl_xor(p0,m); p1+=__shfl_xor(p1,m); }
  if(tid==0){
    float bb=bm2[e]; float v0=p0+bb, v1=p1+bb;
    m0[e]=v0; m1[e]=v1;
    int te=(e&63)*64+(e>>6);
    m0T[te]=v0; m1T[te]=v1;
  }
}

// ---------------- K8: ca = sigmoid(Wca * mean(x_) + bca) ----------------
__global__ __launch_bounds__(64) void k_ca(const float* __restrict__ capart,
    const float* __restrict__ Wca, const float* __restrict__ bca, float* __restrict__ ca){
  __shared__ float m[16];
  int b=blockIdx.x, tid=threadIdx.x;
  if(tid<16){
    float s=0.f;
    for(int blk=0;blk<128;blk++) s+=capart[((b*128)+blk)*16+tid];
    m[tid]=s*(1.f/65536.f);
  }
  __syncthreads();
  float a=bca[tid];
  #pragma unroll
  for(int i=0;i<16;i++) a+=Wca[(tid<<4)+i]*m[i];
  ca[(b<<6)+tid]=sigmoidf(a);
}

// ---------------- K_PX: xwb = bf16(x * mask) window-major (single rounding) ----------------
__global__ __launch_bounds__(256) void k_pack_x(const void* __restrict__ x,
    const float* __restrict__ mbin, const float* __restrict__ m0T, const float* __restrict__ m1T,
    const int* __restrict__ fl, unsigned short* __restrict__ xwb){
  int wp=blockIdx.x; int b=wp>>9, np=wp&511;
  int n0=np*2;
  int base=((n0>>5)<<11)+((n0&31)<<3);
  int t=threadIdx.x; int c0=t>>3, row=t&7;
  int isf32=fl[0];
  const float* mTa = (mbin[b*1024+n0  ]>0.5f)? m1T : m0T;
  const float* mTb = (mbin[b*1024+n0+1]>0.5f)? m1T : m0T;
  for(int h=0;h<2;h++){
    int ch=c0+h*32;
    size_t gb=(((size_t)(b*64+ch))<<16) + base + row*256;
    float xv[16];
    if(isf32){
      const float* xp=(const float*)x+gb;
      #pragma unroll
      for(int i=0;i<16;i++) xv[i]=xp[i];
    } else {
      const bf16* xp=(const bf16*)x+gb;
      #pragma unroll
      for(int i=0;i<16;i++) xv[i]=b2f(xp[i]);
    }
    size_t o0=((size_t)(b*1024+n0)*64+ch)*64 + row*8;
    #pragma unroll
    for(int wnd=0;wnd<2;wnd++){
      const float* mT = wnd? mTb : mTa;
      size_t oo=o0+(size_t)wnd*4096;
      int s=wnd*8;
      float mk[8];
      #pragma unroll
      for(int j=0;j<8;j++) mk[j]=mT[ch*64+row*8+j];
      uint4 ux;
      ux.x=pack2(xv[s+0]*mk[0],xv[s+1]*mk[1]); ux.y=pack2(xv[s+2]*mk[2],xv[s+3]*mk[3]);
      ux.z=pack2(xv[s+4]*mk[4],xv[s+5]*mk[5]); ux.w=pack2(xv[s+6]*mk[6],xv[s+7]*mk[7]);
      *(uint4*)(xwb+oo)=ux;
    }
  }
}

// ---------------- K9: windowed attention via MFMA -> img (bf16) ----------------
#define STR 72
#define STRF 65
__global__ __launch_bounds__(256,4) void k_attn_mfma(
    const unsigned short* __restrict__ xwb, const unsigned short* __restrict__ vw,
    const unsigned short* __restrict__ sa_w, const float* __restrict__ mbin,
    const float* __restrict__ m0T, const float* __restrict__ m1T,
    const short* __restrict__ Wqb, const float* __restrict__ bq,
    const short* __restrict__ Wkb, const float* __restrict__ bk,
    unsigned short* __restrict__ img){
  __shared__ short sT[64*STR];
  __shared__ short sQK[2*64*STR];
  __shared__ short sV1[64*STR];
  __shared__ float ssa[64];
  short* sQ=sQK; short* sK=sQK+64*STR;
  float* sF=(float*)sQK;
  int tid=threadIdx.x, blk=blockIdx.x;
  int b=blk>>10, n=blk&1023;
  int base=((n>>5)<<11) + ((n&31)<<3);
  size_t plane=((size_t)b*64)<<16;
  const float* mT = (mbin[blk]>0.5f)? m1T : m0T;
  const unsigned short* xw=xwb+(size_t)blk*4096;
  const unsigned short* vw2=vw+(size_t)blk*4096;
  if(tid<64) ssa[tid]=us2f(sa_w[((size_t)blk<<6)+tid]);
  for(int e=tid;e<4096;e+=256){
    int c=e>>6, tok=e&63;
    sT[tok*STR+c]=(short)xw[e];
    sV1[c*STR+tok]=f2bs(us2f(vw2[e])*mT[e]);
  }
  __syncthreads();
  int lane=tid&63, wid=tid>>6;
  int pb=wid*16, lr=lane&15, lg=lane>>4;
  short8v ta[2];
  #pragma unroll
  for(int ks=0;ks<2;ks++) ta[ks]=*(const short8v*)&sT[(pb+lr)*STR + ks*32 + lg*8];
  #pragma unroll
  for(int nt=0;nt<4;nt++){
    float bqv=bq[nt*16+lr], bkv=bk[nt*16+lr];
    f32x4 qa={bqv,bqv,bqv,bqv}, ka={bkv,bkv,bkv,bkv};
    #pragma unroll
    for(int ks=0;ks<2;ks++){
      short8v wq=*(const short8v*)(Wqb + (nt*16+lr)*64 + ks*32 + lg*8);
      short8v wk=*(const short8v*)(Wkb + (nt*16+lr)*64 + ks*32 + lg*8);
      qa=__builtin_amdgcn_mfma_f32_16x16x32_bf16(ta[ks],wq,qa,0,0,0);
      ka=__builtin_amdgcn_mfma_f32_16x16x32_bf16(ta[ks],wk,ka,0,0,0);
    }
    #pragma unroll
    for(int r=0;r<4;r++){
      sQ[(pb+lg*4+r)*STR + nt*16+lr]=f2bs(qa[r]);
      sK[(pb+lg*4+r)*STR + nt*16+lr]=f2bs(ka[r]);
    }
  }
  __syncthreads();
  short8v qa2[2];
  #pragma unroll
  for(int ks=0;ks<2;ks++) qa2[ks]=*(const short8v*)&sQ[(pb+lr)*STR + ks*32 + lg*8];
  f32x4 sacc[4];
  #pragma unroll
  for(int nt=0;nt<4;nt++){
    f32x4 a={0.f,0.f,0.f,0.f};
    #pragma unroll
    for(int ks=0;ks<2;ks++){
      short8v kb=*(const short8v*)&sK[(nt*16+lr)*STR + ks*32 + lg*8];
      a=__builtin_amdgcn_mfma_f32_16x16x32_bf16(qa2[ks],kb,a,0,0,0);
    }
    sacc[nt]=a;
  }
  f32x4 pa[4];
  #pragma unroll
  for(int r=0;r<4;r++){
    float mx=fmaxf(fmaxf(sacc[0][r],sacc[1][r]),fmaxf(sacc[2][r],sacc[3][r]));
    #pragma unroll
    for(int m=1;m<16;m<<=1) mx=fmaxf(mx,__shfl_xor(mx,m));
    float e0=__expf(sacc[0][r]-mx), e1=__expf(sacc[1][r]-mx);
    float e2=__expf(sacc[2][r]-mx), e3=__expf(sacc[3][r]-mx);
    float sum=e0+e1+e2+e3;
    #pragma unroll
    for(int m=1;m<16;m<<=1) sum+=__shfl_xor(sum,m);
    float inv=1.f/sum;
    pa[0][r]=e0*inv; pa[1][r]=e1*inv; pa[2][r]=e2*inv; pa[3][r]=e3*inv;
  }
  #pragma unroll
  for(int nt=0;nt<4;nt++){
    #pragma unroll
    for(int r=0;r<4;r++)
      sT[(pb+lg*4+r)*STR + nt*16+lr]=f2bs(pa[nt][r]);
  }
  __syncthreads();
  short8v aa[2];
  #pragma unroll
  for(int ks=0;ks<2;ks++) aa[ks]=*(const short8v*)&sT[(pb+lr)*STR + ks*32 + lg*8];
  #pragma unroll
  for(int nt=0;nt<4;nt++){
    f32x4 f={0.f,0.f,0.f,0.f};
    #pragma unroll
    for(int ks=0;ks<2;ks++){
      short8v vb=*(const short8v*)&sV1[(nt*16+lr)*STR + ks*32 + lg*8];
      f=__builtin_amdgcn_mfma_f32_16x16x32_bf16(aa[ks],vb,f,0,0,0);
    }
    #pragma unroll
    for(int r=0;r<4;r++) sF[(pb+lg*4+r)*STRF + nt*16+lr]=f[r];
  }
  __syncthreads();
  for(int e2=tid;e2<2048;e2+=256){
    int c=e2>>5, tp=e2&31; int tok=tp*2;
    float f0=sF[tok*STRF+c], f1=sF[(tok+1)*STRF+c];
    unsigned uv=*(const unsigned*)(vw2 + c*64 + tok);
    float mk0=mT[c*64+tok], mk1=mT[c*64+tok+1];
    float vs0=us2f(uv&0xffff)*ssa[tok]*(1.f-mk0);
    float vs1=us2f(uv>>16)*ssa[tok+1]*(1.f-mk1);
    int pix=base+((tok>>3)<<8)+(tok&7);
    *(unsigned*)(img+plane+(((size_t)c)<<16)+pix)=pack2(f0+vs0, f1+vs1);
  }
}

// ---------------- K_DWF v2: fused dw dil1+dil2+gelu*ca+img, 4-col groups, vector LDS ----------------
#define DWI 264
__global__ __launch_bounds__(256) void k_dwfuse(const unsigned short* __restrict__ img,
    const float* __restrict__ dw1w, const float* __restrict__ dwb1,
    const float* __restrict__ dw2w, const float* __restrict__ dwb2,
    const float* __restrict__ ca, unsigned short* __restrict__ outb){
  __shared__ float sImg[22*DWI];   // rows y0-3..y0+18, slot = gx+4
  __shared__ float sTmp[20*DWI];   // rows y0-2..y0+17, slot = tc+2
  __shared__ float k1[9], k2[9];
  __shared__ float bb1, bb2, cav;
  int bid=blockIdx.x; int b=bid>>10, c=(bid>>4)&63, sy=bid&15;
  int y0=sy*16;
  int tid=threadIdx.x;
  if(tid<9){ k1[tid]=dw1w[c*9+tid]; k2[tid]=dw2w[c*9+tid]; }
  if(tid==9)  bb1=dwb1[c];
  if(tid==10) bb2=dwb2[c];
  if(tid==11) cav=ca[b*64+c];
  const unsigned short* ip=img+(((size_t)(b*64+c))<<16);
  // load: 22 rows x 66 groups of 4 cols (gx0 = 4j-4). Groups never straddle x-border.
  for(int task=tid;task<1452;task+=256){
    int r=task/66, j=task-r*66;
    int gy=y0-3+r, gx0=4*j-4;
    float4 v=make_float4(0.f,0.f,0.f,0.f);
    if((unsigned)gy<256u && j>=1 && j<=64){
      uint2 u=*(const uint2*)(ip+(gy<<8)+gx0);
      v.x=us2f(u.x&0xffff); v.y=us2f(u.x>>16); v.z=us2f(u.y&0xffff); v.w=us2f(u.y>>16);
    }
    *(float4*)&sImg[r*DWI+4*j]=v;
  }
  __syncthreads();
  // sTmp: 20 rows x 65 groups of 4 (tc0 = 4g-2)
  for(int task=tid;task<1300;task+=256){
    int r=task/65, g=task-r*65;
    int ty=y0-2+r, tc0=4*g-2;
    float t[4]={bb1,bb1,bb1,bb1};
    #pragma unroll
    for(int dy=0;dy<3;dy++){
      float4 A0=*(const float4*)&sImg[(r+dy)*DWI+4*g];
      float4 A1=*(const float4*)&sImg[(r+dy)*DWI+4*g+4];
      float F[8]={A0.x,A0.y,A0.z,A0.w,A1.x,A1.y,A1.z,A1.w};
      #pragma unroll
      for(int dx=0;dx<3;dx++){
        float kk=k1[dy*3+dx];
        #pragma unroll
        for(int e=0;e<4;e++) t[e]+=F[1+e+dx]*kk;
      }
    }
    float4 res;
    bool rowok=((unsigned)ty<256u);
    #pragma unroll
    for(int e=0;e<4;e++){
      int tc=tc0+e;
      ((float*)&res)[e]= (rowok && (unsigned)tc<256u)? t[e] : 0.f;
    }
    *(float4*)&sTmp[r*DWI+4*g]=res;
  }
  __syncthreads();
  // out: each thread 4 cols (q) x 4 rows (rr)
  int q=tid&63, rr=tid>>6;
  unsigned short* op=outb+(((size_t)(b*64+c))<<16);
  #pragma unroll
  for(int l4=0;l4<4;l4++){
    int ly=rr*4+l4;
    float cs[4]={bb2,bb2,bb2,bb2};
    #pragma unroll
    for(int dy=0;dy<3;dy++){
      int r=ly+2*dy;
      float4 T0=*(const float4*)&sTmp[r*DWI+4*q];
      float4 T1=*(const float4*)&sTmp[r*DWI+4*q+4];
      float T[8]={T0.x,T0.y,T0.z,T0.w,T1.x,T1.y,T1.z,T1.w};
      #pragma unroll
      for(int dx=0;dx<3;dx++){
        float kk=k2[dy*3+dx];
        #pragma unroll
        for(int e=0;e<4;e++) cs[e]+=T[e+2*dx]*kk;
      }
    }
    float4 C=*(const float4*)&sImg[(ly+3)*DWI+4*q+4];
    float o0=geluf(cs[0])*cav+C.x;
    float o1=geluf(cs[1])*cav+C.y;
    float o2=geluf(cs[2])*cav+C.z;
    float o3=geluf(cs[3])*cav+C.w;
    uint2 u; u.x=pack2(o0,o1); u.y=pack2(o2,o3);
    *(uint2*)(op+((y0+ly)<<8)+4*q)=u;
  }
}

// ---------------- K_FDW v2: ffn depthwise (E bf16) + gelu gate, 4-col groups ----------------
#define FEI 264
__global__ __launch_bounds__(256) void k_ffn_dw_t(const unsigned short* __restrict__ E,
    const float* __restrict__ dwf, unsigned short* __restrict__ g){
  __shared__ unsigned short sE1[18*FEI];  // rows y0-1..y0+16, slot = gx+4
  __shared__ unsigned short sE2[18*FEI];
  __shared__ float k1[9], k2[9];
  int bid=blockIdx.x; int b=bid>>10, c=(bid>>4)&63, sy=bid&15;
  int y0=sy*16;
  int tid=threadIdx.x;
  if(tid<9){ k1[tid]=dwf[c*9+tid]; k2[tid]=dwf[(64+c)*9+tid]; }
  const unsigned short* p1=E+(((size_t)(b*128+c))<<16);
  const unsigned short* p2=E+(((size_t)(b*128+64+c))<<16);
  for(int task=tid;task<1188;task+=256){
    int r=task/66, j=task-r*66;
    int gy=y0-1+r, gx0=4*j-4;
    uint2 u1=make_uint2(0,0), u2=make_uint2(0,0);
    if((unsigned)gy<256u && j>=1 && j<=64){
      u1=*(const uint2*)(p1+(gy<<8)+gx0);
      u2=*(const uint2*)(p2+(gy<<8)+gx0);
    }
    *(uint2*)&sE1[r*FEI+4*j]=u1;
    *(uint2*)&sE2[r*FEI+4*j]=u2;
  }
  __syncthreads();
  int q=tid&63, rr=tid>>6;
  unsigned short* op=g+(((size_t)(b*64+c))<<16);
  #pragma unroll
  for(int l4=0;l4<4;l4++){
    int ly=rr*4+l4;
    float a1[4]={0.f,0.f,0.f,0.f}, a2[4]={0.f,0.f,0.f,0.f};
    #pragma unroll
    for(int dy=0;dy<3;dy++){
      int r=ly+dy;
      // needed cols: 4q-1 .. 4q+4 -> slots 4q+3 .. 4q+8 -> G[0..5]
      unsigned w0=*(const unsigned*)&sE1[r*FEI+4*q+2];
      uint2   w1=*(const uint2*)  &sE1[r*FEI+4*q+4];
      unsigned w2=*(const unsigned*)&sE1[r*FEI+4*q+8];
      float GA[6]={us2f(w0>>16),us2f(w1.x&0xffff),us2f(w1.x>>16),us2f(w1.y&0xffff),us2f(w1.y>>16),us2f(w2&0xffff)};
      unsigned v0=*(const unsigned*)&sE2[r*FEI+4*q+2];
      uint2   v1=*(const uint2*)  &sE2[r*FEI+4*q+4];
      unsigned v2=*(const unsigned*)&sE2[r*FEI+4*q+8];
      float GB[6]={us2f(v0>>16),us2f(v1.x&0xffff),us2f(v1.x>>16),us2f(v1.y&0xffff),us2f(v1.y>>16),us2f(v2&0xffff)};
      #pragma unroll
      for(int dx=0;dx<3;dx++){
        float ka=k1[dy*3+dx], kb=k2[dy*3+dx];
        #pragma unroll
        for(int e=0;e<4;e++){
          a1[e]+=GA[e+dx]*ka;
          a2[e]+=GB[e+dx]*kb;
        }
      }
    }
    float o0=geluf(a1[0])*a2[0];
    float o1=geluf(a1[1])*a2[1];
    float o2=geluf(a1[2])*a2[2];
    float o3=geluf(a1[3])*a2[3];
    uint2 u; u.x=pack2(o0,o1); u.y=pack2(o2,o3);
    *(uint2*)(op+((y0+ly)<<8)+4*q)=u;
  }
}

extern "C" void kernel_launch(void* const* d_in, const int* in_sizes, int n_in,
                              void* d_out, int out_size, void* d_ws, size_t ws_size,
                              hipStream_t stream){
  (void)in_sizes; (void)n_in; (void)out_size; (void)ws_size;
  const void* x  = d_in[0];
  const void* Wm1= d_in[23];
  const void* Wm2= d_in[25];

  char* ws=(char*)d_ws;
  unsigned short* E=(unsigned short*)(ws);
  unsigned short* img=(unsigned short*)(ws+67108864);
  unsigned short* x1b=(unsigned short*)(ws+67108864);
  unsigned short* xwb=(unsigned short*)(ws+134217728);
  unsigned short* outb=(unsigned short*)(ws+134217728);
  unsigned short* gbuf=(unsigned short*)(ws+134217728);
  unsigned short* vw =(unsigned short*)(ws+230686720);
  char* sm = ws+201326592;
  float* x_    =(float*)(sm);              // 16 MB
  unsigned short* sa_w=(unsigned short*)(sm+16777216); // 0.5 MB
  float* xm    =(float*)(sm+17825792);     // 1 MB
  float* var   =(float*)(sm+18874368);     // 16 KB
  float* mbin  =(float*)(sm+18890752);     // 16 KB
  float* h0    =(float*)(sm+18907136);     // 8 KB
  float* h1    =(float*)(sm+18915328);     // 8 KB
  float* m0    =(float*)(sm+18923520);     // 16 KB
  float* m1    =(float*)(sm+18939904);     // 16 KB
  float* capart=(float*)(sm+18956288);     // 64 KB
  float* ca    =(float*)(sm+19021824);     // 1 KB
  int*   flag  =(int*)  (sm+19022848);     // 4 B
  float* wbuf  =(float*)(sm+19023872);     // ~161 KB
  short* Wqb   =(short*)(sm+19200000);     // 8 KB
  short* Wkb   =(short*)(sm+19208192);     // 8 KB
  float* m0T   =(float*)(sm+19216384);     // 16 KB
  float* m1T   =(float*)(sm+19232768);     // 16 KB
  short* Wob   =(short*)(sm+19249152);     // 8 KB
  short* Wfib  =(short*)(sm+19257344);     // 16 KB
  short* Wfob  =(short*)(sm+19273728);     // 8 KB
  short* Wvb   =(short*)(sm+19281920);     // 8 KB
  float* WaC   =(float*)(sm+19290112);     // 4 KB
  float* WbC   =(float*)(sm+19294208);     // 4 KB
  float* baC   =(float*)(sm+19298304);     // 64 B
  float* bbC   =(float*)(sm+19298560);     // 64 B

  static const int din_idx[31]={5,6,7,8,9,10,11,12,13,14,15,16,17,18,19,20,21,22,24,26,27,28,29,30,31,32,33,1,2,3,4};
  static const int szs[31]  ={4096,64,4096,64,4096,64,576,64,576,64,4096,64,1024,16,1024,16,16,16,2048,4096,1024,64,144,1,8192,1152,4096,64,64,64,64};
  CvtArgs ca_args;
  int off=0;
  int offs[31];
  for(int t=0;t<31;t++){
    ca_args.src[t]=d_in[din_idx[t]];
    ca_args.sz[t]=szs[t];
    ca_args.off[t]=off;
    offs[t]=off;
    off+=szs[t];
  }
  const float* Wv  =wbuf+offs[0];  const float* bv  =wbuf+offs[1];
  const float* Wq  =wbuf+offs[2];  const float* bq  =wbuf+offs[3];
  const float* Wk  =wbuf+offs[4];  const float* bk  =wbuf+offs[5];
  const float* dw1 =wbuf+offs[6];  const float* dwb1=wbuf+offs[7];
  const float* dw2 =wbuf+offs[8];  const float* dwb2=wbuf+offs[9];
  const float* Wo  =wbuf+offs[10]; const float* bo  =wbuf+offs[11];
  const float* W_in=wbuf+offs[12]; const float* b_in=wbuf+offs[13];
  const float* Wc  =wbuf+offs[14]; const float* bc  =wbuf+offs[15];
  const float* lnw =wbuf+offs[16]; const float* lnb =wbuf+offs[17];
  const float* bm1 =wbuf+offs[18]; const float* bm2 =wbuf+offs[19];
  const float* Wca =wbuf+offs[20]; const float* bca =wbuf+offs[21];
  const float* Wsa =wbuf+offs[22]; const float* bsa =wbuf+offs[23];
  const float* Wfi =wbuf+offs[24]; const float* dwf =wbuf+offs[25];
  const float* Wfo =wbuf+offs[26];
  const float* wn1 =wbuf+offs[27]; const float* bn1 =wbuf+offs[28];
  const float* wn2 =wbuf+offs[29]; const float* bn2 =wbuf+offs[30];

  hipLaunchKernelGGL(k_detect,   dim3(1),      dim3(256), 0, stream, x, flag);
  hipLaunchKernelGGL(k_cvt,      dim3(31),     dim3(256), 0, stream, ca_args, flag, wbuf);
  hipLaunchKernelGGL(k_w2b6,     dim3(32),     dim3(256), 0, stream, Wq, Wk, Wo, Wfi, Wfo, Wv, Wqb, Wkb, Wob, Wfib, Wfob, Wvb);
  hipLaunchKernelGGL(k_wcomp,    dim3(1),      dim3(256), 0, stream, W_in, b_in, Wc, bc, Wv, bv, WaC, baC, WbC, bbC);
  hipLaunchKernelGGL(k_convv_mf, dim3(4096),   dim3(256), 0, stream, x, flag, Wvb, bv, vw);
  hipLaunchKernelGGL(k_route,    dim3(512),    dim3(256), 0, stream, x, flag, WaC, baC, WbC, bbC, lnw, lnb, x_, xm, capart);
  hipLaunchKernelGGL(k_sa,       dim3(1024),   dim3(256), 0, stream, x_, Wsa, bsa, sa_w);
  hipLaunchKernelGGL(k_var,      dim3(4096),   dim3(64),  0, stream, xm, var);
  hipLaunchKernelGGL(k_rank,     dim3(16),     dim3(256), 0, stream, var, mbin);
  hipLaunchKernelGGL(k_hvec,     dim3(2048),   dim3(64),  0, stream, Wm1, bm1, h0, h1, flag);
  hipLaunchKernelGGL(k_mask,     dim3(4096),   dim3(64),  0, stream, Wm2, bm2, h0, h1, m0, m1, m0T, m1T, flag);
  hipLaunchKernelGGL(k_ca,       dim3(4),      dim3(64),  0, stream, capart, Wca, bca, ca);
  hipLaunchKernelGGL(k_pack_x,   dim3(2048),   dim3(256), 0, stream, x, mbin, m0T, m1T, flag, xwb);
  hipLaunchKernelGGL(k_attn_mfma,dim3(4096),   dim3(256), 0, stream, xwb, vw, sa_w, mbin, m0T, m1T, Wqb, bq, Wkb, bk, img);
  hipLaunchKernelGGL(k_dwfuse,   dim3(4096),   dim3(256), 0, stream, img, dw1, dwb1, dw2, dwb2, ca, outb);
  hipLaunchKernelGGL(k_gemm_ln,  dim3(4096),   dim3(256), 0, stream, outb, Wob, bo, 1, x, wn1, bn1, (void*)x1b, flag, 0, 2);
  hipLaunchKernelGGL(k_gemm_mf,  dim3(4096),   dim3(256), 0, stream, (const void*)x1b, 0, Wfib, wbuf, 0, (void*)E, 128, 1);
  hipLaunchKernelGGL(k_ffn_dw_t, dim3(4096),   dim3(256), 0, stream, E, dwf, gbuf);
  hipLaunchKernelGGL(k_gemm_ln,  dim3(4096),   dim3(256), 0, stream, gbuf, Wfob, wbuf, 0, (const void*)x1b, wn2, bn2, d_out, flag, 2, 0);
}